// Round 5
// baseline (17584.491 us; speedup 1.0000x reference)
//
#include <hip/hip_runtime.h>

constexpr int H_  = 64;   // hidden
constexpr int DIN = 32;   // atom feature dim
constexpr int DE  = 16;   // edge feature dim
constexpr int LDW  = 68;  // padded LDS row stride (floats)
constexpr int LDW4 = 17;  // in float4
#define SLOPE 0.2f

__device__ __forceinline__ float sigm_(float x){ return 1.0f/(1.0f+__expf(-x)); }
__device__ __forceinline__ float tanh_(float x){ float e=__expf(2.0f*x); return 1.0f - 2.0f/(e+1.0f); }
__device__ __forceinline__ float fma4_(float4 a, float4 b, float acc){
  return fmaf(a.w,b.w, fmaf(a.z,b.z, fmaf(a.y,b.y, fmaf(a.x,b.x, acc))));
}

// dst[b][c][r] = src[b][r][c]
__global__ void k_transpose(const float* __restrict__ src, float* __restrict__ dst, int B,int R,int C){
  int id = blockIdx.x*blockDim.x+threadIdx.x;
  if (id >= B*R*C) return;
  int rc=R*C, b=id/rc, rem=id-b*rc, r=rem/C, c=rem-r*C;
  dst[b*rc + c*R + r] = src[id];
}

// ve[l][k] = sum_j conv_We[l][k][j] * att_e[l][j]
__global__ void k_ve(const float* __restrict__ We, const float* __restrict__ ae, float* __restrict__ ve){
  int id = blockIdx.x*blockDim.x+threadIdx.x;
  if (id >= 3*H_) return;
  int l=id/H_, k=id-l*H_;
  const float* w = We + (size_t)(l*H_+k)*H_;
  const float* a = ae + l*H_;
  float s=0.f;
  #pragma unroll
  for(int j=0;j<H_;j++) s += w[j]*a[j];
  ve[id]=s;
}

__global__ void k_init(int* __restrict__ deg, float* __restrict__ ssum, int N){
  int n = blockIdx.x*blockDim.x+threadIdx.x;
  if (n>=N) return;
  deg[n]=1;                 // self-loop
  ssum[n]=0.f; ssum[N+n]=0.f; ssum[2*N+n]=0.f;
}

// xi = relu(x @ w_node + b_node), thread per node, wT transposed [64][32]
__global__ void k_node_mlp(const float* __restrict__ x, const float* __restrict__ wT,
                           const float* __restrict__ b, float* __restrict__ xi, int N){
  int n = blockIdx.x*blockDim.x+threadIdx.x;
  if (n>=N) return;
  float xv[DIN];
  const float4* xr = (const float4*)(x + (size_t)n*DIN);
  #pragma unroll
  for(int q=0;q<DIN/4;q++){ float4 v=xr[q]; xv[4*q]=v.x; xv[4*q+1]=v.y; xv[4*q+2]=v.z; xv[4*q+3]=v.w; }
  for(int j0=0;j0<H_;j0+=4){
    float o[4];
    #pragma unroll
    for(int jj=0;jj<4;jj++){
      int j=j0+jj;
      const float* wr = wT + j*DIN;   // uniform -> s_load
      float acc = b[j];
      #pragma unroll
      for(int k=0;k<DIN;k++) acc += xv[k]*wr[k];
      o[jj] = fmaxf(acc,0.f);
    }
    *(float4*)(xi + (size_t)n*H_ + j0) = make_float4(o[0],o[1],o[2],o[3]);
  }
}

// per-edge: ea = relu(attr@w_edge+b); escore[l][e] = ea . ve[l];
__global__ void k_edge_scores(const float* __restrict__ attr, const float* __restrict__ weT,
                              const float* __restrict__ be, const float* __restrict__ ve,
                              const int* __restrict__ dst, float* __restrict__ escore,
                              float* __restrict__ ssum, int* __restrict__ deg,
                              int E, int EN, int N){
  int e = blockIdx.x*blockDim.x+threadIdx.x;
  if (e>=E) return;
  float av[DE];
  const float4* ar = (const float4*)(attr + (size_t)e*DE);
  #pragma unroll
  for(int q=0;q<DE/4;q++){ float4 v=ar[q]; av[4*q]=v.x; av[4*q+1]=v.y; av[4*q+2]=v.z; av[4*q+3]=v.w; }
  float s0=0.f,s1=0.f,s2=0.f;
  for(int j=0;j<H_;j++){
    const float* wr = weT + j*DE;     // uniform
    float acc = be[j];
    #pragma unroll
    for(int k=0;k<DE;k++) acc += av[k]*wr[k];
    acc = fmaxf(acc,0.f);
    s0 += acc*ve[j]; s1 += acc*ve[H_+j]; s2 += acc*ve[2*H_+j];
  }
  escore[e] = s0; escore[EN+e] = s1; escore[2*EN+e] = s2;
  int d = dst[e];
  atomicAdd(&ssum[d],     s0);
  atomicAdd(&ssum[N+d],   s1);
  atomicAdd(&ssum[2*N+d], s2);
  atomicAdd(&deg[d], 1);
}

__global__ void k_selfloop(const float* __restrict__ ssum, const int* __restrict__ deg,
                           float* __restrict__ escore, int E, int EN, int N){
  int n = blockIdx.x*blockDim.x+threadIdx.x;
  if (n>=N) return;
  float c = (float)(deg[n]-1);
  float inv = (c>0.f) ? 1.0f/c : 0.0f;
  escore[E+n]        = ssum[n]*inv;
  escore[EN+E+n]     = ssum[N+n]*inv;
  escore[2*EN+E+n]   = ssum[2*N+n]*inv;
}

// ---- hierarchical scan of deg -> off (exclusive), cur copy ----
__global__ void k_bsum(const int* __restrict__ deg, int* __restrict__ bsum, int N){
  int i = blockIdx.x*256 + threadIdx.x;
  int v = (i<N) ? deg[i] : 0;
  #pragma unroll
  for(int d=32; d; d>>=1) v += __shfl_xor(v, d);
  __shared__ int sh[4];
  if ((threadIdx.x&63)==0) sh[threadIdx.x>>6] = v;
  __syncthreads();
  if (threadIdx.x==0) bsum[blockIdx.x] = sh[0]+sh[1]+sh[2]+sh[3];
}

__global__ void k_bscan(const int* __restrict__ bsum, int* __restrict__ boff, int NB,
                        int* __restrict__ offN, int EN){
  __shared__ int sh[1024];
  int tid = threadIdx.x;
  int v = (tid<NB) ? bsum[tid] : 0;
  sh[tid] = v;
  __syncthreads();
  for(int d=1; d<1024; d<<=1){
    int t = 0;
    if (tid>=d) t = sh[tid-d];
    __syncthreads();
    if (tid>=d) sh[tid] += t;
    __syncthreads();
  }
  if (tid<NB) boff[tid] = sh[tid] - v;  // exclusive
  if (tid==0) offN[0] = EN;
}

__global__ void k_scan_fin(const int* __restrict__ deg, const int* __restrict__ boff,
                           int* __restrict__ off, int* __restrict__ cur, int N){
  __shared__ int sh[256];
  int i = blockIdx.x*256 + threadIdx.x;
  int v = (i<N) ? deg[i] : 0;
  sh[threadIdx.x] = v;
  __syncthreads();
  for(int d=1; d<256; d<<=1){
    int t = 0;
    if (threadIdx.x>=d) t = sh[threadIdx.x-d];
    __syncthreads();
    if (threadIdx.x>=d) sh[threadIdx.x] += t;
    __syncthreads();
  }
  if (i<N){
    int e = boff[blockIdx.x] + sh[threadIdx.x] - v;
    off[i] = e; cur[i] = e;
  }
}

__global__ void k_fill(const int* __restrict__ dst, int* __restrict__ cur, int* __restrict__ eid, int E, int N){
  int e = blockIdx.x*blockDim.x+threadIdx.x;
  if (e>=E+N) return;
  int d = (e<E) ? dst[e] : (e-E);
  int p = atomicAdd(&cur[d],1);
  eid[p] = e;
}

// stage 64-node x 64-feature tile into sA (padded rows)
__device__ __forceinline__ void stage_tile(const float* __restrict__ src, float* sA,
                                           int n0, int N, int tid){
  const float4* s4 = (const float4*)src;
  float4* dA = (float4*)sA;
  #pragma unroll
  for(int r=0;r<4;r++){
    int q = tid + 256*r;              // 0..1023
    int row = q>>4, col = q&15;
    int gn = n0+row; if (gn>N-1) gn=N-1;
    dA[row*LDW4+col] = s4[(size_t)gn*16+col];
  }
}

// stage 96 weight rows (row-major [96][64]) into sW
__device__ __forceinline__ void stage_w(const float* __restrict__ Wsrc, float* sW, int tid){
  const float4* ws = (const float4*)Wsrc;
  float4* dW = (float4*)sW;
  #pragma unroll
  for (int r=0;r<6;r++){
    int q = tid + 256*r;                    // 0..1535
    dW[(q>>4)*LDW4 + (q&15)] = ws[q];
  }
}

// window rows 0..95: jj 0..3 -> r_[i][jj]; jj 4,5 -> z_[i][jj-4]. All indices static.
__device__ __forceinline__ void mm_A(const float* sW, const float* sA, int jt, int nt,
                                     float (&r_)[4][4], float (&z_)[4][4]){
  const float4* sW4 = (const float4*)sW;
  const float4* sA4 = (const float4*)sA;
  #pragma unroll
  for (int kq=0;kq<16;kq++){
    float4 af[4];
    #pragma unroll
    for (int i=0;i<4;i++) af[i] = sA4[(nt*4+i)*LDW4 + kq];
    #pragma unroll
    for (int jj=0;jj<4;jj++){
      float4 b = sW4[(jt+16*jj)*LDW4 + kq];
      #pragma unroll
      for (int i=0;i<4;i++) r_[i][jj] = fma4_(af[i], b, r_[i][jj]);
    }
    #pragma unroll
    for (int jj=0;jj<2;jj++){
      float4 b = sW4[(jt+16*(4+jj))*LDW4 + kq];
      #pragma unroll
      for (int i=0;i<4;i++) z_[i][jj] = fma4_(af[i], b, z_[i][jj]);
    }
  }
}

// window rows 96..191: jj 0,1 -> z_[i][2+jj]; jj 2..5 -> g4[i][jj-2]. All indices static.
__device__ __forceinline__ void mm_B(const float* sW, const float* sA, int jt, int nt,
                                     float (&z_)[4][4], float (&g4)[4][4]){
  const float4* sW4 = (const float4*)sW;
  const float4* sA4 = (const float4*)sA;
  #pragma unroll
  for (int kq=0;kq<16;kq++){
    float4 af[4];
    #pragma unroll
    for (int i=0;i<4;i++) af[i] = sA4[(nt*4+i)*LDW4 + kq];
    #pragma unroll
    for (int jj=0;jj<2;jj++){
      float4 b = sW4[(jt+16*jj)*LDW4 + kq];
      #pragma unroll
      for (int i=0;i<4;i++) z_[i][2+jj] = fma4_(af[i], b, z_[i][2+jj]);
    }
    #pragma unroll
    for (int jj=0;jj<4;jj++){
      float4 b = sW4[(jt+16*(2+jj))*LDW4 + kq];
      #pragma unroll
      for (int i=0;i<4;i++) g4[i][jj] = fma4_(af[i], b, g4[i][jj]);
    }
  }
}

// fused GRU: block = 64 nodes. 64 accumulators, all statically indexed -> no scratch.
__global__ void __launch_bounds__(256,3)
k_gru_t(const float* __restrict__ hg, const float* __restrict__ xin, float* __restrict__ xout,
        const float* __restrict__ WihT, const float* __restrict__ WhhT,
        const float* __restrict__ bih, const float* __restrict__ bhh, int N){
  __shared__ float sW[96*LDW];        // 26112 B
  __shared__ float sA[64*LDW];        // 17408 B (hg tile, then xin tile)
  int tid = threadIdx.x;
  int jt = tid & 15, nt = tid >> 4;
  int n0 = blockIdx.x * 64;

  float r_[4][4], z_[4][4], ni[4][4], nh[4][4];
  #pragma unroll
  for (int i=0;i<4;i++){
    #pragma unroll
    for (int j=0;j<4;j++){ r_[i][j]=0.f; z_[i][j]=0.f; ni[i][j]=0.f; nh[i][j]=0.f; }
  }

  stage_tile(hg, sA, n0, N, tid);
  __syncthreads();
  stage_w(WihT, sW, tid);
  __syncthreads();
  mm_A(sW, sA, jt, nt, r_, z_);        // Wih rows 0..95  (r + z-lo)
  __syncthreads();
  stage_w(WihT + 96*H_, sW, tid);
  __syncthreads();
  mm_B(sW, sA, jt, nt, z_, ni);        // Wih rows 96..191 (z-hi + n)
  __syncthreads();                     // done reading hg tile
  stage_tile(xin, sA, n0, N, tid);
  stage_w(WhhT, sW, tid);
  __syncthreads();
  mm_A(sW, sA, jt, nt, r_, z_);        // Whh rows 0..95
  __syncthreads();
  stage_w(WhhT + 96*H_, sW, tid);
  __syncthreads();
  mm_B(sW, sA, jt, nt, z_, nh);        // Whh rows 96..191

  // epilogue: gates + blend + relu (sA holds xin tile)
  #pragma unroll
  for (int jj2=0;jj2<4;jj2++){
    int f = jt + 16*jj2;
    float br = bih[f]     + bhh[f];
    float bz = bih[64+f]  + bhh[64+f];
    float bin= bih[128+f], bhn = bhh[128+f];
    #pragma unroll
    for (int i=0;i<4;i++){
      int node = n0 + nt*4 + i;
      if (node < N){
        float r  = sigm_(r_[i][jj2] + br);
        float z  = sigm_(z_[i][jj2] + bz);
        float nn = tanh_(ni[i][jj2] + bin + r*(nh[i][jj2] + bhn));
        float xv = sA[(nt*4+i)*LDW + f];
        xout[(size_t)node*H_ + f] = fmaxf((1.f-z)*nn + z*xv, 0.f);
      }
    }
  }
}

// h = xi @ conv_W[l] (LDS-tiled) + ssc/dsc reductions
__global__ void __launch_bounds__(256,3)
k_linh_t(const float* __restrict__ xi, const float* __restrict__ wT,
         const float* __restrict__ atts, const float* __restrict__ attd,
         float* __restrict__ h, float* __restrict__ ssc, float* __restrict__ dsc, int N){
  __shared__ float sW[64*LDW];          // 17408
  __shared__ float sA[64*LDW];          // 17408
  __shared__ float sred[64][17][2];
  int tid = threadIdx.x;
  int jt = tid & 15, nt = tid >> 4;
  int n0 = blockIdx.x * 64;

  { // stage
    const float4* srcA = (const float4*)xi;
    const float4* srcW = (const float4*)wT;
    float4* dA = (float4*)sA;
    float4* dW = (float4*)sW;
    #pragma unroll
    for (int r = 0; r < 4; r++){
      int q = tid + 256*r;              // 0..1023
      int row = q >> 4, col = q & 15;
      int gn = n0 + row; if (gn > N-1) gn = N-1;
      dA[row*LDW4 + col] = srcA[(size_t)gn*16 + col];
      dW[row*LDW4 + col] = srcW[q];
    }
  }
  __syncthreads();

  float acc[4][4];
  #pragma unroll
  for (int i=0;i<4;i++){
    #pragma unroll
    for (int j=0;j<4;j++) acc[i][j]=0.f;
  }
  const float4* sA4 = (const float4*)sA;
  const float4* sW4 = (const float4*)sW;
  #pragma unroll
  for (int kq=0;kq<16;kq++){
    float4 af[4];
    #pragma unroll
    for (int i=0;i<4;i++) af[i] = sA4[(nt*4+i)*LDW4 + kq];
    #pragma unroll
    for (int jj=0;jj<4;jj++){
      float4 b = sW4[(jt+16*jj)*LDW4 + kq];
      #pragma unroll
      for (int i=0;i<4;i++) acc[i][jj] = fma4_(af[i], b, acc[i][jj]);
    }
  }

  float ps[4]={0.f,0.f,0.f,0.f}, pd[4]={0.f,0.f,0.f,0.f};
  #pragma unroll
  for (int jj=0;jj<4;jj++){
    int f = jt + 16*jj;
    float as = atts[f], ad = attd[f];
    #pragma unroll
    for (int i=0;i<4;i++){
      int node = n0 + nt*4 + i;
      float v = acc[i][jj];
      if (node < N) h[(size_t)node*H_ + f] = v;
      ps[i] += v*as; pd[i] += v*ad;
    }
  }
  #pragma unroll
  for (int i=0;i<4;i++){ sred[nt*4+i][jt][0]=ps[i]; sred[nt*4+i][jt][1]=pd[i]; }
  __syncthreads();
  if (tid < 64){
    float s=0.f, d=0.f;
    #pragma unroll
    for (int w=0;w<16;w++){ s += sred[tid][w][0]; d += sred[tid][w][1]; }
    int node = n0 + tid;
    if (node < N){ ssc[node]=s; dsc[node]=d; }
  }
}

// block per node (4 waves): segment softmax + weighted aggregation
__global__ void __launch_bounds__(256)
k_gat_b(const float* __restrict__ h, const float* __restrict__ ssc,
        const float* __restrict__ dsc, const float* __restrict__ escore,
        const int* __restrict__ off, const int* __restrict__ eid,
        const int* __restrict__ srcarr, const float* __restrict__ bias,
        float* __restrict__ hgat, int E, int N){
  int node = blockIdx.x;
  int tid = threadIdx.x, lane = tid & 63, w = tid >> 6;
  int e0 = off[node], e1 = off[node+1];
  float dval = dsc[node];
  __shared__ float smax[4], sden[4], sacc[4][64];
  float mx = -1e30f;
  for (int p = e0 + tid; p < e1; p += 256){
    int e = eid[p];
    int s = (e < E) ? srcarr[e] : (e - E);
    float a = ssc[s] + dval + escore[e];
    a = (a > 0.f) ? a : SLOPE*a;
    mx = fmaxf(mx, a);
  }
  #pragma unroll
  for (int d=32; d; d>>=1) mx = fmaxf(mx, __shfl_xor(mx, d));
  if (lane==0) smax[w] = mx;
  __syncthreads();
  mx = fmaxf(fmaxf(smax[0],smax[1]), fmaxf(smax[2],smax[3]));
  float acc = 0.f, den = 0.f;
  for (int p = e0 + w; p < e1; p += 4){
    int e = eid[p];
    int s = (e < E) ? srcarr[e] : (e - E);
    float a = ssc[s] + dval + escore[e];
    a = (a > 0.f) ? a : SLOPE*a;
    float ex = __expf(a - mx);
    den += ex;
    acc += ex * h[(size_t)s*H_ + lane];
  }
  sacc[w][lane] = acc;
  if (lane==0) sden[w] = den;
  __syncthreads();
  if (w==0){
    float a4 = sacc[0][lane]+sacc[1][lane]+sacc[2][lane]+sacc[3][lane];
    float d4 = sden[0]+sden[1]+sden[2]+sden[3];
    hgat[(size_t)node*H_ + lane] = fmaxf(a4/d4 + bias[lane], 0.f);
  }
}

__global__ void k_pool_init(float* __restrict__ out, const float* __restrict__ b_out, int G){
  int g = blockIdx.x*blockDim.x+threadIdx.x;
  if (g<G) out[g] = b_out[0];
}

__global__ void k_pool(const float* __restrict__ xi, const float* __restrict__ wout,
                       const int* __restrict__ batch, float* __restrict__ out, int N){
  int n = blockIdx.x*blockDim.x+threadIdx.x;
  if (n>=N) return;
  float acc=0.f;
  const float4* xr=(const float4*)(xi + (size_t)n*H_);
  #pragma unroll
  for(int q=0;q<H_/4;q++){
    float4 v=xr[q];
    acc += v.x*wout[4*q] + v.y*wout[4*q+1] + v.z*wout[4*q+2] + v.w*wout[4*q+3];
  }
  atomicAdd(&out[batch[n]], acc);
}

extern "C" void kernel_launch(void* const* d_in, const int* in_sizes, int n_in,
                              void* d_out, int out_size, void* d_ws, size_t ws_size,
                              hipStream_t stream){
  const float* x       = (const float*)d_in[0];
  const float* eattr   = (const float*)d_in[1];
  const float* w_node  = (const float*)d_in[2];
  const float* b_node  = (const float*)d_in[3];
  const float* w_edge  = (const float*)d_in[4];
  const float* b_edge  = (const float*)d_in[5];
  const float* conv_W  = (const float*)d_in[6];
  const float* conv_We = (const float*)d_in[7];
  const float* att_s   = (const float*)d_in[8];
  const float* att_d   = (const float*)d_in[9];
  const float* att_e   = (const float*)d_in[10];
  const float* conv_b  = (const float*)d_in[11];
  const float* gWih    = (const float*)d_in[12];
  const float* gWhh    = (const float*)d_in[13];
  const float* gbih    = (const float*)d_in[14];
  const float* gbhh    = (const float*)d_in[15];
  const float* w_out   = (const float*)d_in[16];
  const float* b_out   = (const float*)d_in[17];
  const int*   eidx    = (const int*)d_in[18];
  const int*   batch   = (const int*)d_in[19];
  float* out = (float*)d_out;

  int N = in_sizes[0]/DIN;
  int E = in_sizes[1]/DE;
  int G = out_size;
  int EN = E + N;
  const int* src = eidx;
  const int* dst = eidx + E;

  char* p = (char*)d_ws;
  auto carve = [&](size_t bytes)->void*{ void* r=(void*)p; p += (bytes+255)&~(size_t)255; return r; };
  float* xi0   = (float*)carve((size_t)N*H_*4);
  float* xi1   = (float*)carve((size_t)N*H_*4);
  float* hbuf  = (float*)carve((size_t)N*H_*4);
  float* hgat  = (float*)carve((size_t)N*H_*4);
  float* ssc   = (float*)carve((size_t)N*4);
  float* dsc   = (float*)carve((size_t)N*4);
  float* escore= (float*)carve((size_t)3*EN*4);
  float* ssum  = (float*)carve((size_t)3*N*4);
  int*   deg   = (int*)carve((size_t)N*4);
  int*   off   = (int*)carve((size_t)(N+1)*4);
  int*   cur   = (int*)carve((size_t)(N+1)*4);
  int*   eid   = (int*)carve((size_t)EN*4);
  int*   bsum  = (int*)carve((size_t)1024*4);
  int*   boff  = (int*)carve((size_t)1024*4);
  float* wnT   = (float*)carve((size_t)DIN*H_*4);
  float* weT   = (float*)carve((size_t)DE*H_*4);
  float* cWT   = (float*)carve((size_t)3*H_*H_*4);
  float* WihT  = (float*)carve((size_t)3*H_*3*H_*4);
  float* WhhT  = (float*)carve((size_t)3*H_*3*H_*4);
  float* ve    = (float*)carve((size_t)3*H_*4);

  auto cdiv=[](int a,int b){return (a+b-1)/b;};
  int NB = cdiv(N,256);

  k_transpose<<<cdiv(DIN*H_,256),256,0,stream>>>(w_node, wnT, 1, DIN, H_);
  k_transpose<<<cdiv(DE*H_,256),256,0,stream>>>(w_edge, weT, 1, DE, H_);
  k_transpose<<<cdiv(3*H_*H_,256),256,0,stream>>>(conv_W, cWT, 3, H_, H_);
  k_transpose<<<cdiv(3*H_*3*H_,256),256,0,stream>>>(gWih, WihT, 3, H_, 3*H_);
  k_transpose<<<cdiv(3*H_*3*H_,256),256,0,stream>>>(gWhh, WhhT, 3, H_, 3*H_);
  k_ve<<<1,3*H_,0,stream>>>(conv_We, att_e, ve);

  k_init<<<cdiv(N,256),256,0,stream>>>(deg, ssum, N);
  k_node_mlp<<<cdiv(N,256),256,0,stream>>>(x, wnT, b_node, xi0, N);
  k_edge_scores<<<cdiv(E,256),256,0,stream>>>(eattr, weT, b_edge, ve, dst, escore, ssum, deg, E, EN, N);
  k_selfloop<<<cdiv(N,256),256,0,stream>>>(ssum, deg, escore, E, EN, N);
  k_bsum<<<NB,256,0,stream>>>(deg, bsum, N);
  k_bscan<<<1,1024,0,stream>>>(bsum, boff, NB, off+N, EN);
  k_scan_fin<<<NB,256,0,stream>>>(deg, boff, off, cur, N);
  k_fill<<<cdiv(EN,256),256,0,stream>>>(dst, cur, eid, E, N);

  int NB64 = cdiv(N,64);
  for (int l=0; l<3; l++){
    const float* xin = (l&1) ? xi1 : xi0;
    float*       xo  = (l&1) ? xi0 : xi1;
    k_linh_t<<<NB64,256,0,stream>>>(xin, cWT + (size_t)l*H_*H_, att_s + l*H_, att_d + l*H_,
                                    hbuf, ssc, dsc, N);
    k_gat_b<<<N,256,0,stream>>>(hbuf, ssc, dsc, escore + (size_t)l*EN, off, eid, src,
                                conv_b + l*H_, hgat, E, N);
    k_gru_t<<<NB64,256,0,stream>>>(hgat, xin, xo, WihT + (size_t)l*192*H_, WhhT + (size_t)l*192*H_,
                                   gbih + l*3*H_, gbhh + l*3*H_, N);
  }

  k_pool_init<<<cdiv(G,256),256,0,stream>>>(out, b_out, G);
  k_pool<<<cdiv(N,256),256,0,stream>>>(xi1, w_out, batch, out, N);
}

// Round 6
// 17483.478 us; speedup vs baseline: 1.0058x; 1.0058x over previous
//
#include <hip/hip_runtime.h>

constexpr int H_  = 64;   // hidden
constexpr int DIN = 32;   // atom feature dim
constexpr int DE  = 16;   // edge feature dim
constexpr int LDW  = 68;  // padded LDS row stride (floats)
constexpr int LDW4 = 17;  // in float4
#define SLOPE 0.2f

__device__ __forceinline__ float sigm_(float x){ return 1.0f/(1.0f+__expf(-x)); }
__device__ __forceinline__ float tanh_(float x){ float e=__expf(2.0f*x); return 1.0f - 2.0f/(e+1.0f); }
__device__ __forceinline__ float fma4_(float4 a, float4 b, float acc){
  return fmaf(a.w,b.w, fmaf(a.z,b.z, fmaf(a.y,b.y, fmaf(a.x,b.x, acc))));
}

// dst[b][c][r] = src[b][r][c]
__global__ void k_transpose(const float* __restrict__ src, float* __restrict__ dst, int B,int R,int C){
  int id = blockIdx.x*blockDim.x+threadIdx.x;
  if (id >= B*R*C) return;
  int rc=R*C, b=id/rc, rem=id-b*rc, r=rem/C, c=rem-r*C;
  dst[b*rc + c*R + r] = src[id];
}

// ve[l][k] = sum_j conv_We[l][k][j] * att_e[l][j]
__global__ void k_ve(const float* __restrict__ We, const float* __restrict__ ae, float* __restrict__ ve){
  int id = blockIdx.x*blockDim.x+threadIdx.x;
  if (id >= 3*H_) return;
  int l=id/H_, k=id-l*H_;
  const float* w = We + (size_t)(l*H_+k)*H_;
  const float* a = ae + l*H_;
  float s=0.f;
  #pragma unroll
  for(int j=0;j<H_;j++) s += w[j]*a[j];
  ve[id]=s;
}

__global__ void k_init(int* __restrict__ deg, float* __restrict__ ssum, int N){
  int n = blockIdx.x*blockDim.x+threadIdx.x;
  if (n>=N) return;
  deg[n]=1;                 // self-loop
  ssum[n]=0.f; ssum[N+n]=0.f; ssum[2*N+n]=0.f;
}

// xi = relu(x @ w_node + b_node), thread per node, wT transposed [64][32]
__global__ void k_node_mlp(const float* __restrict__ x, const float* __restrict__ wT,
                           const float* __restrict__ b, float* __restrict__ xi, int N){
  int n = blockIdx.x*blockDim.x+threadIdx.x;
  if (n>=N) return;
  float xv[DIN];
  const float4* xr = (const float4*)(x + (size_t)n*DIN);
  #pragma unroll
  for(int q=0;q<DIN/4;q++){ float4 v=xr[q]; xv[4*q]=v.x; xv[4*q+1]=v.y; xv[4*q+2]=v.z; xv[4*q+3]=v.w; }
  for(int j0=0;j0<H_;j0+=4){
    float o[4];
    #pragma unroll
    for(int jj=0;jj<4;jj++){
      int j=j0+jj;
      const float* wr = wT + j*DIN;   // uniform -> s_load
      float acc = b[j];
      #pragma unroll
      for(int k=0;k<DIN;k++) acc += xv[k]*wr[k];
      o[jj] = fmaxf(acc,0.f);
    }
    *(float4*)(xi + (size_t)n*H_ + j0) = make_float4(o[0],o[1],o[2],o[3]);
  }
}

// per-edge: ea = relu(attr@w_edge+b); escore[l][e] = ea . ve[l];
__global__ void k_edge_scores(const float* __restrict__ attr, const float* __restrict__ weT,
                              const float* __restrict__ be, const float* __restrict__ ve,
                              const int* __restrict__ dst, float* __restrict__ escore,
                              float* __restrict__ ssum, int* __restrict__ deg,
                              int E, int EN, int N){
  int e = blockIdx.x*blockDim.x+threadIdx.x;
  if (e>=E) return;
  float av[DE];
  const float4* ar = (const float4*)(attr + (size_t)e*DE);
  #pragma unroll
  for(int q=0;q<DE/4;q++){ float4 v=ar[q]; av[4*q]=v.x; av[4*q+1]=v.y; av[4*q+2]=v.z; av[4*q+3]=v.w; }
  float s0=0.f,s1=0.f,s2=0.f;
  for(int j=0;j<H_;j++){
    const float* wr = weT + j*DE;     // uniform
    float acc = be[j];
    #pragma unroll
    for(int k=0;k<DE;k++) acc += av[k]*wr[k];
    acc = fmaxf(acc,0.f);
    s0 += acc*ve[j]; s1 += acc*ve[H_+j]; s2 += acc*ve[2*H_+j];
  }
  escore[e] = s0; escore[EN+e] = s1; escore[2*EN+e] = s2;
  int d = dst[e];
  atomicAdd(&ssum[d],     s0);
  atomicAdd(&ssum[N+d],   s1);
  atomicAdd(&ssum[2*N+d], s2);
  atomicAdd(&deg[d], 1);
}

__global__ void k_selfloop(const float* __restrict__ ssum, const int* __restrict__ deg,
                           float* __restrict__ escore, int E, int EN, int N){
  int n = blockIdx.x*blockDim.x+threadIdx.x;
  if (n>=N) return;
  float c = (float)(deg[n]-1);
  float inv = (c>0.f) ? 1.0f/c : 0.0f;
  escore[E+n]        = ssum[n]*inv;
  escore[EN+E+n]     = ssum[N+n]*inv;
  escore[2*EN+E+n]   = ssum[2*N+n]*inv;
}

// ---- hierarchical scan of deg -> off (exclusive), cur copy ----
__global__ void k_bsum(const int* __restrict__ deg, int* __restrict__ bsum, int N){
  int i = blockIdx.x*256 + threadIdx.x;
  int v = (i<N) ? deg[i] : 0;
  #pragma unroll
  for(int d=32; d; d>>=1) v += __shfl_xor(v, d);
  __shared__ int sh[4];
  if ((threadIdx.x&63)==0) sh[threadIdx.x>>6] = v;
  __syncthreads();
  if (threadIdx.x==0) bsum[blockIdx.x] = sh[0]+sh[1]+sh[2]+sh[3];
}

__global__ void k_bscan(const int* __restrict__ bsum, int* __restrict__ boff, int NB,
                        int* __restrict__ offN, int EN){
  __shared__ int sh[1024];
  int tid = threadIdx.x;
  int v = (tid<NB) ? bsum[tid] : 0;
  sh[tid] = v;
  __syncthreads();
  for(int d=1; d<1024; d<<=1){
    int t = 0;
    if (tid>=d) t = sh[tid-d];
    __syncthreads();
    if (tid>=d) sh[tid] += t;
    __syncthreads();
  }
  if (tid<NB) boff[tid] = sh[tid] - v;  // exclusive
  if (tid==0) offN[0] = EN;
}

__global__ void k_scan_fin(const int* __restrict__ deg, const int* __restrict__ boff,
                           int* __restrict__ off, int* __restrict__ cur, int N){
  __shared__ int sh[256];
  int i = blockIdx.x*256 + threadIdx.x;
  int v = (i<N) ? deg[i] : 0;
  sh[threadIdx.x] = v;
  __syncthreads();
  for(int d=1; d<256; d<<=1){
    int t = 0;
    if (threadIdx.x>=d) t = sh[threadIdx.x-d];
    __syncthreads();
    if (threadIdx.x>=d) sh[threadIdx.x] += t;
    __syncthreads();
  }
  if (i<N){
    int e = boff[blockIdx.x] + sh[threadIdx.x] - v;
    off[i] = e; cur[i] = e;
  }
}

__global__ void k_fill(const int* __restrict__ dst, int* __restrict__ cur, int* __restrict__ eid, int E, int N){
  int e = blockIdx.x*blockDim.x+threadIdx.x;
  if (e>=E+N) return;
  int d = (e<E) ? dst[e] : (e-E);
  int p = atomicAdd(&cur[d],1);
  eid[p] = e;
}

// stage 64-node x 64-feature tile into sA (padded rows)
__device__ __forceinline__ void stage_tile(const float* __restrict__ src, float* sA,
                                           int n0, int N, int tid){
  const float4* s4 = (const float4*)src;
  float4* dA = (float4*)sA;
  #pragma unroll
  for(int r=0;r<4;r++){
    int q = tid + 256*r;              // 0..1023
    int row = q>>4, col = q&15;
    int gn = n0+row; if (gn>N-1) gn=N-1;
    dA[row*LDW4+col] = s4[(size_t)gn*16+col];
  }
}

// stage 96 weight rows (row-major [96][64]) into sW
__device__ __forceinline__ void stage_w(const float* __restrict__ Wsrc, float* sW, int tid){
  const float4* ws = (const float4*)Wsrc;
  float4* dW = (float4*)sW;
  #pragma unroll
  for (int r=0;r<6;r++){
    int q = tid + 256*r;                    // 0..1535
    dW[(q>>4)*LDW4 + (q&15)] = ws[q];
  }
}

// window rows 0..95: jj 0..3 -> r_[i][jj]; jj 4,5 -> z_[i][jj-4]. All indices static.
__device__ __forceinline__ void mm_A(const float* sW, const float* sA, int jt, int nt,
                                     float (&r_)[4][4], float (&z_)[4][4]){
  const float4* sW4 = (const float4*)sW;
  const float4* sA4 = (const float4*)sA;
  #pragma unroll
  for (int kq=0;kq<16;kq++){
    float4 af[4];
    #pragma unroll
    for (int i=0;i<4;i++) af[i] = sA4[(nt*4+i)*LDW4 + kq];
    #pragma unroll
    for (int jj=0;jj<4;jj++){
      float4 b = sW4[(jt+16*jj)*LDW4 + kq];
      #pragma unroll
      for (int i=0;i<4;i++) r_[i][jj] = fma4_(af[i], b, r_[i][jj]);
    }
    #pragma unroll
    for (int jj=0;jj<2;jj++){
      float4 b = sW4[(jt+16*(4+jj))*LDW4 + kq];
      #pragma unroll
      for (int i=0;i<4;i++) z_[i][jj] = fma4_(af[i], b, z_[i][jj]);
    }
  }
}

// window rows 96..191: jj 0,1 -> z_[i][2+jj]; jj 2..5 -> g4[i][jj-2]. All indices static.
__device__ __forceinline__ void mm_B(const float* sW, const float* sA, int jt, int nt,
                                     float (&z_)[4][4], float (&g4)[4][4]){
  const float4* sW4 = (const float4*)sW;
  const float4* sA4 = (const float4*)sA;
  #pragma unroll
  for (int kq=0;kq<16;kq++){
    float4 af[4];
    #pragma unroll
    for (int i=0;i<4;i++) af[i] = sA4[(nt*4+i)*LDW4 + kq];
    #pragma unroll
    for (int jj=0;jj<2;jj++){
      float4 b = sW4[(jt+16*jj)*LDW4 + kq];
      #pragma unroll
      for (int i=0;i<4;i++) z_[i][2+jj] = fma4_(af[i], b, z_[i][2+jj]);
    }
    #pragma unroll
    for (int jj=0;jj<4;jj++){
      float4 b = sW4[(jt+16*(2+jj))*LDW4 + kq];
      #pragma unroll
      for (int i=0;i<4;i++) g4[i][jj] = fma4_(af[i], b, g4[i][jj]);
    }
  }
}

// fused GRU: block = 64 nodes. 64 accumulators, static indices, 128-VGPR budget -> no scratch.
__global__ void __launch_bounds__(256,2)
k_gru_t(const float* __restrict__ hg, const float* __restrict__ xin, float* __restrict__ xout,
        const float* __restrict__ WihT, const float* __restrict__ WhhT,
        const float* __restrict__ bih, const float* __restrict__ bhh, int N){
  __shared__ float sW[96*LDW];        // 26112 B
  __shared__ float sA[64*LDW];        // 17408 B (hg tile, then xin tile)
  int tid = threadIdx.x;
  int jt = tid & 15, nt = tid >> 4;
  int n0 = blockIdx.x * 64;

  float r_[4][4], z_[4][4], ni[4][4], nh[4][4];
  #pragma unroll
  for (int i=0;i<4;i++){
    #pragma unroll
    for (int j=0;j<4;j++){ r_[i][j]=0.f; z_[i][j]=0.f; ni[i][j]=0.f; nh[i][j]=0.f; }
  }

  stage_tile(hg, sA, n0, N, tid);
  __syncthreads();
  stage_w(WihT, sW, tid);
  __syncthreads();
  mm_A(sW, sA, jt, nt, r_, z_);        // Wih rows 0..95  (r + z-lo)
  __syncthreads();
  stage_w(WihT + 96*H_, sW, tid);
  __syncthreads();
  mm_B(sW, sA, jt, nt, z_, ni);        // Wih rows 96..191 (z-hi + n)
  __syncthreads();                     // done reading hg tile
  stage_tile(xin, sA, n0, N, tid);
  stage_w(WhhT, sW, tid);
  __syncthreads();
  mm_A(sW, sA, jt, nt, r_, z_);        // Whh rows 0..95
  __syncthreads();
  stage_w(WhhT + 96*H_, sW, tid);
  __syncthreads();
  mm_B(sW, sA, jt, nt, z_, nh);        // Whh rows 96..191

  // epilogue: gates + blend + relu (sA holds xin tile)
  #pragma unroll
  for (int jj2=0;jj2<4;jj2++){
    int f = jt + 16*jj2;
    float br = bih[f]     + bhh[f];
    float bz = bih[64+f]  + bhh[64+f];
    float bin= bih[128+f], bhn = bhh[128+f];
    #pragma unroll
    for (int i=0;i<4;i++){
      int node = n0 + nt*4 + i;
      if (node < N){
        float r  = sigm_(r_[i][jj2] + br);
        float z  = sigm_(z_[i][jj2] + bz);
        float nn = tanh_(ni[i][jj2] + bin + r*(nh[i][jj2] + bhn));
        float xv = sA[(nt*4+i)*LDW + f];
        xout[(size_t)node*H_ + f] = fmaxf((1.f-z)*nn + z*xv, 0.f);
      }
    }
  }
}

// h = xi @ conv_W[l] (LDS-tiled) + ssc/dsc reductions
__global__ void __launch_bounds__(256,3)
k_linh_t(const float* __restrict__ xi, const float* __restrict__ wT,
         const float* __restrict__ atts, const float* __restrict__ attd,
         float* __restrict__ h, float* __restrict__ ssc, float* __restrict__ dsc, int N){
  __shared__ float sW[64*LDW];          // 17408
  __shared__ float sA[64*LDW];          // 17408
  __shared__ float sred[64][17][2];
  int tid = threadIdx.x;
  int jt = tid & 15, nt = tid >> 4;
  int n0 = blockIdx.x * 64;

  { // stage
    const float4* srcA = (const float4*)xi;
    const float4* srcW = (const float4*)wT;
    float4* dA = (float4*)sA;
    float4* dW = (float4*)sW;
    #pragma unroll
    for (int r = 0; r < 4; r++){
      int q = tid + 256*r;              // 0..1023
      int row = q >> 4, col = q & 15;
      int gn = n0 + row; if (gn > N-1) gn = N-1;
      dA[row*LDW4 + col] = srcA[(size_t)gn*16 + col];
      dW[row*LDW4 + col] = srcW[q];
    }
  }
  __syncthreads();

  float acc[4][4];
  #pragma unroll
  for (int i=0;i<4;i++){
    #pragma unroll
    for (int j=0;j<4;j++) acc[i][j]=0.f;
  }
  const float4* sA4 = (const float4*)sA;
  const float4* sW4 = (const float4*)sW;
  #pragma unroll
  for (int kq=0;kq<16;kq++){
    float4 af[4];
    #pragma unroll
    for (int i=0;i<4;i++) af[i] = sA4[(nt*4+i)*LDW4 + kq];
    #pragma unroll
    for (int jj=0;jj<4;jj++){
      float4 b = sW4[(jt+16*jj)*LDW4 + kq];
      #pragma unroll
      for (int i=0;i<4;i++) acc[i][jj] = fma4_(af[i], b, acc[i][jj]);
    }
  }

  float ps[4]={0.f,0.f,0.f,0.f}, pd[4]={0.f,0.f,0.f,0.f};
  #pragma unroll
  for (int jj=0;jj<4;jj++){
    int f = jt + 16*jj;
    float as = atts[f], ad = attd[f];
    #pragma unroll
    for (int i=0;i<4;i++){
      int node = n0 + nt*4 + i;
      float v = acc[i][jj];
      if (node < N) h[(size_t)node*H_ + f] = v;
      ps[i] += v*as; pd[i] += v*ad;
    }
  }
  #pragma unroll
  for (int i=0;i<4;i++){ sred[nt*4+i][jt][0]=ps[i]; sred[nt*4+i][jt][1]=pd[i]; }
  __syncthreads();
  if (tid < 64){
    float s=0.f, d=0.f;
    #pragma unroll
    for (int w=0;w<16;w++){ s += sred[tid][w][0]; d += sred[tid][w][1]; }
    int node = n0 + tid;
    if (node < N){ ssc[node]=s; dsc[node]=d; }
  }
}

// block per node (4 waves): segment softmax + weighted aggregation
__global__ void __launch_bounds__(256)
k_gat_b(const float* __restrict__ h, const float* __restrict__ ssc,
        const float* __restrict__ dsc, const float* __restrict__ escore,
        const int* __restrict__ off, const int* __restrict__ eid,
        const int* __restrict__ srcarr, const float* __restrict__ bias,
        float* __restrict__ hgat, int E, int N){
  int node = blockIdx.x;
  int tid = threadIdx.x, lane = tid & 63, w = tid >> 6;
  int e0 = off[node], e1 = off[node+1];
  float dval = dsc[node];
  __shared__ float smax[4], sden[4], sacc[4][64];
  float mx = -1e30f;
  for (int p = e0 + tid; p < e1; p += 256){
    int e = eid[p];
    int s = (e < E) ? srcarr[e] : (e - E);
    float a = ssc[s] + dval + escore[e];
    a = (a > 0.f) ? a : SLOPE*a;
    mx = fmaxf(mx, a);
  }
  #pragma unroll
  for (int d=32; d; d>>=1) mx = fmaxf(mx, __shfl_xor(mx, d));
  if (lane==0) smax[w] = mx;
  __syncthreads();
  mx = fmaxf(fmaxf(smax[0],smax[1]), fmaxf(smax[2],smax[3]));
  float acc = 0.f, den = 0.f;
  for (int p = e0 + w; p < e1; p += 4){
    int e = eid[p];
    int s = (e < E) ? srcarr[e] : (e - E);
    float a = ssc[s] + dval + escore[e];
    a = (a > 0.f) ? a : SLOPE*a;
    float ex = __expf(a - mx);
    den += ex;
    acc += ex * h[(size_t)s*H_ + lane];
  }
  sacc[w][lane] = acc;
  if (lane==0) sden[w] = den;
  __syncthreads();
  if (w==0){
    float a4 = sacc[0][lane]+sacc[1][lane]+sacc[2][lane]+sacc[3][lane];
    float d4 = sden[0]+sden[1]+sden[2]+sden[3];
    hgat[(size_t)node*H_ + lane] = fmaxf(a4/d4 + bias[lane], 0.f);
  }
}

__global__ void k_pool_init(float* __restrict__ out, const float* __restrict__ b_out, int G){
  int g = blockIdx.x*blockDim.x+threadIdx.x;
  if (g<G) out[g] = b_out[0];
}

__global__ void k_pool(const float* __restrict__ xi, const float* __restrict__ wout,
                       const int* __restrict__ batch, float* __restrict__ out, int N){
  int n = blockIdx.x*blockDim.x+threadIdx.x;
  if (n>=N) return;
  float acc=0.f;
  const float4* xr=(const float4*)(xi + (size_t)n*H_);
  #pragma unroll
  for(int q=0;q<H_/4;q++){
    float4 v=xr[q];
    acc += v.x*wout[4*q] + v.y*wout[4*q+1] + v.z*wout[4*q+2] + v.w*wout[4*q+3];
  }
  atomicAdd(&out[batch[n]], acc);
}

extern "C" void kernel_launch(void* const* d_in, const int* in_sizes, int n_in,
                              void* d_out, int out_size, void* d_ws, size_t ws_size,
                              hipStream_t stream){
  const float* x       = (const float*)d_in[0];
  const float* eattr   = (const float*)d_in[1];
  const float* w_node  = (const float*)d_in[2];
  const float* b_node  = (const float*)d_in[3];
  const float* w_edge  = (const float*)d_in[4];
  const float* b_edge  = (const float*)d_in[5];
  const float* conv_W  = (const float*)d_in[6];
  const float* conv_We = (const float*)d_in[7];
  const float* att_s   = (const float*)d_in[8];
  const float* att_d   = (const float*)d_in[9];
  const float* att_e   = (const float*)d_in[10];
  const float* conv_b  = (const float*)d_in[11];
  const float* gWih    = (const float*)d_in[12];
  const float* gWhh    = (const float*)d_in[13];
  const float* gbih    = (const float*)d_in[14];
  const float* gbhh    = (const float*)d_in[15];
  const float* w_out   = (const float*)d_in[16];
  const float* b_out   = (const float*)d_in[17];
  const int*   eidx    = (const int*)d_in[18];
  const int*   batch   = (const int*)d_in[19];
  float* out = (float*)d_out;

  int N = in_sizes[0]/DIN;
  int E = in_sizes[1]/DE;
  int G = out_size;
  int EN = E + N;
  const int* src = eidx;
  const int* dst = eidx + E;

  char* p = (char*)d_ws;
  auto carve = [&](size_t bytes)->void*{ void* r=(void*)p; p += (bytes+255)&~(size_t)255; return r; };
  float* xi0   = (float*)carve((size_t)N*H_*4);
  float* xi1   = (float*)carve((size_t)N*H_*4);
  float* hbuf  = (float*)carve((size_t)N*H_*4);
  float* hgat  = (float*)carve((size_t)N*H_*4);
  float* ssc   = (float*)carve((size_t)N*4);
  float* dsc   = (float*)carve((size_t)N*4);
  float* escore= (float*)carve((size_t)3*EN*4);
  float* ssum  = (float*)carve((size_t)3*N*4);
  int*   deg   = (int*)carve((size_t)N*4);
  int*   off   = (int*)carve((size_t)(N+1)*4);
  int*   cur   = (int*)carve((size_t)(N+1)*4);
  int*   eid   = (int*)carve((size_t)EN*4);
  int*   bsum  = (int*)carve((size_t)1024*4);
  int*   boff  = (int*)carve((size_t)1024*4);
  float* wnT   = (float*)carve((size_t)DIN*H_*4);
  float* weT   = (float*)carve((size_t)DE*H_*4);
  float* cWT   = (float*)carve((size_t)3*H_*H_*4);
  float* WihT  = (float*)carve((size_t)3*H_*3*H_*4);
  float* WhhT  = (float*)carve((size_t)3*H_*3*H_*4);
  float* ve    = (float*)carve((size_t)3*H_*4);

  auto cdiv=[](int a,int b){return (a+b-1)/b;};
  int NB = cdiv(N,256);

  k_transpose<<<cdiv(DIN*H_,256),256,0,stream>>>(w_node, wnT, 1, DIN, H_);
  k_transpose<<<cdiv(DE*H_,256),256,0,stream>>>(w_edge, weT, 1, DE, H_);
  k_transpose<<<cdiv(3*H_*H_,256),256,0,stream>>>(conv_W, cWT, 3, H_, H_);
  k_transpose<<<cdiv(3*H_*3*H_,256),256,0,stream>>>(gWih, WihT, 3, H_, 3*H_);
  k_transpose<<<cdiv(3*H_*3*H_,256),256,0,stream>>>(gWhh, WhhT, 3, H_, 3*H_);
  k_ve<<<1,3*H_,0,stream>>>(conv_We, att_e, ve);

  k_init<<<cdiv(N,256),256,0,stream>>>(deg, ssum, N);
  k_node_mlp<<<cdiv(N,256),256,0,stream>>>(x, wnT, b_node, xi0, N);
  k_edge_scores<<<cdiv(E,256),256,0,stream>>>(eattr, weT, b_edge, ve, dst, escore, ssum, deg, E, EN, N);
  k_selfloop<<<cdiv(N,256),256,0,stream>>>(ssum, deg, escore, E, EN, N);
  k_bsum<<<NB,256,0,stream>>>(deg, bsum, N);
  k_bscan<<<1,1024,0,stream>>>(bsum, boff, NB, off+N, EN);
  k_scan_fin<<<NB,256,0,stream>>>(deg, boff, off, cur, N);
  k_fill<<<cdiv(EN,256),256,0,stream>>>(dst, cur, eid, E, N);

  int NB64 = cdiv(N,64);
  for (int l=0; l<3; l++){
    const float* xin = (l&1) ? xi1 : xi0;
    float*       xo  = (l&1) ? xi0 : xi1;
    k_linh_t<<<NB64,256,0,stream>>>(xin, cWT + (size_t)l*H_*H_, att_s + l*H_, att_d + l*H_,
                                    hbuf, ssc, dsc, N);
    k_gat_b<<<N,256,0,stream>>>(hbuf, ssc, dsc, escore + (size_t)l*EN, off, eid, src,
                                conv_b + l*H_, hgat, E, N);
    k_gru_t<<<NB64,256,0,stream>>>(hgat, xin, xo, WihT + (size_t)l*192*H_, WhhT + (size_t)l*192*H_,
                                   gbih + l*3*H_, gbhh + l*3*H_, N);
  }

  k_pool_init<<<cdiv(G,256),256,0,stream>>>(out, b_out, G);
  k_pool<<<cdiv(N,256),256,0,stream>>>(xi1, w_out, batch, out, N);
}

// Round 7
// 1505.139 us; speedup vs baseline: 11.6830x; 11.6159x over previous
//
#include <hip/hip_runtime.h>

constexpr int H_  = 64;   // hidden
constexpr int DIN = 32;   // atom feature dim
constexpr int DE  = 16;   // edge feature dim
constexpr int LDW  = 68;  // padded LDS row stride (floats)
constexpr int LDW4 = 17;  // in float4
#define SLOPE 0.2f

__device__ __forceinline__ float sigm_(float x){ return 1.0f/(1.0f+__expf(-x)); }
__device__ __forceinline__ float tanh_(float x){ float e=__expf(2.0f*x); return 1.0f - 2.0f/(e+1.0f); }
__device__ __forceinline__ float fma4_(float4 a, float4 b, float acc){
  return fmaf(a.w,b.w, fmaf(a.z,b.z, fmaf(a.y,b.y, fmaf(a.x,b.x, acc))));
}

// dst[b][c][r] = src[b][r][c]
__global__ void k_transpose(const float* __restrict__ src, float* __restrict__ dst, int B,int R,int C){
  int id = blockIdx.x*blockDim.x+threadIdx.x;
  if (id >= B*R*C) return;
  int rc=R*C, b=id/rc, rem=id-b*rc, r=rem/C, c=rem-r*C;
  dst[b*rc + c*R + r] = src[id];
}

// ve[l][k] = sum_j conv_We[l][k][j] * att_e[l][j]
__global__ void k_ve(const float* __restrict__ We, const float* __restrict__ ae, float* __restrict__ ve){
  int id = blockIdx.x*blockDim.x+threadIdx.x;
  if (id >= 3*H_) return;
  int l=id/H_, k=id-l*H_;
  const float* w = We + (size_t)(l*H_+k)*H_;
  const float* a = ae + l*H_;
  float s=0.f;
  #pragma unroll
  for(int j=0;j<H_;j++) s += w[j]*a[j];
  ve[id]=s;
}

__global__ void k_init(int* __restrict__ deg, float* __restrict__ ssum, int N){
  int n = blockIdx.x*blockDim.x+threadIdx.x;
  if (n>=N) return;
  deg[n]=1;                 // self-loop
  ssum[n]=0.f; ssum[N+n]=0.f; ssum[2*N+n]=0.f;
}

// xi = relu(x @ w_node + b_node), thread per node, wT transposed [64][32]
__global__ void k_node_mlp(const float* __restrict__ x, const float* __restrict__ wT,
                           const float* __restrict__ b, float* __restrict__ xi, int N){
  int n = blockIdx.x*blockDim.x+threadIdx.x;
  if (n>=N) return;
  float xv[DIN];
  const float4* xr = (const float4*)(x + (size_t)n*DIN);
  #pragma unroll
  for(int q=0;q<DIN/4;q++){ float4 v=xr[q]; xv[4*q]=v.x; xv[4*q+1]=v.y; xv[4*q+2]=v.z; xv[4*q+3]=v.w; }
  for(int j0=0;j0<H_;j0+=4){
    float o[4];
    #pragma unroll
    for(int jj=0;jj<4;jj++){
      int j=j0+jj;
      const float* wr = wT + j*DIN;   // uniform -> s_load
      float acc = b[j];
      #pragma unroll
      for(int k=0;k<DIN;k++) acc += xv[k]*wr[k];
      o[jj] = fmaxf(acc,0.f);
    }
    *(float4*)(xi + (size_t)n*H_ + j0) = make_float4(o[0],o[1],o[2],o[3]);
  }
}

// per-edge: ea = relu(attr@w_edge+b); escore[l][e] = ea . ve[l];
__global__ void k_edge_scores(const float* __restrict__ attr, const float* __restrict__ weT,
                              const float* __restrict__ be, const float* __restrict__ ve,
                              const int* __restrict__ dst, float* __restrict__ escore,
                              float* __restrict__ ssum, int* __restrict__ deg,
                              int E, int EN, int N){
  int e = blockIdx.x*blockDim.x+threadIdx.x;
  if (e>=E) return;
  float av[DE];
  const float4* ar = (const float4*)(attr + (size_t)e*DE);
  #pragma unroll
  for(int q=0;q<DE/4;q++){ float4 v=ar[q]; av[4*q]=v.x; av[4*q+1]=v.y; av[4*q+2]=v.z; av[4*q+3]=v.w; }
  float s0=0.f,s1=0.f,s2=0.f;
  for(int j=0;j<H_;j++){
    const float* wr = weT + j*DE;     // uniform
    float acc = be[j];
    #pragma unroll
    for(int k=0;k<DE;k++) acc += av[k]*wr[k];
    acc = fmaxf(acc,0.f);
    s0 += acc*ve[j]; s1 += acc*ve[H_+j]; s2 += acc*ve[2*H_+j];
  }
  escore[e] = s0; escore[EN+e] = s1; escore[2*EN+e] = s2;
  int d = dst[e];
  atomicAdd(&ssum[d],     s0);
  atomicAdd(&ssum[N+d],   s1);
  atomicAdd(&ssum[2*N+d], s2);
  atomicAdd(&deg[d], 1);
}

__global__ void k_selfloop(const float* __restrict__ ssum, const int* __restrict__ deg,
                           float* __restrict__ escore, int E, int EN, int N){
  int n = blockIdx.x*blockDim.x+threadIdx.x;
  if (n>=N) return;
  float c = (float)(deg[n]-1);
  float inv = (c>0.f) ? 1.0f/c : 0.0f;
  escore[E+n]        = ssum[n]*inv;
  escore[EN+E+n]     = ssum[N+n]*inv;
  escore[2*EN+E+n]   = ssum[2*N+n]*inv;
}

// ---- hierarchical scan of deg -> off (exclusive), cur copy ----
__global__ void k_bsum(const int* __restrict__ deg, int* __restrict__ bsum, int N){
  int i = blockIdx.x*256 + threadIdx.x;
  int v = (i<N) ? deg[i] : 0;
  #pragma unroll
  for(int d=32; d; d>>=1) v += __shfl_xor(v, d);
  __shared__ int sh[4];
  if ((threadIdx.x&63)==0) sh[threadIdx.x>>6] = v;
  __syncthreads();
  if (threadIdx.x==0) bsum[blockIdx.x] = sh[0]+sh[1]+sh[2]+sh[3];
}

__global__ void k_bscan(const int* __restrict__ bsum, int* __restrict__ boff, int NB,
                        int* __restrict__ offN, int EN){
  __shared__ int sh[1024];
  int tid = threadIdx.x;
  int v = (tid<NB) ? bsum[tid] : 0;
  sh[tid] = v;
  __syncthreads();
  for(int d=1; d<1024; d<<=1){
    int t = 0;
    if (tid>=d) t = sh[tid-d];
    __syncthreads();
    if (tid>=d) sh[tid] += t;
    __syncthreads();
  }
  if (tid<NB) boff[tid] = sh[tid] - v;  // exclusive
  if (tid==0) offN[0] = EN;
}

__global__ void k_scan_fin(const int* __restrict__ deg, const int* __restrict__ boff,
                           int* __restrict__ off, int* __restrict__ cur, int N){
  __shared__ int sh[256];
  int i = blockIdx.x*256 + threadIdx.x;
  int v = (i<N) ? deg[i] : 0;
  sh[threadIdx.x] = v;
  __syncthreads();
  for(int d=1; d<256; d<<=1){
    int t = 0;
    if (threadIdx.x>=d) t = sh[threadIdx.x-d];
    __syncthreads();
    if (threadIdx.x>=d) sh[threadIdx.x] += t;
    __syncthreads();
  }
  if (i<N){
    int e = boff[blockIdx.x] + sh[threadIdx.x] - v;
    off[i] = e; cur[i] = e;
  }
}

__global__ void k_fill(const int* __restrict__ dst, int* __restrict__ cur, int* __restrict__ eid, int E, int N){
  int e = blockIdx.x*blockDim.x+threadIdx.x;
  if (e>=E+N) return;
  int d = (e<E) ? dst[e] : (e-E);
  int p = atomicAdd(&cur[d],1);
  eid[p] = e;
}

// stage 64-node x 64-feature tile into sA (padded rows), 512 threads
__device__ __forceinline__ void stage_tile512(const float* __restrict__ src, float* sA,
                                              int n0, int N, int tid){
  const float4* s4 = (const float4*)src;
  float4* dA = (float4*)sA;
  #pragma unroll
  for(int r=0;r<2;r++){
    int q = tid + 512*r;              // 0..1023
    int row = q>>4, col = q&15;
    int gn = n0+row; if (gn>N-1) gn=N-1;
    dA[row*LDW4+col] = s4[(size_t)gn*16+col];
  }
}

// stage 96 weight rows (row-major [96][64]) into sW, 512 threads
__device__ __forceinline__ void stage_w512(const float* __restrict__ Wsrc, float* sW, int tid){
  const float4* ws = (const float4*)Wsrc;
  float4* dW = (float4*)sW;
  #pragma unroll
  for (int r=0;r<3;r++){
    int q = tid + 512*r;                    // 0..1535
    dW[(q>>4)*LDW4 + (q&15)] = ws[q];
  }
}

// window rows 0..95: jj 0..3 -> r_[i][jj]; jj 4,5 -> z_[i][jj-4]. Static indices, rolled kq.
__device__ __forceinline__ void mm_A2(const float* sW, const float* sA, int jt, int nt,
                                      float (&r_)[2][4], float (&z_)[2][4]){
  const float4* sW4 = (const float4*)sW;
  const float4* sA4 = (const float4*)sA;
  #pragma unroll 2
  for (int kq=0;kq<16;kq++){
    float4 af[2];
    #pragma unroll
    for (int i=0;i<2;i++) af[i] = sA4[(nt*2+i)*LDW4 + kq];
    #pragma unroll
    for (int jj=0;jj<4;jj++){
      float4 b = sW4[(jt+16*jj)*LDW4 + kq];
      #pragma unroll
      for (int i=0;i<2;i++) r_[i][jj] = fma4_(af[i], b, r_[i][jj]);
    }
    #pragma unroll
    for (int jj=0;jj<2;jj++){
      float4 b = sW4[(jt+16*(4+jj))*LDW4 + kq];
      #pragma unroll
      for (int i=0;i<2;i++) z_[i][jj] = fma4_(af[i], b, z_[i][jj]);
    }
  }
}

// window rows 96..191: jj 0,1 -> z_[i][2+jj]; jj 2..5 -> g4[i][jj-2]. Static indices, rolled kq.
__device__ __forceinline__ void mm_B2(const float* sW, const float* sA, int jt, int nt,
                                      float (&z_)[2][4], float (&g4)[2][4]){
  const float4* sW4 = (const float4*)sW;
  const float4* sA4 = (const float4*)sA;
  #pragma unroll 2
  for (int kq=0;kq<16;kq++){
    float4 af[2];
    #pragma unroll
    for (int i=0;i<2;i++) af[i] = sA4[(nt*2+i)*LDW4 + kq];
    #pragma unroll
    for (int jj=0;jj<2;jj++){
      float4 b = sW4[(jt+16*jj)*LDW4 + kq];
      #pragma unroll
      for (int i=0;i<2;i++) z_[i][2+jj] = fma4_(af[i], b, z_[i][2+jj]);
    }
    #pragma unroll
    for (int jj=0;jj<4;jj++){
      float4 b = sW4[(jt+16*(2+jj))*LDW4 + kq];
      #pragma unroll
      for (int i=0;i<2;i++) g4[i][jj] = fma4_(af[i], b, g4[i][jj]);
    }
  }
}

// fused GRU: block = 64 nodes, 512 threads -> 32 accumulators/thread, no spill.
__global__ void __launch_bounds__(512,4)
k_gru_t(const float* __restrict__ hg, const float* __restrict__ xin, float* __restrict__ xout,
        const float* __restrict__ WihT, const float* __restrict__ WhhT,
        const float* __restrict__ bih, const float* __restrict__ bhh, int N){
  __shared__ float sW[96*LDW];        // 26112 B
  __shared__ float sA[64*LDW];        // 17408 B (hg tile, then xin tile)
  int tid = threadIdx.x;
  int jt = tid & 15, nt = tid >> 4;   // nt 0..31, 2 nodes each
  int n0 = blockIdx.x * 64;

  float r_[2][4], z_[2][4], ni[2][4], nh[2][4];
  #pragma unroll
  for (int i=0;i<2;i++){
    #pragma unroll
    for (int j=0;j<4;j++){ r_[i][j]=0.f; z_[i][j]=0.f; ni[i][j]=0.f; nh[i][j]=0.f; }
  }

  stage_tile512(hg, sA, n0, N, tid);
  stage_w512(WihT, sW, tid);
  __syncthreads();
  mm_A2(sW, sA, jt, nt, r_, z_);       // Wih rows 0..95  (r + z-lo)
  __syncthreads();
  stage_w512(WihT + 96*H_, sW, tid);
  __syncthreads();
  mm_B2(sW, sA, jt, nt, z_, ni);       // Wih rows 96..191 (z-hi + n)
  __syncthreads();                     // done reading hg tile
  stage_tile512(xin, sA, n0, N, tid);
  stage_w512(WhhT, sW, tid);
  __syncthreads();
  mm_A2(sW, sA, jt, nt, r_, z_);       // Whh rows 0..95
  __syncthreads();
  stage_w512(WhhT + 96*H_, sW, tid);
  __syncthreads();
  mm_B2(sW, sA, jt, nt, z_, nh);       // Whh rows 96..191

  // epilogue: gates + blend + relu (sA holds xin tile)
  #pragma unroll
  for (int jj2=0;jj2<4;jj2++){
    int f = jt + 16*jj2;
    float br = bih[f]     + bhh[f];
    float bz = bih[64+f]  + bhh[64+f];
    float bin= bih[128+f], bhn = bhh[128+f];
    #pragma unroll
    for (int i=0;i<2;i++){
      int node = n0 + nt*2 + i;
      if (node < N){
        float r  = sigm_(r_[i][jj2] + br);
        float z  = sigm_(z_[i][jj2] + bz);
        float nn = tanh_(ni[i][jj2] + bin + r*(nh[i][jj2] + bhn));
        float xv = sA[(nt*2+i)*LDW + f];
        xout[(size_t)node*H_ + f] = fmaxf((1.f-z)*nn + z*xv, 0.f);
      }
    }
  }
}

// h = xi @ conv_W[l] (LDS-tiled) + ssc/dsc reductions
__global__ void __launch_bounds__(256,3)
k_linh_t(const float* __restrict__ xi, const float* __restrict__ wT,
         const float* __restrict__ atts, const float* __restrict__ attd,
         float* __restrict__ h, float* __restrict__ ssc, float* __restrict__ dsc, int N){
  __shared__ float sW[64*LDW];          // 17408
  __shared__ float sA[64*LDW];          // 17408
  __shared__ float sred[64][17][2];
  int tid = threadIdx.x;
  int jt = tid & 15, nt = tid >> 4;
  int n0 = blockIdx.x * 64;

  { // stage
    const float4* srcA = (const float4*)xi;
    const float4* srcW = (const float4*)wT;
    float4* dA = (float4*)sA;
    float4* dW = (float4*)sW;
    #pragma unroll
    for (int r = 0; r < 4; r++){
      int q = tid + 256*r;              // 0..1023
      int row = q >> 4, col = q & 15;
      int gn = n0 + row; if (gn > N-1) gn = N-1;
      dA[row*LDW4 + col] = srcA[(size_t)gn*16 + col];
      dW[row*LDW4 + col] = srcW[q];
    }
  }
  __syncthreads();

  float acc[4][4];
  #pragma unroll
  for (int i=0;i<4;i++){
    #pragma unroll
    for (int j=0;j<4;j++) acc[i][j]=0.f;
  }
  const float4* sA4 = (const float4*)sA;
  const float4* sW4 = (const float4*)sW;
  #pragma unroll 2
  for (int kq=0;kq<16;kq++){
    float4 af[4];
    #pragma unroll
    for (int i=0;i<4;i++) af[i] = sA4[(nt*4+i)*LDW4 + kq];
    #pragma unroll
    for (int jj=0;jj<4;jj++){
      float4 b = sW4[(jt+16*jj)*LDW4 + kq];
      #pragma unroll
      for (int i=0;i<4;i++) acc[i][jj] = fma4_(af[i], b, acc[i][jj]);
    }
  }

  float ps[4]={0.f,0.f,0.f,0.f}, pd[4]={0.f,0.f,0.f,0.f};
  #pragma unroll
  for (int jj=0;jj<4;jj++){
    int f = jt + 16*jj;
    float as = atts[f], ad = attd[f];
    #pragma unroll
    for (int i=0;i<4;i++){
      int node = n0 + nt*4 + i;
      float v = acc[i][jj];
      if (node < N) h[(size_t)node*H_ + f] = v;
      ps[i] += v*as; pd[i] += v*ad;
    }
  }
  #pragma unroll
  for (int i=0;i<4;i++){ sred[nt*4+i][jt][0]=ps[i]; sred[nt*4+i][jt][1]=pd[i]; }
  __syncthreads();
  if (tid < 64){
    float s=0.f, d=0.f;
    #pragma unroll
    for (int w=0;w<16;w++){ s += sred[tid][w][0]; d += sred[tid][w][1]; }
    int node = n0 + tid;
    if (node < N){ ssc[node]=s; dsc[node]=d; }
  }
}

// block per node (4 waves): segment softmax + weighted aggregation
__global__ void __launch_bounds__(256)
k_gat_b(const float* __restrict__ h, const float* __restrict__ ssc,
        const float* __restrict__ dsc, const float* __restrict__ escore,
        const int* __restrict__ off, const int* __restrict__ eid,
        const int* __restrict__ srcarr, const float* __restrict__ bias,
        float* __restrict__ hgat, int E, int N){
  int node = blockIdx.x;
  int tid = threadIdx.x, lane = tid & 63, w = tid >> 6;
  int e0 = off[node], e1 = off[node+1];
  float dval = dsc[node];
  __shared__ float smax[4], sden[4], sacc[4][64];
  float mx = -1e30f;
  for (int p = e0 + tid; p < e1; p += 256){
    int e = eid[p];
    int s = (e < E) ? srcarr[e] : (e - E);
    float a = ssc[s] + dval + escore[e];
    a = (a > 0.f) ? a : SLOPE*a;
    mx = fmaxf(mx, a);
  }
  #pragma unroll
  for (int d=32; d; d>>=1) mx = fmaxf(mx, __shfl_xor(mx, d));
  if (lane==0) smax[w] = mx;
  __syncthreads();
  mx = fmaxf(fmaxf(smax[0],smax[1]), fmaxf(smax[2],smax[3]));
  float acc = 0.f, den = 0.f;
  for (int p = e0 + w; p < e1; p += 4){
    int e = eid[p];
    int s = (e < E) ? srcarr[e] : (e - E);
    float a = ssc[s] + dval + escore[e];
    a = (a > 0.f) ? a : SLOPE*a;
    float ex = __expf(a - mx);
    den += ex;
    acc += ex * h[(size_t)s*H_ + lane];
  }
  sacc[w][lane] = acc;
  if (lane==0) sden[w] = den;
  __syncthreads();
  if (w==0){
    float a4 = sacc[0][lane]+sacc[1][lane]+sacc[2][lane]+sacc[3][lane];
    float d4 = sden[0]+sden[1]+sden[2]+sden[3];
    hgat[(size_t)node*H_ + lane] = fmaxf(a4/d4 + bias[lane], 0.f);
  }
}

__global__ void k_pool_init(float* __restrict__ out, const float* __restrict__ b_out, int G){
  int g = blockIdx.x*blockDim.x+threadIdx.x;
  if (g<G) out[g] = b_out[0];
}

__global__ void k_pool(const float* __restrict__ xi, const float* __restrict__ wout,
                       const int* __restrict__ batch, float* __restrict__ out, int N){
  int n = blockIdx.x*blockDim.x+threadIdx.x;
  if (n>=N) return;
  float acc=0.f;
  const float4* xr=(const float4*)(xi + (size_t)n*H_);
  #pragma unroll
  for(int q=0;q<H_/4;q++){
    float4 v=xr[q];
    acc += v.x*wout[4*q] + v.y*wout[4*q+1] + v.z*wout[4*q+2] + v.w*wout[4*q+3];
  }
  atomicAdd(&out[batch[n]], acc);
}

extern "C" void kernel_launch(void* const* d_in, const int* in_sizes, int n_in,
                              void* d_out, int out_size, void* d_ws, size_t ws_size,
                              hipStream_t stream){
  const float* x       = (const float*)d_in[0];
  const float* eattr   = (const float*)d_in[1];
  const float* w_node  = (const float*)d_in[2];
  const float* b_node  = (const float*)d_in[3];
  const float* w_edge  = (const float*)d_in[4];
  const float* b_edge  = (const float*)d_in[5];
  const float* conv_W  = (const float*)d_in[6];
  const float* conv_We = (const float*)d_in[7];
  const float* att_s   = (const float*)d_in[8];
  const float* att_d   = (const float*)d_in[9];
  const float* att_e   = (const float*)d_in[10];
  const float* conv_b  = (const float*)d_in[11];
  const float* gWih    = (const float*)d_in[12];
  const float* gWhh    = (const float*)d_in[13];
  const float* gbih    = (const float*)d_in[14];
  const float* gbhh    = (const float*)d_in[15];
  const float* w_out   = (const float*)d_in[16];
  const float* b_out   = (const float*)d_in[17];
  const int*   eidx    = (const int*)d_in[18];
  const int*   batch   = (const int*)d_in[19];
  float* out = (float*)d_out;

  int N = in_sizes[0]/DIN;
  int E = in_sizes[1]/DE;
  int G = out_size;
  int EN = E + N;
  const int* src = eidx;
  const int* dst = eidx + E;

  char* p = (char*)d_ws;
  auto carve = [&](size_t bytes)->void*{ void* r=(void*)p; p += (bytes+255)&~(size_t)255; return r; };
  float* xi0   = (float*)carve((size_t)N*H_*4);
  float* xi1   = (float*)carve((size_t)N*H_*4);
  float* hbuf  = (float*)carve((size_t)N*H_*4);
  float* hgat  = (float*)carve((size_t)N*H_*4);
  float* ssc   = (float*)carve((size_t)N*4);
  float* dsc   = (float*)carve((size_t)N*4);
  float* escore= (float*)carve((size_t)3*EN*4);
  float* ssum  = (float*)carve((size_t)3*N*4);
  int*   deg   = (int*)carve((size_t)N*4);
  int*   off   = (int*)carve((size_t)(N+1)*4);
  int*   cur   = (int*)carve((size_t)(N+1)*4);
  int*   eid   = (int*)carve((size_t)EN*4);
  int*   bsum  = (int*)carve((size_t)1024*4);
  int*   boff  = (int*)carve((size_t)1024*4);
  float* wnT   = (float*)carve((size_t)DIN*H_*4);
  float* weT   = (float*)carve((size_t)DE*H_*4);
  float* cWT   = (float*)carve((size_t)3*H_*H_*4);
  float* WihT  = (float*)carve((size_t)3*H_*3*H_*4);
  float* WhhT  = (float*)carve((size_t)3*H_*3*H_*4);
  float* ve    = (float*)carve((size_t)3*H_*4);

  auto cdiv=[](int a,int b){return (a+b-1)/b;};
  int NB = cdiv(N,256);

  k_transpose<<<cdiv(DIN*H_,256),256,0,stream>>>(w_node, wnT, 1, DIN, H_);
  k_transpose<<<cdiv(DE*H_,256),256,0,stream>>>(w_edge, weT, 1, DE, H_);
  k_transpose<<<cdiv(3*H_*H_,256),256,0,stream>>>(conv_W, cWT, 3, H_, H_);
  k_transpose<<<cdiv(3*H_*3*H_,256),256,0,stream>>>(gWih, WihT, 3, H_, 3*H_);
  k_transpose<<<cdiv(3*H_*3*H_,256),256,0,stream>>>(gWhh, WhhT, 3, H_, 3*H_);
  k_ve<<<1,3*H_,0,stream>>>(conv_We, att_e, ve);

  k_init<<<cdiv(N,256),256,0,stream>>>(deg, ssum, N);
  k_node_mlp<<<cdiv(N,256),256,0,stream>>>(x, wnT, b_node, xi0, N);
  k_edge_scores<<<cdiv(E,256),256,0,stream>>>(eattr, weT, b_edge, ve, dst, escore, ssum, deg, E, EN, N);
  k_selfloop<<<cdiv(N,256),256,0,stream>>>(ssum, deg, escore, E, EN, N);
  k_bsum<<<NB,256,0,stream>>>(deg, bsum, N);
  k_bscan<<<1,1024,0,stream>>>(bsum, boff, NB, off+N, EN);
  k_scan_fin<<<NB,256,0,stream>>>(deg, boff, off, cur, N);
  k_fill<<<cdiv(EN,256),256,0,stream>>>(dst, cur, eid, E, N);

  int NB64 = cdiv(N,64);
  for (int l=0; l<3; l++){
    const float* xin = (l&1) ? xi1 : xi0;
    float*       xo  = (l&1) ? xi0 : xi1;
    k_linh_t<<<NB64,256,0,stream>>>(xin, cWT + (size_t)l*H_*H_, att_s + l*H_, att_d + l*H_,
                                    hbuf, ssc, dsc, N);
    k_gat_b<<<N,256,0,stream>>>(hbuf, ssc, dsc, escore + (size_t)l*EN, off, eid, src,
                                conv_b + l*H_, hgat, E, N);
    k_gru_t<<<NB64,512,0,stream>>>(hgat, xin, xo, WihT + (size_t)l*192*H_, WhhT + (size_t)l*192*H_,
                                   gbih + l*3*H_, gbhh + l*3*H_, N);
  }

  k_pool_init<<<cdiv(G,256),256,0,stream>>>(out, b_out, G);
  k_pool<<<cdiv(N,256),256,0,stream>>>(xi1, w_out, batch, out, N);
}

// Round 8
// 1067.165 us; speedup vs baseline: 16.4778x; 1.4104x over previous
//
#include <hip/hip_runtime.h>

constexpr int H_  = 64;   // hidden
constexpr int DIN = 32;   // atom feature dim
constexpr int DE  = 16;   // edge feature dim
constexpr int LDW  = 68;  // padded LDS row stride (floats)
constexpr int LDW4 = 17;  // in float4
#define SLOPE 0.2f

__device__ __forceinline__ float sigm_(float x){ return 1.0f/(1.0f+__expf(-x)); }
__device__ __forceinline__ float tanh_(float x){ float e=__expf(2.0f*x); return 1.0f - 2.0f/(e+1.0f); }
__device__ __forceinline__ float fma4_(float4 a, float4 b, float acc){
  return fmaf(a.w,b.w, fmaf(a.z,b.z, fmaf(a.y,b.y, fmaf(a.x,b.x, acc))));
}

// dst[b][c][r] = src[b][r][c]
__global__ void k_transpose(const float* __restrict__ src, float* __restrict__ dst, int B,int R,int C){
  int id = blockIdx.x*blockDim.x+threadIdx.x;
  if (id >= B*R*C) return;
  int rc=R*C, b=id/rc, rem=id-b*rc, r=rem/C, c=rem-r*C;
  dst[b*rc + c*R + r] = src[id];
}

// ve[l][k] = sum_j conv_We[l][k][j] * att_e[l][j]
__global__ void k_ve(const float* __restrict__ We, const float* __restrict__ ae, float* __restrict__ ve){
  int id = blockIdx.x*blockDim.x+threadIdx.x;
  if (id >= 3*H_) return;
  int l=id/H_, k=id-l*H_;
  const float* w = We + (size_t)(l*H_+k)*H_;
  const float* a = ae + l*H_;
  float s=0.f;
  #pragma unroll
  for(int j=0;j<H_;j++) s += w[j]*a[j];
  ve[id]=s;
}

__global__ void k_init(int* __restrict__ deg, float* __restrict__ ssum, int N){
  int n = blockIdx.x*blockDim.x+threadIdx.x;
  if (n>=N) return;
  deg[n]=1;                 // self-loop
  ssum[n]=0.f; ssum[N+n]=0.f; ssum[2*N+n]=0.f;
}

// xi = relu(x @ w_node + b_node), thread per node, wT transposed [64][32]
__global__ void k_node_mlp(const float* __restrict__ x, const float* __restrict__ wT,
                           const float* __restrict__ b, float* __restrict__ xi, int N){
  int n = blockIdx.x*blockDim.x+threadIdx.x;
  if (n>=N) return;
  float xv[DIN];
  const float4* xr = (const float4*)(x + (size_t)n*DIN);
  #pragma unroll
  for(int q=0;q<DIN/4;q++){ float4 v=xr[q]; xv[4*q]=v.x; xv[4*q+1]=v.y; xv[4*q+2]=v.z; xv[4*q+3]=v.w; }
  for(int j0=0;j0<H_;j0+=4){
    float o[4];
    #pragma unroll
    for(int jj=0;jj<4;jj++){
      int j=j0+jj;
      const float* wr = wT + j*DIN;   // uniform -> s_load
      float acc = b[j];
      #pragma unroll
      for(int k=0;k<DIN;k++) acc += xv[k]*wr[k];
      o[jj] = fmaxf(acc,0.f);
    }
    *(float4*)(xi + (size_t)n*H_ + j0) = make_float4(o[0],o[1],o[2],o[3]);
  }
}

// per-edge: ea = relu(attr@w_edge+b); escore[l][e] = ea . ve[l];
__global__ void k_edge_scores(const float* __restrict__ attr, const float* __restrict__ weT,
                              const float* __restrict__ be, const float* __restrict__ ve,
                              const int* __restrict__ dst, float* __restrict__ escore,
                              float* __restrict__ ssum, int* __restrict__ deg,
                              int E, int EN, int N){
  int e = blockIdx.x*blockDim.x+threadIdx.x;
  if (e>=E) return;
  float av[DE];
  const float4* ar = (const float4*)(attr + (size_t)e*DE);
  #pragma unroll
  for(int q=0;q<DE/4;q++){ float4 v=ar[q]; av[4*q]=v.x; av[4*q+1]=v.y; av[4*q+2]=v.z; av[4*q+3]=v.w; }
  float s0=0.f,s1=0.f,s2=0.f;
  for(int j=0;j<H_;j++){
    const float* wr = weT + j*DE;     // uniform
    float acc = be[j];
    #pragma unroll
    for(int k=0;k<DE;k++) acc += av[k]*wr[k];
    acc = fmaxf(acc,0.f);
    s0 += acc*ve[j]; s1 += acc*ve[H_+j]; s2 += acc*ve[2*H_+j];
  }
  escore[e] = s0; escore[EN+e] = s1; escore[2*EN+e] = s2;
  int d = dst[e];
  atomicAdd(&ssum[d],     s0);
  atomicAdd(&ssum[N+d],   s1);
  atomicAdd(&ssum[2*N+d], s2);
  atomicAdd(&deg[d], 1);
}

__global__ void k_selfloop(const float* __restrict__ ssum, const int* __restrict__ deg,
                           float* __restrict__ escore, int E, int EN, int N){
  int n = blockIdx.x*blockDim.x+threadIdx.x;
  if (n>=N) return;
  float c = (float)(deg[n]-1);
  float inv = (c>0.f) ? 1.0f/c : 0.0f;
  escore[E+n]        = ssum[n]*inv;
  escore[EN+E+n]     = ssum[N+n]*inv;
  escore[2*EN+E+n]   = ssum[2*N+n]*inv;
}

// ---- hierarchical scan of deg -> off (exclusive), cur copy ----
__global__ void k_bsum(const int* __restrict__ deg, int* __restrict__ bsum, int N){
  int i = blockIdx.x*256 + threadIdx.x;
  int v = (i<N) ? deg[i] : 0;
  #pragma unroll
  for(int d=32; d; d>>=1) v += __shfl_xor(v, d);
  __shared__ int sh[4];
  if ((threadIdx.x&63)==0) sh[threadIdx.x>>6] = v;
  __syncthreads();
  if (threadIdx.x==0) bsum[blockIdx.x] = sh[0]+sh[1]+sh[2]+sh[3];
}

__global__ void k_bscan(const int* __restrict__ bsum, int* __restrict__ boff, int NB,
                        int* __restrict__ offN, int EN){
  __shared__ int sh[1024];
  int tid = threadIdx.x;
  int v = (tid<NB) ? bsum[tid] : 0;
  sh[tid] = v;
  __syncthreads();
  for(int d=1; d<1024; d<<=1){
    int t = 0;
    if (tid>=d) t = sh[tid-d];
    __syncthreads();
    if (tid>=d) sh[tid] += t;
    __syncthreads();
  }
  if (tid<NB) boff[tid] = sh[tid] - v;  // exclusive
  if (tid==0) offN[0] = EN;
}

__global__ void k_scan_fin(const int* __restrict__ deg, const int* __restrict__ boff,
                           int* __restrict__ off, int* __restrict__ cur, int N){
  __shared__ int sh[256];
  int i = blockIdx.x*256 + threadIdx.x;
  int v = (i<N) ? deg[i] : 0;
  sh[threadIdx.x] = v;
  __syncthreads();
  for(int d=1; d<256; d<<=1){
    int t = 0;
    if (threadIdx.x>=d) t = sh[threadIdx.x-d];
    __syncthreads();
    if (threadIdx.x>=d) sh[threadIdx.x] += t;
    __syncthreads();
  }
  if (i<N){
    int e = boff[blockIdx.x] + sh[threadIdx.x] - v;
    off[i] = e; cur[i] = e;
  }
}

// scatter edges into CSR order, materializing src and per-layer scores (kills eid indirection)
__global__ void k_fill(const int* __restrict__ src, const int* __restrict__ dst,
                       const float* __restrict__ escore, int* __restrict__ cur,
                       int* __restrict__ srcp, float* __restrict__ esc_csr,
                       int E, int EN, int N){
  int e = blockIdx.x*blockDim.x+threadIdx.x;
  if (e>=EN) return;
  int s, d;
  if (e<E){ s=src[e]; d=dst[e]; } else { s=e-E; d=e-E; }
  int p = atomicAdd(&cur[d],1);
  srcp[p] = s;
  esc_csr[p]        = escore[e];
  esc_csr[EN+p]     = escore[EN+e];
  esc_csr[2*EN+p]   = escore[2*EN+e];
}

// stage 64-node x 64-feature tile into sA (padded rows), 512 threads
__device__ __forceinline__ void stage_tile512(const float* __restrict__ src, float* sA,
                                              int n0, int N, int tid){
  const float4* s4 = (const float4*)src;
  float4* dA = (float4*)sA;
  #pragma unroll
  for(int r=0;r<2;r++){
    int q = tid + 512*r;              // 0..1023
    int row = q>>4, col = q&15;
    int gn = n0+row; if (gn>N-1) gn=N-1;
    dA[row*LDW4+col] = s4[(size_t)gn*16+col];
  }
}

// stage 96 weight rows (row-major [96][64]) into sW, 512 threads
__device__ __forceinline__ void stage_w512(const float* __restrict__ Wsrc, float* sW, int tid){
  const float4* ws = (const float4*)Wsrc;
  float4* dW = (float4*)sW;
  #pragma unroll
  for (int r=0;r<3;r++){
    int q = tid + 512*r;                    // 0..1535
    dW[(q>>4)*LDW4 + (q&15)] = ws[q];
  }
}

// window rows 0..95: jj 0..3 -> r_[i][jj]; jj 4,5 -> z_[i][jj-4]. Static indices, rolled kq.
__device__ __forceinline__ void mm_A2(const float* sW, const float* sA, int jt, int nt,
                                      float (&r_)[2][4], float (&z_)[2][4]){
  const float4* sW4 = (const float4*)sW;
  const float4* sA4 = (const float4*)sA;
  #pragma unroll 2
  for (int kq=0;kq<16;kq++){
    float4 af[2];
    #pragma unroll
    for (int i=0;i<2;i++) af[i] = sA4[(nt*2+i)*LDW4 + kq];
    #pragma unroll
    for (int jj=0;jj<4;jj++){
      float4 b = sW4[(jt+16*jj)*LDW4 + kq];
      #pragma unroll
      for (int i=0;i<2;i++) r_[i][jj] = fma4_(af[i], b, r_[i][jj]);
    }
    #pragma unroll
    for (int jj=0;jj<2;jj++){
      float4 b = sW4[(jt+16*(4+jj))*LDW4 + kq];
      #pragma unroll
      for (int i=0;i<2;i++) z_[i][jj] = fma4_(af[i], b, z_[i][jj]);
    }
  }
}

// window rows 96..191: jj 0,1 -> z_[i][2+jj]; jj 2..5 -> g4[i][jj-2]. Static indices, rolled kq.
__device__ __forceinline__ void mm_B2(const float* sW, const float* sA, int jt, int nt,
                                      float (&z_)[2][4], float (&g4)[2][4]){
  const float4* sW4 = (const float4*)sW;
  const float4* sA4 = (const float4*)sA;
  #pragma unroll 2
  for (int kq=0;kq<16;kq++){
    float4 af[2];
    #pragma unroll
    for (int i=0;i<2;i++) af[i] = sA4[(nt*2+i)*LDW4 + kq];
    #pragma unroll
    for (int jj=0;jj<2;jj++){
      float4 b = sW4[(jt+16*jj)*LDW4 + kq];
      #pragma unroll
      for (int i=0;i<2;i++) z_[i][2+jj] = fma4_(af[i], b, z_[i][2+jj]);
    }
    #pragma unroll
    for (int jj=0;jj<4;jj++){
      float4 b = sW4[(jt+16*(2+jj))*LDW4 + kq];
      #pragma unroll
      for (int i=0;i<2;i++) g4[i][jj] = fma4_(af[i], b, g4[i][jj]);
    }
  }
}

// fused GRU: block = 64 nodes, 512 threads -> 32 accumulators/thread, no spill.
__global__ void __launch_bounds__(512,4)
k_gru_t(const float* __restrict__ hg, const float* __restrict__ xin, float* __restrict__ xout,
        const float* __restrict__ WihT, const float* __restrict__ WhhT,
        const float* __restrict__ bih, const float* __restrict__ bhh, int N){
  __shared__ float sW[96*LDW];        // 26112 B
  __shared__ float sA[64*LDW];        // 17408 B (hg tile, then xin tile)
  int tid = threadIdx.x;
  int jt = tid & 15, nt = tid >> 4;   // nt 0..31, 2 nodes each
  int n0 = blockIdx.x * 64;

  float r_[2][4], z_[2][4], ni[2][4], nh[2][4];
  #pragma unroll
  for (int i=0;i<2;i++){
    #pragma unroll
    for (int j=0;j<4;j++){ r_[i][j]=0.f; z_[i][j]=0.f; ni[i][j]=0.f; nh[i][j]=0.f; }
  }

  stage_tile512(hg, sA, n0, N, tid);
  stage_w512(WihT, sW, tid);
  __syncthreads();
  mm_A2(sW, sA, jt, nt, r_, z_);       // Wih rows 0..95  (r + z-lo)
  __syncthreads();
  stage_w512(WihT + 96*H_, sW, tid);
  __syncthreads();
  mm_B2(sW, sA, jt, nt, z_, ni);       // Wih rows 96..191 (z-hi + n)
  __syncthreads();                     // done reading hg tile
  stage_tile512(xin, sA, n0, N, tid);
  stage_w512(WhhT, sW, tid);
  __syncthreads();
  mm_A2(sW, sA, jt, nt, r_, z_);       // Whh rows 0..95
  __syncthreads();
  stage_w512(WhhT + 96*H_, sW, tid);
  __syncthreads();
  mm_B2(sW, sA, jt, nt, z_, nh);       // Whh rows 96..191

  // epilogue: gates + blend + relu (sA holds xin tile)
  #pragma unroll
  for (int jj2=0;jj2<4;jj2++){
    int f = jt + 16*jj2;
    float br = bih[f]     + bhh[f];
    float bz = bih[64+f]  + bhh[64+f];
    float bin= bih[128+f], bhn = bhh[128+f];
    #pragma unroll
    for (int i=0;i<2;i++){
      int node = n0 + nt*2 + i;
      if (node < N){
        float r  = sigm_(r_[i][jj2] + br);
        float z  = sigm_(z_[i][jj2] + bz);
        float nn = tanh_(ni[i][jj2] + bin + r*(nh[i][jj2] + bhn));
        float xv = sA[(nt*2+i)*LDW + f];
        xout[(size_t)node*H_ + f] = fmaxf((1.f-z)*nn + z*xv, 0.f);
      }
    }
  }
}

// h = xi @ conv_W[l] (LDS-tiled) + ssc/dsc reductions
__global__ void __launch_bounds__(256,3)
k_linh_t(const float* __restrict__ xi, const float* __restrict__ wT,
         const float* __restrict__ atts, const float* __restrict__ attd,
         float* __restrict__ h, float* __restrict__ ssc, float* __restrict__ dsc, int N){
  __shared__ float sW[64*LDW];          // 17408
  __shared__ float sA[64*LDW];          // 17408
  __shared__ float sred[64][17][2];
  int tid = threadIdx.x;
  int jt = tid & 15, nt = tid >> 4;
  int n0 = blockIdx.x * 64;

  { // stage
    const float4* srcA = (const float4*)xi;
    const float4* srcW = (const float4*)wT;
    float4* dA = (float4*)sA;
    float4* dW = (float4*)sW;
    #pragma unroll
    for (int r = 0; r < 4; r++){
      int q = tid + 256*r;              // 0..1023
      int row = q >> 4, col = q & 15;
      int gn = n0 + row; if (gn > N-1) gn = N-1;
      dA[row*LDW4 + col] = srcA[(size_t)gn*16 + col];
      dW[row*LDW4 + col] = srcW[q];
    }
  }
  __syncthreads();

  float acc[4][4];
  #pragma unroll
  for (int i=0;i<4;i++){
    #pragma unroll
    for (int j=0;j<4;j++) acc[i][j]=0.f;
  }
  const float4* sA4 = (const float4*)sA;
  const float4* sW4 = (const float4*)sW;
  #pragma unroll 2
  for (int kq=0;kq<16;kq++){
    float4 af[4];
    #pragma unroll
    for (int i=0;i<4;i++) af[i] = sA4[(nt*4+i)*LDW4 + kq];
    #pragma unroll
    for (int jj=0;jj<4;jj++){
      float4 b = sW4[(jt+16*jj)*LDW4 + kq];
      #pragma unroll
      for (int i=0;i<4;i++) acc[i][jj] = fma4_(af[i], b, acc[i][jj]);
    }
  }

  float ps[4]={0.f,0.f,0.f,0.f}, pd[4]={0.f,0.f,0.f,0.f};
  #pragma unroll
  for (int jj=0;jj<4;jj++){
    int f = jt + 16*jj;
    float as = atts[f], ad = attd[f];
    #pragma unroll
    for (int i=0;i<4;i++){
      int node = n0 + nt*4 + i;
      float v = acc[i][jj];
      if (node < N) h[(size_t)node*H_ + f] = v;
      ps[i] += v*as; pd[i] += v*ad;
    }
  }
  #pragma unroll
  for (int i=0;i<4;i++){ sred[nt*4+i][jt][0]=ps[i]; sred[nt*4+i][jt][1]=pd[i]; }
  __syncthreads();
  if (tid < 64){
    float s=0.f, d=0.f;
    #pragma unroll
    for (int w=0;w<16;w++){ s += sred[tid][w][0]; d += sred[tid][w][1]; }
    int node = n0 + tid;
    if (node < N){ ssc[node]=s; dsc[node]=d; }
  }
}

// wave per node: segment softmax + weighted aggregation. All index loads sequential;
// only the h-row gather is random. ssc (400KB) is L2-resident.
__global__ void __launch_bounds__(256)
k_gat_w(const float* __restrict__ h, const float* __restrict__ ssc,
        const float* __restrict__ dsc, const float* __restrict__ esc,
        const int* __restrict__ off, const int* __restrict__ srcp,
        const float* __restrict__ bias, float* __restrict__ hgat, int N){
  int w = threadIdx.x >> 6, lane = threadIdx.x & 63;
  int node = blockIdx.x*4 + w;
  if (node >= N) return;
  int e0 = off[node], e1 = off[node+1];
  float dval = dsc[node];
  // pass 1: lane-parallel max over sequential score reads
  float mx = -1e30f;
  for (int p = e0 + lane; p < e1; p += 64){
    float a = ssc[srcp[p]] + dval + esc[p];
    a = (a > 0.f) ? a : SLOPE*a;
    mx = fmaxf(mx, a);
  }
  #pragma unroll
  for (int d=32; d; d>>=1) mx = fmaxf(mx, __shfl_xor(mx, d));
  // pass 2: serial edges (x2 unrolled), lanes = feature dims
  float acc = 0.f, den = 0.f;
  int p = e0;
  for (; p+2 <= e1; p += 2){
    int s0 = srcp[p], s1 = srcp[p+1];
    float a0 = ssc[s0] + dval + esc[p];   a0 = (a0>0.f)?a0:SLOPE*a0;
    float a1 = ssc[s1] + dval + esc[p+1]; a1 = (a1>0.f)?a1:SLOPE*a1;
    float h0 = h[(size_t)s0*H_ + lane];
    float h1 = h[(size_t)s1*H_ + lane];
    float ex0 = __expf(a0-mx), ex1 = __expf(a1-mx);
    den += ex0 + ex1;
    acc = fmaf(ex0, h0, fmaf(ex1, h1, acc));
  }
  if (p < e1){
    int s0 = srcp[p];
    float a0 = ssc[s0] + dval + esc[p]; a0 = (a0>0.f)?a0:SLOPE*a0;
    float ex0 = __expf(a0-mx);
    den += ex0;
    acc = fmaf(ex0, h[(size_t)s0*H_ + lane], acc);
  }
  hgat[(size_t)node*H_ + lane] = fmaxf(acc/den + bias[lane], 0.f);
}

__global__ void k_pool_init(float* __restrict__ out, const float* __restrict__ b_out, int G){
  int g = blockIdx.x*blockDim.x+threadIdx.x;
  if (g<G) out[g] = b_out[0];
}

__global__ void k_pool(const float* __restrict__ xi, const float* __restrict__ wout,
                       const int* __restrict__ batch, float* __restrict__ out, int N){
  int n = blockIdx.x*blockDim.x+threadIdx.x;
  if (n>=N) return;
  float acc=0.f;
  const float4* xr=(const float4*)(xi + (size_t)n*H_);
  #pragma unroll
  for(int q=0;q<H_/4;q++){
    float4 v=xr[q];
    acc += v.x*wout[4*q] + v.y*wout[4*q+1] + v.z*wout[4*q+2] + v.w*wout[4*q+3];
  }
  atomicAdd(&out[batch[n]], acc);
}

extern "C" void kernel_launch(void* const* d_in, const int* in_sizes, int n_in,
                              void* d_out, int out_size, void* d_ws, size_t ws_size,
                              hipStream_t stream){
  const float* x       = (const float*)d_in[0];
  const float* eattr   = (const float*)d_in[1];
  const float* w_node  = (const float*)d_in[2];
  const float* b_node  = (const float*)d_in[3];
  const float* w_edge  = (const float*)d_in[4];
  const float* b_edge  = (const float*)d_in[5];
  const float* conv_W  = (const float*)d_in[6];
  const float* conv_We = (const float*)d_in[7];
  const float* att_s   = (const float*)d_in[8];
  const float* att_d   = (const float*)d_in[9];
  const float* att_e   = (const float*)d_in[10];
  const float* conv_b  = (const float*)d_in[11];
  const float* gWih    = (const float*)d_in[12];
  const float* gWhh    = (const float*)d_in[13];
  const float* gbih    = (const float*)d_in[14];
  const float* gbhh    = (const float*)d_in[15];
  const float* w_out   = (const float*)d_in[16];
  const float* b_out   = (const float*)d_in[17];
  const int*   eidx    = (const int*)d_in[18];
  const int*   batch   = (const int*)d_in[19];
  float* out = (float*)d_out;

  int N = in_sizes[0]/DIN;
  int E = in_sizes[1]/DE;
  int G = out_size;
  int EN = E + N;
  const int* src = eidx;
  const int* dst = eidx + E;

  char* p = (char*)d_ws;
  auto carve = [&](size_t bytes)->void*{ void* r=(void*)p; p += (bytes+255)&~(size_t)255; return r; };
  float* xi0    = (float*)carve((size_t)N*H_*4);
  float* xi1    = (float*)carve((size_t)N*H_*4);
  float* hbuf   = (float*)carve((size_t)N*H_*4);
  float* hgat   = (float*)carve((size_t)N*H_*4);
  float* ssc    = (float*)carve((size_t)N*4);
  float* dsc    = (float*)carve((size_t)N*4);
  float* escore = (float*)carve((size_t)3*EN*4);
  float* esc_csr= (float*)carve((size_t)3*EN*4);
  float* ssum   = (float*)carve((size_t)3*N*4);
  int*   deg    = (int*)carve((size_t)N*4);
  int*   off    = (int*)carve((size_t)(N+1)*4);
  int*   cur    = (int*)carve((size_t)(N+1)*4);
  int*   srcp   = (int*)carve((size_t)EN*4);
  int*   bsum   = (int*)carve((size_t)1024*4);
  int*   boff   = (int*)carve((size_t)1024*4);
  float* wnT    = (float*)carve((size_t)DIN*H_*4);
  float* weT    = (float*)carve((size_t)DE*H_*4);
  float* cWT    = (float*)carve((size_t)3*H_*H_*4);
  float* WihT   = (float*)carve((size_t)3*H_*3*H_*4);
  float* WhhT   = (float*)carve((size_t)3*H_*3*H_*4);
  float* ve     = (float*)carve((size_t)3*H_*4);

  auto cdiv=[](int a,int b){return (a+b-1)/b;};
  int NB = cdiv(N,256);

  k_transpose<<<cdiv(DIN*H_,256),256,0,stream>>>(w_node, wnT, 1, DIN, H_);
  k_transpose<<<cdiv(DE*H_,256),256,0,stream>>>(w_edge, weT, 1, DE, H_);
  k_transpose<<<cdiv(3*H_*H_,256),256,0,stream>>>(conv_W, cWT, 3, H_, H_);
  k_transpose<<<cdiv(3*H_*3*H_,256),256,0,stream>>>(gWih, WihT, 3, H_, 3*H_);
  k_transpose<<<cdiv(3*H_*3*H_,256),256,0,stream>>>(gWhh, WhhT, 3, H_, 3*H_);
  k_ve<<<1,3*H_,0,stream>>>(conv_We, att_e, ve);

  k_init<<<cdiv(N,256),256,0,stream>>>(deg, ssum, N);
  k_node_mlp<<<cdiv(N,256),256,0,stream>>>(x, wnT, b_node, xi0, N);
  k_edge_scores<<<cdiv(E,256),256,0,stream>>>(eattr, weT, b_edge, ve, dst, escore, ssum, deg, E, EN, N);
  k_selfloop<<<cdiv(N,256),256,0,stream>>>(ssum, deg, escore, E, EN, N);
  k_bsum<<<NB,256,0,stream>>>(deg, bsum, N);
  k_bscan<<<1,1024,0,stream>>>(bsum, boff, NB, off+N, EN);
  k_scan_fin<<<NB,256,0,stream>>>(deg, boff, off, cur, N);
  k_fill<<<cdiv(EN,256),256,0,stream>>>(src, dst, escore, cur, srcp, esc_csr, E, EN, N);

  int NB64 = cdiv(N,64);
  int NB4  = cdiv(N,4);
  for (int l=0; l<3; l++){
    const float* xin = (l&1) ? xi1 : xi0;
    float*       xo  = (l&1) ? xi0 : xi1;
    k_linh_t<<<NB64,256,0,stream>>>(xin, cWT + (size_t)l*H_*H_, att_s + l*H_, att_d + l*H_,
                                    hbuf, ssc, dsc, N);
    k_gat_w<<<NB4,256,0,stream>>>(hbuf, ssc, dsc, esc_csr + (size_t)l*EN, off, srcp,
                                  conv_b + l*H_, hgat, N);
    k_gru_t<<<NB64,512,0,stream>>>(hgat, xin, xo, WihT + (size_t)l*192*H_, WhhT + (size_t)l*192*H_,
                                   gbih + l*3*H_, gbhh + l*3*H_, N);
  }

  k_pool_init<<<cdiv(G,256),256,0,stream>>>(out, b_out, G);
  k_pool<<<cdiv(N,256),256,0,stream>>>(xi1, w_out, batch, out, N);
}

// Round 9
// 908.775 us; speedup vs baseline: 19.3497x; 1.1743x over previous
//
#include <hip/hip_runtime.h>
#include <hip/hip_fp16.h>

constexpr int H_  = 64;   // hidden
constexpr int DIN = 32;   // atom feature dim
constexpr int DE  = 16;   // edge feature dim
constexpr int LDW  = 68;  // padded LDS row stride (floats)
constexpr int LDW4 = 17;  // in float4
#define SLOPE 0.2f

__device__ __forceinline__ float sigm_(float x){ return 1.0f/(1.0f+__expf(-x)); }
__device__ __forceinline__ float tanh_(float x){ float e=__expf(2.0f*x); return 1.0f - 2.0f/(e+1.0f); }
__device__ __forceinline__ float fma4_(float4 a, float4 b, float acc){
  return fmaf(a.w,b.w, fmaf(a.z,b.z, fmaf(a.y,b.y, fmaf(a.x,b.x, acc))));
}

// dst[b][c][r] = src[b][r][c]
__global__ void k_transpose(const float* __restrict__ src, float* __restrict__ dst, int B,int R,int C){
  int id = blockIdx.x*blockDim.x+threadIdx.x;
  if (id >= B*R*C) return;
  int rc=R*C, b=id/rc, rem=id-b*rc, r=rem/C, c=rem-r*C;
  dst[b*rc + c*R + r] = src[id];
}

// ve[l][k] = sum_j conv_We[l][k][j] * att_e[l][j]
__global__ void k_ve(const float* __restrict__ We, const float* __restrict__ ae, float* __restrict__ ve){
  int id = blockIdx.x*blockDim.x+threadIdx.x;
  if (id >= 3*H_) return;
  int l=id/H_, k=id-l*H_;
  const float* w = We + (size_t)(l*H_+k)*H_;
  const float* a = ae + l*H_;
  float s=0.f;
  #pragma unroll
  for(int j=0;j<H_;j++) s += w[j]*a[j];
  ve[id]=s;
}

__global__ void k_init(int* __restrict__ deg, int N){
  int n = blockIdx.x*blockDim.x+threadIdx.x;
  if (n>=N) return;
  deg[n]=1;                 // self-loop
}

// xi = relu(x @ w_node + b_node), thread per node, wT transposed [64][32]
__global__ void k_node_mlp(const float* __restrict__ x, const float* __restrict__ wT,
                           const float* __restrict__ b, float* __restrict__ xi, int N){
  int n = blockIdx.x*blockDim.x+threadIdx.x;
  if (n>=N) return;
  float xv[DIN];
  const float4* xr = (const float4*)(x + (size_t)n*DIN);
  #pragma unroll
  for(int q=0;q<DIN/4;q++){ float4 v=xr[q]; xv[4*q]=v.x; xv[4*q+1]=v.y; xv[4*q+2]=v.z; xv[4*q+3]=v.w; }
  for(int j0=0;j0<H_;j0+=4){
    float o[4];
    #pragma unroll
    for(int jj=0;jj<4;jj++){
      int j=j0+jj;
      const float* wr = wT + j*DIN;   // uniform -> s_load
      float acc = b[j];
      #pragma unroll
      for(int k=0;k<DIN;k++) acc += xv[k]*wr[k];
      o[jj] = fmaxf(acc,0.f);
    }
    *(float4*)(xi + (size_t)n*H_ + j0) = make_float4(o[0],o[1],o[2],o[3]);
  }
}

// per-edge: ea = relu(attr@w_edge+b); escore4[e] = (ea.ve0, ea.ve1, ea.ve2, 0); deg histogram
__global__ void k_edge_scores(const float* __restrict__ attr, const float* __restrict__ weT,
                              const float* __restrict__ be, const float* __restrict__ ve,
                              const int* __restrict__ dst, float4* __restrict__ escore4,
                              int* __restrict__ deg, int E){
  int e = blockIdx.x*blockDim.x+threadIdx.x;
  if (e>=E) return;
  float av[DE];
  const float4* ar = (const float4*)(attr + (size_t)e*DE);
  #pragma unroll
  for(int q=0;q<DE/4;q++){ float4 v=ar[q]; av[4*q]=v.x; av[4*q+1]=v.y; av[4*q+2]=v.z; av[4*q+3]=v.w; }
  float s0=0.f,s1=0.f,s2=0.f;
  for(int j=0;j<H_;j++){
    const float* wr = weT + j*DE;     // uniform
    float acc = be[j];
    #pragma unroll
    for(int k=0;k<DE;k++) acc += av[k]*wr[k];
    acc = fmaxf(acc,0.f);
    s0 += acc*ve[j]; s1 += acc*ve[H_+j]; s2 += acc*ve[2*H_+j];
  }
  escore4[e] = make_float4(s0,s1,s2,0.f);
  atomicAdd(&deg[dst[e]], 1);
}

// ---- hierarchical scan of deg -> off (exclusive); cur = off+1 (self-loop slot reserved) ----
__global__ void k_bsum(const int* __restrict__ deg, int* __restrict__ bsum, int N){
  int i = blockIdx.x*256 + threadIdx.x;
  int v = (i<N) ? deg[i] : 0;
  #pragma unroll
  for(int d=32; d; d>>=1) v += __shfl_xor(v, d);
  __shared__ int sh[4];
  if ((threadIdx.x&63)==0) sh[threadIdx.x>>6] = v;
  __syncthreads();
  if (threadIdx.x==0) bsum[blockIdx.x] = sh[0]+sh[1]+sh[2]+sh[3];
}

__global__ void k_bscan(const int* __restrict__ bsum, int* __restrict__ boff, int NB,
                        int* __restrict__ offN, int EN){
  __shared__ int sh[1024];
  int tid = threadIdx.x;
  int v = (tid<NB) ? bsum[tid] : 0;
  sh[tid] = v;
  __syncthreads();
  for(int d=1; d<1024; d<<=1){
    int t = 0;
    if (tid>=d) t = sh[tid-d];
    __syncthreads();
    if (tid>=d) sh[tid] += t;
    __syncthreads();
  }
  if (tid<NB) boff[tid] = sh[tid] - v;  // exclusive
  if (tid==0) offN[0] = EN;
}

__global__ void k_scan_fin(const int* __restrict__ deg, const int* __restrict__ boff,
                           int* __restrict__ off, int* __restrict__ cur, int N){
  __shared__ int sh[256];
  int i = blockIdx.x*256 + threadIdx.x;
  int v = (i<N) ? deg[i] : 0;
  sh[threadIdx.x] = v;
  __syncthreads();
  for(int d=1; d<256; d<<=1){
    int t = 0;
    if (threadIdx.x>=d) t = sh[threadIdx.x-d];
    __syncthreads();
    if (threadIdx.x>=d) sh[threadIdx.x] += t;
    __syncthreads();
  }
  if (i<N){
    int e = boff[blockIdx.x] + sh[threadIdx.x] - v;
    off[i] = e; cur[i] = e+1;          // slot off[i] reserved for self-loop
  }
}

// scatter real edges into CSR order as a single 16B record {s0,s1,s2,src}
__global__ void k_fill(const int* __restrict__ src, const int* __restrict__ dst,
                       const float4* __restrict__ escore4, int* __restrict__ cur,
                       float4* __restrict__ rec, int E){
  int e = blockIdx.x*blockDim.x+threadIdx.x;
  if (e>=E) return;
  float4 r = escore4[e];
  r.w = __int_as_float(src[e]);
  int p = atomicAdd(&cur[dst[e]],1);
  rec[p] = r;
}

// self-loop record at off[n]: mean of the segment's real-edge scores (0 if none), src=n
__global__ void k_selfloop_csr(const int* __restrict__ off, float4* __restrict__ rec, int N){
  int n = blockIdx.x*blockDim.x+threadIdx.x;
  if (n>=N) return;
  int a = off[n]+1, b = off[n+1];
  float s0=0.f,s1=0.f,s2=0.f;
  for (int p=a;p<b;p++){ float4 r=rec[p]; s0+=r.x; s1+=r.y; s2+=r.z; }
  float inv = (b>a) ? 1.0f/(float)(b-a) : 0.0f;
  rec[off[n]] = make_float4(s0*inv, s1*inv, s2*inv, __int_as_float(n));
}

// stage 64-node x 64-feature tile into sA (padded rows), 512 threads
__device__ __forceinline__ void stage_tile512(const float* __restrict__ src, float* sA,
                                              int n0, int N, int tid){
  const float4* s4 = (const float4*)src;
  float4* dA = (float4*)sA;
  #pragma unroll
  for(int r=0;r<2;r++){
    int q = tid + 512*r;              // 0..1023
    int row = q>>4, col = q&15;
    int gn = n0+row; if (gn>N-1) gn=N-1;
    dA[row*LDW4+col] = s4[(size_t)gn*16+col];
  }
}

// stage 96 weight rows (row-major [96][64]) into sW, 512 threads
__device__ __forceinline__ void stage_w512(const float* __restrict__ Wsrc, float* sW, int tid){
  const float4* ws = (const float4*)Wsrc;
  float4* dW = (float4*)sW;
  #pragma unroll
  for (int r=0;r<3;r++){
    int q = tid + 512*r;                    // 0..1535
    dW[(q>>4)*LDW4 + (q&15)] = ws[q];
  }
}

// window rows 0..95: jj 0..3 -> r_[i][jj]; jj 4,5 -> z_[i][jj-4]. Static indices, rolled kq.
__device__ __forceinline__ void mm_A2(const float* sW, const float* sA, int jt, int nt,
                                      float (&r_)[2][4], float (&z_)[2][4]){
  const float4* sW4 = (const float4*)sW;
  const float4* sA4 = (const float4*)sA;
  #pragma unroll 2
  for (int kq=0;kq<16;kq++){
    float4 af[2];
    #pragma unroll
    for (int i=0;i<2;i++) af[i] = sA4[(nt*2+i)*LDW4 + kq];
    #pragma unroll
    for (int jj=0;jj<4;jj++){
      float4 b = sW4[(jt+16*jj)*LDW4 + kq];
      #pragma unroll
      for (int i=0;i<2;i++) r_[i][jj] = fma4_(af[i], b, r_[i][jj]);
    }
    #pragma unroll
    for (int jj=0;jj<2;jj++){
      float4 b = sW4[(jt+16*(4+jj))*LDW4 + kq];
      #pragma unroll
      for (int i=0;i<2;i++) z_[i][jj] = fma4_(af[i], b, z_[i][jj]);
    }
  }
}

// window rows 96..191: jj 0,1 -> z_[i][2+jj]; jj 2..5 -> g4[i][jj-2]. Static indices, rolled kq.
__device__ __forceinline__ void mm_B2(const float* sW, const float* sA, int jt, int nt,
                                      float (&z_)[2][4], float (&g4)[2][4]){
  const float4* sW4 = (const float4*)sW;
  const float4* sA4 = (const float4*)sA;
  #pragma unroll 2
  for (int kq=0;kq<16;kq++){
    float4 af[2];
    #pragma unroll
    for (int i=0;i<2;i++) af[i] = sA4[(nt*2+i)*LDW4 + kq];
    #pragma unroll
    for (int jj=0;jj<2;jj++){
      float4 b = sW4[(jt+16*jj)*LDW4 + kq];
      #pragma unroll
      for (int i=0;i<2;i++) z_[i][2+jj] = fma4_(af[i], b, z_[i][2+jj]);
    }
    #pragma unroll
    for (int jj=0;jj<4;jj++){
      float4 b = sW4[(jt+16*(2+jj))*LDW4 + kq];
      #pragma unroll
      for (int i=0;i<2;i++) g4[i][jj] = fma4_(af[i], b, g4[i][jj]);
    }
  }
}

// fused GRU: block = 64 nodes, 512 threads -> 32 accumulators/thread, no spill.
__global__ void __launch_bounds__(512,4)
k_gru_t(const float* __restrict__ hg, const float* __restrict__ xin, float* __restrict__ xout,
        const float* __restrict__ WihT, const float* __restrict__ WhhT,
        const float* __restrict__ bih, const float* __restrict__ bhh, int N){
  __shared__ float sW[96*LDW];        // 26112 B
  __shared__ float sA[64*LDW];        // 17408 B (hg tile, then xin tile)
  int tid = threadIdx.x;
  int jt = tid & 15, nt = tid >> 4;   // nt 0..31, 2 nodes each
  int n0 = blockIdx.x * 64;

  float r_[2][4], z_[2][4], ni[2][4], nh[2][4];
  #pragma unroll
  for (int i=0;i<2;i++){
    #pragma unroll
    for (int j=0;j<4;j++){ r_[i][j]=0.f; z_[i][j]=0.f; ni[i][j]=0.f; nh[i][j]=0.f; }
  }

  stage_tile512(hg, sA, n0, N, tid);
  stage_w512(WihT, sW, tid);
  __syncthreads();
  mm_A2(sW, sA, jt, nt, r_, z_);       // Wih rows 0..95  (r + z-lo)
  __syncthreads();
  stage_w512(WihT + 96*H_, sW, tid);
  __syncthreads();
  mm_B2(sW, sA, jt, nt, z_, ni);       // Wih rows 96..191 (z-hi + n)
  __syncthreads();                     // done reading hg tile
  stage_tile512(xin, sA, n0, N, tid);
  stage_w512(WhhT, sW, tid);
  __syncthreads();
  mm_A2(sW, sA, jt, nt, r_, z_);       // Whh rows 0..95
  __syncthreads();
  stage_w512(WhhT + 96*H_, sW, tid);
  __syncthreads();
  mm_B2(sW, sA, jt, nt, z_, nh);       // Whh rows 96..191

  // epilogue: gates + blend + relu (sA holds xin tile)
  #pragma unroll
  for (int jj2=0;jj2<4;jj2++){
    int f = jt + 16*jj2;
    float br = bih[f]     + bhh[f];
    float bz = bih[64+f]  + bhh[64+f];
    float bin= bih[128+f], bhn = bhh[128+f];
    #pragma unroll
    for (int i=0;i<2;i++){
      int node = n0 + nt*2 + i;
      if (node < N){
        float r  = sigm_(r_[i][jj2] + br);
        float z  = sigm_(z_[i][jj2] + bz);
        float nn = tanh_(ni[i][jj2] + bin + r*(nh[i][jj2] + bhn));
        float xv = sA[(nt*2+i)*LDW + f];
        xout[(size_t)node*H_ + f] = fmaxf((1.f-z)*nn + z*xv, 0.f);
      }
    }
  }
}

// h16 = fp16(xi @ conv_W[l]) (LDS-tiled) + ssc/dsc reductions
__global__ void __launch_bounds__(256,3)
k_linh_t(const float* __restrict__ xi, const float* __restrict__ wT,
         const float* __restrict__ atts, const float* __restrict__ attd,
         __half* __restrict__ h16, float* __restrict__ ssc, float* __restrict__ dsc, int N){
  __shared__ float sW[64*LDW];          // 17408
  __shared__ float sA[64*LDW];          // 17408
  __shared__ float sred[64][17][2];
  int tid = threadIdx.x;
  int jt = tid & 15, nt = tid >> 4;
  int n0 = blockIdx.x * 64;

  { // stage
    const float4* srcA = (const float4*)xi;
    const float4* srcW = (const float4*)wT;
    float4* dA = (float4*)sA;
    float4* dW = (float4*)sW;
    #pragma unroll
    for (int r = 0; r < 4; r++){
      int q = tid + 256*r;              // 0..1023
      int row = q >> 4, col = q & 15;
      int gn = n0 + row; if (gn > N-1) gn = N-1;
      dA[row*LDW4 + col] = srcA[(size_t)gn*16 + col];
      dW[row*LDW4 + col] = srcW[q];
    }
  }
  __syncthreads();

  float acc[4][4];
  #pragma unroll
  for (int i=0;i<4;i++){
    #pragma unroll
    for (int j=0;j<4;j++) acc[i][j]=0.f;
  }
  const float4* sA4 = (const float4*)sA;
  const float4* sW4 = (const float4*)sW;
  #pragma unroll 2
  for (int kq=0;kq<16;kq++){
    float4 af[4];
    #pragma unroll
    for (int i=0;i<4;i++) af[i] = sA4[(nt*4+i)*LDW4 + kq];
    #pragma unroll
    for (int jj=0;jj<4;jj++){
      float4 b = sW4[(jt+16*jj)*LDW4 + kq];
      #pragma unroll
      for (int i=0;i<4;i++) acc[i][jj] = fma4_(af[i], b, acc[i][jj]);
    }
  }

  float ps[4]={0.f,0.f,0.f,0.f}, pd[4]={0.f,0.f,0.f,0.f};
  #pragma unroll
  for (int jj=0;jj<4;jj++){
    int f = jt + 16*jj;
    float as = atts[f], ad = attd[f];
    #pragma unroll
    for (int i=0;i<4;i++){
      int node = n0 + nt*4 + i;
      float v = acc[i][jj];
      if (node < N) h16[(size_t)node*H_ + f] = __float2half(v);
      ps[i] += v*as; pd[i] += v*ad;
    }
  }
  #pragma unroll
  for (int i=0;i<4;i++){ sred[nt*4+i][jt][0]=ps[i]; sred[nt*4+i][jt][1]=pd[i]; }
  __syncthreads();
  if (tid < 64){
    float s=0.f, d=0.f;
    #pragma unroll
    for (int w=0;w<16;w++){ s += sred[tid][w][0]; d += sred[tid][w][1]; }
    int node = n0 + tid;
    if (node < N){ ssc[node]=s; dsc[node]=d; }
  }
}

// wave per node: segment softmax + weighted aggregation.
// rec[p] = {s0,s1,s2,src}: one sequential 16B load gives score+src; h16 gather = 1 line.
template<int L>
__global__ void __launch_bounds__(256)
k_gat_w(const __half* __restrict__ h16, const float* __restrict__ ssc,
        const float* __restrict__ dsc, const float4* __restrict__ rec,
        const int* __restrict__ off, const float* __restrict__ bias,
        float* __restrict__ hgat, int N){
  int w = threadIdx.x >> 6, lane = threadIdx.x & 63;
  int node = blockIdx.x*4 + w;
  if (node >= N) return;
  int e0 = off[node], e1 = off[node+1];
  float dval = dsc[node];
  // pass 1: lane-parallel max over sequential record reads
  float mx = -1e30f;
  for (int p = e0 + lane; p < e1; p += 64){
    float4 r = rec[p];
    int s = __float_as_int(r.w);
    float sc = (L==0) ? r.x : (L==1) ? r.y : r.z;
    float a = ssc[s] + dval + sc;
    a = (a > 0.f) ? a : SLOPE*a;
    mx = fmaxf(mx, a);
  }
  #pragma unroll
  for (int d=32; d; d>>=1) mx = fmaxf(mx, __shfl_xor(mx, d));
  // pass 2: serial edges (x2 unrolled), lanes = feature dims
  float acc = 0.f, den = 0.f;
  int p = e0;
  for (; p+2 <= e1; p += 2){
    float4 r0 = rec[p], r1 = rec[p+1];
    int s0 = __float_as_int(r0.w), s1 = __float_as_int(r1.w);
    float sc0 = (L==0)?r0.x:(L==1)?r0.y:r0.z;
    float sc1 = (L==0)?r1.x:(L==1)?r1.y:r1.z;
    float a0 = ssc[s0] + dval + sc0; a0 = (a0>0.f)?a0:SLOPE*a0;
    float a1 = ssc[s1] + dval + sc1; a1 = (a1>0.f)?a1:SLOPE*a1;
    float h0 = __half2float(h16[(size_t)s0*H_ + lane]);
    float h1 = __half2float(h16[(size_t)s1*H_ + lane]);
    float ex0 = __expf(a0-mx), ex1 = __expf(a1-mx);
    den += ex0 + ex1;
    acc = fmaf(ex0, h0, fmaf(ex1, h1, acc));
  }
  if (p < e1){
    float4 r0 = rec[p];
    int s0 = __float_as_int(r0.w);
    float sc0 = (L==0)?r0.x:(L==1)?r0.y:r0.z;
    float a0 = ssc[s0] + dval + sc0; a0 = (a0>0.f)?a0:SLOPE*a0;
    float ex0 = __expf(a0-mx);
    den += ex0;
    acc = fmaf(ex0, __half2float(h16[(size_t)s0*H_ + lane]), acc);
  }
  hgat[(size_t)node*H_ + lane] = fmaxf(acc/den + bias[lane], 0.f);
}

__global__ void k_pool_init(float* __restrict__ out, const float* __restrict__ b_out, int G){
  int g = blockIdx.x*blockDim.x+threadIdx.x;
  if (g<G) out[g] = b_out[0];
}

__global__ void k_pool(const float* __restrict__ xi, const float* __restrict__ wout,
                       const int* __restrict__ batch, float* __restrict__ out, int N){
  int n = blockIdx.x*blockDim.x+threadIdx.x;
  if (n>=N) return;
  float acc=0.f;
  const float4* xr=(const float4*)(xi + (size_t)n*H_);
  #pragma unroll
  for(int q=0;q<H_/4;q++){
    float4 v=xr[q];
    acc += v.x*wout[4*q] + v.y*wout[4*q+1] + v.z*wout[4*q+2] + v.w*wout[4*q+3];
  }
  atomicAdd(&out[batch[n]], acc);
}

extern "C" void kernel_launch(void* const* d_in, const int* in_sizes, int n_in,
                              void* d_out, int out_size, void* d_ws, size_t ws_size,
                              hipStream_t stream){
  const float* x       = (const float*)d_in[0];
  const float* eattr   = (const float*)d_in[1];
  const float* w_node  = (const float*)d_in[2];
  const float* b_node  = (const float*)d_in[3];
  const float* w_edge  = (const float*)d_in[4];
  const float* b_edge  = (const float*)d_in[5];
  const float* conv_W  = (const float*)d_in[6];
  const float* conv_We = (const float*)d_in[7];
  const float* att_s   = (const float*)d_in[8];
  const float* att_d   = (const float*)d_in[9];
  const float* att_e   = (const float*)d_in[10];
  const float* conv_b  = (const float*)d_in[11];
  const float* gWih    = (const float*)d_in[12];
  const float* gWhh    = (const float*)d_in[13];
  const float* gbih    = (const float*)d_in[14];
  const float* gbhh    = (const float*)d_in[15];
  const float* w_out   = (const float*)d_in[16];
  const float* b_out   = (const float*)d_in[17];
  const int*   eidx    = (const int*)d_in[18];
  const int*   batch   = (const int*)d_in[19];
  float* out = (float*)d_out;

  int N = in_sizes[0]/DIN;
  int E = in_sizes[1]/DE;
  int G = out_size;
  int EN = E + N;
  const int* src = eidx;
  const int* dst = eidx + E;

  char* p = (char*)d_ws;
  auto carve = [&](size_t bytes)->void*{ void* r=(void*)p; p += (bytes+255)&~(size_t)255; return r; };
  float*  xi0    = (float*)carve((size_t)N*H_*4);
  float*  xi1    = (float*)carve((size_t)N*H_*4);
  __half* h16    = (__half*)carve((size_t)N*H_*2);
  float*  hgat   = (float*)carve((size_t)N*H_*4);
  float*  ssc    = (float*)carve((size_t)N*4);
  float*  dsc    = (float*)carve((size_t)N*4);
  float4* escore4= (float4*)carve((size_t)E*16);
  float4* rec    = (float4*)carve((size_t)EN*16);
  int*    deg    = (int*)carve((size_t)N*4);
  int*    off    = (int*)carve((size_t)(N+1)*4);
  int*    cur    = (int*)carve((size_t)(N+1)*4);
  int*    bsum   = (int*)carve((size_t)1024*4);
  int*    boff   = (int*)carve((size_t)1024*4);
  float*  wnT    = (float*)carve((size_t)DIN*H_*4);
  float*  weT    = (float*)carve((size_t)DE*H_*4);
  float*  cWT    = (float*)carve((size_t)3*H_*H_*4);
  float*  WihT   = (float*)carve((size_t)3*H_*3*H_*4);
  float*  WhhT   = (float*)carve((size_t)3*H_*3*H_*4);
  float*  ve     = (float*)carve((size_t)3*H_*4);

  auto cdiv=[](int a,int b){return (a+b-1)/b;};
  int NB = cdiv(N,256);

  k_transpose<<<cdiv(DIN*H_,256),256,0,stream>>>(w_node, wnT, 1, DIN, H_);
  k_transpose<<<cdiv(DE*H_,256),256,0,stream>>>(w_edge, weT, 1, DE, H_);
  k_transpose<<<cdiv(3*H_*H_,256),256,0,stream>>>(conv_W, cWT, 3, H_, H_);
  k_transpose<<<cdiv(3*H_*3*H_,256),256,0,stream>>>(gWih, WihT, 3, H_, 3*H_);
  k_transpose<<<cdiv(3*H_*3*H_,256),256,0,stream>>>(gWhh, WhhT, 3, H_, 3*H_);
  k_ve<<<1,3*H_,0,stream>>>(conv_We, att_e, ve);

  k_init<<<cdiv(N,256),256,0,stream>>>(deg, N);
  k_node_mlp<<<cdiv(N,256),256,0,stream>>>(x, wnT, b_node, xi0, N);
  k_edge_scores<<<cdiv(E,256),256,0,stream>>>(eattr, weT, b_edge, ve, dst, escore4, deg, E);
  k_bsum<<<NB,256,0,stream>>>(deg, bsum, N);
  k_bscan<<<1,1024,0,stream>>>(bsum, boff, NB, off+N, EN);
  k_scan_fin<<<NB,256,0,stream>>>(deg, boff, off, cur, N);
  k_fill<<<cdiv(E,256),256,0,stream>>>(src, dst, escore4, cur, rec, E);
  k_selfloop_csr<<<cdiv(N,256),256,0,stream>>>(off, rec, N);

  int NB64 = cdiv(N,64);
  int NB4  = cdiv(N,4);
  for (int l=0; l<3; l++){
    const float* xin = (l&1) ? xi1 : xi0;
    float*       xo  = (l&1) ? xi0 : xi1;
    k_linh_t<<<NB64,256,0,stream>>>(xin, cWT + (size_t)l*H_*H_, att_s + l*H_, att_d + l*H_,
                                    h16, ssc, dsc, N);
    if (l==0)      k_gat_w<0><<<NB4,256,0,stream>>>(h16, ssc, dsc, rec, off, conv_b + l*H_, hgat, N);
    else if (l==1) k_gat_w<1><<<NB4,256,0,stream>>>(h16, ssc, dsc, rec, off, conv_b + l*H_, hgat, N);
    else           k_gat_w<2><<<NB4,256,0,stream>>>(h16, ssc, dsc, rec, off, conv_b + l*H_, hgat, N);
    k_gru_t<<<NB64,512,0,stream>>>(hgat, xin, xo, WihT + (size_t)l*192*H_, WhhT + (size_t)l*192*H_,
                                   gbih + l*3*H_, gbhh + l*3*H_, N);
  }

  k_pool_init<<<cdiv(G,256),256,0,stream>>>(out, b_out, G);
  k_pool<<<cdiv(N,256),256,0,stream>>>(xi1, w_out, batch, out, N);
}

// Round 10
// 785.450 us; speedup vs baseline: 22.3878x; 1.1570x over previous
//
#include <hip/hip_runtime.h>
#include <hip/hip_fp16.h>

constexpr int H_  = 64;   // hidden
constexpr int DIN = 32;   // atom feature dim
constexpr int DE  = 16;   // edge feature dim
constexpr int LDW  = 68;  // padded LDS row stride (floats)
constexpr int LDW4 = 17;  // in float4
#define SLOPE 0.2f

__device__ __forceinline__ float sigm_(float x){ return 1.0f/(1.0f+__expf(-x)); }
__device__ __forceinline__ float tanh_(float x){ float e=__expf(2.0f*x); return 1.0f - 2.0f/(e+1.0f); }
__device__ __forceinline__ float fma4_(float4 a, float4 b, float acc){
  return fmaf(a.w,b.w, fmaf(a.z,b.z, fmaf(a.y,b.y, fmaf(a.x,b.x, acc))));
}

// dst[b][c][r] = src[b][r][c]
__global__ void k_transpose(const float* __restrict__ src, float* __restrict__ dst, int B,int R,int C){
  int id = blockIdx.x*blockDim.x+threadIdx.x;
  if (id >= B*R*C) return;
  int rc=R*C, b=id/rc, rem=id-b*rc, r=rem/C, c=rem-r*C;
  dst[b*rc + c*R + r] = src[id];
}

// ve[l][k] = sum_j conv_We[l][k][j] * att_e[l][j]
__global__ void k_ve(const float* __restrict__ We, const float* __restrict__ ae, float* __restrict__ ve){
  int id = blockIdx.x*blockDim.x+threadIdx.x;
  if (id >= 3*H_) return;
  int l=id/H_, k=id-l*H_;
  const float* w = We + (size_t)(l*H_+k)*H_;
  const float* a = ae + l*H_;
  float s=0.f;
  #pragma unroll
  for(int j=0;j<H_;j++) s += w[j]*a[j];
  ve[id]=s;
}

__global__ void k_init(int* __restrict__ deg, int N){
  int n = blockIdx.x*blockDim.x+threadIdx.x;
  if (n>=N) return;
  deg[n]=1;                 // self-loop
}

// xi = relu(x @ w_node + b_node), thread per node, wT transposed [64][32]
__global__ void k_node_mlp(const float* __restrict__ x, const float* __restrict__ wT,
                           const float* __restrict__ b, float* __restrict__ xi, int N){
  int n = blockIdx.x*blockDim.x+threadIdx.x;
  if (n>=N) return;
  float xv[DIN];
  const float4* xr = (const float4*)(x + (size_t)n*DIN);
  #pragma unroll
  for(int q=0;q<DIN/4;q++){ float4 v=xr[q]; xv[4*q]=v.x; xv[4*q+1]=v.y; xv[4*q+2]=v.z; xv[4*q+3]=v.w; }
  for(int j0=0;j0<H_;j0+=4){
    float o[4];
    #pragma unroll
    for(int jj=0;jj<4;jj++){
      int j=j0+jj;
      const float* wr = wT + j*DIN;   // uniform -> s_load
      float acc = b[j];
      #pragma unroll
      for(int k=0;k<DIN;k++) acc += xv[k]*wr[k];
      o[jj] = fmaxf(acc,0.f);
    }
    *(float4*)(xi + (size_t)n*H_ + j0) = make_float4(o[0],o[1],o[2],o[3]);
  }
}

// per-edge: ea = relu(attr@w_edge+b); escore4[e] = (ea.ve0, ea.ve1, ea.ve2, 0); deg histogram
__global__ void k_edge_scores(const float* __restrict__ attr, const float* __restrict__ weT,
                              const float* __restrict__ be, const float* __restrict__ ve,
                              const int* __restrict__ dst, float4* __restrict__ escore4,
                              int* __restrict__ deg, int E){
  int e = blockIdx.x*blockDim.x+threadIdx.x;
  if (e>=E) return;
  float av[DE];
  const float4* ar = (const float4*)(attr + (size_t)e*DE);
  #pragma unroll
  for(int q=0;q<DE/4;q++){ float4 v=ar[q]; av[4*q]=v.x; av[4*q+1]=v.y; av[4*q+2]=v.z; av[4*q+3]=v.w; }
  float s0=0.f,s1=0.f,s2=0.f;
  for(int j=0;j<H_;j++){
    const float* wr = weT + j*DE;     // uniform
    float acc = be[j];
    #pragma unroll
    for(int k=0;k<DE;k++) acc += av[k]*wr[k];
    acc = fmaxf(acc,0.f);
    s0 += acc*ve[j]; s1 += acc*ve[H_+j]; s2 += acc*ve[2*H_+j];
  }
  escore4[e] = make_float4(s0,s1,s2,0.f);
  atomicAdd(&deg[dst[e]], 1);
}

// ---- hierarchical scan of deg -> off (exclusive); cur = off+1 (self-loop slot reserved) ----
__global__ void k_bsum(const int* __restrict__ deg, int* __restrict__ bsum, int N){
  int i = blockIdx.x*256 + threadIdx.x;
  int v = (i<N) ? deg[i] : 0;
  #pragma unroll
  for(int d=32; d; d>>=1) v += __shfl_xor(v, d);
  __shared__ int sh[4];
  if ((threadIdx.x&63)==0) sh[threadIdx.x>>6] = v;
  __syncthreads();
  if (threadIdx.x==0) bsum[blockIdx.x] = sh[0]+sh[1]+sh[2]+sh[3];
}

__global__ void k_bscan(const int* __restrict__ bsum, int* __restrict__ boff, int NB,
                        int* __restrict__ offN, int EN){
  __shared__ int sh[1024];
  int tid = threadIdx.x;
  int v = (tid<NB) ? bsum[tid] : 0;
  sh[tid] = v;
  __syncthreads();
  for(int d=1; d<1024; d<<=1){
    int t = 0;
    if (tid>=d) t = sh[tid-d];
    __syncthreads();
    if (tid>=d) sh[tid] += t;
    __syncthreads();
  }
  if (tid<NB) boff[tid] = sh[tid] - v;  // exclusive
  if (tid==0) offN[0] = EN;
}

__global__ void k_scan_fin(const int* __restrict__ deg, const int* __restrict__ boff,
                           int* __restrict__ off, int* __restrict__ cur, int N){
  __shared__ int sh[256];
  int i = blockIdx.x*256 + threadIdx.x;
  int v = (i<N) ? deg[i] : 0;
  sh[threadIdx.x] = v;
  __syncthreads();
  for(int d=1; d<256; d<<=1){
    int t = 0;
    if (threadIdx.x>=d) t = sh[threadIdx.x-d];
    __syncthreads();
    if (threadIdx.x>=d) sh[threadIdx.x] += t;
    __syncthreads();
  }
  if (i<N){
    int e = boff[blockIdx.x] + sh[threadIdx.x] - v;
    off[i] = e; cur[i] = e+1;          // slot off[i] reserved for self-loop
  }
}

// scatter real edges into CSR order as a single 16B record {s0,s1,s2,src}
__global__ void k_fill(const int* __restrict__ src, const int* __restrict__ dst,
                       const float4* __restrict__ escore4, int* __restrict__ cur,
                       float4* __restrict__ rec, int E){
  int e = blockIdx.x*blockDim.x+threadIdx.x;
  if (e>=E) return;
  float4 r = escore4[e];
  r.w = __int_as_float(src[e]);
  int p = atomicAdd(&cur[dst[e]],1);
  rec[p] = r;
}

// self-loop record at off[n]: mean of the segment's real-edge scores (0 if none), src=n
__global__ void k_selfloop_csr(const int* __restrict__ off, float4* __restrict__ rec, int N){
  int n = blockIdx.x*blockDim.x+threadIdx.x;
  if (n>=N) return;
  int a = off[n]+1, b = off[n+1];
  float s0=0.f,s1=0.f,s2=0.f;
  for (int p=a;p<b;p++){ float4 r=rec[p]; s0+=r.x; s1+=r.y; s2+=r.z; }
  float inv = (b>a) ? 1.0f/(float)(b-a) : 0.0f;
  rec[off[n]] = make_float4(s0*inv, s1*inv, s2*inv, __int_as_float(n));
}

// graph boundaries from sorted batch: gstart[g] = first node of graph g; gstart[G]=N
__global__ void k_gbounds(const int* __restrict__ batch, int* __restrict__ gstart, int N, int G){
  int n = blockIdx.x*blockDim.x+threadIdx.x;
  if (n>=N) return;
  int b = batch[n];
  int bp = (n==0) ? -1 : batch[n-1];
  for (int g=bp+1; g<=b; g++) gstart[g]=n;
  if (n==N-1){ for (int g=b+1; g<=G; g++) gstart[g]=N; }
}

// stage 64-node x 64-feature tile into sA (padded rows), 512 threads
__device__ __forceinline__ void stage_tile512(const float* __restrict__ src, float* sA,
                                              int n0, int N, int tid){
  const float4* s4 = (const float4*)src;
  float4* dA = (float4*)sA;
  #pragma unroll
  for(int r=0;r<2;r++){
    int q = tid + 512*r;              // 0..1023
    int row = q>>4, col = q&15;
    int gn = n0+row; if (gn>N-1) gn=N-1;
    dA[row*LDW4+col] = s4[(size_t)gn*16+col];
  }
}

// stage 96 weight rows (row-major [96][64]) into sW, 512 threads
__device__ __forceinline__ void stage_w512(const float* __restrict__ Wsrc, float* sW, int tid){
  const float4* ws = (const float4*)Wsrc;
  float4* dW = (float4*)sW;
  #pragma unroll
  for (int r=0;r<3;r++){
    int q = tid + 512*r;                    // 0..1535
    dW[(q>>4)*LDW4 + (q&15)] = ws[q];
  }
}

// window rows 0..95: jj 0..3 -> r_[i][jj]; jj 4,5 -> z_[i][jj-4]. Static indices, rolled kq.
__device__ __forceinline__ void mm_A2(const float* sW, const float* sA, int jt, int nt,
                                      float (&r_)[2][4], float (&z_)[2][4]){
  const float4* sW4 = (const float4*)sW;
  const float4* sA4 = (const float4*)sA;
  #pragma unroll 2
  for (int kq=0;kq<16;kq++){
    float4 af[2];
    #pragma unroll
    for (int i=0;i<2;i++) af[i] = sA4[(nt*2+i)*LDW4 + kq];
    #pragma unroll
    for (int jj=0;jj<4;jj++){
      float4 b = sW4[(jt+16*jj)*LDW4 + kq];
      #pragma unroll
      for (int i=0;i<2;i++) r_[i][jj] = fma4_(af[i], b, r_[i][jj]);
    }
    #pragma unroll
    for (int jj=0;jj<2;jj++){
      float4 b = sW4[(jt+16*(4+jj))*LDW4 + kq];
      #pragma unroll
      for (int i=0;i<2;i++) z_[i][jj] = fma4_(af[i], b, z_[i][jj]);
    }
  }
}

// window rows 96..191: jj 0,1 -> z_[i][2+jj]; jj 2..5 -> g4[i][jj-2]. Static indices, rolled kq.
__device__ __forceinline__ void mm_B2(const float* sW, const float* sA, int jt, int nt,
                                      float (&z_)[2][4], float (&g4)[2][4]){
  const float4* sW4 = (const float4*)sW;
  const float4* sA4 = (const float4*)sA;
  #pragma unroll 2
  for (int kq=0;kq<16;kq++){
    float4 af[2];
    #pragma unroll
    for (int i=0;i<2;i++) af[i] = sA4[(nt*2+i)*LDW4 + kq];
    #pragma unroll
    for (int jj=0;jj<2;jj++){
      float4 b = sW4[(jt+16*jj)*LDW4 + kq];
      #pragma unroll
      for (int i=0;i<2;i++) z_[i][2+jj] = fma4_(af[i], b, z_[i][2+jj]);
    }
    #pragma unroll
    for (int jj=0;jj<4;jj++){
      float4 b = sW4[(jt+16*(2+jj))*LDW4 + kq];
      #pragma unroll
      for (int i=0;i<2;i++) g4[i][jj] = fma4_(af[i], b, g4[i][jj]);
    }
  }
}

// fused GRU: block = 64 nodes, 512 threads -> 32 accumulators/thread, no spill.
__global__ void __launch_bounds__(512,4)
k_gru_t(const float* __restrict__ hg, const float* __restrict__ xin, float* __restrict__ xout,
        const float* __restrict__ WihT, const float* __restrict__ WhhT,
        const float* __restrict__ bih, const float* __restrict__ bhh, int N){
  __shared__ float sW[96*LDW];        // 26112 B
  __shared__ float sA[64*LDW];        // 17408 B (hg tile, then xin tile)
  int tid = threadIdx.x;
  int jt = tid & 15, nt = tid >> 4;   // nt 0..31, 2 nodes each
  int n0 = blockIdx.x * 64;

  float r_[2][4], z_[2][4], ni[2][4], nh[2][4];
  #pragma unroll
  for (int i=0;i<2;i++){
    #pragma unroll
    for (int j=0;j<4;j++){ r_[i][j]=0.f; z_[i][j]=0.f; ni[i][j]=0.f; nh[i][j]=0.f; }
  }

  stage_tile512(hg, sA, n0, N, tid);
  stage_w512(WihT, sW, tid);
  __syncthreads();
  mm_A2(sW, sA, jt, nt, r_, z_);       // Wih rows 0..95  (r + z-lo)
  __syncthreads();
  stage_w512(WihT + 96*H_, sW, tid);
  __syncthreads();
  mm_B2(sW, sA, jt, nt, z_, ni);       // Wih rows 96..191 (z-hi + n)
  __syncthreads();                     // done reading hg tile
  stage_tile512(xin, sA, n0, N, tid);
  stage_w512(WhhT, sW, tid);
  __syncthreads();
  mm_A2(sW, sA, jt, nt, r_, z_);       // Whh rows 0..95
  __syncthreads();
  stage_w512(WhhT + 96*H_, sW, tid);
  __syncthreads();
  mm_B2(sW, sA, jt, nt, z_, nh);       // Whh rows 96..191

  // epilogue: gates + blend + relu (sA holds xin tile)
  #pragma unroll
  for (int jj2=0;jj2<4;jj2++){
    int f = jt + 16*jj2;
    float br = bih[f]     + bhh[f];
    float bz = bih[64+f]  + bhh[64+f];
    float bin= bih[128+f], bhn = bhh[128+f];
    #pragma unroll
    for (int i=0;i<2;i++){
      int node = n0 + nt*2 + i;
      if (node < N){
        float r  = sigm_(r_[i][jj2] + br);
        float z  = sigm_(z_[i][jj2] + bz);
        float nn = tanh_(ni[i][jj2] + bin + r*(nh[i][jj2] + bhn));
        float xv = sA[(nt*2+i)*LDW + f];
        xout[(size_t)node*H_ + f] = fmaxf((1.f-z)*nn + z*xv, 0.f);
      }
    }
  }
}

// h16 = fp16(xi @ conv_W[l]) (LDS-tiled) + ssc/dsc reductions
__global__ void __launch_bounds__(256,3)
k_linh_t(const float* __restrict__ xi, const float* __restrict__ wT,
         const float* __restrict__ atts, const float* __restrict__ attd,
         __half* __restrict__ h16, float* __restrict__ ssc, float* __restrict__ dsc, int N){
  __shared__ float sW[64*LDW];          // 17408
  __shared__ float sA[64*LDW];          // 17408
  __shared__ float sred[64][17][2];
  int tid = threadIdx.x;
  int jt = tid & 15, nt = tid >> 4;
  int n0 = blockIdx.x * 64;

  { // stage
    const float4* srcA = (const float4*)xi;
    const float4* srcW = (const float4*)wT;
    float4* dA = (float4*)sA;
    float4* dW = (float4*)sW;
    #pragma unroll
    for (int r = 0; r < 4; r++){
      int q = tid + 256*r;              // 0..1023
      int row = q >> 4, col = q & 15;
      int gn = n0 + row; if (gn > N-1) gn = N-1;
      dA[row*LDW4 + col] = srcA[(size_t)gn*16 + col];
      dW[row*LDW4 + col] = srcW[q];
    }
  }
  __syncthreads();

  float acc[4][4];
  #pragma unroll
  for (int i=0;i<4;i++){
    #pragma unroll
    for (int j=0;j<4;j++) acc[i][j]=0.f;
  }
  const float4* sA4 = (const float4*)sA;
  const float4* sW4 = (const float4*)sW;
  #pragma unroll 2
  for (int kq=0;kq<16;kq++){
    float4 af[4];
    #pragma unroll
    for (int i=0;i<4;i++) af[i] = sA4[(nt*4+i)*LDW4 + kq];
    #pragma unroll
    for (int jj=0;jj<4;jj++){
      float4 b = sW4[(jt+16*jj)*LDW4 + kq];
      #pragma unroll
      for (int i=0;i<4;i++) acc[i][jj] = fma4_(af[i], b, acc[i][jj]);
    }
  }

  float ps[4]={0.f,0.f,0.f,0.f}, pd[4]={0.f,0.f,0.f,0.f};
  #pragma unroll
  for (int jj=0;jj<4;jj++){
    int f = jt + 16*jj;
    float as = atts[f], ad = attd[f];
    #pragma unroll
    for (int i=0;i<4;i++){
      int node = n0 + nt*4 + i;
      float v = acc[i][jj];
      if (node < N) h16[(size_t)node*H_ + f] = __float2half(v);
      ps[i] += v*as; pd[i] += v*ad;
    }
  }
  #pragma unroll
  for (int i=0;i<4;i++){ sred[nt*4+i][jt][0]=ps[i]; sred[nt*4+i][jt][1]=pd[i]; }
  __syncthreads();
  if (tid < 64){
    float s=0.f, d=0.f;
    #pragma unroll
    for (int w=0;w<16;w++){ s += sred[tid][w][0]; d += sred[tid][w][1]; }
    int node = n0 + tid;
    if (node < N){ ssc[node]=s; dsc[node]=d; }
  }
}

// wave per node: segment softmax + weighted aggregation.
// rec[p] = {s0,s1,s2,src}: one sequential 16B load gives score+src; h16 gather = 1 line.
template<int L>
__global__ void __launch_bounds__(256)
k_gat_w(const __half* __restrict__ h16, const float* __restrict__ ssc,
        const float* __restrict__ dsc, const float4* __restrict__ rec,
        const int* __restrict__ off, const float* __restrict__ bias,
        float* __restrict__ hgat, int N){
  int w = threadIdx.x >> 6, lane = threadIdx.x & 63;
  int node = blockIdx.x*4 + w;
  if (node >= N) return;
  int e0 = off[node], e1 = off[node+1];
  float dval = dsc[node];
  // pass 1: lane-parallel max over sequential record reads
  float mx = -1e30f;
  for (int p = e0 + lane; p < e1; p += 64){
    float4 r = rec[p];
    int s = __float_as_int(r.w);
    float sc = (L==0) ? r.x : (L==1) ? r.y : r.z;
    float a = ssc[s] + dval + sc;
    a = (a > 0.f) ? a : SLOPE*a;
    mx = fmaxf(mx, a);
  }
  #pragma unroll
  for (int d=32; d; d>>=1) mx = fmaxf(mx, __shfl_xor(mx, d));
  // pass 2: serial edges (x2 unrolled), lanes = feature dims
  float acc = 0.f, den = 0.f;
  int p = e0;
  for (; p+2 <= e1; p += 2){
    float4 r0 = rec[p], r1 = rec[p+1];
    int s0 = __float_as_int(r0.w), s1 = __float_as_int(r1.w);
    float sc0 = (L==0)?r0.x:(L==1)?r0.y:r0.z;
    float sc1 = (L==0)?r1.x:(L==1)?r1.y:r1.z;
    float a0 = ssc[s0] + dval + sc0; a0 = (a0>0.f)?a0:SLOPE*a0;
    float a1 = ssc[s1] + dval + sc1; a1 = (a1>0.f)?a1:SLOPE*a1;
    float h0 = __half2float(h16[(size_t)s0*H_ + lane]);
    float h1 = __half2float(h16[(size_t)s1*H_ + lane]);
    float ex0 = __expf(a0-mx), ex1 = __expf(a1-mx);
    den += ex0 + ex1;
    acc = fmaf(ex0, h0, fmaf(ex1, h1, acc));
  }
  if (p < e1){
    float4 r0 = rec[p];
    int s0 = __float_as_int(r0.w);
    float sc0 = (L==0)?r0.x:(L==1)?r0.y:r0.z;
    float a0 = ssc[s0] + dval + sc0; a0 = (a0>0.f)?a0:SLOPE*a0;
    float ex0 = __expf(a0-mx);
    den += ex0;
    acc = fmaf(ex0, __half2float(h16[(size_t)s0*H_ + lane]), acc);
  }
  hgat[(size_t)node*H_ + lane] = fmaxf(acc/den + bias[lane], 0.f);
}

// block per graph: zero-atomic pooled output (batch is sorted)
__global__ void __launch_bounds__(256)
k_pool_g(const float* __restrict__ xi, const float* __restrict__ wout,
         const int* __restrict__ gstart, const float* __restrict__ b_out,
         float* __restrict__ out){
  int g = blockIdx.x;
  int a = gstart[g], b = gstart[g+1];
  float acc = 0.f;
  for (int n = a + threadIdx.x; n < b; n += 256){
    const float4* xr = (const float4*)(xi + (size_t)n*H_);
    float s = 0.f;
    #pragma unroll
    for (int q=0;q<H_/4;q++){
      float4 v = xr[q];
      s += v.x*wout[4*q] + v.y*wout[4*q+1] + v.z*wout[4*q+2] + v.w*wout[4*q+3];
    }
    acc += s;
  }
  #pragma unroll
  for (int d=32; d; d>>=1) acc += __shfl_xor(acc, d);
  __shared__ float sh[4];
  if ((threadIdx.x&63)==0) sh[threadIdx.x>>6] = acc;
  __syncthreads();
  if (threadIdx.x==0) out[g] = sh[0]+sh[1]+sh[2]+sh[3] + b_out[0];
}

extern "C" void kernel_launch(void* const* d_in, const int* in_sizes, int n_in,
                              void* d_out, int out_size, void* d_ws, size_t ws_size,
                              hipStream_t stream){
  const float* x       = (const float*)d_in[0];
  const float* eattr   = (const float*)d_in[1];
  const float* w_node  = (const float*)d_in[2];
  const float* b_node  = (const float*)d_in[3];
  const float* w_edge  = (const float*)d_in[4];
  const float* b_edge  = (const float*)d_in[5];
  const float* conv_W  = (const float*)d_in[6];
  const float* conv_We = (const float*)d_in[7];
  const float* att_s   = (const float*)d_in[8];
  const float* att_d   = (const float*)d_in[9];
  const float* att_e   = (const float*)d_in[10];
  const float* conv_b  = (const float*)d_in[11];
  const float* gWih    = (const float*)d_in[12];
  const float* gWhh    = (const float*)d_in[13];
  const float* gbih    = (const float*)d_in[14];
  const float* gbhh    = (const float*)d_in[15];
  const float* w_out   = (const float*)d_in[16];
  const float* b_out   = (const float*)d_in[17];
  const int*   eidx    = (const int*)d_in[18];
  const int*   batch   = (const int*)d_in[19];
  float* out = (float*)d_out;

  int N = in_sizes[0]/DIN;
  int E = in_sizes[1]/DE;
  int G = out_size;
  int EN = E + N;
  const int* src = eidx;
  const int* dst = eidx + E;

  char* p = (char*)d_ws;
  auto carve = [&](size_t bytes)->void*{ void* r=(void*)p; p += (bytes+255)&~(size_t)255; return r; };
  float*  xi0    = (float*)carve((size_t)N*H_*4);
  float*  xi1    = (float*)carve((size_t)N*H_*4);
  __half* h16    = (__half*)carve((size_t)N*H_*2);
  float*  hgat   = (float*)carve((size_t)N*H_*4);
  float*  ssc    = (float*)carve((size_t)N*4);
  float*  dsc    = (float*)carve((size_t)N*4);
  float4* escore4= (float4*)carve((size_t)E*16);
  float4* rec    = (float4*)carve((size_t)EN*16);
  int*    deg    = (int*)carve((size_t)N*4);
  int*    off    = (int*)carve((size_t)(N+1)*4);
  int*    cur    = (int*)carve((size_t)(N+1)*4);
  int*    gstart = (int*)carve((size_t)(G+1)*4);
  int*    bsum   = (int*)carve((size_t)1024*4);
  int*    boff   = (int*)carve((size_t)1024*4);
  float*  wnT    = (float*)carve((size_t)DIN*H_*4);
  float*  weT    = (float*)carve((size_t)DE*H_*4);
  float*  cWT    = (float*)carve((size_t)3*H_*H_*4);
  float*  WihT   = (float*)carve((size_t)3*H_*3*H_*4);
  float*  WhhT   = (float*)carve((size_t)3*H_*3*H_*4);
  float*  ve     = (float*)carve((size_t)3*H_*4);

  auto cdiv=[](int a,int b){return (a+b-1)/b;};
  int NB = cdiv(N,256);

  k_transpose<<<cdiv(DIN*H_,256),256,0,stream>>>(w_node, wnT, 1, DIN, H_);
  k_transpose<<<cdiv(DE*H_,256),256,0,stream>>>(w_edge, weT, 1, DE, H_);
  k_transpose<<<cdiv(3*H_*H_,256),256,0,stream>>>(conv_W, cWT, 3, H_, H_);
  k_transpose<<<cdiv(3*H_*3*H_,256),256,0,stream>>>(gWih, WihT, 3, H_, 3*H_);
  k_transpose<<<cdiv(3*H_*3*H_,256),256,0,stream>>>(gWhh, WhhT, 3, H_, 3*H_);
  k_ve<<<1,3*H_,0,stream>>>(conv_We, att_e, ve);

  k_init<<<cdiv(N,256),256,0,stream>>>(deg, N);
  k_node_mlp<<<cdiv(N,256),256,0,stream>>>(x, wnT, b_node, xi0, N);
  k_edge_scores<<<cdiv(E,256),256,0,stream>>>(eattr, weT, b_edge, ve, dst, escore4, deg, E);
  k_bsum<<<NB,256,0,stream>>>(deg, bsum, N);
  k_bscan<<<1,1024,0,stream>>>(bsum, boff, NB, off+N, EN);
  k_scan_fin<<<NB,256,0,stream>>>(deg, boff, off, cur, N);
  k_fill<<<cdiv(E,256),256,0,stream>>>(src, dst, escore4, cur, rec, E);
  k_selfloop_csr<<<cdiv(N,256),256,0,stream>>>(off, rec, N);
  k_gbounds<<<NB,256,0,stream>>>(batch, gstart, N, G);

  int NB64 = cdiv(N,64);
  int NB4  = cdiv(N,4);
  for (int l=0; l<3; l++){
    const float* xin = (l&1) ? xi1 : xi0;
    float*       xo  = (l&1) ? xi0 : xi1;
    k_linh_t<<<NB64,256,0,stream>>>(xin, cWT + (size_t)l*H_*H_, att_s + l*H_, att_d + l*H_,
                                    h16, ssc, dsc, N);
    if (l==0)      k_gat_w<0><<<NB4,256,0,stream>>>(h16, ssc, dsc, rec, off, conv_b + l*H_, hgat, N);
    else if (l==1) k_gat_w<1><<<NB4,256,0,stream>>>(h16, ssc, dsc, rec, off, conv_b + l*H_, hgat, N);
    else           k_gat_w<2><<<NB4,256,0,stream>>>(h16, ssc, dsc, rec, off, conv_b + l*H_, hgat, N);
    k_gru_t<<<NB64,512,0,stream>>>(hgat, xin, xo, WihT + (size_t)l*192*H_, WhhT + (size_t)l*192*H_,
                                   gbih + l*3*H_, gbhh + l*3*H_, N);
  }

  k_pool_g<<<G,256,0,stream>>>(xi1, w_out, gstart, b_out, out);
}

// Round 11
// 669.433 us; speedup vs baseline: 26.2677x; 1.1733x over previous
//
#include <hip/hip_runtime.h>
#include <hip/hip_fp16.h>

constexpr int H_  = 64;   // hidden
constexpr int DIN = 32;   // atom feature dim
constexpr int DE  = 16;   // edge feature dim
constexpr int LDW  = 68;  // padded LDS row stride (floats)
constexpr int LDW4 = 17;  // in float4
#define SLOPE 0.2f

typedef __attribute__((ext_vector_type(8))) short bf16x8;
typedef __attribute__((ext_vector_type(4))) float f32x4;

__device__ __forceinline__ float sigm_(float x){ return 1.0f/(1.0f+__expf(-x)); }
__device__ __forceinline__ float tanh_(float x){ float e=__expf(2.0f*x); return 1.0f - 2.0f/(e+1.0f); }
__device__ __forceinline__ float fma4_(float4 a, float4 b, float acc){
  return fmaf(a.w,b.w, fmaf(a.z,b.z, fmaf(a.y,b.y, fmaf(a.x,b.x, acc))));
}
__device__ __forceinline__ short f2bf(float f){   // RNE float->bf16
  unsigned u = __float_as_uint(f);
  u += 0x7FFF + ((u>>16)&1);
  return (short)(u>>16);
}

// dst[b][c][r] = src[b][r][c]
__global__ void k_transpose(const float* __restrict__ src, float* __restrict__ dst, int B,int R,int C){
  int id = blockIdx.x*blockDim.x+threadIdx.x;
  if (id >= B*R*C) return;
  int rc=R*C, b=id/rc, rem=id-b*rc, r=rem/C, c=rem-r*C;
  dst[b*rc + c*R + r] = src[id];
}

// dst[b][c][r] = bf16(src[b][r][c])
__global__ void k_transpose_bf16(const float* __restrict__ src, short* __restrict__ dst, int B,int R,int C){
  int id = blockIdx.x*blockDim.x+threadIdx.x;
  if (id >= B*R*C) return;
  int rc=R*C, b=id/rc, rem=id-b*rc, r=rem/C, c=rem-r*C;
  dst[b*rc + c*R + r] = f2bf(src[id]);
}

// ve[l][k] = sum_j conv_We[l][k][j] * att_e[l][j]
__global__ void k_ve(const float* __restrict__ We, const float* __restrict__ ae, float* __restrict__ ve){
  int id = blockIdx.x*blockDim.x+threadIdx.x;
  if (id >= 3*H_) return;
  int l=id/H_, k=id-l*H_;
  const float* w = We + (size_t)(l*H_+k)*H_;
  const float* a = ae + l*H_;
  float s=0.f;
  #pragma unroll
  for(int j=0;j<H_;j++) s += w[j]*a[j];
  ve[id]=s;
}

__global__ void k_init(int* __restrict__ deg, int N){
  int n = blockIdx.x*blockDim.x+threadIdx.x;
  if (n>=N) return;
  deg[n]=1;                 // self-loop
}

// xi = relu(x @ w_node + b_node), thread per node, wT transposed [64][32]
__global__ void k_node_mlp(const float* __restrict__ x, const float* __restrict__ wT,
                           const float* __restrict__ b, float* __restrict__ xi, int N){
  int n = blockIdx.x*blockDim.x+threadIdx.x;
  if (n>=N) return;
  float xv[DIN];
  const float4* xr = (const float4*)(x + (size_t)n*DIN);
  #pragma unroll
  for(int q=0;q<DIN/4;q++){ float4 v=xr[q]; xv[4*q]=v.x; xv[4*q+1]=v.y; xv[4*q+2]=v.z; xv[4*q+3]=v.w; }
  for(int j0=0;j0<H_;j0+=4){
    float o[4];
    #pragma unroll
    for(int jj=0;jj<4;jj++){
      int j=j0+jj;
      const float* wr = wT + j*DIN;   // uniform -> s_load
      float acc = b[j];
      #pragma unroll
      for(int k=0;k<DIN;k++) acc += xv[k]*wr[k];
      o[jj] = fmaxf(acc,0.f);
    }
    *(float4*)(xi + (size_t)n*H_ + j0) = make_float4(o[0],o[1],o[2],o[3]);
  }
}

// per-edge: ea = relu(attr@w_edge+b); escore4[e] = (ea.ve0, ea.ve1, ea.ve2, 0); deg histogram
__global__ void k_edge_scores(const float* __restrict__ attr, const float* __restrict__ weT,
                              const float* __restrict__ be, const float* __restrict__ ve,
                              const int* __restrict__ dst, float4* __restrict__ escore4,
                              int* __restrict__ deg, int E){
  int e = blockIdx.x*blockDim.x+threadIdx.x;
  if (e>=E) return;
  float av[DE];
  const float4* ar = (const float4*)(attr + (size_t)e*DE);
  #pragma unroll
  for(int q=0;q<DE/4;q++){ float4 v=ar[q]; av[4*q]=v.x; av[4*q+1]=v.y; av[4*q+2]=v.z; av[4*q+3]=v.w; }
  float s0=0.f,s1=0.f,s2=0.f;
  for(int j=0;j<H_;j++){
    const float* wr = weT + j*DE;     // uniform
    float acc = be[j];
    #pragma unroll
    for(int k=0;k<DE;k++) acc += av[k]*wr[k];
    acc = fmaxf(acc,0.f);
    s0 += acc*ve[j]; s1 += acc*ve[H_+j]; s2 += acc*ve[2*H_+j];
  }
  escore4[e] = make_float4(s0,s1,s2,0.f);
  atomicAdd(&deg[dst[e]], 1);
}

// ---- hierarchical scan of deg -> off (exclusive); cur = off+1 (self-loop slot reserved) ----
__global__ void k_bsum(const int* __restrict__ deg, int* __restrict__ bsum, int N){
  int i = blockIdx.x*256 + threadIdx.x;
  int v = (i<N) ? deg[i] : 0;
  #pragma unroll
  for(int d=32; d; d>>=1) v += __shfl_xor(v, d);
  __shared__ int sh[4];
  if ((threadIdx.x&63)==0) sh[threadIdx.x>>6] = v;
  __syncthreads();
  if (threadIdx.x==0) bsum[blockIdx.x] = sh[0]+sh[1]+sh[2]+sh[3];
}

__global__ void k_bscan(const int* __restrict__ bsum, int* __restrict__ boff, int NB,
                        int* __restrict__ offN, int EN){
  __shared__ int sh[1024];
  int tid = threadIdx.x;
  int v = (tid<NB) ? bsum[tid] : 0;
  sh[tid] = v;
  __syncthreads();
  for(int d=1; d<1024; d<<=1){
    int t = 0;
    if (tid>=d) t = sh[tid-d];
    __syncthreads();
    if (tid>=d) sh[tid] += t;
    __syncthreads();
  }
  if (tid<NB) boff[tid] = sh[tid] - v;  // exclusive
  if (tid==0) offN[0] = EN;
}

__global__ void k_scan_fin(const int* __restrict__ deg, const int* __restrict__ boff,
                           int* __restrict__ off, int* __restrict__ cur, int N){
  __shared__ int sh[256];
  int i = blockIdx.x*256 + threadIdx.x;
  int v = (i<N) ? deg[i] : 0;
  sh[threadIdx.x] = v;
  __syncthreads();
  for(int d=1; d<256; d<<=1){
    int t = 0;
    if (threadIdx.x>=d) t = sh[threadIdx.x-d];
    __syncthreads();
    if (threadIdx.x>=d) sh[threadIdx.x] += t;
    __syncthreads();
  }
  if (i<N){
    int e = boff[blockIdx.x] + sh[threadIdx.x] - v;
    off[i] = e; cur[i] = e+1;          // slot off[i] reserved for self-loop
  }
}

// scatter real edges into CSR order as a single 16B record {s0,s1,s2,src}
__global__ void k_fill(const int* __restrict__ src, const int* __restrict__ dst,
                       const float4* __restrict__ escore4, int* __restrict__ cur,
                       float4* __restrict__ rec, int E){
  int e = blockIdx.x*blockDim.x+threadIdx.x;
  if (e>=E) return;
  float4 r = escore4[e];
  r.w = __int_as_float(src[e]);
  int p = atomicAdd(&cur[dst[e]],1);
  rec[p] = r;
}

// self-loop record at off[n]: mean of the segment's real-edge scores (0 if none), src=n
__global__ void k_selfloop_csr(const int* __restrict__ off, float4* __restrict__ rec, int N){
  int n = blockIdx.x*blockDim.x+threadIdx.x;
  if (n>=N) return;
  int a = off[n]+1, b = off[n+1];
  float s0=0.f,s1=0.f,s2=0.f;
  for (int p=a;p<b;p++){ float4 r=rec[p]; s0+=r.x; s1+=r.y; s2+=r.z; }
  float inv = (b>a) ? 1.0f/(float)(b-a) : 0.0f;
  rec[off[n]] = make_float4(s0*inv, s1*inv, s2*inv, __int_as_float(n));
}

// graph boundaries from sorted batch: gstart[g] = first node of graph g; gstart[G]=N
__global__ void k_gbounds(const int* __restrict__ batch, int* __restrict__ gstart, int N, int G){
  int n = blockIdx.x*blockDim.x+threadIdx.x;
  if (n>=N) return;
  int b = batch[n];
  int bp = (n==0) ? -1 : batch[n-1];
  for (int g=bp+1; g<=b; g++) gstart[g]=n;
  if (n==N-1){ for (int g=b+1; g<=G; g++) gstart[g]=N; }
}

// MFMA GRU: block = 64 nodes (4 waves x 16-node strip), no LDS.
// D = A(nodes x K) * B(K x outs): A-frag = 8 contiguous k of row (lane&15), k-blk (lane>>4)*8.
// B-frag = 8 contiguous k of W^T row (tile*16 + lane&15). rz-combined accumulators.
__global__ void __launch_bounds__(256,4)
k_gru_m(const short* __restrict__ hg16, const float* __restrict__ xin, float* __restrict__ xout,
        const short* __restrict__ WihT16, const short* __restrict__ WhhT16,
        const float* __restrict__ bih, const float* __restrict__ bhh, int N){
  int lane = threadIdx.x & 63, w = threadIdx.x >> 6;
  int m16 = lane & 15;
  int kb  = lane >> 4;               // k-block 0..3
  int n0 = blockIdx.x*64 + w*16;     // wave's node strip

  // A fragments
  int arow = n0 + m16; if (arow > N-1) arow = N-1;
  const short* hrow = hg16 + (size_t)arow*H_ + kb*8;
  bf16x8 ah0 = *(const bf16x8*)(hrow);
  bf16x8 ah1 = *(const bf16x8*)(hrow + 32);
  const float* xrow = xin + (size_t)arow*H_ + kb*8;
  float4 xa = *(const float4*)(xrow),    xb = *(const float4*)(xrow+4);
  float4 xc = *(const float4*)(xrow+32), xd = *(const float4*)(xrow+36);
  bf16x8 ax0, ax1;
  ax0[0]=f2bf(xa.x); ax0[1]=f2bf(xa.y); ax0[2]=f2bf(xa.z); ax0[3]=f2bf(xa.w);
  ax0[4]=f2bf(xb.x); ax0[5]=f2bf(xb.y); ax0[6]=f2bf(xb.z); ax0[7]=f2bf(xb.w);
  ax1[0]=f2bf(xc.x); ax1[1]=f2bf(xc.y); ax1[2]=f2bf(xc.z); ax1[3]=f2bf(xc.w);
  ax1[4]=f2bf(xd.x); ax1[5]=f2bf(xd.y); ax1[6]=f2bf(xd.z); ax1[7]=f2bf(xd.w);

  f32x4 aR[4], aZ[4], aNi[4], aNh[4];
  #pragma unroll
  for (int t=0;t<4;t++){
    aR[t]=(f32x4){0.f,0.f,0.f,0.f}; aZ[t]=(f32x4){0.f,0.f,0.f,0.f};
    aNi[t]=(f32x4){0.f,0.f,0.f,0.f}; aNh[t]=(f32x4){0.f,0.f,0.f,0.f};
  }

  const short* wi = WihT16 + (size_t)m16*H_ + kb*8;   // + j*H_ selects W^T row j
  const short* wh = WhhT16 + (size_t)m16*H_ + kb*8;
  #pragma unroll
  for (int t=0;t<4;t++){
    bf16x8 b;
    // r gate: rows t*16 (Wih with A=hg, Whh with A=xin -> same acc)
    b = *(const bf16x8*)(wi + (size_t)(t*16)*H_);
    aR[t] = __builtin_amdgcn_mfma_f32_16x16x32_bf16(ah0, b, aR[t], 0,0,0);
    b = *(const bf16x8*)(wi + (size_t)(t*16)*H_ + 32);
    aR[t] = __builtin_amdgcn_mfma_f32_16x16x32_bf16(ah1, b, aR[t], 0,0,0);
    b = *(const bf16x8*)(wh + (size_t)(t*16)*H_);
    aR[t] = __builtin_amdgcn_mfma_f32_16x16x32_bf16(ax0, b, aR[t], 0,0,0);
    b = *(const bf16x8*)(wh + (size_t)(t*16)*H_ + 32);
    aR[t] = __builtin_amdgcn_mfma_f32_16x16x32_bf16(ax1, b, aR[t], 0,0,0);
    // z gate: rows 64 + t*16
    b = *(const bf16x8*)(wi + (size_t)(64+t*16)*H_);
    aZ[t] = __builtin_amdgcn_mfma_f32_16x16x32_bf16(ah0, b, aZ[t], 0,0,0);
    b = *(const bf16x8*)(wi + (size_t)(64+t*16)*H_ + 32);
    aZ[t] = __builtin_amdgcn_mfma_f32_16x16x32_bf16(ah1, b, aZ[t], 0,0,0);
    b = *(const bf16x8*)(wh + (size_t)(64+t*16)*H_);
    aZ[t] = __builtin_amdgcn_mfma_f32_16x16x32_bf16(ax0, b, aZ[t], 0,0,0);
    b = *(const bf16x8*)(wh + (size_t)(64+t*16)*H_ + 32);
    aZ[t] = __builtin_amdgcn_mfma_f32_16x16x32_bf16(ax1, b, aZ[t], 0,0,0);
    // n gate: rows 128 + t*16, Wih(hg) -> aNi ; Whh(xin) -> aNh
    b = *(const bf16x8*)(wi + (size_t)(128+t*16)*H_);
    aNi[t] = __builtin_amdgcn_mfma_f32_16x16x32_bf16(ah0, b, aNi[t], 0,0,0);
    b = *(const bf16x8*)(wi + (size_t)(128+t*16)*H_ + 32);
    aNi[t] = __builtin_amdgcn_mfma_f32_16x16x32_bf16(ah1, b, aNi[t], 0,0,0);
    b = *(const bf16x8*)(wh + (size_t)(128+t*16)*H_);
    aNh[t] = __builtin_amdgcn_mfma_f32_16x16x32_bf16(ax0, b, aNh[t], 0,0,0);
    b = *(const bf16x8*)(wh + (size_t)(128+t*16)*H_ + 32);
    aNh[t] = __builtin_amdgcn_mfma_f32_16x16x32_bf16(ax1, b, aNh[t], 0,0,0);
  }

  // epilogue: D mapping col = lane&15 (=f within tile), row = (lane>>4)*4 + q (=node)
  int mrow = (lane>>4)*4;
  #pragma unroll
  for (int t=0;t<4;t++){
    int f = t*16 + m16;
    float br = bih[f]     + bhh[f];
    float bz = bih[64+f]  + bhh[64+f];
    float bin= bih[128+f], bhn = bhh[128+f];
    #pragma unroll
    for (int q=0;q<4;q++){
      int node = n0 + mrow + q;
      if (node < N){
        float r  = sigm_(aR[t][q] + br);
        float z  = sigm_(aZ[t][q] + bz);
        float nn = tanh_(aNi[t][q] + bin + r*(aNh[t][q] + bhn));
        float xv = xin[(size_t)node*H_ + f];
        xout[(size_t)node*H_ + f] = fmaxf((1.f-z)*nn + z*xv, 0.f);
      }
    }
  }
}

// h16 = fp16(xi @ conv_W[l]) (LDS-tiled) + ssc/dsc reductions
__global__ void __launch_bounds__(256,3)
k_linh_t(const float* __restrict__ xi, const float* __restrict__ wT,
         const float* __restrict__ atts, const float* __restrict__ attd,
         __half* __restrict__ h16, float* __restrict__ ssc, float* __restrict__ dsc, int N){
  __shared__ float sW[64*LDW];          // 17408
  __shared__ float sA[64*LDW];          // 17408
  __shared__ float sred[64][17][2];
  int tid = threadIdx.x;
  int jt = tid & 15, nt = tid >> 4;
  int n0 = blockIdx.x * 64;

  { // stage
    const float4* srcA = (const float4*)xi;
    const float4* srcW = (const float4*)wT;
    float4* dA = (float4*)sA;
    float4* dW = (float4*)sW;
    #pragma unroll
    for (int r = 0; r < 4; r++){
      int q = tid + 256*r;              // 0..1023
      int row = q >> 4, col = q & 15;
      int gn = n0 + row; if (gn > N-1) gn = N-1;
      dA[row*LDW4 + col] = srcA[(size_t)gn*16 + col];
      dW[row*LDW4 + col] = srcW[q];
    }
  }
  __syncthreads();

  float acc[4][4];
  #pragma unroll
  for (int i=0;i<4;i++){
    #pragma unroll
    for (int j=0;j<4;j++) acc[i][j]=0.f;
  }
  const float4* sA4 = (const float4*)sA;
  const float4* sW4 = (const float4*)sW;
  #pragma unroll 2
  for (int kq=0;kq<16;kq++){
    float4 af[4];
    #pragma unroll
    for (int i=0;i<4;i++) af[i] = sA4[(nt*4+i)*LDW4 + kq];
    #pragma unroll
    for (int jj=0;jj<4;jj++){
      float4 b = sW4[(jt+16*jj)*LDW4 + kq];
      #pragma unroll
      for (int i=0;i<4;i++) acc[i][jj] = fma4_(af[i], b, acc[i][jj]);
    }
  }

  float ps[4]={0.f,0.f,0.f,0.f}, pd[4]={0.f,0.f,0.f,0.f};
  #pragma unroll
  for (int jj=0;jj<4;jj++){
    int f = jt + 16*jj;
    float as = atts[f], ad = attd[f];
    #pragma unroll
    for (int i=0;i<4;i++){
      int node = n0 + nt*4 + i;
      float v = acc[i][jj];
      if (node < N) h16[(size_t)node*H_ + f] = __float2half(v);
      ps[i] += v*as; pd[i] += v*ad;
    }
  }
  #pragma unroll
  for (int i=0;i<4;i++){ sred[nt*4+i][jt][0]=ps[i]; sred[nt*4+i][jt][1]=pd[i]; }
  __syncthreads();
  if (tid < 64){
    float s=0.f, d=0.f;
    #pragma unroll
    for (int w=0;w<16;w++){ s += sred[tid][w][0]; d += sred[tid][w][1]; }
    int node = n0 + tid;
    if (node < N){ ssc[node]=s; dsc[node]=d; }
  }
}

// wave per node: segment softmax + weighted aggregation -> bf16 output (GRU GEMM operand).
template<int L>
__global__ void __launch_bounds__(256)
k_gat_w(const __half* __restrict__ h16, const float* __restrict__ ssc,
        const float* __restrict__ dsc, const float4* __restrict__ rec,
        const int* __restrict__ off, const float* __restrict__ bias,
        short* __restrict__ hgat16, int N){
  int w = threadIdx.x >> 6, lane = threadIdx.x & 63;
  int node = blockIdx.x*4 + w;
  if (node >= N) return;
  int e0 = off[node], e1 = off[node+1];
  float dval = dsc[node];
  // pass 1: lane-parallel max over sequential record reads
  float mx = -1e30f;
  for (int p = e0 + lane; p < e1; p += 64){
    float4 r = rec[p];
    int s = __float_as_int(r.w);
    float sc = (L==0) ? r.x : (L==1) ? r.y : r.z;
    float a = ssc[s] + dval + sc;
    a = (a > 0.f) ? a : SLOPE*a;
    mx = fmaxf(mx, a);
  }
  #pragma unroll
  for (int d=32; d; d>>=1) mx = fmaxf(mx, __shfl_xor(mx, d));
  // pass 2: serial edges (x2 unrolled), lanes = feature dims
  float acc = 0.f, den = 0.f;
  int p = e0;
  for (; p+2 <= e1; p += 2){
    float4 r0 = rec[p], r1 = rec[p+1];
    int s0 = __float_as_int(r0.w), s1 = __float_as_int(r1.w);
    float sc0 = (L==0)?r0.x:(L==1)?r0.y:r0.z;
    float sc1 = (L==0)?r1.x:(L==1)?r1.y:r1.z;
    float a0 = ssc[s0] + dval + sc0; a0 = (a0>0.f)?a0:SLOPE*a0;
    float a1 = ssc[s1] + dval + sc1; a1 = (a1>0.f)?a1:SLOPE*a1;
    float h0 = __half2float(h16[(size_t)s0*H_ + lane]);
    float h1 = __half2float(h16[(size_t)s1*H_ + lane]);
    float ex0 = __expf(a0-mx), ex1 = __expf(a1-mx);
    den += ex0 + ex1;
    acc = fmaf(ex0, h0, fmaf(ex1, h1, acc));
  }
  if (p < e1){
    float4 r0 = rec[p];
    int s0 = __float_as_int(r0.w);
    float sc0 = (L==0)?r0.x:(L==1)?r0.y:r0.z;
    float a0 = ssc[s0] + dval + sc0; a0 = (a0>0.f)?a0:SLOPE*a0;
    float ex0 = __expf(a0-mx);
    den += ex0;
    acc = fmaf(ex0, __half2float(h16[(size_t)s0*H_ + lane]), acc);
  }
  hgat16[(size_t)node*H_ + lane] = f2bf(fmaxf(acc/den + bias[lane], 0.f));
}

// block per graph: zero-atomic pooled output (batch is sorted)
__global__ void __launch_bounds__(256)
k_pool_g(const float* __restrict__ xi, const float* __restrict__ wout,
         const int* __restrict__ gstart, const float* __restrict__ b_out,
         float* __restrict__ out){
  int g = blockIdx.x;
  int a = gstart[g], b = gstart[g+1];
  float acc = 0.f;
  for (int n = a + threadIdx.x; n < b; n += 256){
    const float4* xr = (const float4*)(xi + (size_t)n*H_);
    float s = 0.f;
    #pragma unroll
    for (int q=0;q<H_/4;q++){
      float4 v = xr[q];
      s += v.x*wout[4*q] + v.y*wout[4*q+1] + v.z*wout[4*q+2] + v.w*wout[4*q+3];
    }
    acc += s;
  }
  #pragma unroll
  for (int d=32; d; d>>=1) acc += __shfl_xor(acc, d);
  __shared__ float sh[4];
  if ((threadIdx.x&63)==0) sh[threadIdx.x>>6] = acc;
  __syncthreads();
  if (threadIdx.x==0) out[g] = sh[0]+sh[1]+sh[2]+sh[3] + b_out[0];
}

extern "C" void kernel_launch(void* const* d_in, const int* in_sizes, int n_in,
                              void* d_out, int out_size, void* d_ws, size_t ws_size,
                              hipStream_t stream){
  const float* x       = (const float*)d_in[0];
  const float* eattr   = (const float*)d_in[1];
  const float* w_node  = (const float*)d_in[2];
  const float* b_node  = (const float*)d_in[3];
  const float* w_edge  = (const float*)d_in[4];
  const float* b_edge  = (const float*)d_in[5];
  const float* conv_W  = (const float*)d_in[6];
  const float* conv_We = (const float*)d_in[7];
  const float* att_s   = (const float*)d_in[8];
  const float* att_d   = (const float*)d_in[9];
  const float* att_e   = (const float*)d_in[10];
  const float* conv_b  = (const float*)d_in[11];
  const float* gWih    = (const float*)d_in[12];
  const float* gWhh    = (const float*)d_in[13];
  const float* gbih    = (const float*)d_in[14];
  const float* gbhh    = (const float*)d_in[15];
  const float* w_out   = (const float*)d_in[16];
  const float* b_out   = (const float*)d_in[17];
  const int*   eidx    = (const int*)d_in[18];
  const int*   batch   = (const int*)d_in[19];
  float* out = (float*)d_out;

  int N = in_sizes[0]/DIN;
  int E = in_sizes[1]/DE;
  int G = out_size;
  int EN = E + N;
  const int* src = eidx;
  const int* dst = eidx + E;

  char* p = (char*)d_ws;
  auto carve = [&](size_t bytes)->void*{ void* r=(void*)p; p += (bytes+255)&~(size_t)255; return r; };
  float*  xi0    = (float*)carve((size_t)N*H_*4);
  float*  xi1    = (float*)carve((size_t)N*H_*4);
  __half* h16    = (__half*)carve((size_t)N*H_*2);
  short*  hgat16 = (short*)carve((size_t)N*H_*2);
  float*  ssc    = (float*)carve((size_t)N*4);
  float*  dsc    = (float*)carve((size_t)N*4);
  float4* escore4= (float4*)carve((size_t)E*16);
  float4* rec    = (float4*)carve((size_t)EN*16);
  int*    deg    = (int*)carve((size_t)N*4);
  int*    off    = (int*)carve((size_t)(N+1)*4);
  int*    cur    = (int*)carve((size_t)(N+1)*4);
  int*    gstart = (int*)carve((size_t)(G+1)*4);
  int*    bsum   = (int*)carve((size_t)1024*4);
  int*    boff   = (int*)carve((size_t)1024*4);
  float*  wnT    = (float*)carve((size_t)DIN*H_*4);
  float*  weT    = (float*)carve((size_t)DE*H_*4);
  float*  cWT    = (float*)carve((size_t)3*H_*H_*4);
  short*  WihT16 = (short*)carve((size_t)3*192*H_*2);
  short*  WhhT16 = (short*)carve((size_t)3*192*H_*2);
  float*  ve     = (float*)carve((size_t)3*H_*4);

  auto cdiv=[](int a,int b){return (a+b-1)/b;};
  int NB = cdiv(N,256);

  k_transpose<<<cdiv(DIN*H_,256),256,0,stream>>>(w_node, wnT, 1, DIN, H_);
  k_transpose<<<cdiv(DE*H_,256),256,0,stream>>>(w_edge, weT, 1, DE, H_);
  k_transpose<<<cdiv(3*H_*H_,256),256,0,stream>>>(conv_W, cWT, 3, H_, H_);
  k_transpose_bf16<<<cdiv(3*H_*3*H_,256),256,0,stream>>>(gWih, WihT16, 3, H_, 3*H_);
  k_transpose_bf16<<<cdiv(3*H_*3*H_,256),256,0,stream>>>(gWhh, WhhT16, 3, H_, 3*H_);
  k_ve<<<1,3*H_,0,stream>>>(conv_We, att_e, ve);

  k_init<<<cdiv(N,256),256,0,stream>>>(deg, N);
  k_node_mlp<<<cdiv(N,256),256,0,stream>>>(x, wnT, b_node, xi0, N);
  k_edge_scores<<<cdiv(E,256),256,0,stream>>>(eattr, weT, b_edge, ve, dst, escore4, deg, E);
  k_bsum<<<NB,256,0,stream>>>(deg, bsum, N);
  k_bscan<<<1,1024,0,stream>>>(bsum, boff, NB, off+N, EN);
  k_scan_fin<<<NB,256,0,stream>>>(deg, boff, off, cur, N);
  k_fill<<<cdiv(E,256),256,0,stream>>>(src, dst, escore4, cur, rec, E);
  k_selfloop_csr<<<cdiv(N,256),256,0,stream>>>(off, rec, N);
  k_gbounds<<<NB,256,0,stream>>>(batch, gstart, N, G);

  int NB64 = cdiv(N,64);
  int NB4  = cdiv(N,4);
  for (int l=0; l<3; l++){
    const float* xin = (l&1) ? xi1 : xi0;
    float*       xo  = (l&1) ? xi0 : xi1;
    k_linh_t<<<NB64,256,0,stream>>>(xin, cWT + (size_t)l*H_*H_, att_s + l*H_, att_d + l*H_,
                                    h16, ssc, dsc, N);
    if (l==0)      k_gat_w<0><<<NB4,256,0,stream>>>(h16, ssc, dsc, rec, off, conv_b + l*H_, hgat16, N);
    else if (l==1) k_gat_w<1><<<NB4,256,0,stream>>>(h16, ssc, dsc, rec, off, conv_b + l*H_, hgat16, N);
    else           k_gat_w<2><<<NB4,256,0,stream>>>(h16, ssc, dsc, rec, off, conv_b + l*H_, hgat16, N);
    k_gru_m<<<NB64,256,0,stream>>>(hgat16, xin, xo, WihT16 + (size_t)l*192*H_, WhhT16 + (size_t)l*192*H_,
                                   gbih + l*3*H_, gbhh + l*3*H_, N);
  }

  k_pool_g<<<G,256,0,stream>>>(xi1, w_out, gstart, b_out, out);
}

// Round 12
// 578.235 us; speedup vs baseline: 30.4106x; 1.1577x over previous
//
#include <hip/hip_runtime.h>
#include <hip/hip_fp16.h>

constexpr int H_  = 64;   // hidden
constexpr int DIN = 32;   // atom feature dim
constexpr int DE  = 16;   // edge feature dim
#define SLOPE 0.2f

typedef __attribute__((ext_vector_type(8))) short bf16x8;
typedef __attribute__((ext_vector_type(4))) float f32x4;

__device__ __forceinline__ float sigm_(float x){ return 1.0f/(1.0f+__expf(-x)); }
__device__ __forceinline__ float tanh_(float x){ float e=__expf(2.0f*x); return 1.0f - 2.0f/(e+1.0f); }
__device__ __forceinline__ short f2bf(float f){   // RNE float->bf16
  unsigned u = __float_as_uint(f);
  u += 0x7FFF + ((u>>16)&1);
  return (short)(u>>16);
}

// dst[b][c][r] = src[b][r][c]
__global__ void k_transpose(const float* __restrict__ src, float* __restrict__ dst, int B,int R,int C){
  int id = blockIdx.x*blockDim.x+threadIdx.x;
  if (id >= B*R*C) return;
  int rc=R*C, b=id/rc, rem=id-b*rc, r=rem/C, c=rem-r*C;
  dst[b*rc + c*R + r] = src[id];
}

// dst[b][c][r] = bf16(src[b][r][c])
__global__ void k_transpose_bf16(const float* __restrict__ src, short* __restrict__ dst, int B,int R,int C){
  int id = blockIdx.x*blockDim.x+threadIdx.x;
  if (id >= B*R*C) return;
  int rc=R*C, b=id/rc, rem=id-b*rc, r=rem/C, c=rem-r*C;
  dst[b*rc + c*R + r] = f2bf(src[id]);
}

// ve[l][k] = sum_j conv_We[l][k][j] * att_e[l][j]
__global__ void k_ve(const float* __restrict__ We, const float* __restrict__ ae, float* __restrict__ ve){
  int id = blockIdx.x*blockDim.x+threadIdx.x;
  if (id >= 3*H_) return;
  int l=id/H_, k=id-l*H_;
  const float* w = We + (size_t)(l*H_+k)*H_;
  const float* a = ae + l*H_;
  float s=0.f;
  #pragma unroll
  for(int j=0;j<H_;j++) s += w[j]*a[j];
  ve[id]=s;
}

__global__ void k_init(int* __restrict__ deg, int N){
  int n = blockIdx.x*blockDim.x+threadIdx.x;
  if (n>=N) return;
  deg[n]=1;                 // self-loop
}

// xi = relu(x @ w_node + b_node), thread per node, wT transposed [64][32]
__global__ void k_node_mlp(const float* __restrict__ x, const float* __restrict__ wT,
                           const float* __restrict__ b, float* __restrict__ xi, int N){
  int n = blockIdx.x*blockDim.x+threadIdx.x;
  if (n>=N) return;
  float xv[DIN];
  const float4* xr = (const float4*)(x + (size_t)n*DIN);
  #pragma unroll
  for(int q=0;q<DIN/4;q++){ float4 v=xr[q]; xv[4*q]=v.x; xv[4*q+1]=v.y; xv[4*q+2]=v.z; xv[4*q+3]=v.w; }
  for(int j0=0;j0<H_;j0+=4){
    float o[4];
    #pragma unroll
    for(int jj=0;jj<4;jj++){
      int j=j0+jj;
      const float* wr = wT + j*DIN;   // uniform -> s_load
      float acc = b[j];
      #pragma unroll
      for(int k=0;k<DIN;k++) acc += xv[k]*wr[k];
      o[jj] = fmaxf(acc,0.f);
    }
    *(float4*)(xi + (size_t)n*H_ + j0) = make_float4(o[0],o[1],o[2],o[3]);
  }
}

// per-edge: ea = relu(attr@w_edge+b); escore4[e] = (ea.ve0, ea.ve1, ea.ve2, 0); deg histogram
__global__ void k_edge_scores(const float* __restrict__ attr, const float* __restrict__ weT,
                              const float* __restrict__ be, const float* __restrict__ ve,
                              const int* __restrict__ dst, float4* __restrict__ escore4,
                              int* __restrict__ deg, int E){
  int e = blockIdx.x*blockDim.x+threadIdx.x;
  if (e>=E) return;
  float av[DE];
  const float4* ar = (const float4*)(attr + (size_t)e*DE);
  #pragma unroll
  for(int q=0;q<DE/4;q++){ float4 v=ar[q]; av[4*q]=v.x; av[4*q+1]=v.y; av[4*q+2]=v.z; av[4*q+3]=v.w; }
  float s0=0.f,s1=0.f,s2=0.f;
  for(int j=0;j<H_;j++){
    const float* wr = weT + j*DE;     // uniform
    float acc = be[j];
    #pragma unroll
    for(int k=0;k<DE;k++) acc += av[k]*wr[k];
    acc = fmaxf(acc,0.f);
    s0 += acc*ve[j]; s1 += acc*ve[H_+j]; s2 += acc*ve[2*H_+j];
  }
  escore4[e] = make_float4(s0,s1,s2,0.f);
  atomicAdd(&deg[dst[e]], 1);
}

// ---- hierarchical scan of deg -> off (exclusive); cur = off+1 (self-loop slot reserved) ----
__global__ void k_bsum(const int* __restrict__ deg, int* __restrict__ bsum, int N){
  int i = blockIdx.x*256 + threadIdx.x;
  int v = (i<N) ? deg[i] : 0;
  #pragma unroll
  for(int d=32; d; d>>=1) v += __shfl_xor(v, d);
  __shared__ int sh[4];
  if ((threadIdx.x&63)==0) sh[threadIdx.x>>6] = v;
  __syncthreads();
  if (threadIdx.x==0) bsum[blockIdx.x] = sh[0]+sh[1]+sh[2]+sh[3];
}

__global__ void k_bscan(const int* __restrict__ bsum, int* __restrict__ boff, int NB,
                        int* __restrict__ offN, int EN){
  __shared__ int sh[1024];
  int tid = threadIdx.x;
  int v = (tid<NB) ? bsum[tid] : 0;
  sh[tid] = v;
  __syncthreads();
  for(int d=1; d<1024; d<<=1){
    int t = 0;
    if (tid>=d) t = sh[tid-d];
    __syncthreads();
    if (tid>=d) sh[tid] += t;
    __syncthreads();
  }
  if (tid<NB) boff[tid] = sh[tid] - v;  // exclusive
  if (tid==0) offN[0] = EN;
}

__global__ void k_scan_fin(const int* __restrict__ deg, const int* __restrict__ boff,
                           int* __restrict__ off, int* __restrict__ cur, int N){
  __shared__ int sh[256];
  int i = blockIdx.x*256 + threadIdx.x;
  int v = (i<N) ? deg[i] : 0;
  sh[threadIdx.x] = v;
  __syncthreads();
  for(int d=1; d<256; d<<=1){
    int t = 0;
    if (threadIdx.x>=d) t = sh[threadIdx.x-d];
    __syncthreads();
    if (threadIdx.x>=d) sh[threadIdx.x] += t;
    __syncthreads();
  }
  if (i<N){
    int e = boff[blockIdx.x] + sh[threadIdx.x] - v;
    off[i] = e; cur[i] = e+1;          // slot off[i] reserved for self-loop
  }
}

// scatter real edges into CSR order as a single 16B record {s0,s1,s2,src}
__global__ void k_fill(const int* __restrict__ src, const int* __restrict__ dst,
                       const float4* __restrict__ escore4, int* __restrict__ cur,
                       float4* __restrict__ rec, int E){
  int e = blockIdx.x*blockDim.x+threadIdx.x;
  if (e>=E) return;
  float4 r = escore4[e];
  r.w = __int_as_float(src[e]);
  int p = atomicAdd(&cur[dst[e]],1);
  rec[p] = r;
}

// self-loop record at off[n]: mean of the segment's real-edge scores (0 if none), src=n
__global__ void k_selfloop_csr(const int* __restrict__ off, float4* __restrict__ rec, int N){
  int n = blockIdx.x*blockDim.x+threadIdx.x;
  if (n>=N) return;
  int a = off[n]+1, b = off[n+1];
  float s0=0.f,s1=0.f,s2=0.f;
  for (int p=a;p<b;p++){ float4 r=rec[p]; s0+=r.x; s1+=r.y; s2+=r.z; }
  float inv = (b>a) ? 1.0f/(float)(b-a) : 0.0f;
  rec[off[n]] = make_float4(s0*inv, s1*inv, s2*inv, __int_as_float(n));
}

// graph boundaries from sorted batch: gstart[g] = first node of graph g; gstart[G]=N
__global__ void k_gbounds(const int* __restrict__ batch, int* __restrict__ gstart, int N, int G){
  int n = blockIdx.x*blockDim.x+threadIdx.x;
  if (n>=N) return;
  int b = batch[n];
  int bp = (n==0) ? -1 : batch[n-1];
  for (int g=bp+1; g<=b; g++) gstart[g]=n;
  if (n==N-1){ for (int g=b+1; g<=G; g++) gstart[g]=N; }
}

// MFMA GRU: block = 64 nodes (4 waves x 16-node strip), no LDS.
__global__ void __launch_bounds__(256,4)
k_gru_m(const short* __restrict__ hg16, const float* __restrict__ xin, float* __restrict__ xout,
        const short* __restrict__ WihT16, const short* __restrict__ WhhT16,
        const float* __restrict__ bih, const float* __restrict__ bhh, int N){
  int lane = threadIdx.x & 63, w = threadIdx.x >> 6;
  int m16 = lane & 15;
  int kb  = lane >> 4;               // k-block 0..3
  int n0 = blockIdx.x*64 + w*16;     // wave's node strip

  int arow = n0 + m16; if (arow > N-1) arow = N-1;
  const short* hrow = hg16 + (size_t)arow*H_ + kb*8;
  bf16x8 ah0 = *(const bf16x8*)(hrow);
  bf16x8 ah1 = *(const bf16x8*)(hrow + 32);
  const float* xrow = xin + (size_t)arow*H_ + kb*8;
  float4 xa = *(const float4*)(xrow),    xb = *(const float4*)(xrow+4);
  float4 xc = *(const float4*)(xrow+32), xd = *(const float4*)(xrow+36);
  bf16x8 ax0, ax1;
  ax0[0]=f2bf(xa.x); ax0[1]=f2bf(xa.y); ax0[2]=f2bf(xa.z); ax0[3]=f2bf(xa.w);
  ax0[4]=f2bf(xb.x); ax0[5]=f2bf(xb.y); ax0[6]=f2bf(xb.z); ax0[7]=f2bf(xb.w);
  ax1[0]=f2bf(xc.x); ax1[1]=f2bf(xc.y); ax1[2]=f2bf(xc.z); ax1[3]=f2bf(xc.w);
  ax1[4]=f2bf(xd.x); ax1[5]=f2bf(xd.y); ax1[6]=f2bf(xd.z); ax1[7]=f2bf(xd.w);

  f32x4 aR[4], aZ[4], aNi[4], aNh[4];
  #pragma unroll
  for (int t=0;t<4;t++){
    aR[t]=(f32x4){0.f,0.f,0.f,0.f}; aZ[t]=(f32x4){0.f,0.f,0.f,0.f};
    aNi[t]=(f32x4){0.f,0.f,0.f,0.f}; aNh[t]=(f32x4){0.f,0.f,0.f,0.f};
  }

  const short* wi = WihT16 + (size_t)m16*H_ + kb*8;
  const short* wh = WhhT16 + (size_t)m16*H_ + kb*8;
  #pragma unroll
  for (int t=0;t<4;t++){
    bf16x8 b;
    b = *(const bf16x8*)(wi + (size_t)(t*16)*H_);
    aR[t] = __builtin_amdgcn_mfma_f32_16x16x32_bf16(ah0, b, aR[t], 0,0,0);
    b = *(const bf16x8*)(wi + (size_t)(t*16)*H_ + 32);
    aR[t] = __builtin_amdgcn_mfma_f32_16x16x32_bf16(ah1, b, aR[t], 0,0,0);
    b = *(const bf16x8*)(wh + (size_t)(t*16)*H_);
    aR[t] = __builtin_amdgcn_mfma_f32_16x16x32_bf16(ax0, b, aR[t], 0,0,0);
    b = *(const bf16x8*)(wh + (size_t)(t*16)*H_ + 32);
    aR[t] = __builtin_amdgcn_mfma_f32_16x16x32_bf16(ax1, b, aR[t], 0,0,0);
    b = *(const bf16x8*)(wi + (size_t)(64+t*16)*H_);
    aZ[t] = __builtin_amdgcn_mfma_f32_16x16x32_bf16(ah0, b, aZ[t], 0,0,0);
    b = *(const bf16x8*)(wi + (size_t)(64+t*16)*H_ + 32);
    aZ[t] = __builtin_amdgcn_mfma_f32_16x16x32_bf16(ah1, b, aZ[t], 0,0,0);
    b = *(const bf16x8*)(wh + (size_t)(64+t*16)*H_);
    aZ[t] = __builtin_amdgcn_mfma_f32_16x16x32_bf16(ax0, b, aZ[t], 0,0,0);
    b = *(const bf16x8*)(wh + (size_t)(64+t*16)*H_ + 32);
    aZ[t] = __builtin_amdgcn_mfma_f32_16x16x32_bf16(ax1, b, aZ[t], 0,0,0);
    b = *(const bf16x8*)(wi + (size_t)(128+t*16)*H_);
    aNi[t] = __builtin_amdgcn_mfma_f32_16x16x32_bf16(ah0, b, aNi[t], 0,0,0);
    b = *(const bf16x8*)(wi + (size_t)(128+t*16)*H_ + 32);
    aNi[t] = __builtin_amdgcn_mfma_f32_16x16x32_bf16(ah1, b, aNi[t], 0,0,0);
    b = *(const bf16x8*)(wh + (size_t)(128+t*16)*H_);
    aNh[t] = __builtin_amdgcn_mfma_f32_16x16x32_bf16(ax0, b, aNh[t], 0,0,0);
    b = *(const bf16x8*)(wh + (size_t)(128+t*16)*H_ + 32);
    aNh[t] = __builtin_amdgcn_mfma_f32_16x16x32_bf16(ax1, b, aNh[t], 0,0,0);
  }

  int mrow = (lane>>4)*4;
  #pragma unroll
  for (int t=0;t<4;t++){
    int f = t*16 + m16;
    float br = bih[f]     + bhh[f];
    float bz = bih[64+f]  + bhh[64+f];
    float bin= bih[128+f], bhn = bhh[128+f];
    #pragma unroll
    for (int q=0;q<4;q++){
      int node = n0 + mrow + q;
      if (node < N){
        float r  = sigm_(aR[t][q] + br);
        float z  = sigm_(aZ[t][q] + bz);
        float nn = tanh_(aNi[t][q] + bin + r*(aNh[t][q] + bhn));
        float xv = xin[(size_t)node*H_ + f];
        xout[(size_t)node*H_ + f] = fmaxf((1.f-z)*nn + z*xv, 0.f);
      }
    }
  }
}

// MFMA linear-h: h16 = fp16(xi @ conv_W[l]); ssc/dsc via shfl_xor reduce. No LDS.
__global__ void __launch_bounds__(256,4)
k_linh_m(const float* __restrict__ xi, const short* __restrict__ wT16,
         const float* __restrict__ atts, const float* __restrict__ attd,
         __half* __restrict__ h16, float* __restrict__ ssc, float* __restrict__ dsc, int N){
  int lane = threadIdx.x & 63, w = threadIdx.x >> 6;
  int m16 = lane & 15, kb = lane >> 4;
  int n0 = blockIdx.x*64 + w*16;
  int arow = n0 + m16; if (arow > N-1) arow = N-1;
  const float* xrow = xi + (size_t)arow*H_ + kb*8;
  float4 xa = *(const float4*)(xrow),    xb = *(const float4*)(xrow+4);
  float4 xc = *(const float4*)(xrow+32), xd = *(const float4*)(xrow+36);
  bf16x8 ax0, ax1;
  ax0[0]=f2bf(xa.x); ax0[1]=f2bf(xa.y); ax0[2]=f2bf(xa.z); ax0[3]=f2bf(xa.w);
  ax0[4]=f2bf(xb.x); ax0[5]=f2bf(xb.y); ax0[6]=f2bf(xb.z); ax0[7]=f2bf(xb.w);
  ax1[0]=f2bf(xc.x); ax1[1]=f2bf(xc.y); ax1[2]=f2bf(xc.z); ax1[3]=f2bf(xc.w);
  ax1[4]=f2bf(xd.x); ax1[5]=f2bf(xd.y); ax1[6]=f2bf(xd.z); ax1[7]=f2bf(xd.w);

  f32x4 acc[4];
  #pragma unroll
  for (int t=0;t<4;t++) acc[t]=(f32x4){0.f,0.f,0.f,0.f};
  const short* wp = wT16 + (size_t)m16*H_ + kb*8;
  #pragma unroll
  for (int t=0;t<4;t++){
    bf16x8 b0 = *(const bf16x8*)(wp + (size_t)(t*16)*H_);
    acc[t] = __builtin_amdgcn_mfma_f32_16x16x32_bf16(ax0, b0, acc[t], 0,0,0);
    bf16x8 b1 = *(const bf16x8*)(wp + (size_t)(t*16)*H_ + 32);
    acc[t] = __builtin_amdgcn_mfma_f32_16x16x32_bf16(ax1, b1, acc[t], 0,0,0);
  }

  int mrow = (lane>>4)*4;
  float ps[4]={0.f,0.f,0.f,0.f}, pd[4]={0.f,0.f,0.f,0.f};
  #pragma unroll
  for (int t=0;t<4;t++){
    int f = t*16 + m16;
    float as = atts[f], ad = attd[f];
    #pragma unroll
    for (int q=0;q<4;q++){
      int node = n0 + mrow + q;
      float v = acc[t][q];
      if (node < N) h16[(size_t)node*H_ + f] = __float2half(v);
      ps[q] = fmaf(v, as, ps[q]); pd[q] = fmaf(v, ad, pd[q]);
    }
  }
  #pragma unroll
  for (int d=1; d<16; d<<=1){
    #pragma unroll
    for (int q=0;q<4;q++){ ps[q] += __shfl_xor(ps[q], d); pd[q] += __shfl_xor(pd[q], d); }
  }
  if (m16==0){
    #pragma unroll
    for (int q=0;q<4;q++){
      int node = n0 + mrow + q;
      if (node < N){ ssc[node]=ps[q]; dsc[node]=pd[q]; }
    }
  }
}

// wave per node, single pass: lane-parallel score+exp (no max: |a| bounded, fp32-safe),
// readlane broadcast for the serial h-row aggregation. den = shfl_xor reduce at end.
template<int L>
__global__ void __launch_bounds__(256)
k_gat_s(const __half* __restrict__ h16, const float* __restrict__ ssc,
        const float* __restrict__ dsc, const float4* __restrict__ rec,
        const int* __restrict__ off, const float* __restrict__ bias,
        short* __restrict__ hgat16, int N){
  int w = threadIdx.x >> 6, lane = threadIdx.x & 63;
  int node = blockIdx.x*4 + w;
  if (node >= N) return;
  int e0 = off[node], e1 = off[node+1];
  float dval = dsc[node];
  float acc = 0.f, denl = 0.f;
  for (int base = e0; base < e1; base += 64){
    int p = base + lane;
    float ex = 0.f; int s = 0;
    if (p < e1){
      float4 r = rec[p];
      s = __float_as_int(r.w);
      float sc = (L==0) ? r.x : (L==1) ? r.y : r.z;
      float a = ssc[s] + dval + sc;
      a = (a > 0.f) ? a : SLOPE*a;
      ex = __expf(a);
    }
    denl += ex;
    int cnt = e1 - base; if (cnt > 64) cnt = 64;
    int j = 0;
    for (; j+2 <= cnt; j += 2){
      float ex0 = __shfl(ex, j),  ex1 = __shfl(ex, j+1);
      int   s0  = __shfl(s, j),   s1  = __shfl(s, j+1);
      float h0 = __half2float(h16[(size_t)s0*H_ + lane]);
      float h1 = __half2float(h16[(size_t)s1*H_ + lane]);
      acc = fmaf(ex0, h0, fmaf(ex1, h1, acc));
    }
    if (j < cnt){
      float ex0 = __shfl(ex, j);
      int   s0  = __shfl(s, j);
      acc = fmaf(ex0, __half2float(h16[(size_t)s0*H_ + lane]), acc);
    }
  }
  #pragma unroll
  for (int d=32; d; d>>=1) denl += __shfl_xor(denl, d);
  hgat16[(size_t)node*H_ + lane] = f2bf(fmaxf(acc/denl + bias[lane], 0.f));
}

// block per graph: zero-atomic pooled output (batch is sorted)
__global__ void __launch_bounds__(256)
k_pool_g(const float* __restrict__ xi, const float* __restrict__ wout,
         const int* __restrict__ gstart, const float* __restrict__ b_out,
         float* __restrict__ out){
  int g = blockIdx.x;
  int a = gstart[g], b = gstart[g+1];
  float acc = 0.f;
  for (int n = a + threadIdx.x; n < b; n += 256){
    const float4* xr = (const float4*)(xi + (size_t)n*H_);
    float s = 0.f;
    #pragma unroll
    for (int q=0;q<H_/4;q++){
      float4 v = xr[q];
      s += v.x*wout[4*q] + v.y*wout[4*q+1] + v.z*wout[4*q+2] + v.w*wout[4*q+3];
    }
    acc += s;
  }
  #pragma unroll
  for (int d=32; d; d>>=1) acc += __shfl_xor(acc, d);
  __shared__ float sh[4];
  if ((threadIdx.x&63)==0) sh[threadIdx.x>>6] = acc;
  __syncthreads();
  if (threadIdx.x==0) out[g] = sh[0]+sh[1]+sh[2]+sh[3] + b_out[0];
}

extern "C" void kernel_launch(void* const* d_in, const int* in_sizes, int n_in,
                              void* d_out, int out_size, void* d_ws, size_t ws_size,
                              hipStream_t stream){
  const float* x       = (const float*)d_in[0];
  const float* eattr   = (const float*)d_in[1];
  const float* w_node  = (const float*)d_in[2];
  const float* b_node  = (const float*)d_in[3];
  const float* w_edge  = (const float*)d_in[4];
  const float* b_edge  = (const float*)d_in[5];
  const float* conv_W  = (const float*)d_in[6];
  const float* conv_We = (const float*)d_in[7];
  const float* att_s   = (const float*)d_in[8];
  const float* att_d   = (const float*)d_in[9];
  const float* att_e   = (const float*)d_in[10];
  const float* conv_b  = (const float*)d_in[11];
  const float* gWih    = (const float*)d_in[12];
  const float* gWhh    = (const float*)d_in[13];
  const float* gbih    = (const float*)d_in[14];
  const float* gbhh    = (const float*)d_in[15];
  const float* w_out   = (const float*)d_in[16];
  const float* b_out   = (const float*)d_in[17];
  const int*   eidx    = (const int*)d_in[18];
  const int*   batch   = (const int*)d_in[19];
  float* out = (float*)d_out;

  int N = in_sizes[0]/DIN;
  int E = in_sizes[1]/DE;
  int G = out_size;
  int EN = E + N;
  const int* src = eidx;
  const int* dst = eidx + E;

  char* p = (char*)d_ws;
  auto carve = [&](size_t bytes)->void*{ void* r=(void*)p; p += (bytes+255)&~(size_t)255; return r; };
  float*  xi0    = (float*)carve((size_t)N*H_*4);
  float*  xi1    = (float*)carve((size_t)N*H_*4);
  __half* h16    = (__half*)carve((size_t)N*H_*2);
  short*  hgat16 = (short*)carve((size_t)N*H_*2);
  float*  ssc    = (float*)carve((size_t)N*4);
  float*  dsc    = (float*)carve((size_t)N*4);
  float4* escore4= (float4*)carve((size_t)E*16);
  float4* rec    = (float4*)carve((size_t)EN*16);
  int*    deg    = (int*)carve((size_t)N*4);
  int*    off    = (int*)carve((size_t)(N+1)*4);
  int*    cur    = (int*)carve((size_t)(N+1)*4);
  int*    gstart = (int*)carve((size_t)(G+1)*4);
  int*    bsum   = (int*)carve((size_t)1024*4);
  int*    boff   = (int*)carve((size_t)1024*4);
  float*  wnT    = (float*)carve((size_t)DIN*H_*4);
  float*  weT    = (float*)carve((size_t)DE*H_*4);
  short*  cWT16  = (short*)carve((size_t)3*H_*H_*2);
  short*  WihT16 = (short*)carve((size_t)3*192*H_*2);
  short*  WhhT16 = (short*)carve((size_t)3*192*H_*2);
  float*  ve     = (float*)carve((size_t)3*H_*4);

  auto cdiv=[](int a,int b){return (a+b-1)/b;};
  int NB = cdiv(N,256);

  k_transpose<<<cdiv(DIN*H_,256),256,0,stream>>>(w_node, wnT, 1, DIN, H_);
  k_transpose<<<cdiv(DE*H_,256),256,0,stream>>>(w_edge, weT, 1, DE, H_);
  k_transpose_bf16<<<cdiv(3*H_*H_,256),256,0,stream>>>(conv_W, cWT16, 3, H_, H_);
  k_transpose_bf16<<<cdiv(3*H_*3*H_,256),256,0,stream>>>(gWih, WihT16, 3, H_, 3*H_);
  k_transpose_bf16<<<cdiv(3*H_*3*H_,256),256,0,stream>>>(gWhh, WhhT16, 3, H_, 3*H_);
  k_ve<<<1,3*H_,0,stream>>>(conv_We, att_e, ve);

  k_init<<<cdiv(N,256),256,0,stream>>>(deg, N);
  k_node_mlp<<<cdiv(N,256),256,0,stream>>>(x, wnT, b_node, xi0, N);
  k_edge_scores<<<cdiv(E,256),256,0,stream>>>(eattr, weT, b_edge, ve, dst, escore4, deg, E);
  k_bsum<<<NB,256,0,stream>>>(deg, bsum, N);
  k_bscan<<<1,1024,0,stream>>>(bsum, boff, NB, off+N, EN);
  k_scan_fin<<<NB,256,0,stream>>>(deg, boff, off, cur, N);
  k_fill<<<cdiv(E,256),256,0,stream>>>(src, dst, escore4, cur, rec, E);
  k_selfloop_csr<<<cdiv(N,256),256,0,stream>>>(off, rec, N);
  k_gbounds<<<NB,256,0,stream>>>(batch, gstart, N, G);

  int NB64 = cdiv(N,64);
  int NB4  = cdiv(N,4);
  for (int l=0; l<3; l++){
    const float* xin = (l&1) ? xi1 : xi0;
    float*       xo  = (l&1) ? xi0 : xi1;
    k_linh_m<<<NB64,256,0,stream>>>(xin, cWT16 + (size_t)l*H_*H_, att_s + l*H_, att_d + l*H_,
                                    h16, ssc, dsc, N);
    if (l==0)      k_gat_s<0><<<NB4,256,0,stream>>>(h16, ssc, dsc, rec, off, conv_b + l*H_, hgat16, N);
    else if (l==1) k_gat_s<1><<<NB4,256,0,stream>>>(h16, ssc, dsc, rec, off, conv_b + l*H_, hgat16, N);
    else           k_gat_s<2><<<NB4,256,0,stream>>>(h16, ssc, dsc, rec, off, conv_b + l*H_, hgat16, N);
    k_gru_m<<<NB64,256,0,stream>>>(hgat16, xin, xo, WihT16 + (size_t)l*192*H_, WhhT16 + (size_t)l*192*H_,
                                   gbih + l*3*H_, gbhh + l*3*H_, N);
  }

  k_pool_g<<<G,256,0,stream>>>(xi1, w_out, gstart, b_out, out);
}

// Round 13
// 538.608 us; speedup vs baseline: 32.6480x; 1.0736x over previous
//
#include <hip/hip_runtime.h>
#include <hip/hip_fp16.h>

constexpr int H_  = 64;   // hidden
constexpr int DIN = 32;   // atom feature dim
constexpr int DE  = 16;   // edge feature dim
#define SLOPE 0.2f

typedef __attribute__((ext_vector_type(8))) short bf16x8;
typedef __attribute__((ext_vector_type(4))) float f32x4;

__device__ __forceinline__ float sigm_(float x){ return 1.0f/(1.0f+__expf(-x)); }
__device__ __forceinline__ float tanh_(float x){ float e=__expf(2.0f*x); return 1.0f - 2.0f/(e+1.0f); }
__device__ __forceinline__ short f2bf(float f){   // RNE float->bf16
  unsigned u = __float_as_uint(f);
  u += 0x7FFF + ((u>>16)&1);
  return (short)(u>>16);
}

// dst[b][c][r] = bf16(src[b][r][c])
__global__ void k_transpose_bf16(const float* __restrict__ src, short* __restrict__ dst, int B,int R,int C){
  int id = blockIdx.x*blockDim.x+threadIdx.x;
  if (id >= B*R*C) return;
  int rc=R*C, b=id/rc, rem=id-b*rc, r=rem/C, c=rem-r*C;
  dst[b*rc + c*R + r] = f2bf(src[id]);
}

// w_edge [16][64] -> padded bf16 [64 j][32 k] (k>=16 zero)
__global__ void k_wedge_pad(const float* __restrict__ we, short* __restrict__ dst){
  int id = blockIdx.x*blockDim.x+threadIdx.x;
  if (id >= 64*32) return;
  int j = id >> 5, k = id & 31;
  dst[id] = (k < DE) ? f2bf(we[k*64 + j]) : (short)0;
}

// ve[l][k] = sum_j conv_We[l][k][j] * att_e[l][j]
__global__ void k_ve(const float* __restrict__ We, const float* __restrict__ ae, float* __restrict__ ve){
  int id = blockIdx.x*blockDim.x+threadIdx.x;
  if (id >= 3*H_) return;
  int l=id/H_, k=id-l*H_;
  const float* w = We + (size_t)(l*H_+k)*H_;
  const float* a = ae + l*H_;
  float s=0.f;
  #pragma unroll
  for(int j=0;j<H_;j++) s += w[j]*a[j];
  ve[id]=s;
}

__global__ void k_init(int* __restrict__ deg, int N){
  int n = blockIdx.x*blockDim.x+threadIdx.x;
  if (n>=N) return;
  deg[n]=1;                 // self-loop
}

// MFMA node MLP: xi = relu(x @ w_node + b), K=32 exact. No LDS.
__global__ void __launch_bounds__(256,4)
k_nmlp_m(const float* __restrict__ x, const short* __restrict__ wT16,
         const float* __restrict__ b, float* __restrict__ xi, int N){
  int lane = threadIdx.x & 63, w = threadIdx.x >> 6;
  int m16 = lane & 15, kb = lane >> 4;
  int n0 = blockIdx.x*64 + w*16;
  int arow = n0 + m16; if (arow > N-1) arow = N-1;
  const float* xr = x + (size_t)arow*DIN + kb*8;
  float4 a0 = *(const float4*)xr, a1 = *(const float4*)(xr+4);
  bf16x8 af;
  af[0]=f2bf(a0.x); af[1]=f2bf(a0.y); af[2]=f2bf(a0.z); af[3]=f2bf(a0.w);
  af[4]=f2bf(a1.x); af[5]=f2bf(a1.y); af[6]=f2bf(a1.z); af[7]=f2bf(a1.w);
  f32x4 acc[4];
  #pragma unroll
  for (int t=0;t<4;t++) acc[t]=(f32x4){0.f,0.f,0.f,0.f};
  const short* wp = wT16 + (size_t)m16*DIN + kb*8;
  #pragma unroll
  for (int t=0;t<4;t++){
    bf16x8 bb = *(const bf16x8*)(wp + (size_t)(t*16)*DIN);
    acc[t] = __builtin_amdgcn_mfma_f32_16x16x32_bf16(af, bb, acc[t], 0,0,0);
  }
  int mrow = (lane>>4)*4;
  #pragma unroll
  for (int t=0;t<4;t++){
    int f = t*16 + m16;
    float bj = b[f];
    #pragma unroll
    for (int q=0;q<4;q++){
      int node = n0 + mrow + q;
      if (node < N) xi[(size_t)node*H_ + f] = fmaxf(acc[t][q] + bj, 0.f);
    }
  }
}

// MFMA edge scores: 16 edges/wave. ea = relu(attr@w_edge+b) via MFMA (K 16->32 zero-pad),
// then 3 ve-dots reduced across the 16 j-lanes. deg histogram.
__global__ void __launch_bounds__(256,4)
k_edge_m(const float* __restrict__ attr, const short* __restrict__ weT16p,
         const float* __restrict__ be, const float* __restrict__ ve,
         const int* __restrict__ dst, float4* __restrict__ escore4,
         int* __restrict__ deg, int E){
  int lane = threadIdx.x & 63, w = threadIdx.x >> 6;
  int m16 = lane & 15, kb = lane >> 4;
  int e0 = (blockIdx.x*4 + w)*16;
  if (e0 >= E) return;
  bf16x8 af = {0,0,0,0,0,0,0,0};
  if (kb < 2){
    int arow = e0 + m16; if (arow > E-1) arow = E-1;
    const float* ap = attr + (size_t)arow*DE + kb*8;
    float4 a0 = *(const float4*)ap, a1 = *(const float4*)(ap+4);
    af[0]=f2bf(a0.x); af[1]=f2bf(a0.y); af[2]=f2bf(a0.z); af[3]=f2bf(a0.w);
    af[4]=f2bf(a1.x); af[5]=f2bf(a1.y); af[6]=f2bf(a1.z); af[7]=f2bf(a1.w);
  }
  f32x4 acc[4];
  #pragma unroll
  for (int t=0;t<4;t++) acc[t]=(f32x4){0.f,0.f,0.f,0.f};
  const short* wp = weT16p + (size_t)m16*32 + kb*8;
  #pragma unroll
  for (int t=0;t<4;t++){
    bf16x8 bb = *(const bf16x8*)(wp + (size_t)(t*16)*32);
    acc[t] = __builtin_amdgcn_mfma_f32_16x16x32_bf16(af, bb, acc[t], 0,0,0);
  }
  int mrow = (lane>>4)*4;
  float s0[4]={0.f,0.f,0.f,0.f}, s1[4]={0.f,0.f,0.f,0.f}, s2[4]={0.f,0.f,0.f,0.f};
  #pragma unroll
  for (int t=0;t<4;t++){
    int j = t*16 + m16;
    float bj = be[j];
    float v0 = ve[j], v1 = ve[64+j], v2 = ve[128+j];
    #pragma unroll
    for (int q=0;q<4;q++){
      float ea = fmaxf(acc[t][q] + bj, 0.f);
      s0[q] = fmaf(ea, v0, s0[q]);
      s1[q] = fmaf(ea, v1, s1[q]);
      s2[q] = fmaf(ea, v2, s2[q]);
    }
  }
  #pragma unroll
  for (int d=1; d<16; d<<=1){
    #pragma unroll
    for (int q=0;q<4;q++){
      s0[q] += __shfl_xor(s0[q], d);
      s1[q] += __shfl_xor(s1[q], d);
      s2[q] += __shfl_xor(s2[q], d);
    }
  }
  if (m16==0){
    #pragma unroll
    for (int q=0;q<4;q++){
      int e = e0 + mrow + q;
      if (e < E){
        escore4[e] = make_float4(s0[q], s1[q], s2[q], 0.f);
        atomicAdd(&deg[dst[e]], 1);
      }
    }
  }
}

// ---- hierarchical scan of deg -> off (exclusive); cur = off+1 (self-loop slot reserved) ----
__global__ void k_bsum(const int* __restrict__ deg, int* __restrict__ bsum, int N){
  int i = blockIdx.x*256 + threadIdx.x;
  int v = (i<N) ? deg[i] : 0;
  #pragma unroll
  for(int d=32; d; d>>=1) v += __shfl_xor(v, d);
  __shared__ int sh[4];
  if ((threadIdx.x&63)==0) sh[threadIdx.x>>6] = v;
  __syncthreads();
  if (threadIdx.x==0) bsum[blockIdx.x] = sh[0]+sh[1]+sh[2]+sh[3];
}

__global__ void k_bscan(const int* __restrict__ bsum, int* __restrict__ boff, int NB,
                        int* __restrict__ offN, int EN){
  __shared__ int sh[1024];
  int tid = threadIdx.x;
  int v = (tid<NB) ? bsum[tid] : 0;
  sh[tid] = v;
  __syncthreads();
  for(int d=1; d<1024; d<<=1){
    int t = 0;
    if (tid>=d) t = sh[tid-d];
    __syncthreads();
    if (tid>=d) sh[tid] += t;
    __syncthreads();
  }
  if (tid<NB) boff[tid] = sh[tid] - v;  // exclusive
  if (tid==0) offN[0] = EN;
}

__global__ void k_scan_fin(const int* __restrict__ deg, const int* __restrict__ boff,
                           int* __restrict__ off, int* __restrict__ cur, int N){
  __shared__ int sh[256];
  int i = blockIdx.x*256 + threadIdx.x;
  int v = (i<N) ? deg[i] : 0;
  sh[threadIdx.x] = v;
  __syncthreads();
  for(int d=1; d<256; d<<=1){
    int t = 0;
    if (threadIdx.x>=d) t = sh[threadIdx.x-d];
    __syncthreads();
    if (threadIdx.x>=d) sh[threadIdx.x] += t;
    __syncthreads();
  }
  if (i<N){
    int e = boff[blockIdx.x] + sh[threadIdx.x] - v;
    off[i] = e; cur[i] = e+1;          // slot off[i] reserved for self-loop
  }
}

// scatter real edges into CSR order as a single 16B record {s0,s1,s2,src}
__global__ void k_fill(const int* __restrict__ src, const int* __restrict__ dst,
                       const float4* __restrict__ escore4, int* __restrict__ cur,
                       float4* __restrict__ rec, int E){
  int e = blockIdx.x*blockDim.x+threadIdx.x;
  if (e>=E) return;
  float4 r = escore4[e];
  r.w = __int_as_float(src[e]);
  int p = atomicAdd(&cur[dst[e]],1);
  rec[p] = r;
}

// self-loop record at off[n]: mean of the segment's real-edge scores (0 if none), src=n
__global__ void k_selfloop_csr(const int* __restrict__ off, float4* __restrict__ rec, int N){
  int n = blockIdx.x*blockDim.x+threadIdx.x;
  if (n>=N) return;
  int a = off[n]+1, b = off[n+1];
  float s0=0.f,s1=0.f,s2=0.f;
  for (int p=a;p<b;p++){ float4 r=rec[p]; s0+=r.x; s1+=r.y; s2+=r.z; }
  float inv = (b>a) ? 1.0f/(float)(b-a) : 0.0f;
  rec[off[n]] = make_float4(s0*inv, s1*inv, s2*inv, __int_as_float(n));
}

// graph boundaries from sorted batch: gstart[g] = first node of graph g; gstart[G]=N
__global__ void k_gbounds(const int* __restrict__ batch, int* __restrict__ gstart, int N, int G){
  int n = blockIdx.x*blockDim.x+threadIdx.x;
  if (n>=N) return;
  int b = batch[n];
  int bp = (n==0) ? -1 : batch[n-1];
  for (int g=bp+1; g<=b; g++) gstart[g]=n;
  if (n==N-1){ for (int g=b+1; g<=G; g++) gstart[g]=N; }
}

// MFMA GRU: block = 64 nodes (4 waves x 16-node strip), no LDS.
__global__ void __launch_bounds__(256,4)
k_gru_m(const short* __restrict__ hg16, const float* __restrict__ xin, float* __restrict__ xout,
        const short* __restrict__ WihT16, const short* __restrict__ WhhT16,
        const float* __restrict__ bih, const float* __restrict__ bhh, int N){
  int lane = threadIdx.x & 63, w = threadIdx.x >> 6;
  int m16 = lane & 15;
  int kb  = lane >> 4;               // k-block 0..3
  int n0 = blockIdx.x*64 + w*16;     // wave's node strip

  int arow = n0 + m16; if (arow > N-1) arow = N-1;
  const short* hrow = hg16 + (size_t)arow*H_ + kb*8;
  bf16x8 ah0 = *(const bf16x8*)(hrow);
  bf16x8 ah1 = *(const bf16x8*)(hrow + 32);
  const float* xrow = xin + (size_t)arow*H_ + kb*8;
  float4 xa = *(const float4*)(xrow),    xb = *(const float4*)(xrow+4);
  float4 xc = *(const float4*)(xrow+32), xd = *(const float4*)(xrow+36);
  bf16x8 ax0, ax1;
  ax0[0]=f2bf(xa.x); ax0[1]=f2bf(xa.y); ax0[2]=f2bf(xa.z); ax0[3]=f2bf(xa.w);
  ax0[4]=f2bf(xb.x); ax0[5]=f2bf(xb.y); ax0[6]=f2bf(xb.z); ax0[7]=f2bf(xb.w);
  ax1[0]=f2bf(xc.x); ax1[1]=f2bf(xc.y); ax1[2]=f2bf(xc.z); ax1[3]=f2bf(xc.w);
  ax1[4]=f2bf(xd.x); ax1[5]=f2bf(xd.y); ax1[6]=f2bf(xd.z); ax1[7]=f2bf(xd.w);

  f32x4 aR[4], aZ[4], aNi[4], aNh[4];
  #pragma unroll
  for (int t=0;t<4;t++){
    aR[t]=(f32x4){0.f,0.f,0.f,0.f}; aZ[t]=(f32x4){0.f,0.f,0.f,0.f};
    aNi[t]=(f32x4){0.f,0.f,0.f,0.f}; aNh[t]=(f32x4){0.f,0.f,0.f,0.f};
  }

  const short* wi = WihT16 + (size_t)m16*H_ + kb*8;
  const short* wh = WhhT16 + (size_t)m16*H_ + kb*8;
  #pragma unroll
  for (int t=0;t<4;t++){
    bf16x8 b;
    b = *(const bf16x8*)(wi + (size_t)(t*16)*H_);
    aR[t] = __builtin_amdgcn_mfma_f32_16x16x32_bf16(ah0, b, aR[t], 0,0,0);
    b = *(const bf16x8*)(wi + (size_t)(t*16)*H_ + 32);
    aR[t] = __builtin_amdgcn_mfma_f32_16x16x32_bf16(ah1, b, aR[t], 0,0,0);
    b = *(const bf16x8*)(wh + (size_t)(t*16)*H_);
    aR[t] = __builtin_amdgcn_mfma_f32_16x16x32_bf16(ax0, b, aR[t], 0,0,0);
    b = *(const bf16x8*)(wh + (size_t)(t*16)*H_ + 32);
    aR[t] = __builtin_amdgcn_mfma_f32_16x16x32_bf16(ax1, b, aR[t], 0,0,0);
    b = *(const bf16x8*)(wi + (size_t)(64+t*16)*H_);
    aZ[t] = __builtin_amdgcn_mfma_f32_16x16x32_bf16(ah0, b, aZ[t], 0,0,0);
    b = *(const bf16x8*)(wi + (size_t)(64+t*16)*H_ + 32);
    aZ[t] = __builtin_amdgcn_mfma_f32_16x16x32_bf16(ah1, b, aZ[t], 0,0,0);
    b = *(const bf16x8*)(wh + (size_t)(64+t*16)*H_);
    aZ[t] = __builtin_amdgcn_mfma_f32_16x16x32_bf16(ax0, b, aZ[t], 0,0,0);
    b = *(const bf16x8*)(wh + (size_t)(64+t*16)*H_ + 32);
    aZ[t] = __builtin_amdgcn_mfma_f32_16x16x32_bf16(ax1, b, aZ[t], 0,0,0);
    b = *(const bf16x8*)(wi + (size_t)(128+t*16)*H_);
    aNi[t] = __builtin_amdgcn_mfma_f32_16x16x32_bf16(ah0, b, aNi[t], 0,0,0);
    b = *(const bf16x8*)(wi + (size_t)(128+t*16)*H_ + 32);
    aNi[t] = __builtin_amdgcn_mfma_f32_16x16x32_bf16(ah1, b, aNi[t], 0,0,0);
    b = *(const bf16x8*)(wh + (size_t)(128+t*16)*H_);
    aNh[t] = __builtin_amdgcn_mfma_f32_16x16x32_bf16(ax0, b, aNh[t], 0,0,0);
    b = *(const bf16x8*)(wh + (size_t)(128+t*16)*H_ + 32);
    aNh[t] = __builtin_amdgcn_mfma_f32_16x16x32_bf16(ax1, b, aNh[t], 0,0,0);
  }

  int mrow = (lane>>4)*4;
  #pragma unroll
  for (int t=0;t<4;t++){
    int f = t*16 + m16;
    float br = bih[f]     + bhh[f];
    float bz = bih[64+f]  + bhh[64+f];
    float bin= bih[128+f], bhn = bhh[128+f];
    #pragma unroll
    for (int q=0;q<4;q++){
      int node = n0 + mrow + q;
      if (node < N){
        float r  = sigm_(aR[t][q] + br);
        float z  = sigm_(aZ[t][q] + bz);
        float nn = tanh_(aNi[t][q] + bin + r*(aNh[t][q] + bhn));
        float xv = xin[(size_t)node*H_ + f];
        xout[(size_t)node*H_ + f] = fmaxf((1.f-z)*nn + z*xv, 0.f);
      }
    }
  }
}

// MFMA linear-h: h16 = fp16(xi @ conv_W[l]); ssc/dsc via shfl_xor reduce. No LDS.
__global__ void __launch_bounds__(256,4)
k_linh_m(const float* __restrict__ xi, const short* __restrict__ wT16,
         const float* __restrict__ atts, const float* __restrict__ attd,
         __half* __restrict__ h16, float* __restrict__ ssc, float* __restrict__ dsc, int N){
  int lane = threadIdx.x & 63, w = threadIdx.x >> 6;
  int m16 = lane & 15, kb = lane >> 4;
  int n0 = blockIdx.x*64 + w*16;
  int arow = n0 + m16; if (arow > N-1) arow = N-1;
  const float* xrow = xi + (size_t)arow*H_ + kb*8;
  float4 xa = *(const float4*)(xrow),    xb = *(const float4*)(xrow+4);
  float4 xc = *(const float4*)(xrow+32), xd = *(const float4*)(xrow+36);
  bf16x8 ax0, ax1;
  ax0[0]=f2bf(xa.x); ax0[1]=f2bf(xa.y); ax0[2]=f2bf(xa.z); ax0[3]=f2bf(xa.w);
  ax0[4]=f2bf(xb.x); ax0[5]=f2bf(xb.y); ax0[6]=f2bf(xb.z); ax0[7]=f2bf(xb.w);
  ax1[0]=f2bf(xc.x); ax1[1]=f2bf(xc.y); ax1[2]=f2bf(xc.z); ax1[3]=f2bf(xc.w);
  ax1[4]=f2bf(xd.x); ax1[5]=f2bf(xd.y); ax1[6]=f2bf(xd.z); ax1[7]=f2bf(xd.w);

  f32x4 acc[4];
  #pragma unroll
  for (int t=0;t<4;t++) acc[t]=(f32x4){0.f,0.f,0.f,0.f};
  const short* wp = wT16 + (size_t)m16*H_ + kb*8;
  #pragma unroll
  for (int t=0;t<4;t++){
    bf16x8 b0 = *(const bf16x8*)(wp + (size_t)(t*16)*H_);
    acc[t] = __builtin_amdgcn_mfma_f32_16x16x32_bf16(ax0, b0, acc[t], 0,0,0);
    bf16x8 b1 = *(const bf16x8*)(wp + (size_t)(t*16)*H_ + 32);
    acc[t] = __builtin_amdgcn_mfma_f32_16x16x32_bf16(ax1, b1, acc[t], 0,0,0);
  }

  int mrow = (lane>>4)*4;
  float ps[4]={0.f,0.f,0.f,0.f}, pd[4]={0.f,0.f,0.f,0.f};
  #pragma unroll
  for (int t=0;t<4;t++){
    int f = t*16 + m16;
    float as = atts[f], ad = attd[f];
    #pragma unroll
    for (int q=0;q<4;q++){
      int node = n0 + mrow + q;
      float v = acc[t][q];
      if (node < N) h16[(size_t)node*H_ + f] = __float2half(v);
      ps[q] = fmaf(v, as, ps[q]); pd[q] = fmaf(v, ad, pd[q]);
    }
  }
  #pragma unroll
  for (int d=1; d<16; d<<=1){
    #pragma unroll
    for (int q=0;q<4;q++){ ps[q] += __shfl_xor(ps[q], d); pd[q] += __shfl_xor(pd[q], d); }
  }
  if (m16==0){
    #pragma unroll
    for (int q=0;q<4;q++){
      int node = n0 + mrow + q;
      if (node < N){ ssc[node]=ps[q]; dsc[node]=pd[q]; }
    }
  }
}

// wave per node, single pass, half2 features: 32 lanes cover 64 features ->
// 2 edges per serial iteration (lanes 0-31: edge 2j, lanes 32-63: edge 2j+1).
template<int L>
__global__ void __launch_bounds__(256)
k_gat_h2(const __half* __restrict__ h16, const float* __restrict__ ssc,
         const float* __restrict__ dsc, const float4* __restrict__ rec,
         const int* __restrict__ off, const float* __restrict__ bias,
         short* __restrict__ hgat16, int N){
  int w = threadIdx.x >> 6, lane = threadIdx.x & 63;
  int node = blockIdx.x*4 + w;
  if (node >= N) return;
  int e0 = off[node], e1 = off[node+1];
  float dval = dsc[node];
  int half = lane >> 5;
  int fl = lane & 31;                       // feature pair: 2*fl, 2*fl+1
  const __half2* h2 = (const __half2*)h16;  // row stride 32
  float accx = 0.f, accy = 0.f, denl = 0.f;
  for (int base = e0; base < e1; base += 64){
    int p = base + lane;
    float ex = 0.f; int s = 0;
    if (p < e1){
      float4 r = rec[p];
      s = __float_as_int(r.w);
      float sc = (L==0) ? r.x : (L==1) ? r.y : r.z;
      float a = ssc[s] + dval + sc;
      a = (a > 0.f) ? a : SLOPE*a;
      ex = __expf(a);
    }
    denl += ex;
    int cnt = e1 - base; if (cnt > 64) cnt = 64;
    int npair = (cnt + 1) >> 1;
    for (int j = 0; j < npair; j++){
      int idx = 2*j + half;                 // idx<=63 always; ex=0 past cnt
      float exb = __shfl(ex, idx);
      int   sb  = __shfl(s, idx);
      float2 hv = __half22float2(h2[(size_t)sb*32 + fl]);
      accx = fmaf(exb, hv.x, accx);
      accy = fmaf(exb, hv.y, accy);
    }
  }
  accx += __shfl_xor(accx, 32);
  accy += __shfl_xor(accy, 32);
  #pragma unroll
  for (int d=32; d; d>>=1) denl += __shfl_xor(denl, d);
  if (half==0){
    float v0 = fmaxf(accx/denl + bias[2*fl],   0.f);
    float v1 = fmaxf(accy/denl + bias[2*fl+1], 0.f);
    unsigned out2 = ((unsigned)(unsigned short)f2bf(v1) << 16) | (unsigned short)f2bf(v0);
    ((unsigned*)hgat16)[(size_t)node*32 + fl] = out2;
  }
}

// block per graph: zero-atomic pooled output (batch is sorted)
__global__ void __launch_bounds__(256)
k_pool_g(const float* __restrict__ xi, const float* __restrict__ wout,
         const int* __restrict__ gstart, const float* __restrict__ b_out,
         float* __restrict__ out){
  int g = blockIdx.x;
  int a = gstart[g], b = gstart[g+1];
  float acc = 0.f;
  for (int n = a + threadIdx.x; n < b; n += 256){
    const float4* xr = (const float4*)(xi + (size_t)n*H_);
    float s = 0.f;
    #pragma unroll
    for (int q=0;q<H_/4;q++){
      float4 v = xr[q];
      s += v.x*wout[4*q] + v.y*wout[4*q+1] + v.z*wout[4*q+2] + v.w*wout[4*q+3];
    }
    acc += s;
  }
  #pragma unroll
  for (int d=32; d; d>>=1) acc += __shfl_xor(acc, d);
  __shared__ float sh[4];
  if ((threadIdx.x&63)==0) sh[threadIdx.x>>6] = acc;
  __syncthreads();
  if (threadIdx.x==0) out[g] = sh[0]+sh[1]+sh[2]+sh[3] + b_out[0];
}

extern "C" void kernel_launch(void* const* d_in, const int* in_sizes, int n_in,
                              void* d_out, int out_size, void* d_ws, size_t ws_size,
                              hipStream_t stream){
  const float* x       = (const float*)d_in[0];
  const float* eattr   = (const float*)d_in[1];
  const float* w_node  = (const float*)d_in[2];
  const float* b_node  = (const float*)d_in[3];
  const float* w_edge  = (const float*)d_in[4];
  const float* b_edge  = (const float*)d_in[5];
  const float* conv_W  = (const float*)d_in[6];
  const float* conv_We = (const float*)d_in[7];
  const float* att_s   = (const float*)d_in[8];
  const float* att_d   = (const float*)d_in[9];
  const float* att_e   = (const float*)d_in[10];
  const float* conv_b  = (const float*)d_in[11];
  const float* gWih    = (const float*)d_in[12];
  const float* gWhh    = (const float*)d_in[13];
  const float* gbih    = (const float*)d_in[14];
  const float* gbhh    = (const float*)d_in[15];
  const float* w_out   = (const float*)d_in[16];
  const float* b_out   = (const float*)d_in[17];
  const int*   eidx    = (const int*)d_in[18];
  const int*   batch   = (const int*)d_in[19];
  float* out = (float*)d_out;

  int N = in_sizes[0]/DIN;
  int E = in_sizes[1]/DE;
  int G = out_size;
  int EN = E + N;
  const int* src = eidx;
  const int* dst = eidx + E;

  char* p = (char*)d_ws;
  auto carve = [&](size_t bytes)->void*{ void* r=(void*)p; p += (bytes+255)&~(size_t)255; return r; };
  float*  xi0    = (float*)carve((size_t)N*H_*4);
  float*  xi1    = (float*)carve((size_t)N*H_*4);
  __half* h16    = (__half*)carve((size_t)N*H_*2);
  short*  hgat16 = (short*)carve((size_t)N*H_*2);
  float*  ssc    = (float*)carve((size_t)N*4);
  float*  dsc    = (float*)carve((size_t)N*4);
  float4* escore4= (float4*)carve((size_t)E*16);
  float4* rec    = (float4*)carve((size_t)EN*16);
  int*    deg    = (int*)carve((size_t)N*4);
  int*    off    = (int*)carve((size_t)(N+1)*4);
  int*    cur    = (int*)carve((size_t)(N+1)*4);
  int*    gstart = (int*)carve((size_t)(G+1)*4);
  int*    bsum   = (int*)carve((size_t)1024*4);
  int*    boff   = (int*)carve((size_t)1024*4);
  short*  wnT16  = (short*)carve((size_t)DIN*H_*2);
  short*  weT16p = (short*)carve((size_t)64*32*2);
  short*  cWT16  = (short*)carve((size_t)3*H_*H_*2);
  short*  WihT16 = (short*)carve((size_t)3*192*H_*2);
  short*  WhhT16 = (short*)carve((size_t)3*192*H_*2);
  float*  ve     = (float*)carve((size_t)3*H_*4);

  auto cdiv=[](int a,int b){return (a+b-1)/b;};
  int NB = cdiv(N,256);

  k_transpose_bf16<<<cdiv(DIN*H_,256),256,0,stream>>>(w_node, wnT16, 1, DIN, H_);
  k_wedge_pad<<<cdiv(64*32,256),256,0,stream>>>(w_edge, weT16p);
  k_transpose_bf16<<<cdiv(3*H_*H_,256),256,0,stream>>>(conv_W, cWT16, 3, H_, H_);
  k_transpose_bf16<<<cdiv(3*H_*3*H_,256),256,0,stream>>>(gWih, WihT16, 3, H_, 3*H_);
  k_transpose_bf16<<<cdiv(3*H_*3*H_,256),256,0,stream>>>(gWhh, WhhT16, 3, H_, 3*H_);
  k_ve<<<1,3*H_,0,stream>>>(conv_We, att_e, ve);

  k_init<<<cdiv(N,256),256,0,stream>>>(deg, N);
  k_nmlp_m<<<cdiv(N,64),256,0,stream>>>(x, wnT16, b_node, xi0, N);
  k_edge_m<<<cdiv(E,64),256,0,stream>>>(eattr, weT16p, b_edge, ve, dst, escore4, deg, E);
  k_bsum<<<NB,256,0,stream>>>(deg, bsum, N);
  k_bscan<<<1,1024,0,stream>>>(bsum, boff, NB, off+N, EN);
  k_scan_fin<<<NB,256,0,stream>>>(deg, boff, off, cur, N);
  k_fill<<<cdiv(E,256),256,0,stream>>>(src, dst, escore4, cur, rec, E);
  k_selfloop_csr<<<cdiv(N,256),256,0,stream>>>(off, rec, N);
  k_gbounds<<<NB,256,0,stream>>>(batch, gstart, N, G);

  int NB64 = cdiv(N,64);
  int NB4  = cdiv(N,4);
  for (int l=0; l<3; l++){
    const float* xin = (l&1) ? xi1 : xi0;
    float*       xo  = (l&1) ? xi0 : xi1;
    k_linh_m<<<NB64,256,0,stream>>>(xin, cWT16 + (size_t)l*H_*H_, att_s + l*H_, att_d + l*H_,
                                    h16, ssc, dsc, N);
    if (l==0)      k_gat_h2<0><<<NB4,256,0,stream>>>(h16, ssc, dsc, rec, off, conv_b + l*H_, hgat16, N);
    else if (l==1) k_gat_h2<1><<<NB4,256,0,stream>>>(h16, ssc, dsc, rec, off, conv_b + l*H_, hgat16, N);
    else           k_gat_h2<2><<<NB4,256,0,stream>>>(h16, ssc, dsc, rec, off, conv_b + l*H_, hgat16, N);
    k_gru_m<<<NB64,256,0,stream>>>(hgat16, xin, xo, WihT16 + (size_t)l*192*H_, WhhT16 + (size_t)l*192*H_,
                                   gbih + l*3*H_, gbhh + l*3*H_, N);
  }

  k_pool_g<<<G,256,0,stream>>>(xi1, w_out, gstart, b_out, out);
}

// Round 14
// 467.702 us; speedup vs baseline: 37.5977x; 1.1516x over previous
//
#include <hip/hip_runtime.h>
#include <hip/hip_fp16.h>

constexpr int H_  = 64;   // hidden
constexpr int DIN = 32;   // atom feature dim
constexpr int DE  = 16;   // edge feature dim
#define SLOPE 0.2f

typedef __attribute__((ext_vector_type(8))) short bf16x8;
typedef __attribute__((ext_vector_type(4))) float f32x4;

__device__ __forceinline__ float sigm_(float x){ return 1.0f/(1.0f+__expf(-x)); }
__device__ __forceinline__ float tanh_(float x){ float e=__expf(2.0f*x); return 1.0f - 2.0f/(e+1.0f); }
__device__ __forceinline__ short f2bf(float f){   // RNE float->bf16
  unsigned u = __float_as_uint(f);
  u += 0x7FFF + ((u>>16)&1);
  return (short)(u>>16);
}
__device__ __forceinline__ float h2f_(unsigned hb){
  return __half2float(__ushort_as_half((unsigned short)hb));
}

// dst[b][c][r] = bf16(src[b][r][c])
__global__ void k_transpose_bf16(const float* __restrict__ src, short* __restrict__ dst, int B,int R,int C){
  int id = blockIdx.x*blockDim.x+threadIdx.x;
  if (id >= B*R*C) return;
  int rc=R*C, b=id/rc, rem=id-b*rc, r=rem/C, c=rem-r*C;
  dst[b*rc + c*R + r] = f2bf(src[id]);
}

// w_edge [16][64] -> padded bf16 [64 j][32 k] (k>=16 zero)
__global__ void k_wedge_pad(const float* __restrict__ we, short* __restrict__ dst){
  int id = blockIdx.x*blockDim.x+threadIdx.x;
  if (id >= 64*32) return;
  int j = id >> 5, k = id & 31;
  dst[id] = (k < DE) ? f2bf(we[k*64 + j]) : (short)0;
}

// ve[l][k] = sum_j conv_We[l][k][j] * att_e[l][j]
__global__ void k_ve(const float* __restrict__ We, const float* __restrict__ ae, float* __restrict__ ve){
  int id = blockIdx.x*blockDim.x+threadIdx.x;
  if (id >= 3*H_) return;
  int l=id/H_, k=id-l*H_;
  const float* w = We + (size_t)(l*H_+k)*H_;
  const float* a = ae + l*H_;
  float s=0.f;
  #pragma unroll
  for(int j=0;j<H_;j++) s += w[j]*a[j];
  ve[id]=s;
}

__global__ void k_init(int* __restrict__ deg, int N){
  int n = blockIdx.x*blockDim.x+threadIdx.x;
  if (n>=N) return;
  deg[n]=1;                 // self-loop
}

// MFMA node MLP: xi = relu(x @ w_node + b), K=32 exact. No LDS.
__global__ void __launch_bounds__(256,4)
k_nmlp_m(const float* __restrict__ x, const short* __restrict__ wT16,
         const float* __restrict__ b, float* __restrict__ xi, int N){
  int lane = threadIdx.x & 63, w = threadIdx.x >> 6;
  int m16 = lane & 15, kb = lane >> 4;
  int n0 = blockIdx.x*64 + w*16;
  int arow = n0 + m16; if (arow > N-1) arow = N-1;
  const float* xr = x + (size_t)arow*DIN + kb*8;
  float4 a0 = *(const float4*)xr, a1 = *(const float4*)(xr+4);
  bf16x8 af;
  af[0]=f2bf(a0.x); af[1]=f2bf(a0.y); af[2]=f2bf(a0.z); af[3]=f2bf(a0.w);
  af[4]=f2bf(a1.x); af[5]=f2bf(a1.y); af[6]=f2bf(a1.z); af[7]=f2bf(a1.w);
  f32x4 acc[4];
  #pragma unroll
  for (int t=0;t<4;t++) acc[t]=(f32x4){0.f,0.f,0.f,0.f};
  const short* wp = wT16 + (size_t)m16*DIN + kb*8;
  #pragma unroll
  for (int t=0;t<4;t++){
    bf16x8 bb = *(const bf16x8*)(wp + (size_t)(t*16)*DIN);
    acc[t] = __builtin_amdgcn_mfma_f32_16x16x32_bf16(af, bb, acc[t], 0,0,0);
  }
  int mrow = (lane>>4)*4;
  #pragma unroll
  for (int t=0;t<4;t++){
    int f = t*16 + m16;
    float bj = b[f];
    #pragma unroll
    for (int q=0;q<4;q++){
      int node = n0 + mrow + q;
      if (node < N) xi[(size_t)node*H_ + f] = fmaxf(acc[t][q] + bj, 0.f);
    }
  }
}

// MFMA edge scores: 16 edges/wave. ea = relu(attr@w_edge+b) via MFMA (K 16->32 zero-pad),
// 3 ve-dots reduced across 16 j-lanes, packed to 8B {fp16 s0(,LSB=0),s1,s2}. deg histogram.
__global__ void __launch_bounds__(256,4)
k_edge_m(const float* __restrict__ attr, const short* __restrict__ weT16p,
         const float* __restrict__ be, const float* __restrict__ ve,
         const int* __restrict__ dst, uint2* __restrict__ esc8,
         int* __restrict__ deg, int E){
  int lane = threadIdx.x & 63, w = threadIdx.x >> 6;
  int m16 = lane & 15, kb = lane >> 4;
  int e0 = (blockIdx.x*4 + w)*16;
  if (e0 >= E) return;
  bf16x8 af = {0,0,0,0,0,0,0,0};
  if (kb < 2){
    int arow = e0 + m16; if (arow > E-1) arow = E-1;
    const float* ap = attr + (size_t)arow*DE + kb*8;
    float4 a0 = *(const float4*)ap, a1 = *(const float4*)(ap+4);
    af[0]=f2bf(a0.x); af[1]=f2bf(a0.y); af[2]=f2bf(a0.z); af[3]=f2bf(a0.w);
    af[4]=f2bf(a1.x); af[5]=f2bf(a1.y); af[6]=f2bf(a1.z); af[7]=f2bf(a1.w);
  }
  f32x4 acc[4];
  #pragma unroll
  for (int t=0;t<4;t++) acc[t]=(f32x4){0.f,0.f,0.f,0.f};
  const short* wp = weT16p + (size_t)m16*32 + kb*8;
  #pragma unroll
  for (int t=0;t<4;t++){
    bf16x8 bb = *(const bf16x8*)(wp + (size_t)(t*16)*32);
    acc[t] = __builtin_amdgcn_mfma_f32_16x16x32_bf16(af, bb, acc[t], 0,0,0);
  }
  int mrow = (lane>>4)*4;
  float s0[4]={0.f,0.f,0.f,0.f}, s1[4]={0.f,0.f,0.f,0.f}, s2[4]={0.f,0.f,0.f,0.f};
  #pragma unroll
  for (int t=0;t<4;t++){
    int j = t*16 + m16;
    float bj = be[j];
    float v0 = ve[j], v1 = ve[64+j], v2 = ve[128+j];
    #pragma unroll
    for (int q=0;q<4;q++){
      float ea = fmaxf(acc[t][q] + bj, 0.f);
      s0[q] = fmaf(ea, v0, s0[q]);
      s1[q] = fmaf(ea, v1, s1[q]);
      s2[q] = fmaf(ea, v2, s2[q]);
    }
  }
  #pragma unroll
  for (int d=1; d<16; d<<=1){
    #pragma unroll
    for (int q=0;q<4;q++){
      s0[q] += __shfl_xor(s0[q], d);
      s1[q] += __shfl_xor(s1[q], d);
      s2[q] += __shfl_xor(s2[q], d);
    }
  }
  if (m16==0){
    #pragma unroll
    for (int q=0;q<4;q++){
      int e = e0 + mrow + q;
      if (e < E){
        unsigned h0 = __half_as_ushort(__float2half(s0[q])) & 0xFFFEu;
        unsigned h1 = __half_as_ushort(__float2half(s1[q]));
        unsigned h2 = __half_as_ushort(__float2half(s2[q]));
        esc8[e] = make_uint2(h0 | (h1<<16), (h2<<16));
        atomicAdd(&deg[dst[e]], 1);
      }
    }
  }
}

// ---- hierarchical scan of deg -> off (exclusive); cur = off+1 (self-loop slot reserved) ----
__global__ void k_bsum(const int* __restrict__ deg, int* __restrict__ bsum, int N){
  int i = blockIdx.x*256 + threadIdx.x;
  int v = (i<N) ? deg[i] : 0;
  #pragma unroll
  for(int d=32; d; d>>=1) v += __shfl_xor(v, d);
  __shared__ int sh[4];
  if ((threadIdx.x&63)==0) sh[threadIdx.x>>6] = v;
  __syncthreads();
  if (threadIdx.x==0) bsum[blockIdx.x] = sh[0]+sh[1]+sh[2]+sh[3];
}

__global__ void k_bscan(const int* __restrict__ bsum, int* __restrict__ boff, int NB,
                        int* __restrict__ offN, int EN){
  __shared__ int sh[1024];
  int tid = threadIdx.x;
  int v = (tid<NB) ? bsum[tid] : 0;
  sh[tid] = v;
  __syncthreads();
  for(int d=1; d<1024; d<<=1){
    int t = 0;
    if (tid>=d) t = sh[tid-d];
    __syncthreads();
    if (tid>=d) sh[tid] += t;
    __syncthreads();
  }
  if (tid<NB) boff[tid] = sh[tid] - v;  // exclusive
  if (tid==0) offN[0] = EN;
}

__global__ void k_scan_fin(const int* __restrict__ deg, const int* __restrict__ boff,
                           int* __restrict__ off, int* __restrict__ cur, int N){
  __shared__ int sh[256];
  int i = blockIdx.x*256 + threadIdx.x;
  int v = (i<N) ? deg[i] : 0;
  sh[threadIdx.x] = v;
  __syncthreads();
  for(int d=1; d<256; d<<=1){
    int t = 0;
    if (threadIdx.x>=d) t = sh[threadIdx.x-d];
    __syncthreads();
    if (threadIdx.x>=d) sh[threadIdx.x] += t;
    __syncthreads();
  }
  if (i<N){
    int e = boff[blockIdx.x] + sh[threadIdx.x] - v;
    off[i] = e; cur[i] = e+1;          // slot off[i] reserved for self-loop
  }
}

// scatter real edges into CSR order: 8B record {s0(fp16,LSB=src b16)|s1<<16, src_lo|s2<<16}
__global__ void k_fill(const int* __restrict__ src, const int* __restrict__ dst,
                       const uint2* __restrict__ esc8, int* __restrict__ cur,
                       uint2* __restrict__ rec, int E){
  int e = blockIdx.x*blockDim.x+threadIdx.x;
  if (e>=E) return;
  uint2 r = esc8[e];
  unsigned s = (unsigned)src[e];
  r.x |= (s >> 16);                 // bit 16 of src (s < 2^17)
  r.y |= (s & 0xFFFFu);
  int p = atomicAdd(&cur[dst[e]],1);
  rec[p] = r;
}

// self-loop record at off[n]: mean of segment's real-edge scores (0 if none), src=n
__global__ void k_selfloop_csr(const int* __restrict__ off, uint2* __restrict__ rec, int N){
  int n = blockIdx.x*blockDim.x+threadIdx.x;
  if (n>=N) return;
  int a = off[n]+1, b = off[n+1];
  float s0=0.f,s1=0.f,s2=0.f;
  for (int p=a;p<b;p++){
    uint2 r=rec[p];
    s0 += h2f_(r.x & 0xFFFEu);
    s1 += h2f_(r.x >> 16);
    s2 += h2f_(r.y >> 16);
  }
  float inv = (b>a) ? 1.0f/(float)(b-a) : 0.0f;
  unsigned h0 = __half_as_ushort(__float2half(s0*inv)) & 0xFFFEu;
  unsigned h1 = __half_as_ushort(__float2half(s1*inv));
  unsigned h2 = __half_as_ushort(__float2half(s2*inv));
  unsigned s = (unsigned)n;
  rec[off[n]] = make_uint2(h0 | (s>>16) | (h1<<16), (s & 0xFFFFu) | (h2<<16));
}

// graph boundaries from sorted batch
__global__ void k_gbounds(const int* __restrict__ batch, int* __restrict__ gstart, int N, int G){
  int n = blockIdx.x*blockDim.x+threadIdx.x;
  if (n>=N) return;
  int b = batch[n];
  int bp = (n==0) ? -1 : batch[n-1];
  for (int g=bp+1; g<=b; g++) gstart[g]=n;
  if (n==N-1){ for (int g=b+1; g<=G; g++) gstart[g]=N; }
}

// MFMA GRU: block = 64 nodes (4 waves x 16-node strip), no LDS.
__global__ void __launch_bounds__(256,4)
k_gru_m(const short* __restrict__ hg16, const float* __restrict__ xin, float* __restrict__ xout,
        const short* __restrict__ WihT16, const short* __restrict__ WhhT16,
        const float* __restrict__ bih, const float* __restrict__ bhh, int N){
  int lane = threadIdx.x & 63, w = threadIdx.x >> 6;
  int m16 = lane & 15;
  int kb  = lane >> 4;
  int n0 = blockIdx.x*64 + w*16;

  int arow = n0 + m16; if (arow > N-1) arow = N-1;
  const short* hrow = hg16 + (size_t)arow*H_ + kb*8;
  bf16x8 ah0 = *(const bf16x8*)(hrow);
  bf16x8 ah1 = *(const bf16x8*)(hrow + 32);
  const float* xrow = xin + (size_t)arow*H_ + kb*8;
  float4 xa = *(const float4*)(xrow),    xb = *(const float4*)(xrow+4);
  float4 xc = *(const float4*)(xrow+32), xd = *(const float4*)(xrow+36);
  bf16x8 ax0, ax1;
  ax0[0]=f2bf(xa.x); ax0[1]=f2bf(xa.y); ax0[2]=f2bf(xa.z); ax0[3]=f2bf(xa.w);
  ax0[4]=f2bf(xb.x); ax0[5]=f2bf(xb.y); ax0[6]=f2bf(xb.z); ax0[7]=f2bf(xb.w);
  ax1[0]=f2bf(xc.x); ax1[1]=f2bf(xc.y); ax1[2]=f2bf(xc.z); ax1[3]=f2bf(xc.w);
  ax1[4]=f2bf(xd.x); ax1[5]=f2bf(xd.y); ax1[6]=f2bf(xd.z); ax1[7]=f2bf(xd.w);

  f32x4 aR[4], aZ[4], aNi[4], aNh[4];
  #pragma unroll
  for (int t=0;t<4;t++){
    aR[t]=(f32x4){0.f,0.f,0.f,0.f}; aZ[t]=(f32x4){0.f,0.f,0.f,0.f};
    aNi[t]=(f32x4){0.f,0.f,0.f,0.f}; aNh[t]=(f32x4){0.f,0.f,0.f,0.f};
  }

  const short* wi = WihT16 + (size_t)m16*H_ + kb*8;
  const short* wh = WhhT16 + (size_t)m16*H_ + kb*8;
  #pragma unroll
  for (int t=0;t<4;t++){
    bf16x8 b;
    b = *(const bf16x8*)(wi + (size_t)(t*16)*H_);
    aR[t] = __builtin_amdgcn_mfma_f32_16x16x32_bf16(ah0, b, aR[t], 0,0,0);
    b = *(const bf16x8*)(wi + (size_t)(t*16)*H_ + 32);
    aR[t] = __builtin_amdgcn_mfma_f32_16x16x32_bf16(ah1, b, aR[t], 0,0,0);
    b = *(const bf16x8*)(wh + (size_t)(t*16)*H_);
    aR[t] = __builtin_amdgcn_mfma_f32_16x16x32_bf16(ax0, b, aR[t], 0,0,0);
    b = *(const bf16x8*)(wh + (size_t)(t*16)*H_ + 32);
    aR[t] = __builtin_amdgcn_mfma_f32_16x16x32_bf16(ax1, b, aR[t], 0,0,0);
    b = *(const bf16x8*)(wi + (size_t)(64+t*16)*H_);
    aZ[t] = __builtin_amdgcn_mfma_f32_16x16x32_bf16(ah0, b, aZ[t], 0,0,0);
    b = *(const bf16x8*)(wi + (size_t)(64+t*16)*H_ + 32);
    aZ[t] = __builtin_amdgcn_mfma_f32_16x16x32_bf16(ah1, b, aZ[t], 0,0,0);
    b = *(const bf16x8*)(wh + (size_t)(64+t*16)*H_);
    aZ[t] = __builtin_amdgcn_mfma_f32_16x16x32_bf16(ax0, b, aZ[t], 0,0,0);
    b = *(const bf16x8*)(wh + (size_t)(64+t*16)*H_ + 32);
    aZ[t] = __builtin_amdgcn_mfma_f32_16x16x32_bf16(ax1, b, aZ[t], 0,0,0);
    b = *(const bf16x8*)(wi + (size_t)(128+t*16)*H_);
    aNi[t] = __builtin_amdgcn_mfma_f32_16x16x32_bf16(ah0, b, aNi[t], 0,0,0);
    b = *(const bf16x8*)(wi + (size_t)(128+t*16)*H_ + 32);
    aNi[t] = __builtin_amdgcn_mfma_f32_16x16x32_bf16(ah1, b, aNi[t], 0,0,0);
    b = *(const bf16x8*)(wh + (size_t)(128+t*16)*H_);
    aNh[t] = __builtin_amdgcn_mfma_f32_16x16x32_bf16(ax0, b, aNh[t], 0,0,0);
    b = *(const bf16x8*)(wh + (size_t)(128+t*16)*H_ + 32);
    aNh[t] = __builtin_amdgcn_mfma_f32_16x16x32_bf16(ax1, b, aNh[t], 0,0,0);
  }

  int mrow = (lane>>4)*4;
  #pragma unroll
  for (int t=0;t<4;t++){
    int f = t*16 + m16;
    float br = bih[f]     + bhh[f];
    float bz = bih[64+f]  + bhh[64+f];
    float bin= bih[128+f], bhn = bhh[128+f];
    #pragma unroll
    for (int q=0;q<4;q++){
      int node = n0 + mrow + q;
      if (node < N){
        float r  = sigm_(aR[t][q] + br);
        float z  = sigm_(aZ[t][q] + bz);
        float nn = tanh_(aNi[t][q] + bin + r*(aNh[t][q] + bhn));
        float xv = xin[(size_t)node*H_ + f];
        xout[(size_t)node*H_ + f] = fmaxf((1.f-z)*nn + z*xv, 0.f);
      }
    }
  }
}

// MFMA linear-h: h16 = fp16(xi @ conv_W[l]); ssc/dsc via shfl_xor reduce. No LDS.
__global__ void __launch_bounds__(256,4)
k_linh_m(const float* __restrict__ xi, const short* __restrict__ wT16,
         const float* __restrict__ atts, const float* __restrict__ attd,
         __half* __restrict__ h16, float* __restrict__ ssc, float* __restrict__ dsc, int N){
  int lane = threadIdx.x & 63, w = threadIdx.x >> 6;
  int m16 = lane & 15, kb = lane >> 4;
  int n0 = blockIdx.x*64 + w*16;
  int arow = n0 + m16; if (arow > N-1) arow = N-1;
  const float* xrow = xi + (size_t)arow*H_ + kb*8;
  float4 xa = *(const float4*)(xrow),    xb = *(const float4*)(xrow+4);
  float4 xc = *(const float4*)(xrow+32), xd = *(const float4*)(xrow+36);
  bf16x8 ax0, ax1;
  ax0[0]=f2bf(xa.x); ax0[1]=f2bf(xa.y); ax0[2]=f2bf(xa.z); ax0[3]=f2bf(xa.w);
  ax0[4]=f2bf(xb.x); ax0[5]=f2bf(xb.y); ax0[6]=f2bf(xb.z); ax0[7]=f2bf(xb.w);
  ax1[0]=f2bf(xc.x); ax1[1]=f2bf(xc.y); ax1[2]=f2bf(xc.z); ax1[3]=f2bf(xc.w);
  ax1[4]=f2bf(xd.x); ax1[5]=f2bf(xd.y); ax1[6]=f2bf(xd.z); ax1[7]=f2bf(xd.w);

  f32x4 acc[4];
  #pragma unroll
  for (int t=0;t<4;t++) acc[t]=(f32x4){0.f,0.f,0.f,0.f};
  const short* wp = wT16 + (size_t)m16*H_ + kb*8;
  #pragma unroll
  for (int t=0;t<4;t++){
    bf16x8 b0 = *(const bf16x8*)(wp + (size_t)(t*16)*H_);
    acc[t] = __builtin_amdgcn_mfma_f32_16x16x32_bf16(ax0, b0, acc[t], 0,0,0);
    bf16x8 b1 = *(const bf16x8*)(wp + (size_t)(t*16)*H_ + 32);
    acc[t] = __builtin_amdgcn_mfma_f32_16x16x32_bf16(ax1, b1, acc[t], 0,0,0);
  }

  int mrow = (lane>>4)*4;
  float ps[4]={0.f,0.f,0.f,0.f}, pd[4]={0.f,0.f,0.f,0.f};
  #pragma unroll
  for (int t=0;t<4;t++){
    int f = t*16 + m16;
    float as = atts[f], ad = attd[f];
    #pragma unroll
    for (int q=0;q<4;q++){
      int node = n0 + mrow + q;
      float v = acc[t][q];
      if (node < N) h16[(size_t)node*H_ + f] = __float2half(v);
      ps[q] = fmaf(v, as, ps[q]); pd[q] = fmaf(v, ad, pd[q]);
    }
  }
  #pragma unroll
  for (int d=1; d<16; d<<=1){
    #pragma unroll
    for (int q=0;q<4;q++){ ps[q] += __shfl_xor(ps[q], d); pd[q] += __shfl_xor(pd[q], d); }
  }
  if (m16==0){
    #pragma unroll
    for (int q=0;q<4;q++){
      int node = n0 + mrow + q;
      if (node < N){ ssc[node]=ps[q]; dsc[node]=pd[q]; }
    }
  }
}

// GAT: 4 nodes/wave, 16 lanes/node (half4 = 4 features/lane). Single-pass safe-exp softmax.
// Score phase: 16 edges/group in parallel; inner: 1 edge/group/iter (4 edges/wave/iter).
template<int L>
__global__ void __launch_bounds__(256)
k_gat_g4(const __half* __restrict__ h16, const float* __restrict__ ssc,
         const float* __restrict__ dsc, const uint2* __restrict__ rec,
         const int* __restrict__ off, const float* __restrict__ bias,
         short* __restrict__ hgat16, int N){
  int lane = threadIdx.x & 63, w = threadIdx.x >> 6;
  int g = lane >> 4, fl = lane & 15;
  int node = blockIdx.x*16 + w*4 + g;
  if (node >= N) return;
  int e0 = off[node], e1 = off[node+1];
  float dval = dsc[node];
  float acc0=0.f, acc1=0.f, acc2=0.f, acc3=0.f, den=0.f;
  int gbase = lane & 48;                 // g*16
  for (int base = e0; base < e1; base += 16){
    int p = base + fl;
    float ex = 0.f; int s = 0;
    if (p < e1){
      uint2 r = rec[p];
      s = (int)((r.y & 0xFFFFu) | ((r.x & 1u) << 16));
      unsigned hb = (L==0) ? (r.x & 0xFFFEu) : (L==1) ? (r.x >> 16) : (r.y >> 16);
      float a = ssc[s] + dval + h2f_(hb);
      a = (a > 0.f) ? a : SLOPE*a;
      ex = __expf(a);
    }
    den += ex;
    int cnt = e1 - base; if (cnt > 16) cnt = 16;
    for (int j = 0; j < cnt; j++){
      float exb = __shfl(ex, gbase + j);
      int   sb  = __shfl(s,  gbase + j);
      uint2 hv = *(const uint2*)(h16 + (size_t)sb*H_ + 4*fl);
      float2 f0 = __half22float2(*(__half2*)&hv.x);
      float2 f1 = __half22float2(*(__half2*)&hv.y);
      acc0 = fmaf(exb, f0.x, acc0);
      acc1 = fmaf(exb, f0.y, acc1);
      acc2 = fmaf(exb, f1.x, acc2);
      acc3 = fmaf(exb, f1.y, acc3);
    }
  }
  #pragma unroll
  for (int d=1; d<16; d<<=1) den += __shfl_xor(den, d);
  float4 bv = *(const float4*)(bias + 4*fl);
  float inv = 1.0f/den;
  float v0 = fmaxf(fmaf(acc0,inv,bv.x), 0.f);
  float v1 = fmaxf(fmaf(acc1,inv,bv.y), 0.f);
  float v2 = fmaxf(fmaf(acc2,inv,bv.z), 0.f);
  float v3 = fmaxf(fmaf(acc3,inv,bv.w), 0.f);
  uint2 o;
  o.x = ((unsigned)(unsigned short)f2bf(v1)<<16) | (unsigned short)f2bf(v0);
  o.y = ((unsigned)(unsigned short)f2bf(v3)<<16) | (unsigned short)f2bf(v2);
  *(uint2*)(hgat16 + (size_t)node*H_ + 4*fl) = o;
}

// block per graph: zero-atomic pooled output (batch is sorted)
__global__ void __launch_bounds__(256)
k_pool_g(const float* __restrict__ xi, const float* __restrict__ wout,
         const int* __restrict__ gstart, const float* __restrict__ b_out,
         float* __restrict__ out){
  int g = blockIdx.x;
  int a = gstart[g], b = gstart[g+1];
  float acc = 0.f;
  for (int n = a + threadIdx.x; n < b; n += 256){
    const float4* xr = (const float4*)(xi + (size_t)n*H_);
    float s = 0.f;
    #pragma unroll
    for (int q=0;q<H_/4;q++){
      float4 v = xr[q];
      s += v.x*wout[4*q] + v.y*wout[4*q+1] + v.z*wout[4*q+2] + v.w*wout[4*q+3];
    }
    acc += s;
  }
  #pragma unroll
  for (int d=32; d; d>>=1) acc += __shfl_xor(acc, d);
  __shared__ float sh[4];
  if ((threadIdx.x&63)==0) sh[threadIdx.x>>6] = acc;
  __syncthreads();
  if (threadIdx.x==0) out[g] = sh[0]+sh[1]+sh[2]+sh[3] + b_out[0];
}

extern "C" void kernel_launch(void* const* d_in, const int* in_sizes, int n_in,
                              void* d_out, int out_size, void* d_ws, size_t ws_size,
                              hipStream_t stream){
  const float* x       = (const float*)d_in[0];
  const float* eattr   = (const float*)d_in[1];
  const float* w_node  = (const float*)d_in[2];
  const float* b_node  = (const float*)d_in[3];
  const float* w_edge  = (const float*)d_in[4];
  const float* b_edge  = (const float*)d_in[5];
  const float* conv_W  = (const float*)d_in[6];
  const float* conv_We = (const float*)d_in[7];
  const float* att_s   = (const float*)d_in[8];
  const float* att_d   = (const float*)d_in[9];
  const float* att_e   = (const float*)d_in[10];
  const float* conv_b  = (const float*)d_in[11];
  const float* gWih    = (const float*)d_in[12];
  const float* gWhh    = (const float*)d_in[13];
  const float* gbih    = (const float*)d_in[14];
  const float* gbhh    = (const float*)d_in[15];
  const float* w_out   = (const float*)d_in[16];
  const float* b_out   = (const float*)d_in[17];
  const int*   eidx    = (const int*)d_in[18];
  const int*   batch   = (const int*)d_in[19];
  float* out = (float*)d_out;

  int N = in_sizes[0]/DIN;
  int E = in_sizes[1]/DE;
  int G = out_size;
  int EN = E + N;
  const int* src = eidx;
  const int* dst = eidx + E;

  char* p = (char*)d_ws;
  auto carve = [&](size_t bytes)->void*{ void* r=(void*)p; p += (bytes+255)&~(size_t)255; return r; };
  float*  xi0    = (float*)carve((size_t)N*H_*4);
  float*  xi1    = (float*)carve((size_t)N*H_*4);
  __half* h16    = (__half*)carve((size_t)N*H_*2);
  short*  hgat16 = (short*)carve((size_t)N*H_*2);
  float*  ssc    = (float*)carve((size_t)N*4);
  float*  dsc    = (float*)carve((size_t)N*4);
  uint2*  esc8   = (uint2*)carve((size_t)E*8);
  uint2*  rec    = (uint2*)carve((size_t)EN*8);
  int*    deg    = (int*)carve((size_t)N*4);
  int*    off    = (int*)carve((size_t)(N+1)*4);
  int*    cur    = (int*)carve((size_t)(N+1)*4);
  int*    gstart = (int*)carve((size_t)(G+1)*4);
  int*    bsum   = (int*)carve((size_t)1024*4);
  int*    boff   = (int*)carve((size_t)1024*4);
  short*  wnT16  = (short*)carve((size_t)DIN*H_*2);
  short*  weT16p = (short*)carve((size_t)64*32*2);
  short*  cWT16  = (short*)carve((size_t)3*H_*H_*2);
  short*  WihT16 = (short*)carve((size_t)3*192*H_*2);
  short*  WhhT16 = (short*)carve((size_t)3*192*H_*2);
  float*  ve     = (float*)carve((size_t)3*H_*4);

  auto cdiv=[](int a,int b){return (a+b-1)/b;};
  int NB = cdiv(N,256);

  k_transpose_bf16<<<cdiv(DIN*H_,256),256,0,stream>>>(w_node, wnT16, 1, DIN, H_);
  k_wedge_pad<<<cdiv(64*32,256),256,0,stream>>>(w_edge, weT16p);
  k_transpose_bf16<<<cdiv(3*H_*H_,256),256,0,stream>>>(conv_W, cWT16, 3, H_, H_);
  k_transpose_bf16<<<cdiv(3*H_*3*H_,256),256,0,stream>>>(gWih, WihT16, 3, H_, 3*H_);
  k_transpose_bf16<<<cdiv(3*H_*3*H_,256),256,0,stream>>>(gWhh, WhhT16, 3, H_, 3*H_);
  k_ve<<<1,3*H_,0,stream>>>(conv_We, att_e, ve);

  k_init<<<cdiv(N,256),256,0,stream>>>(deg, N);
  k_nmlp_m<<<cdiv(N,64),256,0,stream>>>(x, wnT16, b_node, xi0, N);
  k_edge_m<<<cdiv(E,64),256,0,stream>>>(eattr, weT16p, b_edge, ve, dst, esc8, deg, E);
  k_bsum<<<NB,256,0,stream>>>(deg, bsum, N);
  k_bscan<<<1,1024,0,stream>>>(bsum, boff, NB, off+N, EN);
  k_scan_fin<<<NB,256,0,stream>>>(deg, boff, off, cur, N);
  k_fill<<<cdiv(E,256),256,0,stream>>>(src, dst, esc8, cur, rec, E);
  k_selfloop_csr<<<cdiv(N,256),256,0,stream>>>(off, rec, N);
  k_gbounds<<<NB,256,0,stream>>>(batch, gstart, N, G);

  int NB64 = cdiv(N,64);
  int NB16 = cdiv(N,16);
  for (int l=0; l<3; l++){
    const float* xin = (l&1) ? xi1 : xi0;
    float*       xo  = (l&1) ? xi0 : xi1;
    k_linh_m<<<NB64,256,0,stream>>>(xin, cWT16 + (size_t)l*H_*H_, att_s + l*H_, att_d + l*H_,
                                    h16, ssc, dsc, N);
    if (l==0)      k_gat_g4<0><<<NB16,256,0,stream>>>(h16, ssc, dsc, rec, off, conv_b + l*H_, hgat16, N);
    else if (l==1) k_gat_g4<1><<<NB16,256,0,stream>>>(h16, ssc, dsc, rec, off, conv_b + l*H_, hgat16, N);
    else           k_gat_g4<2><<<NB16,256,0,stream>>>(h16, ssc, dsc, rec, off, conv_b + l*H_, hgat16, N);
    k_gru_m<<<NB64,256,0,stream>>>(hgat16, xin, xo, WihT16 + (size_t)l*192*H_, WhhT16 + (size_t)l*192*H_,
                                   gbih + l*3*H_, gbhh + l*3*H_, N);
  }

  k_pool_g<<<G,256,0,stream>>>(xi1, w_out, gstart, b_out, out);
}

// Round 15
// 429.336 us; speedup vs baseline: 40.9574x; 1.0894x over previous
//
#include <hip/hip_runtime.h>
#include <hip/hip_fp16.h>

constexpr int H_  = 64;   // hidden
constexpr int DIN = 32;   // atom feature dim
constexpr int DE  = 16;   // edge feature dim
constexpr int BNODE = 512; // nodes per scatter bucket (dstlocal < 512)
constexpr int ACH   = 2048;// edges per binning chunk
#define SLOPE 0.2f

typedef __attribute__((ext_vector_type(8))) short bf16x8;
typedef __attribute__((ext_vector_type(4))) float f32x4;

__device__ __forceinline__ float sigm_(float x){ return 1.0f/(1.0f+__expf(-x)); }
__device__ __forceinline__ float tanh_(float x){ float e=__expf(2.0f*x); return 1.0f - 2.0f/(e+1.0f); }
__device__ __forceinline__ short f2bf(float f){   // RNE float->bf16
  unsigned u = __float_as_uint(f);
  u += 0x7FFF + ((u>>16)&1);
  return (short)(u>>16);
}
__device__ __forceinline__ float h2f_(unsigned hb){
  return __half2float(__ushort_as_half((unsigned short)hb));
}

// one mega-kernel for all weight prep + deg init (replaces 7 tiny launches)
__global__ void k_prep(const float* __restrict__ w_node, const float* __restrict__ w_edge,
                       const float* __restrict__ conv_W, const float* __restrict__ gWih,
                       const float* __restrict__ gWhh, const float* __restrict__ conv_We,
                       const float* __restrict__ att_e,
                       short* __restrict__ wnT16, short* __restrict__ weT16p,
                       short* __restrict__ cWT16, short* __restrict__ WihT16,
                       short* __restrict__ WhhT16, float* __restrict__ ve,
                       int* __restrict__ deg, int N){
  int id = blockIdx.x*blockDim.x + threadIdx.x;
  if (id < 2048){                                   // wnT16 [64][32]
    int j = id >> 5, k = id & 31;
    wnT16[id] = f2bf(w_node[k*64 + j]);
    return;
  }
  id -= 2048;
  if (id < 2048){                                   // weT16p [64][32], k>=16 zero
    int j = id >> 5, k = id & 31;
    weT16p[id] = (k < DE) ? f2bf(w_edge[k*64 + j]) : (short)0;
    return;
  }
  id -= 2048;
  if (id < 12288){                                  // cWT16 [3][64 j][64 k]
    int l = id / 4096, rem = id & 4095, j = rem >> 6, k = rem & 63;
    cWT16[id] = f2bf(conv_W[l*4096 + k*64 + j]);
    return;
  }
  id -= 12288;
  if (id < 36864){                                  // WihT16 [3][192 j][64 k]
    int l = id / 12288, rem = id % 12288, j = rem >> 6, k = rem & 63;
    WihT16[id] = f2bf(gWih[l*12288 + k*192 + j]);
    return;
  }
  id -= 36864;
  if (id < 36864){                                  // WhhT16
    int l = id / 12288, rem = id % 12288, j = rem >> 6, k = rem & 63;
    WhhT16[id] = f2bf(gWhh[l*12288 + k*192 + j]);
    return;
  }
  id -= 36864;
  if (id < 192){                                    // ve[l][k] = conv_We[l][k][:] . att_e[l][:]
    int l = id >> 6, k = id & 63;
    const float* w = conv_We + (size_t)(l*64+k)*64;
    const float* a = att_e + l*64;
    float s = 0.f;
    #pragma unroll
    for (int j=0;j<64;j++) s += w[j]*a[j];
    ve[id] = s;
    return;
  }
  id -= 192;
  if (id < N) deg[id] = 1;                          // self-loop
}

// MFMA node MLP: xi = relu(x @ w_node + b), K=32 exact. No LDS.
__global__ void __launch_bounds__(256,4)
k_nmlp_m(const float* __restrict__ x, const short* __restrict__ wT16,
         const float* __restrict__ b, float* __restrict__ xi, int N){
  int lane = threadIdx.x & 63, w = threadIdx.x >> 6;
  int m16 = lane & 15, kb = lane >> 4;
  int n0 = blockIdx.x*64 + w*16;
  int arow = n0 + m16; if (arow > N-1) arow = N-1;
  const float* xr = x + (size_t)arow*DIN + kb*8;
  float4 a0 = *(const float4*)xr, a1 = *(const float4*)(xr+4);
  bf16x8 af;
  af[0]=f2bf(a0.x); af[1]=f2bf(a0.y); af[2]=f2bf(a0.z); af[3]=f2bf(a0.w);
  af[4]=f2bf(a1.x); af[5]=f2bf(a1.y); af[6]=f2bf(a1.z); af[7]=f2bf(a1.w);
  f32x4 acc[4];
  #pragma unroll
  for (int t=0;t<4;t++) acc[t]=(f32x4){0.f,0.f,0.f,0.f};
  const short* wp = wT16 + (size_t)m16*DIN + kb*8;
  #pragma unroll
  for (int t=0;t<4;t++){
    bf16x8 bb = *(const bf16x8*)(wp + (size_t)(t*16)*DIN);
    acc[t] = __builtin_amdgcn_mfma_f32_16x16x32_bf16(af, bb, acc[t], 0,0,0);
  }
  int mrow = (lane>>4)*4;
  #pragma unroll
  for (int t=0;t<4;t++){
    int f = t*16 + m16;
    float bj = b[f];
    #pragma unroll
    for (int q=0;q<4;q++){
      int node = n0 + mrow + q;
      if (node < N) xi[(size_t)node*H_ + f] = fmaxf(acc[t][q] + bj, 0.f);
    }
  }
}

// MFMA edge scores: 16 edges/wave, packed 8B record with src bits spliced in. deg histogram.
__global__ void __launch_bounds__(256,4)
k_edge_m(const float* __restrict__ attr, const short* __restrict__ weT16p,
         const float* __restrict__ be, const float* __restrict__ ve,
         const int* __restrict__ src, const int* __restrict__ dst,
         uint2* __restrict__ esc8, int* __restrict__ deg, int E){
  int lane = threadIdx.x & 63, w = threadIdx.x >> 6;
  int m16 = lane & 15, kb = lane >> 4;
  int e0 = (blockIdx.x*4 + w)*16;
  if (e0 >= E) return;
  bf16x8 af = {0,0,0,0,0,0,0,0};
  if (kb < 2){
    int arow = e0 + m16; if (arow > E-1) arow = E-1;
    const float* ap = attr + (size_t)arow*DE + kb*8;
    float4 a0 = *(const float4*)ap, a1 = *(const float4*)(ap+4);
    af[0]=f2bf(a0.x); af[1]=f2bf(a0.y); af[2]=f2bf(a0.z); af[3]=f2bf(a0.w);
    af[4]=f2bf(a1.x); af[5]=f2bf(a1.y); af[6]=f2bf(a1.z); af[7]=f2bf(a1.w);
  }
  f32x4 acc[4];
  #pragma unroll
  for (int t=0;t<4;t++) acc[t]=(f32x4){0.f,0.f,0.f,0.f};
  const short* wp = weT16p + (size_t)m16*32 + kb*8;
  #pragma unroll
  for (int t=0;t<4;t++){
    bf16x8 bb = *(const bf16x8*)(wp + (size_t)(t*16)*32);
    acc[t] = __builtin_amdgcn_mfma_f32_16x16x32_bf16(af, bb, acc[t], 0,0,0);
  }
  int mrow = (lane>>4)*4;
  float s0[4]={0.f,0.f,0.f,0.f}, s1[4]={0.f,0.f,0.f,0.f}, s2[4]={0.f,0.f,0.f,0.f};
  #pragma unroll
  for (int t=0;t<4;t++){
    int j = t*16 + m16;
    float bj = be[j];
    float v0 = ve[j], v1 = ve[64+j], v2 = ve[128+j];
    #pragma unroll
    for (int q=0;q<4;q++){
      float ea = fmaxf(acc[t][q] + bj, 0.f);
      s0[q] = fmaf(ea, v0, s0[q]);
      s1[q] = fmaf(ea, v1, s1[q]);
      s2[q] = fmaf(ea, v2, s2[q]);
    }
  }
  #pragma unroll
  for (int d=1; d<16; d<<=1){
    #pragma unroll
    for (int q=0;q<4;q++){
      s0[q] += __shfl_xor(s0[q], d);
      s1[q] += __shfl_xor(s1[q], d);
      s2[q] += __shfl_xor(s2[q], d);
    }
  }
  if (m16==0){
    #pragma unroll
    for (int q=0;q<4;q++){
      int e = e0 + mrow + q;
      if (e < E){
        unsigned sv = (unsigned)src[e];
        unsigned h0 = (__half_as_ushort(__float2half(s0[q])) & 0xFFFEu) | (sv >> 16);
        unsigned h1 = __half_as_ushort(__float2half(s1[q]));
        unsigned h2 = __half_as_ushort(__float2half(s2[q]));
        esc8[e] = make_uint2(h0 | (h1<<16), (sv & 0xFFFFu) | (h2<<16));
        atomicAdd(&deg[dst[e]], 1);
      }
    }
  }
}

// ---- hierarchical scan of deg -> off (exclusive) ----
__global__ void k_bsum(const int* __restrict__ deg, int* __restrict__ bsum, int N){
  int i = blockIdx.x*256 + threadIdx.x;
  int v = (i<N) ? deg[i] : 0;
  #pragma unroll
  for(int d=32; d; d>>=1) v += __shfl_xor(v, d);
  __shared__ int sh[4];
  if ((threadIdx.x&63)==0) sh[threadIdx.x>>6] = v;
  __syncthreads();
  if (threadIdx.x==0) bsum[blockIdx.x] = sh[0]+sh[1]+sh[2]+sh[3];
}

__global__ void k_bscan(const int* __restrict__ bsum, int* __restrict__ boff, int NB,
                        int* __restrict__ offN, int EN){
  __shared__ int sh[1024];
  int tid = threadIdx.x;
  int v = (tid<NB) ? bsum[tid] : 0;
  sh[tid] = v;
  __syncthreads();
  for(int d=1; d<1024; d<<=1){
    int t = 0;
    if (tid>=d) t = sh[tid-d];
    __syncthreads();
    if (tid>=d) sh[tid] += t;
    __syncthreads();
  }
  if (tid<NB) boff[tid] = sh[tid] - v;  // exclusive
  if (tid==0) offN[0] = EN;
}

__global__ void k_scan_fin(const int* __restrict__ deg, const int* __restrict__ boff,
                           int* __restrict__ off, int N){
  __shared__ int sh[256];
  int i = blockIdx.x*256 + threadIdx.x;
  int v = (i<N) ? deg[i] : 0;
  sh[threadIdx.x] = v;
  __syncthreads();
  for(int d=1; d<256; d<<=1){
    int t = 0;
    if (threadIdx.x>=d) t = sh[threadIdx.x-d];
    __syncthreads();
    if (threadIdx.x>=d) sh[threadIdx.x] += t;
    __syncthreads();
  }
  if (i<N) off[i] = boff[blockIdx.x] + sh[threadIdx.x] - v;
}

// bcur[b] = number of real edges before bucket b = off[b*BNODE] - b*BNODE
__global__ void k_binit(const int* __restrict__ off, int* __restrict__ bcur, int N, int NBK){
  int b = blockIdx.x*blockDim.x + threadIdx.x;
  if (b >= 256) return;
  int n0 = b*BNODE; if (n0 > N) n0 = N;
  bcur[b] = (b <= NBK) ? off[n0] - n0 : 0;
}

// pass A: LDS-binned append of 8B records + 2B dstlocal into per-bucket compact regions.
__global__ void __launch_bounds__(256)
k_binA(const uint2* __restrict__ esc8, const int* __restrict__ dst,
       int* __restrict__ bcur, uint2* __restrict__ bin8, unsigned short* __restrict__ bin2,
       int E){
  __shared__ int cnt[256];
  __shared__ int ofs[256];
  __shared__ int gofs[256];
  __shared__ uint2 st8[ACH];
  __shared__ unsigned short st2[ACH];
  __shared__ unsigned char sbid[ACH];
  int tid = threadIdx.x;
  int base = blockIdx.x * ACH;
  cnt[tid] = 0;
  __syncthreads();
  uint2 r8[8]; int bb[8]; int ms[8]; int dl[8];
  #pragma unroll
  for (int k=0;k<8;k++){
    int e = base + tid + k*256;
    bb[k] = -1;
    if (e < E){
      r8[k] = esc8[e];
      int d = dst[e];
      bb[k] = d >> 9;
      dl[k] = d & (BNODE-1);
      ms[k] = atomicAdd(&cnt[bb[k]], 1);
    }
  }
  __syncthreads();
  int v = cnt[tid];
  ofs[tid] = v;
  __syncthreads();
  for (int d=1; d<256; d<<=1){
    int t = 0;
    if (tid>=d) t = ofs[tid-d];
    __syncthreads();
    if (tid>=d) ofs[tid] += t;
    __syncthreads();
  }
  int total = ofs[255];
  int excl = ofs[tid] - v;
  __syncthreads();
  ofs[tid] = excl;
  __syncthreads();
  #pragma unroll
  for (int k=0;k<8;k++){
    if (bb[k] >= 0){
      int slot = ofs[bb[k]] + ms[k];
      st8[slot] = r8[k];
      st2[slot] = (unsigned short)dl[k];
      sbid[slot] = (unsigned char)bb[k];
    }
  }
  if (v > 0) gofs[tid] = atomicAdd(&bcur[tid], v);
  __syncthreads();
  for (int slot = tid; slot < total; slot += 256){
    int b = sbid[slot];
    int gp = gofs[b] + (slot - ofs[b]);
    bin8[gp] = st8[slot];
    bin2[gp] = st2[slot];
  }
}

// pass B: one WG per bucket; scatter within the bucket's L2-local CSR window.
__global__ void __launch_bounds__(256)
k_binB(const uint2* __restrict__ bin8, const unsigned short* __restrict__ bin2,
       const int* __restrict__ off, uint2* __restrict__ rec, int N){
  __shared__ int lcur[BNODE];
  int b = blockIdx.x;
  int n0 = b*BNODE;
  int n1 = n0 + BNODE; if (n1 > N) n1 = N;
  int nn = n1 - n0;
  for (int i = threadIdx.x; i < nn; i += 256) lcur[i] = off[n0+i] + 1;  // slot off[n] = self-loop
  __syncthreads();
  int ebeg = off[n0] - n0;
  int eend = off[n1] - n1;
  for (int idx = ebeg + threadIdx.x; idx < eend; idx += 256){
    uint2 r = bin8[idx];
    int dl = bin2[idx];
    int p = atomicAdd(&lcur[dl], 1);
    rec[p] = r;
  }
}

// self-loop record at off[n]: mean of segment's real-edge scores (0 if none), src=n
__global__ void k_selfloop_csr(const int* __restrict__ off, uint2* __restrict__ rec, int N){
  int n = blockIdx.x*blockDim.x+threadIdx.x;
  if (n>=N) return;
  int a = off[n]+1, b = off[n+1];
  float s0=0.f,s1=0.f,s2=0.f;
  for (int p=a;p<b;p++){
    uint2 r=rec[p];
    s0 += h2f_(r.x & 0xFFFEu);
    s1 += h2f_(r.x >> 16);
    s2 += h2f_(r.y >> 16);
  }
  float inv = (b>a) ? 1.0f/(float)(b-a) : 0.0f;
  unsigned h0 = __half_as_ushort(__float2half(s0*inv)) & 0xFFFEu;
  unsigned h1 = __half_as_ushort(__float2half(s1*inv));
  unsigned h2 = __half_as_ushort(__float2half(s2*inv));
  unsigned s = (unsigned)n;
  rec[off[n]] = make_uint2(h0 | (s>>16) | (h1<<16), (s & 0xFFFFu) | (h2<<16));
}

// graph boundaries from sorted batch
__global__ void k_gbounds(const int* __restrict__ batch, int* __restrict__ gstart, int N, int G){
  int n = blockIdx.x*blockDim.x+threadIdx.x;
  if (n>=N) return;
  int b = batch[n];
  int bp = (n==0) ? -1 : batch[n-1];
  for (int g=bp+1; g<=b; g++) gstart[g]=n;
  if (n==N-1){ for (int g=b+1; g<=G; g++) gstart[g]=N; }
}

// MFMA GRU: block = 64 nodes (4 waves x 16-node strip), no LDS.
__global__ void __launch_bounds__(256,4)
k_gru_m(const short* __restrict__ hg16, const float* __restrict__ xin, float* __restrict__ xout,
        const short* __restrict__ WihT16, const short* __restrict__ WhhT16,
        const float* __restrict__ bih, const float* __restrict__ bhh, int N){
  int lane = threadIdx.x & 63, w = threadIdx.x >> 6;
  int m16 = lane & 15;
  int kb  = lane >> 4;
  int n0 = blockIdx.x*64 + w*16;

  int arow = n0 + m16; if (arow > N-1) arow = N-1;
  const short* hrow = hg16 + (size_t)arow*H_ + kb*8;
  bf16x8 ah0 = *(const bf16x8*)(hrow);
  bf16x8 ah1 = *(const bf16x8*)(hrow + 32);
  const float* xrow = xin + (size_t)arow*H_ + kb*8;
  float4 xa = *(const float4*)(xrow),    xb = *(const float4*)(xrow+4);
  float4 xc = *(const float4*)(xrow+32), xd = *(const float4*)(xrow+36);
  bf16x8 ax0, ax1;
  ax0[0]=f2bf(xa.x); ax0[1]=f2bf(xa.y); ax0[2]=f2bf(xa.z); ax0[3]=f2bf(xa.w);
  ax0[4]=f2bf(xb.x); ax0[5]=f2bf(xb.y); ax0[6]=f2bf(xb.z); ax0[7]=f2bf(xb.w);
  ax1[0]=f2bf(xc.x); ax1[1]=f2bf(xc.y); ax1[2]=f2bf(xc.z); ax1[3]=f2bf(xc.w);
  ax1[4]=f2bf(xd.x); ax1[5]=f2bf(xd.y); ax1[6]=f2bf(xd.z); ax1[7]=f2bf(xd.w);

  f32x4 aR[4], aZ[4], aNi[4], aNh[4];
  #pragma unroll
  for (int t=0;t<4;t++){
    aR[t]=(f32x4){0.f,0.f,0.f,0.f}; aZ[t]=(f32x4){0.f,0.f,0.f,0.f};
    aNi[t]=(f32x4){0.f,0.f,0.f,0.f}; aNh[t]=(f32x4){0.f,0.f,0.f,0.f};
  }

  const short* wi = WihT16 + (size_t)m16*H_ + kb*8;
  const short* wh = WhhT16 + (size_t)m16*H_ + kb*8;
  #pragma unroll
  for (int t=0;t<4;t++){
    bf16x8 b;
    b = *(const bf16x8*)(wi + (size_t)(t*16)*H_);
    aR[t] = __builtin_amdgcn_mfma_f32_16x16x32_bf16(ah0, b, aR[t], 0,0,0);
    b = *(const bf16x8*)(wi + (size_t)(t*16)*H_ + 32);
    aR[t] = __builtin_amdgcn_mfma_f32_16x16x32_bf16(ah1, b, aR[t], 0,0,0);
    b = *(const bf16x8*)(wh + (size_t)(t*16)*H_);
    aR[t] = __builtin_amdgcn_mfma_f32_16x16x32_bf16(ax0, b, aR[t], 0,0,0);
    b = *(const bf16x8*)(wh + (size_t)(t*16)*H_ + 32);
    aR[t] = __builtin_amdgcn_mfma_f32_16x16x32_bf16(ax1, b, aR[t], 0,0,0);
    b = *(const bf16x8*)(wi + (size_t)(64+t*16)*H_);
    aZ[t] = __builtin_amdgcn_mfma_f32_16x16x32_bf16(ah0, b, aZ[t], 0,0,0);
    b = *(const bf16x8*)(wi + (size_t)(64+t*16)*H_ + 32);
    aZ[t] = __builtin_amdgcn_mfma_f32_16x16x32_bf16(ah1, b, aZ[t], 0,0,0);
    b = *(const bf16x8*)(wh + (size_t)(64+t*16)*H_);
    aZ[t] = __builtin_amdgcn_mfma_f32_16x16x32_bf16(ax0, b, aZ[t], 0,0,0);
    b = *(const bf16x8*)(wh + (size_t)(64+t*16)*H_ + 32);
    aZ[t] = __builtin_amdgcn_mfma_f32_16x16x32_bf16(ax1, b, aZ[t], 0,0,0);
    b = *(const bf16x8*)(wi + (size_t)(128+t*16)*H_);
    aNi[t] = __builtin_amdgcn_mfma_f32_16x16x32_bf16(ah0, b, aNi[t], 0,0,0);
    b = *(const bf16x8*)(wi + (size_t)(128+t*16)*H_ + 32);
    aNi[t] = __builtin_amdgcn_mfma_f32_16x16x32_bf16(ah1, b, aNi[t], 0,0,0);
    b = *(const bf16x8*)(wh + (size_t)(128+t*16)*H_);
    aNh[t] = __builtin_amdgcn_mfma_f32_16x16x32_bf16(ax0, b, aNh[t], 0,0,0);
    b = *(const bf16x8*)(wh + (size_t)(128+t*16)*H_ + 32);
    aNh[t] = __builtin_amdgcn_mfma_f32_16x16x32_bf16(ax1, b, aNh[t], 0,0,0);
  }

  int mrow = (lane>>4)*4;
  #pragma unroll
  for (int t=0;t<4;t++){
    int f = t*16 + m16;
    float br = bih[f]     + bhh[f];
    float bz = bih[64+f]  + bhh[64+f];
    float bin= bih[128+f], bhn = bhh[128+f];
    #pragma unroll
    for (int q=0;q<4;q++){
      int node = n0 + mrow + q;
      if (node < N){
        float r  = sigm_(aR[t][q] + br);
        float z  = sigm_(aZ[t][q] + bz);
        float nn = tanh_(aNi[t][q] + bin + r*(aNh[t][q] + bhn));
        float xv = xin[(size_t)node*H_ + f];
        xout[(size_t)node*H_ + f] = fmaxf((1.f-z)*nn + z*xv, 0.f);
      }
    }
  }
}

// MFMA linear-h: h16 = fp16(xi @ conv_W[l]); ssc/dsc via shfl_xor reduce. No LDS.
__global__ void __launch_bounds__(256,4)
k_linh_m(const float* __restrict__ xi, const short* __restrict__ wT16,
         const float* __restrict__ atts, const float* __restrict__ attd,
         __half* __restrict__ h16, float* __restrict__ ssc, float* __restrict__ dsc, int N){
  int lane = threadIdx.x & 63, w = threadIdx.x >> 6;
  int m16 = lane & 15, kb = lane >> 4;
  int n0 = blockIdx.x*64 + w*16;
  int arow = n0 + m16; if (arow > N-1) arow = N-1;
  const float* xrow = xi + (size_t)arow*H_ + kb*8;
  float4 xa = *(const float4*)(xrow),    xb = *(const float4*)(xrow+4);
  float4 xc = *(const float4*)(xrow+32), xd = *(const float4*)(xrow+36);
  bf16x8 ax0, ax1;
  ax0[0]=f2bf(xa.x); ax0[1]=f2bf(xa.y); ax0[2]=f2bf(xa.z); ax0[3]=f2bf(xa.w);
  ax0[4]=f2bf(xb.x); ax0[5]=f2bf(xb.y); ax0[6]=f2bf(xb.z); ax0[7]=f2bf(xb.w);
  ax1[0]=f2bf(xc.x); ax1[1]=f2bf(xc.y); ax1[2]=f2bf(xc.z); ax1[3]=f2bf(xc.w);
  ax1[4]=f2bf(xd.x); ax1[5]=f2bf(xd.y); ax1[6]=f2bf(xd.z); ax1[7]=f2bf(xd.w);

  f32x4 acc[4];
  #pragma unroll
  for (int t=0;t<4;t++) acc[t]=(f32x4){0.f,0.f,0.f,0.f};
  const short* wp = wT16 + (size_t)m16*H_ + kb*8;
  #pragma unroll
  for (int t=0;t<4;t++){
    bf16x8 b0 = *(const bf16x8*)(wp + (size_t)(t*16)*H_);
    acc[t] = __builtin_amdgcn_mfma_f32_16x16x32_bf16(ax0, b0, acc[t], 0,0,0);
    bf16x8 b1 = *(const bf16x8*)(wp + (size_t)(t*16)*H_ + 32);
    acc[t] = __builtin_amdgcn_mfma_f32_16x16x32_bf16(ax1, b1, acc[t], 0,0,0);
  }

  int mrow = (lane>>4)*4;
  float ps[4]={0.f,0.f,0.f,0.f}, pd[4]={0.f,0.f,0.f,0.f};
  #pragma unroll
  for (int t=0;t<4;t++){
    int f = t*16 + m16;
    float as = atts[f], ad = attd[f];
    #pragma unroll
    for (int q=0;q<4;q++){
      int node = n0 + mrow + q;
      float v = acc[t][q];
      if (node < N) h16[(size_t)node*H_ + f] = __float2half(v);
      ps[q] = fmaf(v, as, ps[q]); pd[q] = fmaf(v, ad, pd[q]);
    }
  }
  #pragma unroll
  for (int d=1; d<16; d<<=1){
    #pragma unroll
    for (int q=0;q<4;q++){ ps[q] += __shfl_xor(ps[q], d); pd[q] += __shfl_xor(pd[q], d); }
  }
  if (m16==0){
    #pragma unroll
    for (int q=0;q<4;q++){
      int node = n0 + mrow + q;
      if (node < N){ ssc[node]=ps[q]; dsc[node]=pd[q]; }
    }
  }
}

// GAT: 4 nodes/wave, 16 lanes/node (half4 = 4 features/lane). Single-pass safe-exp softmax.
template<int L>
__global__ void __launch_bounds__(256)
k_gat_g4(const __half* __restrict__ h16, const float* __restrict__ ssc,
         const float* __restrict__ dsc, const uint2* __restrict__ rec,
         const int* __restrict__ off, const float* __restrict__ bias,
         short* __restrict__ hgat16, int N){
  int lane = threadIdx.x & 63, w = threadIdx.x >> 6;
  int g = lane >> 4, fl = lane & 15;
  int node = blockIdx.x*16 + w*4 + g;
  if (node >= N) return;
  int e0 = off[node], e1 = off[node+1];
  float dval = dsc[node];
  float acc0=0.f, acc1=0.f, acc2=0.f, acc3=0.f, den=0.f;
  int gbase = lane & 48;                 // g*16
  for (int base = e0; base < e1; base += 16){
    int p = base + fl;
    float ex = 0.f; int s = 0;
    if (p < e1){
      uint2 r = rec[p];
      s = (int)((r.y & 0xFFFFu) | ((r.x & 1u) << 16));
      unsigned hb = (L==0) ? (r.x & 0xFFFEu) : (L==1) ? (r.x >> 16) : (r.y >> 16);
      float a = ssc[s] + dval + h2f_(hb);
      a = (a > 0.f) ? a : SLOPE*a;
      ex = __expf(a);
    }
    den += ex;
    int cnt = e1 - base; if (cnt > 16) cnt = 16;
    for (int j = 0; j < cnt; j++){
      float exb = __shfl(ex, gbase + j);
      int   sb  = __shfl(s,  gbase + j);
      uint2 hv = *(const uint2*)(h16 + (size_t)sb*H_ + 4*fl);
      float2 f0 = __half22float2(*(__half2*)&hv.x);
      float2 f1 = __half22float2(*(__half2*)&hv.y);
      acc0 = fmaf(exb, f0.x, acc0);
      acc1 = fmaf(exb, f0.y, acc1);
      acc2 = fmaf(exb, f1.x, acc2);
      acc3 = fmaf(exb, f1.y, acc3);
    }
  }
  #pragma unroll
  for (int d=1; d<16; d<<=1) den += __shfl_xor(den, d);
  float4 bv = *(const float4*)(bias + 4*fl);
  float inv = 1.0f/den;
  float v0 = fmaxf(fmaf(acc0,inv,bv.x), 0.f);
  float v1 = fmaxf(fmaf(acc1,inv,bv.y), 0.f);
  float v2 = fmaxf(fmaf(acc2,inv,bv.z), 0.f);
  float v3 = fmaxf(fmaf(acc3,inv,bv.w), 0.f);
  uint2 o;
  o.x = ((unsigned)(unsigned short)f2bf(v1)<<16) | (unsigned short)f2bf(v0);
  o.y = ((unsigned)(unsigned short)f2bf(v3)<<16) | (unsigned short)f2bf(v2);
  *(uint2*)(hgat16 + (size_t)node*H_ + 4*fl) = o;
}

// block per graph: zero-atomic pooled output (batch is sorted)
__global__ void __launch_bounds__(256)
k_pool_g(const float* __restrict__ xi, const float* __restrict__ wout,
         const int* __restrict__ gstart, const float* __restrict__ b_out,
         float* __restrict__ out){
  int g = blockIdx.x;
  int a = gstart[g], b = gstart[g+1];
  float acc = 0.f;
  for (int n = a + threadIdx.x; n < b; n += 256){
    const float4* xr = (const float4*)(xi + (size_t)n*H_);
    float s = 0.f;
    #pragma unroll
    for (int q=0;q<H_/4;q++){
      float4 v = xr[q];
      s += v.x*wout[4*q] + v.y*wout[4*q+1] + v.z*wout[4*q+2] + v.w*wout[4*q+3];
    }
    acc += s;
  }
  #pragma unroll
  for (int d=32; d; d>>=1) acc += __shfl_xor(acc, d);
  __shared__ float sh[4];
  if ((threadIdx.x&63)==0) sh[threadIdx.x>>6] = acc;
  __syncthreads();
  if (threadIdx.x==0) out[g] = sh[0]+sh[1]+sh[2]+sh[3] + b_out[0];
}

extern "C" void kernel_launch(void* const* d_in, const int* in_sizes, int n_in,
                              void* d_out, int out_size, void* d_ws, size_t ws_size,
                              hipStream_t stream){
  const float* x       = (const float*)d_in[0];
  const float* eattr   = (const float*)d_in[1];
  const float* w_node  = (const float*)d_in[2];
  const float* b_node  = (const float*)d_in[3];
  const float* w_edge  = (const float*)d_in[4];
  const float* b_edge  = (const float*)d_in[5];
  const float* conv_W  = (const float*)d_in[6];
  const float* conv_We = (const float*)d_in[7];
  const float* att_s   = (const float*)d_in[8];
  const float* att_d   = (const float*)d_in[9];
  const float* att_e   = (const float*)d_in[10];
  const float* conv_b  = (const float*)d_in[11];
  const float* gWih    = (const float*)d_in[12];
  const float* gWhh    = (const float*)d_in[13];
  const float* gbih    = (const float*)d_in[14];
  const float* gbhh    = (const float*)d_in[15];
  const float* w_out   = (const float*)d_in[16];
  const float* b_out   = (const float*)d_in[17];
  const int*   eidx    = (const int*)d_in[18];
  const int*   batch   = (const int*)d_in[19];
  float* out = (float*)d_out;

  int N = in_sizes[0]/DIN;
  int E = in_sizes[1]/DE;
  int G = out_size;
  int EN = E + N;
  const int* src = eidx;
  const int* dst = eidx + E;

  char* p = (char*)d_ws;
  auto carve = [&](size_t bytes)->void*{ void* r=(void*)p; p += (bytes+255)&~(size_t)255; return r; };
  float*  xi0    = (float*)carve((size_t)N*H_*4);
  float*  xi1    = (float*)carve((size_t)N*H_*4);
  __half* h16    = (__half*)carve((size_t)N*H_*2);
  short*  hgat16 = (short*)carve((size_t)N*H_*2);
  float*  ssc    = (float*)carve((size_t)N*4);
  float*  dsc    = (float*)carve((size_t)N*4);
  uint2*  esc8   = (uint2*)carve((size_t)E*8);
  uint2*  rec    = (uint2*)carve((size_t)EN*8);
  uint2*  bin8   = (uint2*)carve((size_t)E*8);
  unsigned short* bin2 = (unsigned short*)carve((size_t)E*2);
  int*    deg    = (int*)carve((size_t)N*4);
  int*    off    = (int*)carve((size_t)(N+1)*4);
  int*    bcur   = (int*)carve((size_t)256*4);
  int*    gstart = (int*)carve((size_t)(G+1)*4);
  int*    bsum   = (int*)carve((size_t)1024*4);
  int*    boff   = (int*)carve((size_t)1024*4);
  short*  wnT16  = (short*)carve((size_t)DIN*H_*2);
  short*  weT16p = (short*)carve((size_t)64*32*2);
  short*  cWT16  = (short*)carve((size_t)3*H_*H_*2);
  short*  WihT16 = (short*)carve((size_t)3*192*H_*2);
  short*  WhhT16 = (short*)carve((size_t)3*192*H_*2);
  float*  ve     = (float*)carve((size_t)3*H_*4);

  auto cdiv=[](int a,int b){return (a+b-1)/b;};
  int NB  = cdiv(N,256);
  int NBK = cdiv(N,BNODE);

  int prep_total = 2048+2048+12288+36864+36864+192+N;
  k_prep<<<cdiv(prep_total,256),256,0,stream>>>(w_node, w_edge, conv_W, gWih, gWhh, conv_We, att_e,
                                                wnT16, weT16p, cWT16, WihT16, WhhT16, ve, deg, N);
  k_nmlp_m<<<cdiv(N,64),256,0,stream>>>(x, wnT16, b_node, xi0, N);
  k_edge_m<<<cdiv(E,64),256,0,stream>>>(eattr, weT16p, b_edge, ve, src, dst, esc8, deg, E);
  k_bsum<<<NB,256,0,stream>>>(deg, bsum, N);
  k_bscan<<<1,1024,0,stream>>>(bsum, boff, NB, off+N, EN);
  k_scan_fin<<<NB,256,0,stream>>>(deg, boff, off, N);
  k_binit<<<1,256,0,stream>>>(off, bcur, N, NBK);
  k_binA<<<cdiv(E,ACH),256,0,stream>>>(esc8, dst, bcur, bin8, bin2, E);
  k_binB<<<NBK,256,0,stream>>>(bin8, bin2, off, rec, N);
  k_selfloop_csr<<<cdiv(N,256),256,0,stream>>>(off, rec, N);
  k_gbounds<<<NB,256,0,stream>>>(batch, gstart, N, G);

  int NB64 = cdiv(N,64);
  int NB16 = cdiv(N,16);
  for (int l=0; l<3; l++){
    const float* xin = (l&1) ? xi1 : xi0;
    float*       xo  = (l&1) ? xi0 : xi1;
    k_linh_m<<<NB64,256,0,stream>>>(xin, cWT16 + (size_t)l*H_*H_, att_s + l*H_, att_d + l*H_,
                                    h16, ssc, dsc, N);
    if (l==0)      k_gat_g4<0><<<NB16,256,0,stream>>>(h16, ssc, dsc, rec, off, conv_b + l*H_, hgat16, N);
    else if (l==1) k_gat_g4<1><<<NB16,256,0,stream>>>(h16, ssc, dsc, rec, off, conv_b + l*H_, hgat16, N);
    else           k_gat_g4<2><<<NB16,256,0,stream>>>(h16, ssc, dsc, rec, off, conv_b + l*H_, hgat16, N);
    k_gru_m<<<NB64,256,0,stream>>>(hgat16, xin, xo, WihT16 + (size_t)l*192*H_, WhhT16 + (size_t)l*192*H_,
                                   gbih + l*3*H_, gbhh + l*3*H_, N);
  }

  k_pool_g<<<G,256,0,stream>>>(xi1, w_out, gstart, b_out, out);
}

// Round 16
// 422.000 us; speedup vs baseline: 41.6694x; 1.0174x over previous
//
#include <hip/hip_runtime.h>
#include <hip/hip_fp16.h>

constexpr int H_  = 64;   // hidden
constexpr int DIN = 32;   // atom feature dim
constexpr int DE  = 16;   // edge feature dim
constexpr int BNODE = 512;  // nodes per scatter bucket (dstlocal < 512)
constexpr int ACH   = 2048; // edges per binning chunk
constexpr int CAP   = 6144; // per-bucket region capacity (mean 5120 + 14 sigma)
#define SLOPE 0.2f

typedef __attribute__((ext_vector_type(8))) short bf16x8;
typedef __attribute__((ext_vector_type(4))) float f32x4;

__device__ __forceinline__ float sigm_(float x){ return 1.0f/(1.0f+__expf(-x)); }
__device__ __forceinline__ float tanh_(float x){ float e=__expf(2.0f*x); return 1.0f - 2.0f/(e+1.0f); }
__device__ __forceinline__ short f2bf(float f){   // RNE float->bf16
  unsigned u = __float_as_uint(f);
  u += 0x7FFF + ((u>>16)&1);
  return (short)(u>>16);
}
__device__ __forceinline__ float h2f_(unsigned hb){
  return __half2float(__ushort_as_half((unsigned short)hb));
}

// one mega-kernel for all weight prep + bcur init
__global__ void k_prep(const float* __restrict__ w_node, const float* __restrict__ w_edge,
                       const float* __restrict__ conv_W, const float* __restrict__ gWih,
                       const float* __restrict__ gWhh, const float* __restrict__ conv_We,
                       const float* __restrict__ att_e,
                       short* __restrict__ wnT16, short* __restrict__ weT16p,
                       short* __restrict__ cWT16, short* __restrict__ WihT16,
                       short* __restrict__ WhhT16, float* __restrict__ ve,
                       int* __restrict__ bcur){
  int id = blockIdx.x*blockDim.x + threadIdx.x;
  if (id < 2048){                                   // wnT16 [64][32]
    int j = id >> 5, k = id & 31;
    wnT16[id] = f2bf(w_node[k*64 + j]);
    return;
  }
  id -= 2048;
  if (id < 2048){                                   // weT16p [64][32], k>=16 zero
    int j = id >> 5, k = id & 31;
    weT16p[id] = (k < DE) ? f2bf(w_edge[k*64 + j]) : (short)0;
    return;
  }
  id -= 2048;
  if (id < 12288){                                  // cWT16 [3][64 j][64 k]
    int l = id / 4096, rem = id & 4095, j = rem >> 6, k = rem & 63;
    cWT16[id] = f2bf(conv_W[l*4096 + k*64 + j]);
    return;
  }
  id -= 12288;
  if (id < 36864){                                  // WihT16 [3][192 j][64 k]
    int l = id / 12288, rem = id % 12288, j = rem >> 6, k = rem & 63;
    WihT16[id] = f2bf(gWih[l*12288 + k*192 + j]);
    return;
  }
  id -= 36864;
  if (id < 36864){                                  // WhhT16
    int l = id / 12288, rem = id % 12288, j = rem >> 6, k = rem & 63;
    WhhT16[id] = f2bf(gWhh[l*12288 + k*192 + j]);
    return;
  }
  id -= 36864;
  if (id < 192){                                    // ve[l][k]
    int l = id >> 6, k = id & 63;
    const float* w = conv_We + (size_t)(l*64+k)*64;
    const float* a = att_e + l*64;
    float s = 0.f;
    #pragma unroll
    for (int j=0;j<64;j++) s += w[j]*a[j];
    ve[id] = s;
    return;
  }
  id -= 192;
  if (id < 256) bcur[id] = id*CAP;                  // fixed-capacity bucket regions
}

// MFMA node MLP: xi = relu(x @ w_node + b), K=32 exact. No LDS.
__global__ void __launch_bounds__(256,4)
k_nmlp_m(const float* __restrict__ x, const short* __restrict__ wT16,
         const float* __restrict__ b, float* __restrict__ xi, int N){
  int lane = threadIdx.x & 63, w = threadIdx.x >> 6;
  int m16 = lane & 15, kb = lane >> 4;
  int n0 = blockIdx.x*64 + w*16;
  int arow = n0 + m16; if (arow > N-1) arow = N-1;
  const float* xr = x + (size_t)arow*DIN + kb*8;
  float4 a0 = *(const float4*)xr, a1 = *(const float4*)(xr+4);
  bf16x8 af;
  af[0]=f2bf(a0.x); af[1]=f2bf(a0.y); af[2]=f2bf(a0.z); af[3]=f2bf(a0.w);
  af[4]=f2bf(a1.x); af[5]=f2bf(a1.y); af[6]=f2bf(a1.z); af[7]=f2bf(a1.w);
  f32x4 acc[4];
  #pragma unroll
  for (int t=0;t<4;t++) acc[t]=(f32x4){0.f,0.f,0.f,0.f};
  const short* wp = wT16 + (size_t)m16*DIN + kb*8;
  #pragma unroll
  for (int t=0;t<4;t++){
    bf16x8 bb = *(const bf16x8*)(wp + (size_t)(t*16)*DIN);
    acc[t] = __builtin_amdgcn_mfma_f32_16x16x32_bf16(af, bb, acc[t], 0,0,0);
  }
  int mrow = (lane>>4)*4;
  #pragma unroll
  for (int t=0;t<4;t++){
    int f = t*16 + m16;
    float bj = b[f];
    #pragma unroll
    for (int q=0;q<4;q++){
      int node = n0 + mrow + q;
      if (node < N) xi[(size_t)node*H_ + f] = fmaxf(acc[t][q] + bj, 0.f);
    }
  }
}

// MFMA edge scores: 16 edges/wave, packed 8B record with src bits spliced in. No atomics.
__global__ void __launch_bounds__(256,4)
k_edge_m(const float* __restrict__ attr, const short* __restrict__ weT16p,
         const float* __restrict__ be, const float* __restrict__ ve,
         const int* __restrict__ src, uint2* __restrict__ esc8, int E){
  int lane = threadIdx.x & 63, w = threadIdx.x >> 6;
  int m16 = lane & 15, kb = lane >> 4;
  int e0 = (blockIdx.x*4 + w)*16;
  if (e0 >= E) return;
  bf16x8 af = {0,0,0,0,0,0,0,0};
  if (kb < 2){
    int arow = e0 + m16; if (arow > E-1) arow = E-1;
    const float* ap = attr + (size_t)arow*DE + kb*8;
    float4 a0 = *(const float4*)ap, a1 = *(const float4*)(ap+4);
    af[0]=f2bf(a0.x); af[1]=f2bf(a0.y); af[2]=f2bf(a0.z); af[3]=f2bf(a0.w);
    af[4]=f2bf(a1.x); af[5]=f2bf(a1.y); af[6]=f2bf(a1.z); af[7]=f2bf(a1.w);
  }
  f32x4 acc[4];
  #pragma unroll
  for (int t=0;t<4;t++) acc[t]=(f32x4){0.f,0.f,0.f,0.f};
  const short* wp = weT16p + (size_t)m16*32 + kb*8;
  #pragma unroll
  for (int t=0;t<4;t++){
    bf16x8 bb = *(const bf16x8*)(wp + (size_t)(t*16)*32);
    acc[t] = __builtin_amdgcn_mfma_f32_16x16x32_bf16(af, bb, acc[t], 0,0,0);
  }
  int mrow = (lane>>4)*4;
  float s0[4]={0.f,0.f,0.f,0.f}, s1[4]={0.f,0.f,0.f,0.f}, s2[4]={0.f,0.f,0.f,0.f};
  #pragma unroll
  for (int t=0;t<4;t++){
    int j = t*16 + m16;
    float bj = be[j];
    float v0 = ve[j], v1 = ve[64+j], v2 = ve[128+j];
    #pragma unroll
    for (int q=0;q<4;q++){
      float ea = fmaxf(acc[t][q] + bj, 0.f);
      s0[q] = fmaf(ea, v0, s0[q]);
      s1[q] = fmaf(ea, v1, s1[q]);
      s2[q] = fmaf(ea, v2, s2[q]);
    }
  }
  #pragma unroll
  for (int d=1; d<16; d<<=1){
    #pragma unroll
    for (int q=0;q<4;q++){
      s0[q] += __shfl_xor(s0[q], d);
      s1[q] += __shfl_xor(s1[q], d);
      s2[q] += __shfl_xor(s2[q], d);
    }
  }
  if (m16==0){
    #pragma unroll
    for (int q=0;q<4;q++){
      int e = e0 + mrow + q;
      if (e < E){
        unsigned sv = (unsigned)src[e];
        unsigned h0 = (__half_as_ushort(__float2half(s0[q])) & 0xFFFEu) | (sv >> 16);
        unsigned h1 = __half_as_ushort(__float2half(s1[q]));
        unsigned h2 = __half_as_ushort(__float2half(s2[q]));
        esc8[e] = make_uint2(h0 | (h1<<16), (sv & 0xFFFFu) | (h2<<16));
      }
    }
  }
}

// pass A: LDS-binned append of 8B records + 2B dstlocal into fixed per-bucket regions.
__global__ void __launch_bounds__(256)
k_binA(const uint2* __restrict__ esc8, const int* __restrict__ dst,
       int* __restrict__ bcur, uint2* __restrict__ bin8, unsigned short* __restrict__ bin2,
       int E){
  __shared__ int cnt[256];
  __shared__ int ofs[256];
  __shared__ int gofs[256];
  __shared__ uint2 st8[ACH];
  __shared__ unsigned short st2[ACH];
  __shared__ unsigned char sbid[ACH];
  int tid = threadIdx.x;
  int base = blockIdx.x * ACH;
  cnt[tid] = 0;
  __syncthreads();
  uint2 r8[8]; int bb[8]; int ms[8]; int dl[8];
  #pragma unroll
  for (int k=0;k<8;k++){
    int e = base + tid + k*256;
    bb[k] = -1;
    if (e < E){
      r8[k] = esc8[e];
      int d = dst[e];
      bb[k] = d >> 9;
      dl[k] = d & (BNODE-1);
      ms[k] = atomicAdd(&cnt[bb[k]], 1);
    }
  }
  __syncthreads();
  int v = cnt[tid];
  ofs[tid] = v;
  __syncthreads();
  for (int d=1; d<256; d<<=1){
    int t = 0;
    if (tid>=d) t = ofs[tid-d];
    __syncthreads();
    if (tid>=d) ofs[tid] += t;
    __syncthreads();
  }
  int total = ofs[255];
  int excl = ofs[tid] - v;
  __syncthreads();
  ofs[tid] = excl;
  __syncthreads();
  #pragma unroll
  for (int k=0;k<8;k++){
    if (bb[k] >= 0){
      int slot = ofs[bb[k]] + ms[k];
      st8[slot] = r8[k];
      st2[slot] = (unsigned short)dl[k];
      sbid[slot] = (unsigned char)bb[k];
    }
  }
  if (v > 0) gofs[tid] = atomicAdd(&bcur[tid], v);
  __syncthreads();
  for (int slot = tid; slot < total; slot += 256){
    int b = sbid[slot];
    int gp = gofs[b] + (slot - ofs[b]);
    bin8[gp] = st8[slot];
    bin2[gp] = st2[slot];
  }
}

// per-bucket LDS histogram -> deg (zero global atomics)
__global__ void __launch_bounds__(256)
k_hist(const unsigned short* __restrict__ bin2, const int* __restrict__ bcur,
       int* __restrict__ deg, int N){
  __shared__ int lcnt[BNODE];
  int b = blockIdx.x;
  int n0 = b*BNODE;
  int n1 = n0 + BNODE; if (n1 > N) n1 = N;
  int nn = n1 - n0;
  for (int i = threadIdx.x; i < nn; i += 256) lcnt[i] = 0;
  __syncthreads();
  int beg = b*CAP, cntb = bcur[b] - beg;
  for (int idx = threadIdx.x; idx < cntb; idx += 256)
    atomicAdd(&lcnt[bin2[beg+idx]], 1);
  __syncthreads();
  for (int i = threadIdx.x; i < nn; i += 256) deg[n0+i] = lcnt[i] + 1;   // +1 self-loop
}

// ---- hierarchical scan of deg -> off (exclusive) ----
__global__ void k_bsum(const int* __restrict__ deg, int* __restrict__ bsum, int N){
  int i = blockIdx.x*256 + threadIdx.x;
  int v = (i<N) ? deg[i] : 0;
  #pragma unroll
  for(int d=32; d; d>>=1) v += __shfl_xor(v, d);
  __shared__ int sh[4];
  if ((threadIdx.x&63)==0) sh[threadIdx.x>>6] = v;
  __syncthreads();
  if (threadIdx.x==0) bsum[blockIdx.x] = sh[0]+sh[1]+sh[2]+sh[3];
}

__global__ void k_bscan(const int* __restrict__ bsum, int* __restrict__ boff, int NB,
                        int* __restrict__ offN, int EN){
  __shared__ int sh[1024];
  int tid = threadIdx.x;
  int v = (tid<NB) ? bsum[tid] : 0;
  sh[tid] = v;
  __syncthreads();
  for(int d=1; d<1024; d<<=1){
    int t = 0;
    if (tid>=d) t = sh[tid-d];
    __syncthreads();
    if (tid>=d) sh[tid] += t;
    __syncthreads();
  }
  if (tid<NB) boff[tid] = sh[tid] - v;  // exclusive
  if (tid==0) offN[0] = EN;
}

__global__ void k_scan_fin(const int* __restrict__ deg, const int* __restrict__ boff,
                           int* __restrict__ off, int N){
  __shared__ int sh[256];
  int i = blockIdx.x*256 + threadIdx.x;
  int v = (i<N) ? deg[i] : 0;
  sh[threadIdx.x] = v;
  __syncthreads();
  for(int d=1; d<256; d<<=1){
    int t = 0;
    if (threadIdx.x>=d) t = sh[threadIdx.x-d];
    __syncthreads();
    if (threadIdx.x>=d) sh[threadIdx.x] += t;
    __syncthreads();
  }
  if (i<N) off[i] = boff[blockIdx.x] + sh[threadIdx.x] - v;
}

// pass B: one WG per bucket; scatter within the bucket's L2-local CSR window.
__global__ void __launch_bounds__(256)
k_binB(const uint2* __restrict__ bin8, const unsigned short* __restrict__ bin2,
       const int* __restrict__ bcur, const int* __restrict__ off,
       uint2* __restrict__ rec, int N){
  __shared__ int lcur[BNODE];
  int b = blockIdx.x;
  int n0 = b*BNODE;
  int n1 = n0 + BNODE; if (n1 > N) n1 = N;
  int nn = n1 - n0;
  for (int i = threadIdx.x; i < nn; i += 256) lcur[i] = off[n0+i] + 1;  // slot off[n] = self-loop
  __syncthreads();
  int beg = b*CAP, cntb = bcur[b] - beg;
  for (int idx = threadIdx.x; idx < cntb; idx += 256){
    uint2 r = bin8[beg+idx];
    int dl = bin2[beg+idx];
    int p = atomicAdd(&lcur[dl], 1);
    rec[p] = r;
  }
}

// self-loop record at off[n]: mean of segment's real-edge scores (0 if none), src=n
__global__ void k_selfloop_csr(const int* __restrict__ off, uint2* __restrict__ rec, int N){
  int n = blockIdx.x*blockDim.x+threadIdx.x;
  if (n>=N) return;
  int a = off[n]+1, b = off[n+1];
  float s0=0.f,s1=0.f,s2=0.f;
  for (int p=a;p<b;p++){
    uint2 r=rec[p];
    s0 += h2f_(r.x & 0xFFFEu);
    s1 += h2f_(r.x >> 16);
    s2 += h2f_(r.y >> 16);
  }
  float inv = (b>a) ? 1.0f/(float)(b-a) : 0.0f;
  unsigned h0 = __half_as_ushort(__float2half(s0*inv)) & 0xFFFEu;
  unsigned h1 = __half_as_ushort(__float2half(s1*inv));
  unsigned h2 = __half_as_ushort(__float2half(s2*inv));
  unsigned s = (unsigned)n;
  rec[off[n]] = make_uint2(h0 | (s>>16) | (h1<<16), (s & 0xFFFFu) | (h2<<16));
}

// graph boundaries from sorted batch
__global__ void k_gbounds(const int* __restrict__ batch, int* __restrict__ gstart, int N, int G){
  int n = blockIdx.x*blockDim.x+threadIdx.x;
  if (n>=N) return;
  int b = batch[n];
  int bp = (n==0) ? -1 : batch[n-1];
  for (int g=bp+1; g<=b; g++) gstart[g]=n;
  if (n==N-1){ for (int g=b+1; g<=G; g++) gstart[g]=N; }
}

// MFMA GRU: block = 64 nodes (4 waves x 16-node strip), no LDS.
__global__ void __launch_bounds__(256,4)
k_gru_m(const short* __restrict__ hg16, const float* __restrict__ xin, float* __restrict__ xout,
        const short* __restrict__ WihT16, const short* __restrict__ WhhT16,
        const float* __restrict__ bih, const float* __restrict__ bhh, int N){
  int lane = threadIdx.x & 63, w = threadIdx.x >> 6;
  int m16 = lane & 15;
  int kb  = lane >> 4;
  int n0 = blockIdx.x*64 + w*16;

  int arow = n0 + m16; if (arow > N-1) arow = N-1;
  const short* hrow = hg16 + (size_t)arow*H_ + kb*8;
  bf16x8 ah0 = *(const bf16x8*)(hrow);
  bf16x8 ah1 = *(const bf16x8*)(hrow + 32);
  const float* xrow = xin + (size_t)arow*H_ + kb*8;
  float4 xa = *(const float4*)(xrow),    xb = *(const float4*)(xrow+4);
  float4 xc = *(const float4*)(xrow+32), xd = *(const float4*)(xrow+36);
  bf16x8 ax0, ax1;
  ax0[0]=f2bf(xa.x); ax0[1]=f2bf(xa.y); ax0[2]=f2bf(xa.z); ax0[3]=f2bf(xa.w);
  ax0[4]=f2bf(xb.x); ax0[5]=f2bf(xb.y); ax0[6]=f2bf(xb.z); ax0[7]=f2bf(xb.w);
  ax1[0]=f2bf(xc.x); ax1[1]=f2bf(xc.y); ax1[2]=f2bf(xc.z); ax1[3]=f2bf(xc.w);
  ax1[4]=f2bf(xd.x); ax1[5]=f2bf(xd.y); ax1[6]=f2bf(xd.z); ax1[7]=f2bf(xd.w);

  f32x4 aR[4], aZ[4], aNi[4], aNh[4];
  #pragma unroll
  for (int t=0;t<4;t++){
    aR[t]=(f32x4){0.f,0.f,0.f,0.f}; aZ[t]=(f32x4){0.f,0.f,0.f,0.f};
    aNi[t]=(f32x4){0.f,0.f,0.f,0.f}; aNh[t]=(f32x4){0.f,0.f,0.f,0.f};
  }

  const short* wi = WihT16 + (size_t)m16*H_ + kb*8;
  const short* wh = WhhT16 + (size_t)m16*H_ + kb*8;
  #pragma unroll
  for (int t=0;t<4;t++){
    bf16x8 b;
    b = *(const bf16x8*)(wi + (size_t)(t*16)*H_);
    aR[t] = __builtin_amdgcn_mfma_f32_16x16x32_bf16(ah0, b, aR[t], 0,0,0);
    b = *(const bf16x8*)(wi + (size_t)(t*16)*H_ + 32);
    aR[t] = __builtin_amdgcn_mfma_f32_16x16x32_bf16(ah1, b, aR[t], 0,0,0);
    b = *(const bf16x8*)(wh + (size_t)(t*16)*H_);
    aR[t] = __builtin_amdgcn_mfma_f32_16x16x32_bf16(ax0, b, aR[t], 0,0,0);
    b = *(const bf16x8*)(wh + (size_t)(t*16)*H_ + 32);
    aR[t] = __builtin_amdgcn_mfma_f32_16x16x32_bf16(ax1, b, aR[t], 0,0,0);
    b = *(const bf16x8*)(wi + (size_t)(64+t*16)*H_);
    aZ[t] = __builtin_amdgcn_mfma_f32_16x16x32_bf16(ah0, b, aZ[t], 0,0,0);
    b = *(const bf16x8*)(wi + (size_t)(64+t*16)*H_ + 32);
    aZ[t] = __builtin_amdgcn_mfma_f32_16x16x32_bf16(ah1, b, aZ[t], 0,0,0);
    b = *(const bf16x8*)(wh + (size_t)(64+t*16)*H_);
    aZ[t] = __builtin_amdgcn_mfma_f32_16x16x32_bf16(ax0, b, aZ[t], 0,0,0);
    b = *(const bf16x8*)(wh + (size_t)(64+t*16)*H_ + 32);
    aZ[t] = __builtin_amdgcn_mfma_f32_16x16x32_bf16(ax1, b, aZ[t], 0,0,0);
    b = *(const bf16x8*)(wi + (size_t)(128+t*16)*H_);
    aNi[t] = __builtin_amdgcn_mfma_f32_16x16x32_bf16(ah0, b, aNi[t], 0,0,0);
    b = *(const bf16x8*)(wi + (size_t)(128+t*16)*H_ + 32);
    aNi[t] = __builtin_amdgcn_mfma_f32_16x16x32_bf16(ah1, b, aNi[t], 0,0,0);
    b = *(const bf16x8*)(wh + (size_t)(128+t*16)*H_);
    aNh[t] = __builtin_amdgcn_mfma_f32_16x16x32_bf16(ax0, b, aNh[t], 0,0,0);
    b = *(const bf16x8*)(wh + (size_t)(128+t*16)*H_ + 32);
    aNh[t] = __builtin_amdgcn_mfma_f32_16x16x32_bf16(ax1, b, aNh[t], 0,0,0);
  }

  int mrow = (lane>>4)*4;
  #pragma unroll
  for (int t=0;t<4;t++){
    int f = t*16 + m16;
    float br = bih[f]     + bhh[f];
    float bz = bih[64+f]  + bhh[64+f];
    float bin= bih[128+f], bhn = bhh[128+f];
    #pragma unroll
    for (int q=0;q<4;q++){
      int node = n0 + mrow + q;
      if (node < N){
        float r  = sigm_(aR[t][q] + br);
        float z  = sigm_(aZ[t][q] + bz);
        float nn = tanh_(aNi[t][q] + bin + r*(aNh[t][q] + bhn));
        float xv = xin[(size_t)node*H_ + f];
        xout[(size_t)node*H_ + f] = fmaxf((1.f-z)*nn + z*xv, 0.f);
      }
    }
  }
}

// MFMA linear-h: h16 = fp16(xi @ conv_W[l]); ssc/dsc via shfl_xor reduce. No LDS.
__global__ void __launch_bounds__(256,4)
k_linh_m(const float* __restrict__ xi, const short* __restrict__ wT16,
         const float* __restrict__ atts, const float* __restrict__ attd,
         __half* __restrict__ h16, float* __restrict__ ssc, float* __restrict__ dsc, int N){
  int lane = threadIdx.x & 63, w = threadIdx.x >> 6;
  int m16 = lane & 15, kb = lane >> 4;
  int n0 = blockIdx.x*64 + w*16;
  int arow = n0 + m16; if (arow > N-1) arow = N-1;
  const float* xrow = xi + (size_t)arow*H_ + kb*8;
  float4 xa = *(const float4*)(xrow),    xb = *(const float4*)(xrow+4);
  float4 xc = *(const float4*)(xrow+32), xd = *(const float4*)(xrow+36);
  bf16x8 ax0, ax1;
  ax0[0]=f2bf(xa.x); ax0[1]=f2bf(xa.y); ax0[2]=f2bf(xa.z); ax0[3]=f2bf(xa.w);
  ax0[4]=f2bf(xb.x); ax0[5]=f2bf(xb.y); ax0[6]=f2bf(xb.z); ax0[7]=f2bf(xb.w);
  ax1[0]=f2bf(xc.x); ax1[1]=f2bf(xc.y); ax1[2]=f2bf(xc.z); ax1[3]=f2bf(xc.w);
  ax1[4]=f2bf(xd.x); ax1[5]=f2bf(xd.y); ax1[6]=f2bf(xd.z); ax1[7]=f2bf(xd.w);

  f32x4 acc[4];
  #pragma unroll
  for (int t=0;t<4;t++) acc[t]=(f32x4){0.f,0.f,0.f,0.f};
  const short* wp = wT16 + (size_t)m16*H_ + kb*8;
  #pragma unroll
  for (int t=0;t<4;t++){
    bf16x8 b0 = *(const bf16x8*)(wp + (size_t)(t*16)*H_);
    acc[t] = __builtin_amdgcn_mfma_f32_16x16x32_bf16(ax0, b0, acc[t], 0,0,0);
    bf16x8 b1 = *(const bf16x8*)(wp + (size_t)(t*16)*H_ + 32);
    acc[t] = __builtin_amdgcn_mfma_f32_16x16x32_bf16(ax1, b1, acc[t], 0,0,0);
  }

  int mrow = (lane>>4)*4;
  float ps[4]={0.f,0.f,0.f,0.f}, pd[4]={0.f,0.f,0.f,0.f};
  #pragma unroll
  for (int t=0;t<4;t++){
    int f = t*16 + m16;
    float as = atts[f], ad = attd[f];
    #pragma unroll
    for (int q=0;q<4;q++){
      int node = n0 + mrow + q;
      float v = acc[t][q];
      if (node < N) h16[(size_t)node*H_ + f] = __float2half(v);
      ps[q] = fmaf(v, as, ps[q]); pd[q] = fmaf(v, ad, pd[q]);
    }
  }
  #pragma unroll
  for (int d=1; d<16; d<<=1){
    #pragma unroll
    for (int q=0;q<4;q++){ ps[q] += __shfl_xor(ps[q], d); pd[q] += __shfl_xor(pd[q], d); }
  }
  if (m16==0){
    #pragma unroll
    for (int q=0;q<4;q++){
      int node = n0 + mrow + q;
      if (node < N){ ssc[node]=ps[q]; dsc[node]=pd[q]; }
    }
  }
}

// GAT: 4 nodes/wave, 16 lanes/node (half4 = 4 features/lane). Single-pass safe-exp softmax.
template<int L>
__global__ void __launch_bounds__(256)
k_gat_g4(const __half* __restrict__ h16, const float* __restrict__ ssc,
         const float* __restrict__ dsc, const uint2* __restrict__ rec,
         const int* __restrict__ off, const float* __restrict__ bias,
         short* __restrict__ hgat16, int N){
  int lane = threadIdx.x & 63, w = threadIdx.x >> 6;
  int g = lane >> 4, fl = lane & 15;
  int node = blockIdx.x*16 + w*4 + g;
  if (node >= N) return;
  int e0 = off[node], e1 = off[node+1];
  float dval = dsc[node];
  float acc0=0.f, acc1=0.f, acc2=0.f, acc3=0.f, den=0.f;
  int gbase = lane & 48;                 // g*16
  for (int base = e0; base < e1; base += 16){
    int p = base + fl;
    float ex = 0.f; int s = 0;
    if (p < e1){
      uint2 r = rec[p];
      s = (int)((r.y & 0xFFFFu) | ((r.x & 1u) << 16));
      unsigned hb = (L==0) ? (r.x & 0xFFFEu) : (L==1) ? (r.x >> 16) : (r.y >> 16);
      float a = ssc[s] + dval + h2f_(hb);
      a = (a > 0.f) ? a : SLOPE*a;
      ex = __expf(a);
    }
    den += ex;
    int cnt = e1 - base; if (cnt > 16) cnt = 16;
    for (int j = 0; j < cnt; j++){
      float exb = __shfl(ex, gbase + j);
      int   sb  = __shfl(s,  gbase + j);
      uint2 hv = *(const uint2*)(h16 + (size_t)sb*H_ + 4*fl);
      float2 f0 = __half22float2(*(__half2*)&hv.x);
      float2 f1 = __half22float2(*(__half2*)&hv.y);
      acc0 = fmaf(exb, f0.x, acc0);
      acc1 = fmaf(exb, f0.y, acc1);
      acc2 = fmaf(exb, f1.x, acc2);
      acc3 = fmaf(exb, f1.y, acc3);
    }
  }
  #pragma unroll
  for (int d=1; d<16; d<<=1) den += __shfl_xor(den, d);
  float4 bv = *(const float4*)(bias + 4*fl);
  float inv = 1.0f/den;
  float v0 = fmaxf(fmaf(acc0,inv,bv.x), 0.f);
  float v1 = fmaxf(fmaf(acc1,inv,bv.y), 0.f);
  float v2 = fmaxf(fmaf(acc2,inv,bv.z), 0.f);
  float v3 = fmaxf(fmaf(acc3,inv,bv.w), 0.f);
  uint2 o;
  o.x = ((unsigned)(unsigned short)f2bf(v1)<<16) | (unsigned short)f2bf(v0);
  o.y = ((unsigned)(unsigned short)f2bf(v3)<<16) | (unsigned short)f2bf(v2);
  *(uint2*)(hgat16 + (size_t)node*H_ + 4*fl) = o;
}

// block per graph: zero-atomic pooled output (batch is sorted)
__global__ void __launch_bounds__(256)
k_pool_g(const float* __restrict__ xi, const float* __restrict__ wout,
         const int* __restrict__ gstart, const float* __restrict__ b_out,
         float* __restrict__ out){
  int g = blockIdx.x;
  int a = gstart[g], b = gstart[g+1];
  float acc = 0.f;
  for (int n = a + threadIdx.x; n < b; n += 256){
    const float4* xr = (const float4*)(xi + (size_t)n*H_);
    float s = 0.f;
    #pragma unroll
    for (int q=0;q<H_/4;q++){
      float4 v = xr[q];
      s += v.x*wout[4*q] + v.y*wout[4*q+1] + v.z*wout[4*q+2] + v.w*wout[4*q+3];
    }
    acc += s;
  }
  #pragma unroll
  for (int d=32; d; d>>=1) acc += __shfl_xor(acc, d);
  __shared__ float sh[4];
  if ((threadIdx.x&63)==0) sh[threadIdx.x>>6] = acc;
  __syncthreads();
  if (threadIdx.x==0) out[g] = sh[0]+sh[1]+sh[2]+sh[3] + b_out[0];
}

extern "C" void kernel_launch(void* const* d_in, const int* in_sizes, int n_in,
                              void* d_out, int out_size, void* d_ws, size_t ws_size,
                              hipStream_t stream){
  const float* x       = (const float*)d_in[0];
  const float* eattr   = (const float*)d_in[1];
  const float* w_node  = (const float*)d_in[2];
  const float* b_node  = (const float*)d_in[3];
  const float* w_edge  = (const float*)d_in[4];
  const float* b_edge  = (const float*)d_in[5];
  const float* conv_W  = (const float*)d_in[6];
  const float* conv_We = (const float*)d_in[7];
  const float* att_s   = (const float*)d_in[8];
  const float* att_d   = (const float*)d_in[9];
  const float* att_e   = (const float*)d_in[10];
  const float* conv_b  = (const float*)d_in[11];
  const float* gWih    = (const float*)d_in[12];
  const float* gWhh    = (const float*)d_in[13];
  const float* gbih    = (const float*)d_in[14];
  const float* gbhh    = (const float*)d_in[15];
  const float* w_out   = (const float*)d_in[16];
  const float* b_out   = (const float*)d_in[17];
  const int*   eidx    = (const int*)d_in[18];
  const int*   batch   = (const int*)d_in[19];
  float* out = (float*)d_out;

  int N = in_sizes[0]/DIN;
  int E = in_sizes[1]/DE;
  int G = out_size;
  int EN = E + N;
  const int* src = eidx;
  const int* dst = eidx + E;

  char* p = (char*)d_ws;
  auto carve = [&](size_t bytes)->void*{ void* r=(void*)p; p += (bytes+255)&~(size_t)255; return r; };
  float*  xi0    = (float*)carve((size_t)N*H_*4);
  float*  xi1    = (float*)carve((size_t)N*H_*4);
  __half* h16    = (__half*)carve((size_t)N*H_*2);
  short*  hgat16 = (short*)carve((size_t)N*H_*2);
  float*  ssc    = (float*)carve((size_t)N*4);
  float*  dsc    = (float*)carve((size_t)N*4);
  uint2*  esc8   = (uint2*)carve((size_t)E*8);
  uint2*  rec    = (uint2*)carve((size_t)EN*8);
  uint2*  bin8   = (uint2*)carve((size_t)256*CAP*8);
  unsigned short* bin2 = (unsigned short*)carve((size_t)256*CAP*2);
  int*    deg    = (int*)carve((size_t)N*4);
  int*    off    = (int*)carve((size_t)(N+1)*4);
  int*    bcur   = (int*)carve((size_t)256*4);
  int*    gstart = (int*)carve((size_t)(G+1)*4);
  int*    bsum   = (int*)carve((size_t)1024*4);
  int*    boff   = (int*)carve((size_t)1024*4);
  short*  wnT16  = (short*)carve((size_t)DIN*H_*2);
  short*  weT16p = (short*)carve((size_t)64*32*2);
  short*  cWT16  = (short*)carve((size_t)3*H_*H_*2);
  short*  WihT16 = (short*)carve((size_t)3*192*H_*2);
  short*  WhhT16 = (short*)carve((size_t)3*192*H_*2);
  float*  ve     = (float*)carve((size_t)3*H_*4);

  auto cdiv=[](int a,int b){return (a+b-1)/b;};
  int NB  = cdiv(N,256);
  int NBK = cdiv(N,BNODE);

  int prep_total = 2048+2048+12288+36864+36864+192+256;
  k_prep<<<cdiv(prep_total,256),256,0,stream>>>(w_node, w_edge, conv_W, gWih, gWhh, conv_We, att_e,
                                                wnT16, weT16p, cWT16, WihT16, WhhT16, ve, bcur);
  k_nmlp_m<<<cdiv(N,64),256,0,stream>>>(x, wnT16, b_node, xi0, N);
  k_edge_m<<<cdiv(E,64),256,0,stream>>>(eattr, weT16p, b_edge, ve, src, esc8, E);
  k_binA<<<cdiv(E,ACH),256,0,stream>>>(esc8, dst, bcur, bin8, bin2, E);
  k_hist<<<NBK,256,0,stream>>>(bin2, bcur, deg, N);
  k_bsum<<<NB,256,0,stream>>>(deg, bsum, N);
  k_bscan<<<1,1024,0,stream>>>(bsum, boff, NB, off+N, EN);
  k_scan_fin<<<NB,256,0,stream>>>(deg, boff, off, N);
  k_binB<<<NBK,256,0,stream>>>(bin8, bin2, bcur, off, rec, N);
  k_selfloop_csr<<<cdiv(N,256),256,0,stream>>>(off, rec, N);
  k_gbounds<<<NB,256,0,stream>>>(batch, gstart, N, G);

  int NB64 = cdiv(N,64);
  int NB16 = cdiv(N,16);
  for (int l=0; l<3; l++){
    const float* xin = (l&1) ? xi1 : xi0;
    float*       xo  = (l&1) ? xi0 : xi1;
    k_linh_m<<<NB64,256,0,stream>>>(xin, cWT16 + (size_t)l*H_*H_, att_s + l*H_, att_d + l*H_,
                                    h16, ssc, dsc, N);
    if (l==0)      k_gat_g4<0><<<NB16,256,0,stream>>>(h16, ssc, dsc, rec, off, conv_b + l*H_, hgat16, N);
    else if (l==1) k_gat_g4<1><<<NB16,256,0,stream>>>(h16, ssc, dsc, rec, off, conv_b + l*H_, hgat16, N);
    else           k_gat_g4<2><<<NB16,256,0,stream>>>(h16, ssc, dsc, rec, off, conv_b + l*H_, hgat16, N);
    k_gru_m<<<NB64,256,0,stream>>>(hgat16, xin, xo, WihT16 + (size_t)l*192*H_, WhhT16 + (size_t)l*192*H_,
                                   gbih + l*3*H_, gbhh + l*3*H_, N);
  }

  k_pool_g<<<G,256,0,stream>>>(xi1, w_out, gstart, b_out, out);
}

// Round 17
// 409.097 us; speedup vs baseline: 42.9837x; 1.0315x over previous
//
#include <hip/hip_runtime.h>
#include <hip/hip_fp16.h>

constexpr int H_  = 64;   // hidden
constexpr int DIN = 32;   // atom feature dim
constexpr int DE  = 16;   // edge feature dim
constexpr int BNODE = 512;  // nodes per scatter bucket (dstlocal < 512)
constexpr int ACH   = 2048; // edges per binning chunk
constexpr int CAP   = 6144; // per-bucket region capacity (mean 5120 + 14 sigma)
#define SLOPE 0.2f

typedef __attribute__((ext_vector_type(8))) short bf16x8;
typedef __attribute__((ext_vector_type(4))) float f32x4;

__device__ __forceinline__ float sigm_(float x){ return 1.0f/(1.0f+__expf(-x)); }
__device__ __forceinline__ float tanh_(float x){ float e=__expf(2.0f*x); return 1.0f - 2.0f/(e+1.0f); }
__device__ __forceinline__ short f2bf(float f){   // RNE float->bf16
  unsigned u = __float_as_uint(f);
  u += 0x7FFF + ((u>>16)&1);
  return (short)(u>>16);
}
__device__ __forceinline__ float bf2f(unsigned short s){
  return __uint_as_float(((unsigned)s)<<16);
}
__device__ __forceinline__ float h2f_(unsigned hb){
  return __half2float(__ushort_as_half((unsigned short)hb));
}

// one mega-kernel for all weight prep + bcur init
__global__ void k_prep(const float* __restrict__ w_node, const float* __restrict__ w_edge,
                       const float* __restrict__ conv_W, const float* __restrict__ gWih,
                       const float* __restrict__ gWhh, const float* __restrict__ conv_We,
                       const float* __restrict__ att_e,
                       short* __restrict__ wnT16, short* __restrict__ weT16p,
                       short* __restrict__ cWT16, short* __restrict__ WihT16,
                       short* __restrict__ WhhT16, float* __restrict__ ve,
                       int* __restrict__ bcur){
  int id = blockIdx.x*blockDim.x + threadIdx.x;
  if (id < 2048){                                   // wnT16 [64][32]
    int j = id >> 5, k = id & 31;
    wnT16[id] = f2bf(w_node[k*64 + j]);
    return;
  }
  id -= 2048;
  if (id < 2048){                                   // weT16p [64][32], k>=16 zero
    int j = id >> 5, k = id & 31;
    weT16p[id] = (k < DE) ? f2bf(w_edge[k*64 + j]) : (short)0;
    return;
  }
  id -= 2048;
  if (id < 12288){                                  // cWT16 [3][64 j][64 k]
    int l = id / 4096, rem = id & 4095, j = rem >> 6, k = rem & 63;
    cWT16[id] = f2bf(conv_W[l*4096 + k*64 + j]);
    return;
  }
  id -= 12288;
  if (id < 36864){                                  // WihT16 [3][192 j][64 k]
    int l = id / 12288, rem = id % 12288, j = rem >> 6, k = rem & 63;
    WihT16[id] = f2bf(gWih[l*12288 + k*192 + j]);
    return;
  }
  id -= 36864;
  if (id < 36864){                                  // WhhT16
    int l = id / 12288, rem = id % 12288, j = rem >> 6, k = rem & 63;
    WhhT16[id] = f2bf(gWhh[l*12288 + k*192 + j]);
    return;
  }
  id -= 36864;
  if (id < 192){                                    // ve[l][k]
    int l = id >> 6, k = id & 63;
    const float* w = conv_We + (size_t)(l*64+k)*64;
    const float* a = att_e + l*64;
    float s = 0.f;
    #pragma unroll
    for (int j=0;j<64;j++) s += w[j]*a[j];
    ve[id] = s;
    return;
  }
  id -= 192;
  if (id < 256) bcur[id] = id*CAP;                  // fixed-capacity bucket regions
}

// MFMA node MLP: xi16 = bf16(relu(x @ w_node + b)), K=32 exact. No LDS.
__global__ void __launch_bounds__(256,4)
k_nmlp_m(const float* __restrict__ x, const short* __restrict__ wT16,
         const float* __restrict__ b, short* __restrict__ xi, int N){
  int lane = threadIdx.x & 63, w = threadIdx.x >> 6;
  int m16 = lane & 15, kb = lane >> 4;
  int n0 = blockIdx.x*64 + w*16;
  int arow = n0 + m16; if (arow > N-1) arow = N-1;
  const float* xr = x + (size_t)arow*DIN + kb*8;
  float4 a0 = *(const float4*)xr, a1 = *(const float4*)(xr+4);
  bf16x8 af;
  af[0]=f2bf(a0.x); af[1]=f2bf(a0.y); af[2]=f2bf(a0.z); af[3]=f2bf(a0.w);
  af[4]=f2bf(a1.x); af[5]=f2bf(a1.y); af[6]=f2bf(a1.z); af[7]=f2bf(a1.w);
  f32x4 acc[4];
  #pragma unroll
  for (int t=0;t<4;t++) acc[t]=(f32x4){0.f,0.f,0.f,0.f};
  const short* wp = wT16 + (size_t)m16*DIN + kb*8;
  #pragma unroll
  for (int t=0;t<4;t++){
    bf16x8 bb = *(const bf16x8*)(wp + (size_t)(t*16)*DIN);
    acc[t] = __builtin_amdgcn_mfma_f32_16x16x32_bf16(af, bb, acc[t], 0,0,0);
  }
  int mrow = (lane>>4)*4;
  #pragma unroll
  for (int t=0;t<4;t++){
    int f = t*16 + m16;
    float bj = b[f];
    #pragma unroll
    for (int q=0;q<4;q++){
      int node = n0 + mrow + q;
      if (node < N) xi[(size_t)node*H_ + f] = f2bf(fmaxf(acc[t][q] + bj, 0.f));
    }
  }
}

// MFMA edge scores: 16 edges/wave, packed 8B record with src bits spliced in. No atomics.
__global__ void __launch_bounds__(256,4)
k_edge_m(const float* __restrict__ attr, const short* __restrict__ weT16p,
         const float* __restrict__ be, const float* __restrict__ ve,
         const int* __restrict__ src, uint2* __restrict__ esc8, int E){
  int lane = threadIdx.x & 63, w = threadIdx.x >> 6;
  int m16 = lane & 15, kb = lane >> 4;
  int e0 = (blockIdx.x*4 + w)*16;
  if (e0 >= E) return;
  bf16x8 af = {0,0,0,0,0,0,0,0};
  if (kb < 2){
    int arow = e0 + m16; if (arow > E-1) arow = E-1;
    const float* ap = attr + (size_t)arow*DE + kb*8;
    float4 a0 = *(const float4*)ap, a1 = *(const float4*)(ap+4);
    af[0]=f2bf(a0.x); af[1]=f2bf(a0.y); af[2]=f2bf(a0.z); af[3]=f2bf(a0.w);
    af[4]=f2bf(a1.x); af[5]=f2bf(a1.y); af[6]=f2bf(a1.z); af[7]=f2bf(a1.w);
  }
  f32x4 acc[4];
  #pragma unroll
  for (int t=0;t<4;t++) acc[t]=(f32x4){0.f,0.f,0.f,0.f};
  const short* wp = weT16p + (size_t)m16*32 + kb*8;
  #pragma unroll
  for (int t=0;t<4;t++){
    bf16x8 bb = *(const bf16x8*)(wp + (size_t)(t*16)*32);
    acc[t] = __builtin_amdgcn_mfma_f32_16x16x32_bf16(af, bb, acc[t], 0,0,0);
  }
  int mrow = (lane>>4)*4;
  float s0[4]={0.f,0.f,0.f,0.f}, s1[4]={0.f,0.f,0.f,0.f}, s2[4]={0.f,0.f,0.f,0.f};
  #pragma unroll
  for (int t=0;t<4;t++){
    int j = t*16 + m16;
    float bj = be[j];
    float v0 = ve[j], v1 = ve[64+j], v2 = ve[128+j];
    #pragma unroll
    for (int q=0;q<4;q++){
      float ea = fmaxf(acc[t][q] + bj, 0.f);
      s0[q] = fmaf(ea, v0, s0[q]);
      s1[q] = fmaf(ea, v1, s1[q]);
      s2[q] = fmaf(ea, v2, s2[q]);
    }
  }
  #pragma unroll
  for (int d=1; d<16; d<<=1){
    #pragma unroll
    for (int q=0;q<4;q++){
      s0[q] += __shfl_xor(s0[q], d);
      s1[q] += __shfl_xor(s1[q], d);
      s2[q] += __shfl_xor(s2[q], d);
    }
  }
  if (m16==0){
    #pragma unroll
    for (int q=0;q<4;q++){
      int e = e0 + mrow + q;
      if (e < E){
        unsigned sv = (unsigned)src[e];
        unsigned h0 = (__half_as_ushort(__float2half(s0[q])) & 0xFFFEu) | (sv >> 16);
        unsigned h1 = __half_as_ushort(__float2half(s1[q]));
        unsigned h2 = __half_as_ushort(__float2half(s2[q]));
        esc8[e] = make_uint2(h0 | (h1<<16), (sv & 0xFFFFu) | (h2<<16));
      }
    }
  }
}

// pass A: LDS-binned append of 8B records + 2B dstlocal into fixed per-bucket regions.
__global__ void __launch_bounds__(256)
k_binA(const uint2* __restrict__ esc8, const int* __restrict__ dst,
       int* __restrict__ bcur, uint2* __restrict__ bin8, unsigned short* __restrict__ bin2,
       int E){
  __shared__ int cnt[256];
  __shared__ int ofs[256];
  __shared__ int gofs[256];
  __shared__ uint2 st8[ACH];
  __shared__ unsigned short st2[ACH];
  __shared__ unsigned char sbid[ACH];
  int tid = threadIdx.x;
  int base = blockIdx.x * ACH;
  cnt[tid] = 0;
  __syncthreads();
  uint2 r8[8]; int bb[8]; int ms[8]; int dl[8];
  #pragma unroll
  for (int k=0;k<8;k++){
    int e = base + tid + k*256;
    bb[k] = -1;
    if (e < E){
      r8[k] = esc8[e];
      int d = dst[e];
      bb[k] = d >> 9;
      dl[k] = d & (BNODE-1);
      ms[k] = atomicAdd(&cnt[bb[k]], 1);
    }
  }
  __syncthreads();
  int v = cnt[tid];
  ofs[tid] = v;
  __syncthreads();
  for (int d=1; d<256; d<<=1){
    int t = 0;
    if (tid>=d) t = ofs[tid-d];
    __syncthreads();
    if (tid>=d) ofs[tid] += t;
    __syncthreads();
  }
  int total = ofs[255];
  int excl = ofs[tid] - v;
  __syncthreads();
  ofs[tid] = excl;
  __syncthreads();
  #pragma unroll
  for (int k=0;k<8;k++){
    if (bb[k] >= 0){
      int slot = ofs[bb[k]] + ms[k];
      st8[slot] = r8[k];
      st2[slot] = (unsigned short)dl[k];
      sbid[slot] = (unsigned char)bb[k];
    }
  }
  if (v > 0) gofs[tid] = atomicAdd(&bcur[tid], v);
  __syncthreads();
  for (int slot = tid; slot < total; slot += 256){
    int b = sbid[slot];
    int gp = gofs[b] + (slot - ofs[b]);
    bin8[gp] = st8[slot];
    bin2[gp] = st2[slot];
  }
}

// per-bucket LDS histogram -> deg (zero global atomics)
__global__ void __launch_bounds__(256)
k_hist(const unsigned short* __restrict__ bin2, const int* __restrict__ bcur,
       int* __restrict__ deg, int N){
  __shared__ int lcnt[BNODE];
  int b = blockIdx.x;
  int n0 = b*BNODE;
  int n1 = n0 + BNODE; if (n1 > N) n1 = N;
  int nn = n1 - n0;
  for (int i = threadIdx.x; i < nn; i += 256) lcnt[i] = 0;
  __syncthreads();
  int beg = b*CAP, cntb = bcur[b] - beg;
  for (int idx = threadIdx.x; idx < cntb; idx += 256)
    atomicAdd(&lcnt[bin2[beg+idx]], 1);
  __syncthreads();
  for (int i = threadIdx.x; i < nn; i += 256) deg[n0+i] = lcnt[i] + 1;   // +1 self-loop
}

// ---- hierarchical scan of deg -> off (exclusive) ----
__global__ void k_bsum(const int* __restrict__ deg, int* __restrict__ bsum, int N){
  int i = blockIdx.x*256 + threadIdx.x;
  int v = (i<N) ? deg[i] : 0;
  #pragma unroll
  for(int d=32; d; d>>=1) v += __shfl_xor(v, d);
  __shared__ int sh[4];
  if ((threadIdx.x&63)==0) sh[threadIdx.x>>6] = v;
  __syncthreads();
  if (threadIdx.x==0) bsum[blockIdx.x] = sh[0]+sh[1]+sh[2]+sh[3];
}

__global__ void k_bscan(const int* __restrict__ bsum, int* __restrict__ boff, int NB,
                        int* __restrict__ offN, int EN){
  __shared__ int sh[1024];
  int tid = threadIdx.x;
  int v = (tid<NB) ? bsum[tid] : 0;
  sh[tid] = v;
  __syncthreads();
  for(int d=1; d<1024; d<<=1){
    int t = 0;
    if (tid>=d) t = sh[tid-d];
    __syncthreads();
    if (tid>=d) sh[tid] += t;
    __syncthreads();
  }
  if (tid<NB) boff[tid] = sh[tid] - v;  // exclusive
  if (tid==0) offN[0] = EN;
}

__global__ void k_scan_fin(const int* __restrict__ deg, const int* __restrict__ boff,
                           int* __restrict__ off, int N){
  __shared__ int sh[256];
  int i = blockIdx.x*256 + threadIdx.x;
  int v = (i<N) ? deg[i] : 0;
  sh[threadIdx.x] = v;
  __syncthreads();
  for(int d=1; d<256; d<<=1){
    int t = 0;
    if (threadIdx.x>=d) t = sh[threadIdx.x-d];
    __syncthreads();
    if (threadIdx.x>=d) sh[threadIdx.x] += t;
    __syncthreads();
  }
  if (i<N) off[i] = boff[blockIdx.x] + sh[threadIdx.x] - v;
}

// pass B: one WG per bucket; scatter within the bucket's L2-local CSR window.
__global__ void __launch_bounds__(256)
k_binB(const uint2* __restrict__ bin8, const unsigned short* __restrict__ bin2,
       const int* __restrict__ bcur, const int* __restrict__ off,
       uint2* __restrict__ rec, int N){
  __shared__ int lcur[BNODE];
  int b = blockIdx.x;
  int n0 = b*BNODE;
  int n1 = n0 + BNODE; if (n1 > N) n1 = N;
  int nn = n1 - n0;
  for (int i = threadIdx.x; i < nn; i += 256) lcur[i] = off[n0+i] + 1;  // slot off[n] = self-loop
  __syncthreads();
  int beg = b*CAP, cntb = bcur[b] - beg;
  for (int idx = threadIdx.x; idx < cntb; idx += 256){
    uint2 r = bin8[beg+idx];
    int dl = bin2[beg+idx];
    int p = atomicAdd(&lcur[dl], 1);
    rec[p] = r;
  }
}

// self-loop record at off[n]: mean of segment's real-edge scores (0 if none), src=n
__global__ void k_selfloop_csr(const int* __restrict__ off, uint2* __restrict__ rec, int N){
  int n = blockIdx.x*blockDim.x+threadIdx.x;
  if (n>=N) return;
  int a = off[n]+1, b = off[n+1];
  float s0=0.f,s1=0.f,s2=0.f;
  for (int p=a;p<b;p++){
    uint2 r=rec[p];
    s0 += h2f_(r.x & 0xFFFEu);
    s1 += h2f_(r.x >> 16);
    s2 += h2f_(r.y >> 16);
  }
  float inv = (b>a) ? 1.0f/(float)(b-a) : 0.0f;
  unsigned h0 = __half_as_ushort(__float2half(s0*inv)) & 0xFFFEu;
  unsigned h1 = __half_as_ushort(__float2half(s1*inv));
  unsigned h2 = __half_as_ushort(__float2half(s2*inv));
  unsigned s = (unsigned)n;
  rec[off[n]] = make_uint2(h0 | (s>>16) | (h1<<16), (s & 0xFFFFu) | (h2<<16));
}

// graph boundaries from sorted batch
__global__ void k_gbounds(const int* __restrict__ batch, int* __restrict__ gstart, int N, int G){
  int n = blockIdx.x*blockDim.x+threadIdx.x;
  if (n>=N) return;
  int b = batch[n];
  int bp = (n==0) ? -1 : batch[n-1];
  for (int g=bp+1; g<=b; g++) gstart[g]=n;
  if (n==N-1){ for (int g=b+1; g<=G; g++) gstart[g]=N; }
}

// MFMA GRU: block = 64 nodes (4 waves x 16-node strip), bf16 state buffers, no LDS.
__global__ void __launch_bounds__(256,4)
k_gru_m(const short* __restrict__ hg16, const short* __restrict__ xin, short* __restrict__ xout,
        const short* __restrict__ WihT16, const short* __restrict__ WhhT16,
        const float* __restrict__ bih, const float* __restrict__ bhh, int N){
  int lane = threadIdx.x & 63, w = threadIdx.x >> 6;
  int m16 = lane & 15;
  int kb  = lane >> 4;
  int n0 = blockIdx.x*64 + w*16;

  int arow = n0 + m16; if (arow > N-1) arow = N-1;
  const short* hrow = hg16 + (size_t)arow*H_ + kb*8;
  bf16x8 ah0 = *(const bf16x8*)(hrow);
  bf16x8 ah1 = *(const bf16x8*)(hrow + 32);
  const short* xrow = xin + (size_t)arow*H_ + kb*8;
  bf16x8 ax0 = *(const bf16x8*)(xrow);
  bf16x8 ax1 = *(const bf16x8*)(xrow + 32);

  f32x4 aR[4], aZ[4], aNi[4], aNh[4];
  #pragma unroll
  for (int t=0;t<4;t++){
    aR[t]=(f32x4){0.f,0.f,0.f,0.f}; aZ[t]=(f32x4){0.f,0.f,0.f,0.f};
    aNi[t]=(f32x4){0.f,0.f,0.f,0.f}; aNh[t]=(f32x4){0.f,0.f,0.f,0.f};
  }

  const short* wi = WihT16 + (size_t)m16*H_ + kb*8;
  const short* wh = WhhT16 + (size_t)m16*H_ + kb*8;
  #pragma unroll
  for (int t=0;t<4;t++){
    bf16x8 b;
    b = *(const bf16x8*)(wi + (size_t)(t*16)*H_);
    aR[t] = __builtin_amdgcn_mfma_f32_16x16x32_bf16(ah0, b, aR[t], 0,0,0);
    b = *(const bf16x8*)(wi + (size_t)(t*16)*H_ + 32);
    aR[t] = __builtin_amdgcn_mfma_f32_16x16x32_bf16(ah1, b, aR[t], 0,0,0);
    b = *(const bf16x8*)(wh + (size_t)(t*16)*H_);
    aR[t] = __builtin_amdgcn_mfma_f32_16x16x32_bf16(ax0, b, aR[t], 0,0,0);
    b = *(const bf16x8*)(wh + (size_t)(t*16)*H_ + 32);
    aR[t] = __builtin_amdgcn_mfma_f32_16x16x32_bf16(ax1, b, aR[t], 0,0,0);
    b = *(const bf16x8*)(wi + (size_t)(64+t*16)*H_);
    aZ[t] = __builtin_amdgcn_mfma_f32_16x16x32_bf16(ah0, b, aZ[t], 0,0,0);
    b = *(const bf16x8*)(wi + (size_t)(64+t*16)*H_ + 32);
    aZ[t] = __builtin_amdgcn_mfma_f32_16x16x32_bf16(ah1, b, aZ[t], 0,0,0);
    b = *(const bf16x8*)(wh + (size_t)(64+t*16)*H_);
    aZ[t] = __builtin_amdgcn_mfma_f32_16x16x32_bf16(ax0, b, aZ[t], 0,0,0);
    b = *(const bf16x8*)(wh + (size_t)(64+t*16)*H_ + 32);
    aZ[t] = __builtin_amdgcn_mfma_f32_16x16x32_bf16(ax1, b, aZ[t], 0,0,0);
    b = *(const bf16x8*)(wi + (size_t)(128+t*16)*H_);
    aNi[t] = __builtin_amdgcn_mfma_f32_16x16x32_bf16(ah0, b, aNi[t], 0,0,0);
    b = *(const bf16x8*)(wi + (size_t)(128+t*16)*H_ + 32);
    aNi[t] = __builtin_amdgcn_mfma_f32_16x16x32_bf16(ah1, b, aNi[t], 0,0,0);
    b = *(const bf16x8*)(wh + (size_t)(128+t*16)*H_);
    aNh[t] = __builtin_amdgcn_mfma_f32_16x16x32_bf16(ax0, b, aNh[t], 0,0,0);
    b = *(const bf16x8*)(wh + (size_t)(128+t*16)*H_ + 32);
    aNh[t] = __builtin_amdgcn_mfma_f32_16x16x32_bf16(ax1, b, aNh[t], 0,0,0);
  }

  int mrow = (lane>>4)*4;
  #pragma unroll
  for (int t=0;t<4;t++){
    int f = t*16 + m16;
    float br = bih[f]     + bhh[f];
    float bz = bih[64+f]  + bhh[64+f];
    float bin= bih[128+f], bhn = bhh[128+f];
    #pragma unroll
    for (int q=0;q<4;q++){
      int node = n0 + mrow + q;
      if (node < N){
        float r  = sigm_(aR[t][q] + br);
        float z  = sigm_(aZ[t][q] + bz);
        float nn = tanh_(aNi[t][q] + bin + r*(aNh[t][q] + bhn));
        float xv = bf2f((unsigned short)xin[(size_t)node*H_ + f]);
        xout[(size_t)node*H_ + f] = f2bf(fmaxf((1.f-z)*nn + z*xv, 0.f));
      }
    }
  }
}

// MFMA linear-h: h16 = fp16(xi @ conv_W[l]); bf16 input; ssc/dsc via shfl_xor. No LDS.
__global__ void __launch_bounds__(256,4)
k_linh_m(const short* __restrict__ xi, const short* __restrict__ wT16,
         const float* __restrict__ atts, const float* __restrict__ attd,
         __half* __restrict__ h16, float* __restrict__ ssc, float* __restrict__ dsc, int N){
  int lane = threadIdx.x & 63, w = threadIdx.x >> 6;
  int m16 = lane & 15, kb = lane >> 4;
  int n0 = blockIdx.x*64 + w*16;
  int arow = n0 + m16; if (arow > N-1) arow = N-1;
  const short* xrow = xi + (size_t)arow*H_ + kb*8;
  bf16x8 ax0 = *(const bf16x8*)(xrow);
  bf16x8 ax1 = *(const bf16x8*)(xrow + 32);

  f32x4 acc[4];
  #pragma unroll
  for (int t=0;t<4;t++) acc[t]=(f32x4){0.f,0.f,0.f,0.f};
  const short* wp = wT16 + (size_t)m16*H_ + kb*8;
  #pragma unroll
  for (int t=0;t<4;t++){
    bf16x8 b0 = *(const bf16x8*)(wp + (size_t)(t*16)*H_);
    acc[t] = __builtin_amdgcn_mfma_f32_16x16x32_bf16(ax0, b0, acc[t], 0,0,0);
    bf16x8 b1 = *(const bf16x8*)(wp + (size_t)(t*16)*H_ + 32);
    acc[t] = __builtin_amdgcn_mfma_f32_16x16x32_bf16(ax1, b1, acc[t], 0,0,0);
  }

  int mrow = (lane>>4)*4;
  float ps[4]={0.f,0.f,0.f,0.f}, pd[4]={0.f,0.f,0.f,0.f};
  #pragma unroll
  for (int t=0;t<4;t++){
    int f = t*16 + m16;
    float as = atts[f], ad = attd[f];
    #pragma unroll
    for (int q=0;q<4;q++){
      int node = n0 + mrow + q;
      float v = acc[t][q];
      if (node < N) h16[(size_t)node*H_ + f] = __float2half(v);
      ps[q] = fmaf(v, as, ps[q]); pd[q] = fmaf(v, ad, pd[q]);
    }
  }
  #pragma unroll
  for (int d=1; d<16; d<<=1){
    #pragma unroll
    for (int q=0;q<4;q++){ ps[q] += __shfl_xor(ps[q], d); pd[q] += __shfl_xor(pd[q], d); }
  }
  if (m16==0){
    #pragma unroll
    for (int q=0;q<4;q++){
      int node = n0 + mrow + q;
      if (node < N){ ssc[node]=ps[q]; dsc[node]=pd[q]; }
    }
  }
}

// GAT: 4 nodes/wave, 16 lanes/node (half4 = 4 features/lane). Single-pass safe-exp softmax.
template<int L>
__global__ void __launch_bounds__(256)
k_gat_g4(const __half* __restrict__ h16, const float* __restrict__ ssc,
         const float* __restrict__ dsc, const uint2* __restrict__ rec,
         const int* __restrict__ off, const float* __restrict__ bias,
         short* __restrict__ hgat16, int N){
  int lane = threadIdx.x & 63, w = threadIdx.x >> 6;
  int g = lane >> 4, fl = lane & 15;
  int node = blockIdx.x*16 + w*4 + g;
  if (node >= N) return;
  int e0 = off[node], e1 = off[node+1];
  float dval = dsc[node];
  float acc0=0.f, acc1=0.f, acc2=0.f, acc3=0.f, den=0.f;
  int gbase = lane & 48;                 // g*16
  for (int base = e0; base < e1; base += 16){
    int p = base + fl;
    float ex = 0.f; int s = 0;
    if (p < e1){
      uint2 r = rec[p];
      s = (int)((r.y & 0xFFFFu) | ((r.x & 1u) << 16));
      unsigned hb = (L==0) ? (r.x & 0xFFFEu) : (L==1) ? (r.x >> 16) : (r.y >> 16);
      float a = ssc[s] + dval + h2f_(hb);
      a = (a > 0.f) ? a : SLOPE*a;
      ex = __expf(a);
    }
    den += ex;
    int cnt = e1 - base; if (cnt > 16) cnt = 16;
    for (int j = 0; j < cnt; j++){
      float exb = __shfl(ex, gbase + j);
      int   sb  = __shfl(s,  gbase + j);
      uint2 hv = *(const uint2*)(h16 + (size_t)sb*H_ + 4*fl);
      float2 f0 = __half22float2(*(__half2*)&hv.x);
      float2 f1 = __half22float2(*(__half2*)&hv.y);
      acc0 = fmaf(exb, f0.x, acc0);
      acc1 = fmaf(exb, f0.y, acc1);
      acc2 = fmaf(exb, f1.x, acc2);
      acc3 = fmaf(exb, f1.y, acc3);
    }
  }
  #pragma unroll
  for (int d=1; d<16; d<<=1) den += __shfl_xor(den, d);
  float4 bv = *(const float4*)(bias + 4*fl);
  float inv = 1.0f/den;
  float v0 = fmaxf(fmaf(acc0,inv,bv.x), 0.f);
  float v1 = fmaxf(fmaf(acc1,inv,bv.y), 0.f);
  float v2 = fmaxf(fmaf(acc2,inv,bv.z), 0.f);
  float v3 = fmaxf(fmaf(acc3,inv,bv.w), 0.f);
  uint2 o;
  o.x = ((unsigned)(unsigned short)f2bf(v1)<<16) | (unsigned short)f2bf(v0);
  o.y = ((unsigned)(unsigned short)f2bf(v3)<<16) | (unsigned short)f2bf(v2);
  *(uint2*)(hgat16 + (size_t)node*H_ + 4*fl) = o;
}

// block per graph: zero-atomic pooled output (batch sorted, xi bf16)
__global__ void __launch_bounds__(256)
k_pool_g(const short* __restrict__ xi, const float* __restrict__ wout,
         const int* __restrict__ gstart, const float* __restrict__ b_out,
         float* __restrict__ out){
  int g = blockIdx.x;
  int a = gstart[g], b = gstart[g+1];
  float acc = 0.f;
  for (int n = a + threadIdx.x; n < b; n += 256){
    const uint4* xr = (const uint4*)(xi + (size_t)n*H_);   // 8 bf16 per uint4
    float s = 0.f;
    #pragma unroll
    for (int q=0;q<8;q++){
      uint4 v = xr[q];
      s += bf2f((unsigned short)(v.x&0xFFFF))*wout[8*q]   + bf2f((unsigned short)(v.x>>16))*wout[8*q+1]
         + bf2f((unsigned short)(v.y&0xFFFF))*wout[8*q+2] + bf2f((unsigned short)(v.y>>16))*wout[8*q+3]
         + bf2f((unsigned short)(v.z&0xFFFF))*wout[8*q+4] + bf2f((unsigned short)(v.z>>16))*wout[8*q+5]
         + bf2f((unsigned short)(v.w&0xFFFF))*wout[8*q+6] + bf2f((unsigned short)(v.w>>16))*wout[8*q+7];
    }
    acc += s;
  }
  #pragma unroll
  for (int d=32; d; d>>=1) acc += __shfl_xor(acc, d);
  __shared__ float sh[4];
  if ((threadIdx.x&63)==0) sh[threadIdx.x>>6] = acc;
  __syncthreads();
  if (threadIdx.x==0) out[g] = sh[0]+sh[1]+sh[2]+sh[3] + b_out[0];
}

extern "C" void kernel_launch(void* const* d_in, const int* in_sizes, int n_in,
                              void* d_out, int out_size, void* d_ws, size_t ws_size,
                              hipStream_t stream){
  const float* x       = (const float*)d_in[0];
  const float* eattr   = (const float*)d_in[1];
  const float* w_node  = (const float*)d_in[2];
  const float* b_node  = (const float*)d_in[3];
  const float* w_edge  = (const float*)d_in[4];
  const float* b_edge  = (const float*)d_in[5];
  const float* conv_W  = (const float*)d_in[6];
  const float* conv_We = (const float*)d_in[7];
  const float* att_s   = (const float*)d_in[8];
  const float* att_d   = (const float*)d_in[9];
  const float* att_e   = (const float*)d_in[10];
  const float* conv_b  = (const float*)d_in[11];
  const float* gWih    = (const float*)d_in[12];
  const float* gWhh    = (const float*)d_in[13];
  const float* gbih    = (const float*)d_in[14];
  const float* gbhh    = (const float*)d_in[15];
  const float* w_out   = (const float*)d_in[16];
  const float* b_out   = (const float*)d_in[17];
  const int*   eidx    = (const int*)d_in[18];
  const int*   batch   = (const int*)d_in[19];
  float* out = (float*)d_out;

  int N = in_sizes[0]/DIN;
  int E = in_sizes[1]/DE;
  int G = out_size;
  int EN = E + N;
  const int* src = eidx;
  const int* dst = eidx + E;

  char* p = (char*)d_ws;
  auto carve = [&](size_t bytes)->void*{ void* r=(void*)p; p += (bytes+255)&~(size_t)255; return r; };
  short*  xi0    = (short*)carve((size_t)N*H_*2);
  short*  xi1    = (short*)carve((size_t)N*H_*2);
  __half* h16    = (__half*)carve((size_t)N*H_*2);
  short*  hgat16 = (short*)carve((size_t)N*H_*2);
  float*  ssc    = (float*)carve((size_t)N*4);
  float*  dsc    = (float*)carve((size_t)N*4);
  uint2*  esc8   = (uint2*)carve((size_t)E*8);
  uint2*  rec    = (uint2*)carve((size_t)EN*8);
  uint2*  bin8   = (uint2*)carve((size_t)256*CAP*8);
  unsigned short* bin2 = (unsigned short*)carve((size_t)256*CAP*2);
  int*    deg    = (int*)carve((size_t)N*4);
  int*    off    = (int*)carve((size_t)(N+1)*4);
  int*    bcur   = (int*)carve((size_t)256*4);
  int*    gstart = (int*)carve((size_t)(G+1)*4);
  int*    bsum   = (int*)carve((size_t)1024*4);
  int*    boff   = (int*)carve((size_t)1024*4);
  short*  wnT16  = (short*)carve((size_t)DIN*H_*2);
  short*  weT16p = (short*)carve((size_t)64*32*2);
  short*  cWT16  = (short*)carve((size_t)3*H_*H_*2);
  short*  WihT16 = (short*)carve((size_t)3*192*H_*2);
  short*  WhhT16 = (short*)carve((size_t)3*192*H_*2);
  float*  ve     = (float*)carve((size_t)3*H_*4);

  auto cdiv=[](int a,int b){return (a+b-1)/b;};
  int NB  = cdiv(N,256);
  int NBK = cdiv(N,BNODE);

  int prep_total = 2048+2048+12288+36864+36864+192+256;
  k_prep<<<cdiv(prep_total,256),256,0,stream>>>(w_node, w_edge, conv_W, gWih, gWhh, conv_We, att_e,
                                                wnT16, weT16p, cWT16, WihT16, WhhT16, ve, bcur);
  k_nmlp_m<<<cdiv(N,64),256,0,stream>>>(x, wnT16, b_node, xi0, N);
  k_edge_m<<<cdiv(E,64),256,0,stream>>>(eattr, weT16p, b_edge, ve, src, esc8, E);
  k_binA<<<cdiv(E,ACH),256,0,stream>>>(esc8, dst, bcur, bin8, bin2, E);
  k_hist<<<NBK,256,0,stream>>>(bin2, bcur, deg, N);
  k_bsum<<<NB,256,0,stream>>>(deg, bsum, N);
  k_bscan<<<1,1024,0,stream>>>(bsum, boff, NB, off+N, EN);
  k_scan_fin<<<NB,256,0,stream>>>(deg, boff, off, N);
  k_binB<<<NBK,256,0,stream>>>(bin8, bin2, bcur, off, rec, N);
  k_selfloop_csr<<<cdiv(N,256),256,0,stream>>>(off, rec, N);
  k_gbounds<<<NB,256,0,stream>>>(batch, gstart, N, G);

  int NB64 = cdiv(N,64);
  int NB16 = cdiv(N,16);
  for (int l=0; l<3; l++){
    const short* xin = (l&1) ? xi1 : xi0;
    short*       xo  = (l&1) ? xi0 : xi1;
    k_linh_m<<<NB64,256,0,stream>>>(xin, cWT16 + (size_t)l*H_*H_, att_s + l*H_, att_d + l*H_,
                                    h16, ssc, dsc, N);
    if (l==0)      k_gat_g4<0><<<NB16,256,0,stream>>>(h16, ssc, dsc, rec, off, conv_b + l*H_, hgat16, N);
    else if (l==1) k_gat_g4<1><<<NB16,256,0,stream>>>(h16, ssc, dsc, rec, off, conv_b + l*H_, hgat16, N);
    else           k_gat_g4<2><<<NB16,256,0,stream>>>(h16, ssc, dsc, rec, off, conv_b + l*H_, hgat16, N);
    k_gru_m<<<NB64,256,0,stream>>>(hgat16, xin, xo, WihT16 + (size_t)l*192*H_, WhhT16 + (size_t)l*192*H_,
                                   gbih + l*3*H_, gbhh + l*3*H_, N);
  }

  k_pool_g<<<G,256,0,stream>>>(xi1, w_out, gstart, b_out, out);
}

// Round 18
// 378.414 us; speedup vs baseline: 46.4689x; 1.0811x over previous
//
#include <hip/hip_runtime.h>
#include <hip/hip_fp16.h>

constexpr int H_  = 64;   // hidden
constexpr int DIN = 32;   // atom feature dim
constexpr int DE  = 16;   // edge feature dim
constexpr int BNODE = 512;  // nodes per scatter bucket (dstlocal < 512)
constexpr int ACH   = 2048; // edges per binning chunk
constexpr int CAP   = 6144; // per-bucket region capacity (mean 5120 + 14 sigma)
#define SLOPE 0.2f

typedef __attribute__((ext_vector_type(8))) short bf16x8;
typedef __attribute__((ext_vector_type(4))) float f32x4;

__device__ __forceinline__ float sigm_(float x){ return 1.0f/(1.0f+__expf(-x)); }
__device__ __forceinline__ float tanh_(float x){ float e=__expf(2.0f*x); return 1.0f - 2.0f/(e+1.0f); }
__device__ __forceinline__ short f2bf(float f){   // RNE float->bf16
  unsigned u = __float_as_uint(f);
  u += 0x7FFF + ((u>>16)&1);
  return (short)(u>>16);
}
__device__ __forceinline__ float bf2f(unsigned short s){
  return __uint_as_float(((unsigned)s)<<16);
}
__device__ __forceinline__ float h2f_(unsigned hb){
  return __half2float(__ushort_as_half((unsigned short)hb));
}

// one mega-kernel for all weight prep + bcur init
__global__ void k_prep(const float* __restrict__ w_node, const float* __restrict__ w_edge,
                       const float* __restrict__ conv_W, const float* __restrict__ gWih,
                       const float* __restrict__ gWhh, const float* __restrict__ conv_We,
                       const float* __restrict__ att_e,
                       short* __restrict__ wnT16, short* __restrict__ weT16p,
                       short* __restrict__ cWT16, short* __restrict__ WihT16,
                       short* __restrict__ WhhT16, float* __restrict__ ve,
                       int* __restrict__ bcur){
  int id = blockIdx.x*blockDim.x + threadIdx.x;
  if (id < 2048){                                   // wnT16 [64][32]
    int j = id >> 5, k = id & 31;
    wnT16[id] = f2bf(w_node[k*64 + j]);
    return;
  }
  id -= 2048;
  if (id < 2048){                                   // weT16p [64][32], k>=16 zero
    int j = id >> 5, k = id & 31;
    weT16p[id] = (k < DE) ? f2bf(w_edge[k*64 + j]) : (short)0;
    return;
  }
  id -= 2048;
  if (id < 12288){                                  // cWT16 [3][64 j][64 k]
    int l = id / 4096, rem = id & 4095, j = rem >> 6, k = rem & 63;
    cWT16[id] = f2bf(conv_W[l*4096 + k*64 + j]);
    return;
  }
  id -= 12288;
  if (id < 36864){                                  // WihT16 [3][192 j][64 k]
    int l = id / 12288, rem = id % 12288, j = rem >> 6, k = rem & 63;
    WihT16[id] = f2bf(gWih[l*12288 + k*192 + j]);
    return;
  }
  id -= 36864;
  if (id < 36864){                                  // WhhT16
    int l = id / 12288, rem = id % 12288, j = rem >> 6, k = rem & 63;
    WhhT16[id] = f2bf(gWhh[l*12288 + k*192 + j]);
    return;
  }
  id -= 36864;
  if (id < 192){                                    // ve[l][k]
    int l = id >> 6, k = id & 63;
    const float* w = conv_We + (size_t)(l*64+k)*64;
    const float* a = att_e + l*64;
    float s = 0.f;
    #pragma unroll
    for (int j=0;j<64;j++) s += w[j]*a[j];
    ve[id] = s;
    return;
  }
  id -= 192;
  if (id < 256) bcur[id] = id*CAP;                  // fixed-capacity bucket regions
}

// MFMA node MLP: xi16 = bf16(relu(x @ w_node + b)), K=32 exact. No LDS.
__global__ void __launch_bounds__(256,4)
k_nmlp_m(const float* __restrict__ x, const short* __restrict__ wT16,
         const float* __restrict__ b, short* __restrict__ xi, int N){
  int lane = threadIdx.x & 63, w = threadIdx.x >> 6;
  int m16 = lane & 15, kb = lane >> 4;
  int n0 = blockIdx.x*64 + w*16;
  int arow = n0 + m16; if (arow > N-1) arow = N-1;
  const float* xr = x + (size_t)arow*DIN + kb*8;
  float4 a0 = *(const float4*)xr, a1 = *(const float4*)(xr+4);
  bf16x8 af;
  af[0]=f2bf(a0.x); af[1]=f2bf(a0.y); af[2]=f2bf(a0.z); af[3]=f2bf(a0.w);
  af[4]=f2bf(a1.x); af[5]=f2bf(a1.y); af[6]=f2bf(a1.z); af[7]=f2bf(a1.w);
  f32x4 acc[4];
  #pragma unroll
  for (int t=0;t<4;t++) acc[t]=(f32x4){0.f,0.f,0.f,0.f};
  const short* wp = wT16 + (size_t)m16*DIN + kb*8;
  #pragma unroll
  for (int t=0;t<4;t++){
    bf16x8 bb = *(const bf16x8*)(wp + (size_t)(t*16)*DIN);
    acc[t] = __builtin_amdgcn_mfma_f32_16x16x32_bf16(af, bb, acc[t], 0,0,0);
  }
  int mrow = (lane>>4)*4;
  #pragma unroll
  for (int t=0;t<4;t++){
    int f = t*16 + m16;
    float bj = b[f];
    #pragma unroll
    for (int q=0;q<4;q++){
      int node = n0 + mrow + q;
      if (node < N) xi[(size_t)node*H_ + f] = f2bf(fmaxf(acc[t][q] + bj, 0.f));
    }
  }
}

// MFMA edge scores: 16 edges/wave, packed 8B record with src bits spliced in. No atomics.
__global__ void __launch_bounds__(256,4)
k_edge_m(const float* __restrict__ attr, const short* __restrict__ weT16p,
         const float* __restrict__ be, const float* __restrict__ ve,
         const int* __restrict__ src, uint2* __restrict__ esc8, int E){
  int lane = threadIdx.x & 63, w = threadIdx.x >> 6;
  int m16 = lane & 15, kb = lane >> 4;
  int e0 = (blockIdx.x*4 + w)*16;
  if (e0 >= E) return;
  bf16x8 af = {0,0,0,0,0,0,0,0};
  if (kb < 2){
    int arow = e0 + m16; if (arow > E-1) arow = E-1;
    const float* ap = attr + (size_t)arow*DE + kb*8;
    float4 a0 = *(const float4*)ap, a1 = *(const float4*)(ap+4);
    af[0]=f2bf(a0.x); af[1]=f2bf(a0.y); af[2]=f2bf(a0.z); af[3]=f2bf(a0.w);
    af[4]=f2bf(a1.x); af[5]=f2bf(a1.y); af[6]=f2bf(a1.z); af[7]=f2bf(a1.w);
  }
  f32x4 acc[4];
  #pragma unroll
  for (int t=0;t<4;t++) acc[t]=(f32x4){0.f,0.f,0.f,0.f};
  const short* wp = weT16p + (size_t)m16*32 + kb*8;
  #pragma unroll
  for (int t=0;t<4;t++){
    bf16x8 bb = *(const bf16x8*)(wp + (size_t)(t*16)*32);
    acc[t] = __builtin_amdgcn_mfma_f32_16x16x32_bf16(af, bb, acc[t], 0,0,0);
  }
  int mrow = (lane>>4)*4;
  float s0[4]={0.f,0.f,0.f,0.f}, s1[4]={0.f,0.f,0.f,0.f}, s2[4]={0.f,0.f,0.f,0.f};
  #pragma unroll
  for (int t=0;t<4;t++){
    int j = t*16 + m16;
    float bj = be[j];
    float v0 = ve[j], v1 = ve[64+j], v2 = ve[128+j];
    #pragma unroll
    for (int q=0;q<4;q++){
      float ea = fmaxf(acc[t][q] + bj, 0.f);
      s0[q] = fmaf(ea, v0, s0[q]);
      s1[q] = fmaf(ea, v1, s1[q]);
      s2[q] = fmaf(ea, v2, s2[q]);
    }
  }
  #pragma unroll
  for (int d=1; d<16; d<<=1){
    #pragma unroll
    for (int q=0;q<4;q++){
      s0[q] += __shfl_xor(s0[q], d);
      s1[q] += __shfl_xor(s1[q], d);
      s2[q] += __shfl_xor(s2[q], d);
    }
  }
  if (m16==0){
    #pragma unroll
    for (int q=0;q<4;q++){
      int e = e0 + mrow + q;
      if (e < E){
        unsigned sv = (unsigned)src[e];
        unsigned h0 = (__half_as_ushort(__float2half(s0[q])) & 0xFFFEu) | (sv >> 16);
        unsigned h1 = __half_as_ushort(__float2half(s1[q]));
        unsigned h2 = __half_as_ushort(__float2half(s2[q]));
        esc8[e] = make_uint2(h0 | (h1<<16), (sv & 0xFFFFu) | (h2<<16));
      }
    }
  }
}

// pass A: LDS-binned append of 8B records + 2B dstlocal into fixed per-bucket regions.
__global__ void __launch_bounds__(256)
k_binA(const uint2* __restrict__ esc8, const int* __restrict__ dst,
       int* __restrict__ bcur, uint2* __restrict__ bin8, unsigned short* __restrict__ bin2,
       int E){
  __shared__ int cnt[256];
  __shared__ int ofs[256];
  __shared__ int gofs[256];
  __shared__ uint2 st8[ACH];
  __shared__ unsigned short st2[ACH];
  __shared__ unsigned char sbid[ACH];
  int tid = threadIdx.x;
  int base = blockIdx.x * ACH;
  cnt[tid] = 0;
  __syncthreads();
  uint2 r8[8]; int bb[8]; int ms[8]; int dl[8];
  #pragma unroll
  for (int k=0;k<8;k++){
    int e = base + tid + k*256;
    bb[k] = -1;
    if (e < E){
      r8[k] = esc8[e];
      int d = dst[e];
      bb[k] = d >> 9;
      dl[k] = d & (BNODE-1);
      ms[k] = atomicAdd(&cnt[bb[k]], 1);
    }
  }
  __syncthreads();
  int v = cnt[tid];
  ofs[tid] = v;
  __syncthreads();
  for (int d=1; d<256; d<<=1){
    int t = 0;
    if (tid>=d) t = ofs[tid-d];
    __syncthreads();
    if (tid>=d) ofs[tid] += t;
    __syncthreads();
  }
  int total = ofs[255];
  int excl = ofs[tid] - v;
  __syncthreads();
  ofs[tid] = excl;
  __syncthreads();
  #pragma unroll
  for (int k=0;k<8;k++){
    if (bb[k] >= 0){
      int slot = ofs[bb[k]] + ms[k];
      st8[slot] = r8[k];
      st2[slot] = (unsigned short)dl[k];
      sbid[slot] = (unsigned char)bb[k];
    }
  }
  if (v > 0) gofs[tid] = atomicAdd(&bcur[tid], v);
  __syncthreads();
  for (int slot = tid; slot < total; slot += 256){
    int b = sbid[slot];
    int gp = gofs[b] + (slot - ofs[b]);
    bin8[gp] = st8[slot];
    bin2[gp] = st2[slot];
  }
}

// per-bucket LDS histogram -> deg (zero global atomics)
__global__ void __launch_bounds__(256)
k_hist(const unsigned short* __restrict__ bin2, const int* __restrict__ bcur,
       int* __restrict__ deg, int N){
  __shared__ int lcnt[BNODE];
  int b = blockIdx.x;
  int n0 = b*BNODE;
  int n1 = n0 + BNODE; if (n1 > N) n1 = N;
  int nn = n1 - n0;
  for (int i = threadIdx.x; i < nn; i += 256) lcnt[i] = 0;
  __syncthreads();
  int beg = b*CAP, cntb = bcur[b] - beg;
  for (int idx = threadIdx.x; idx < cntb; idx += 256)
    atomicAdd(&lcnt[bin2[beg+idx]], 1);
  __syncthreads();
  for (int i = threadIdx.x; i < nn; i += 256) deg[n0+i] = lcnt[i] + 1;   // +1 self-loop
}

// ---- hierarchical scan of deg -> off (exclusive) ----
__global__ void k_bsum(const int* __restrict__ deg, int* __restrict__ bsum, int N){
  int i = blockIdx.x*256 + threadIdx.x;
  int v = (i<N) ? deg[i] : 0;
  #pragma unroll
  for(int d=32; d; d>>=1) v += __shfl_xor(v, d);
  __shared__ int sh[4];
  if ((threadIdx.x&63)==0) sh[threadIdx.x>>6] = v;
  __syncthreads();
  if (threadIdx.x==0) bsum[blockIdx.x] = sh[0]+sh[1]+sh[2]+sh[3];
}

__global__ void k_bscan(const int* __restrict__ bsum, int* __restrict__ boff, int NB,
                        int* __restrict__ offN, int EN){
  __shared__ int sh[1024];
  int tid = threadIdx.x;
  int v = (tid<NB) ? bsum[tid] : 0;
  sh[tid] = v;
  __syncthreads();
  for(int d=1; d<1024; d<<=1){
    int t = 0;
    if (tid>=d) t = sh[tid-d];
    __syncthreads();
    if (tid>=d) sh[tid] += t;
    __syncthreads();
  }
  if (tid<NB) boff[tid] = sh[tid] - v;  // exclusive
  if (tid==0) offN[0] = EN;
}

__global__ void k_scan_fin(const int* __restrict__ deg, const int* __restrict__ boff,
                           int* __restrict__ off, int N){
  __shared__ int sh[256];
  int i = blockIdx.x*256 + threadIdx.x;
  int v = (i<N) ? deg[i] : 0;
  sh[threadIdx.x] = v;
  __syncthreads();
  for(int d=1; d<256; d<<=1){
    int t = 0;
    if (threadIdx.x>=d) t = sh[threadIdx.x-d];
    __syncthreads();
    if (threadIdx.x>=d) sh[threadIdx.x] += t;
    __syncthreads();
  }
  if (i<N) off[i] = boff[blockIdx.x] + sh[threadIdx.x] - v;
}

// pass B: one WG per bucket; scatter within the bucket's L2-local CSR window.
__global__ void __launch_bounds__(256)
k_binB(const uint2* __restrict__ bin8, const unsigned short* __restrict__ bin2,
       const int* __restrict__ bcur, const int* __restrict__ off,
       uint2* __restrict__ rec, int N){
  __shared__ int lcur[BNODE];
  int b = blockIdx.x;
  int n0 = b*BNODE;
  int n1 = n0 + BNODE; if (n1 > N) n1 = N;
  int nn = n1 - n0;
  for (int i = threadIdx.x; i < nn; i += 256) lcur[i] = off[n0+i] + 1;  // slot off[n] = self-loop
  __syncthreads();
  int beg = b*CAP, cntb = bcur[b] - beg;
  for (int idx = threadIdx.x; idx < cntb; idx += 256){
    uint2 r = bin8[beg+idx];
    int dl = bin2[beg+idx];
    int p = atomicAdd(&lcur[dl], 1);
    rec[p] = r;
  }
}

// self-loop record at off[n]: mean of segment's real-edge scores (0 if none), src=n
__global__ void k_selfloop_csr(const int* __restrict__ off, uint2* __restrict__ rec, int N){
  int n = blockIdx.x*blockDim.x+threadIdx.x;
  if (n>=N) return;
  int a = off[n]+1, b = off[n+1];
  float s0=0.f,s1=0.f,s2=0.f;
  for (int p=a;p<b;p++){
    uint2 r=rec[p];
    s0 += h2f_(r.x & 0xFFFEu);
    s1 += h2f_(r.x >> 16);
    s2 += h2f_(r.y >> 16);
  }
  float inv = (b>a) ? 1.0f/(float)(b-a) : 0.0f;
  unsigned h0 = __half_as_ushort(__float2half(s0*inv)) & 0xFFFEu;
  unsigned h1 = __half_as_ushort(__float2half(s1*inv));
  unsigned h2 = __half_as_ushort(__float2half(s2*inv));
  unsigned s = (unsigned)n;
  rec[off[n]] = make_uint2(h0 | (s>>16) | (h1<<16), (s & 0xFFFFu) | (h2<<16));
}

// graph boundaries from sorted batch
__global__ void k_gbounds(const int* __restrict__ batch, int* __restrict__ gstart, int N, int G){
  int n = blockIdx.x*blockDim.x+threadIdx.x;
  if (n>=N) return;
  int b = batch[n];
  int bp = (n==0) ? -1 : batch[n-1];
  for (int g=bp+1; g<=b; g++) gstart[g]=n;
  if (n==N-1){ for (int g=b+1; g<=G; g++) gstart[g]=N; }
}

// MFMA GRU: 2 node-strips per wave (32 nodes), block = 128 nodes.
// B-fragments loaded once, reused for both strips -> 2x arithmetic intensity.
__global__ void __launch_bounds__(256,2)
k_gru_m(const short* __restrict__ hg16, const short* __restrict__ xin, short* __restrict__ xout,
        const short* __restrict__ WihT16, const short* __restrict__ WhhT16,
        const float* __restrict__ bih, const float* __restrict__ bhh, int N){
  int lane = threadIdx.x & 63, w = threadIdx.x >> 6;
  int m16 = lane & 15;
  int kb  = lane >> 4;
  int n0 = blockIdx.x*128 + w*32;

  int r0 = n0 + m16;      if (r0 > N-1) r0 = N-1;
  int r1 = n0 + 16 + m16; if (r1 > N-1) r1 = N-1;
  const short* h0p = hg16 + (size_t)r0*H_ + kb*8;
  const short* h1p = hg16 + (size_t)r1*H_ + kb*8;
  bf16x8 ah0a = *(const bf16x8*)(h0p), ah1a = *(const bf16x8*)(h0p+32);
  bf16x8 ah0b = *(const bf16x8*)(h1p), ah1b = *(const bf16x8*)(h1p+32);
  const short* x0p = xin + (size_t)r0*H_ + kb*8;
  const short* x1p = xin + (size_t)r1*H_ + kb*8;
  bf16x8 ax0a = *(const bf16x8*)(x0p), ax1a = *(const bf16x8*)(x0p+32);
  bf16x8 ax0b = *(const bf16x8*)(x1p), ax1b = *(const bf16x8*)(x1p+32);

  f32x4 aR[2][4], aZ[2][4], aNi[2][4], aNh[2][4];
  #pragma unroll
  for (int s=0;s<2;s++){
    #pragma unroll
    for (int t=0;t<4;t++){
      aR[s][t]=(f32x4){0.f,0.f,0.f,0.f}; aZ[s][t]=(f32x4){0.f,0.f,0.f,0.f};
      aNi[s][t]=(f32x4){0.f,0.f,0.f,0.f}; aNh[s][t]=(f32x4){0.f,0.f,0.f,0.f};
    }
  }

  const short* wi = WihT16 + (size_t)m16*H_ + kb*8;
  const short* wh = WhhT16 + (size_t)m16*H_ + kb*8;
  #pragma unroll
  for (int t=0;t<4;t++){
    bf16x8 b;
    b = *(const bf16x8*)(wi + (size_t)(t*16)*H_);
    aR[0][t] = __builtin_amdgcn_mfma_f32_16x16x32_bf16(ah0a, b, aR[0][t], 0,0,0);
    aR[1][t] = __builtin_amdgcn_mfma_f32_16x16x32_bf16(ah0b, b, aR[1][t], 0,0,0);
    b = *(const bf16x8*)(wi + (size_t)(t*16)*H_ + 32);
    aR[0][t] = __builtin_amdgcn_mfma_f32_16x16x32_bf16(ah1a, b, aR[0][t], 0,0,0);
    aR[1][t] = __builtin_amdgcn_mfma_f32_16x16x32_bf16(ah1b, b, aR[1][t], 0,0,0);
    b = *(const bf16x8*)(wh + (size_t)(t*16)*H_);
    aR[0][t] = __builtin_amdgcn_mfma_f32_16x16x32_bf16(ax0a, b, aR[0][t], 0,0,0);
    aR[1][t] = __builtin_amdgcn_mfma_f32_16x16x32_bf16(ax0b, b, aR[1][t], 0,0,0);
    b = *(const bf16x8*)(wh + (size_t)(t*16)*H_ + 32);
    aR[0][t] = __builtin_amdgcn_mfma_f32_16x16x32_bf16(ax1a, b, aR[0][t], 0,0,0);
    aR[1][t] = __builtin_amdgcn_mfma_f32_16x16x32_bf16(ax1b, b, aR[1][t], 0,0,0);

    b = *(const bf16x8*)(wi + (size_t)(64+t*16)*H_);
    aZ[0][t] = __builtin_amdgcn_mfma_f32_16x16x32_bf16(ah0a, b, aZ[0][t], 0,0,0);
    aZ[1][t] = __builtin_amdgcn_mfma_f32_16x16x32_bf16(ah0b, b, aZ[1][t], 0,0,0);
    b = *(const bf16x8*)(wi + (size_t)(64+t*16)*H_ + 32);
    aZ[0][t] = __builtin_amdgcn_mfma_f32_16x16x32_bf16(ah1a, b, aZ[0][t], 0,0,0);
    aZ[1][t] = __builtin_amdgcn_mfma_f32_16x16x32_bf16(ah1b, b, aZ[1][t], 0,0,0);
    b = *(const bf16x8*)(wh + (size_t)(64+t*16)*H_);
    aZ[0][t] = __builtin_amdgcn_mfma_f32_16x16x32_bf16(ax0a, b, aZ[0][t], 0,0,0);
    aZ[1][t] = __builtin_amdgcn_mfma_f32_16x16x32_bf16(ax0b, b, aZ[1][t], 0,0,0);
    b = *(const bf16x8*)(wh + (size_t)(64+t*16)*H_ + 32);
    aZ[0][t] = __builtin_amdgcn_mfma_f32_16x16x32_bf16(ax1a, b, aZ[0][t], 0,0,0);
    aZ[1][t] = __builtin_amdgcn_mfma_f32_16x16x32_bf16(ax1b, b, aZ[1][t], 0,0,0);

    b = *(const bf16x8*)(wi + (size_t)(128+t*16)*H_);
    aNi[0][t] = __builtin_amdgcn_mfma_f32_16x16x32_bf16(ah0a, b, aNi[0][t], 0,0,0);
    aNi[1][t] = __builtin_amdgcn_mfma_f32_16x16x32_bf16(ah0b, b, aNi[1][t], 0,0,0);
    b = *(const bf16x8*)(wi + (size_t)(128+t*16)*H_ + 32);
    aNi[0][t] = __builtin_amdgcn_mfma_f32_16x16x32_bf16(ah1a, b, aNi[0][t], 0,0,0);
    aNi[1][t] = __builtin_amdgcn_mfma_f32_16x16x32_bf16(ah1b, b, aNi[1][t], 0,0,0);
    b = *(const bf16x8*)(wh + (size_t)(128+t*16)*H_);
    aNh[0][t] = __builtin_amdgcn_mfma_f32_16x16x32_bf16(ax0a, b, aNh[0][t], 0,0,0);
    aNh[1][t] = __builtin_amdgcn_mfma_f32_16x16x32_bf16(ax0b, b, aNh[1][t], 0,0,0);
    b = *(const bf16x8*)(wh + (size_t)(128+t*16)*H_ + 32);
    aNh[0][t] = __builtin_amdgcn_mfma_f32_16x16x32_bf16(ax1a, b, aNh[0][t], 0,0,0);
    aNh[1][t] = __builtin_amdgcn_mfma_f32_16x16x32_bf16(ax1b, b, aNh[1][t], 0,0,0);
  }

  int mrow = (lane>>4)*4;
  #pragma unroll
  for (int s=0;s<2;s++){
    #pragma unroll
    for (int t=0;t<4;t++){
      int f = t*16 + m16;
      float br = bih[f]     + bhh[f];
      float bz = bih[64+f]  + bhh[64+f];
      float bin= bih[128+f], bhn = bhh[128+f];
      #pragma unroll
      for (int q=0;q<4;q++){
        int node = n0 + s*16 + mrow + q;
        if (node < N){
          float r  = sigm_(aR[s][t][q] + br);
          float z  = sigm_(aZ[s][t][q] + bz);
          float nn = tanh_(aNi[s][t][q] + bin + r*(aNh[s][t][q] + bhn));
          float xv = bf2f((unsigned short)xin[(size_t)node*H_ + f]);
          xout[(size_t)node*H_ + f] = f2bf(fmaxf((1.f-z)*nn + z*xv, 0.f));
        }
      }
    }
  }
}

// MFMA linear-h: 2 node-strips per wave (32 nodes), block = 128 nodes. bf16 input.
__global__ void __launch_bounds__(256,4)
k_linh_m(const short* __restrict__ xi, const short* __restrict__ wT16,
         const float* __restrict__ atts, const float* __restrict__ attd,
         __half* __restrict__ h16, float* __restrict__ ssc, float* __restrict__ dsc, int N){
  int lane = threadIdx.x & 63, w = threadIdx.x >> 6;
  int m16 = lane & 15, kb = lane >> 4;
  int n0 = blockIdx.x*128 + w*32;
  int r0 = n0 + m16;      if (r0 > N-1) r0 = N-1;
  int r1 = n0 + 16 + m16; if (r1 > N-1) r1 = N-1;
  const short* x0p = xi + (size_t)r0*H_ + kb*8;
  const short* x1p = xi + (size_t)r1*H_ + kb*8;
  bf16x8 ax0a = *(const bf16x8*)(x0p), ax1a = *(const bf16x8*)(x0p+32);
  bf16x8 ax0b = *(const bf16x8*)(x1p), ax1b = *(const bf16x8*)(x1p+32);

  f32x4 acc[2][4];
  #pragma unroll
  for (int s=0;s<2;s++)
    #pragma unroll
    for (int t=0;t<4;t++) acc[s][t]=(f32x4){0.f,0.f,0.f,0.f};
  const short* wp = wT16 + (size_t)m16*H_ + kb*8;
  #pragma unroll
  for (int t=0;t<4;t++){
    bf16x8 b0 = *(const bf16x8*)(wp + (size_t)(t*16)*H_);
    acc[0][t] = __builtin_amdgcn_mfma_f32_16x16x32_bf16(ax0a, b0, acc[0][t], 0,0,0);
    acc[1][t] = __builtin_amdgcn_mfma_f32_16x16x32_bf16(ax0b, b0, acc[1][t], 0,0,0);
    bf16x8 b1 = *(const bf16x8*)(wp + (size_t)(t*16)*H_ + 32);
    acc[0][t] = __builtin_amdgcn_mfma_f32_16x16x32_bf16(ax1a, b1, acc[0][t], 0,0,0);
    acc[1][t] = __builtin_amdgcn_mfma_f32_16x16x32_bf16(ax1b, b1, acc[1][t], 0,0,0);
  }

  int mrow = (lane>>4)*4;
  float ps[2][4], pd[2][4];
  #pragma unroll
  for (int s=0;s<2;s++)
    #pragma unroll
    for (int q=0;q<4;q++){ ps[s][q]=0.f; pd[s][q]=0.f; }
  #pragma unroll
  for (int t=0;t<4;t++){
    int f = t*16 + m16;
    float as = atts[f], ad = attd[f];
    #pragma unroll
    for (int s=0;s<2;s++){
      #pragma unroll
      for (int q=0;q<4;q++){
        int node = n0 + s*16 + mrow + q;
        float v = acc[s][t][q];
        if (node < N) h16[(size_t)node*H_ + f] = __float2half(v);
        ps[s][q] = fmaf(v, as, ps[s][q]); pd[s][q] = fmaf(v, ad, pd[s][q]);
      }
    }
  }
  #pragma unroll
  for (int d=1; d<16; d<<=1){
    #pragma unroll
    for (int s=0;s<2;s++)
      #pragma unroll
      for (int q=0;q<4;q++){ ps[s][q] += __shfl_xor(ps[s][q], d); pd[s][q] += __shfl_xor(pd[s][q], d); }
  }
  if (m16==0){
    #pragma unroll
    for (int s=0;s<2;s++){
      #pragma unroll
      for (int q=0;q<4;q++){
        int node = n0 + s*16 + mrow + q;
        if (node < N){ ssc[node]=ps[s][q]; dsc[node]=pd[s][q]; }
      }
    }
  }
}

// GAT: 4 nodes/wave, 16 lanes/node (half4 = 4 features/lane). Single-pass safe-exp softmax.
template<int L>
__global__ void __launch_bounds__(256)
k_gat_g4(const __half* __restrict__ h16, const float* __restrict__ ssc,
         const float* __restrict__ dsc, const uint2* __restrict__ rec,
         const int* __restrict__ off, const float* __restrict__ bias,
         short* __restrict__ hgat16, int N){
  int lane = threadIdx.x & 63, w = threadIdx.x >> 6;
  int g = lane >> 4, fl = lane & 15;
  int node = blockIdx.x*16 + w*4 + g;
  if (node >= N) return;
  int e0 = off[node], e1 = off[node+1];
  float dval = dsc[node];
  float acc0=0.f, acc1=0.f, acc2=0.f, acc3=0.f, den=0.f;
  int gbase = lane & 48;                 // g*16
  for (int base = e0; base < e1; base += 16){
    int p = base + fl;
    float ex = 0.f; int s = 0;
    if (p < e1){
      uint2 r = rec[p];
      s = (int)((r.y & 0xFFFFu) | ((r.x & 1u) << 16));
      unsigned hb = (L==0) ? (r.x & 0xFFFEu) : (L==1) ? (r.x >> 16) : (r.y >> 16);
      float a = ssc[s] + dval + h2f_(hb);
      a = (a > 0.f) ? a : SLOPE*a;
      ex = __expf(a);
    }
    den += ex;
    int cnt = e1 - base; if (cnt > 16) cnt = 16;
    for (int j = 0; j < cnt; j++){
      float exb = __shfl(ex, gbase + j);
      int   sb  = __shfl(s,  gbase + j);
      uint2 hv = *(const uint2*)(h16 + (size_t)sb*H_ + 4*fl);
      float2 f0 = __half22float2(*(__half2*)&hv.x);
      float2 f1 = __half22float2(*(__half2*)&hv.y);
      acc0 = fmaf(exb, f0.x, acc0);
      acc1 = fmaf(exb, f0.y, acc1);
      acc2 = fmaf(exb, f1.x, acc2);
      acc3 = fmaf(exb, f1.y, acc3);
    }
  }
  #pragma unroll
  for (int d=1; d<16; d<<=1) den += __shfl_xor(den, d);
  float4 bv = *(const float4*)(bias + 4*fl);
  float inv = 1.0f/den;
  float v0 = fmaxf(fmaf(acc0,inv,bv.x), 0.f);
  float v1 = fmaxf(fmaf(acc1,inv,bv.y), 0.f);
  float v2 = fmaxf(fmaf(acc2,inv,bv.z), 0.f);
  float v3 = fmaxf(fmaf(acc3,inv,bv.w), 0.f);
  uint2 o;
  o.x = ((unsigned)(unsigned short)f2bf(v1)<<16) | (unsigned short)f2bf(v0);
  o.y = ((unsigned)(unsigned short)f2bf(v3)<<16) | (unsigned short)f2bf(v2);
  *(uint2*)(hgat16 + (size_t)node*H_ + 4*fl) = o;
}

// block per graph: zero-atomic pooled output (batch sorted, xi bf16)
__global__ void __launch_bounds__(256)
k_pool_g(const short* __restrict__ xi, const float* __restrict__ wout,
         const int* __restrict__ gstart, const float* __restrict__ b_out,
         float* __restrict__ out){
  int g = blockIdx.x;
  int a = gstart[g], b = gstart[g+1];
  float acc = 0.f;
  for (int n = a + threadIdx.x; n < b; n += 256){
    const uint4* xr = (const uint4*)(xi + (size_t)n*H_);   // 8 bf16 per uint4
    float s = 0.f;
    #pragma unroll
    for (int q=0;q<8;q++){
      uint4 v = xr[q];
      s += bf2f((unsigned short)(v.x&0xFFFF))*wout[8*q]   + bf2f((unsigned short)(v.x>>16))*wout[8*q+1]
         + bf2f((unsigned short)(v.y&0xFFFF))*wout[8*q+2] + bf2f((unsigned short)(v.y>>16))*wout[8*q+3]
         + bf2f((unsigned short)(v.z&0xFFFF))*wout[8*q+4] + bf2f((unsigned short)(v.z>>16))*wout[8*q+5]
         + bf2f((unsigned short)(v.w&0xFFFF))*wout[8*q+6] + bf2f((unsigned short)(v.w>>16))*wout[8*q+7];
    }
    acc += s;
  }
  #pragma unroll
  for (int d=32; d; d>>=1) acc += __shfl_xor(acc, d);
  __shared__ float sh[4];
  if ((threadIdx.x&63)==0) sh[threadIdx.x>>6] = acc;
  __syncthreads();
  if (threadIdx.x==0) out[g] = sh[0]+sh[1]+sh[2]+sh[3] + b_out[0];
}

extern "C" void kernel_launch(void* const* d_in, const int* in_sizes, int n_in,
                              void* d_out, int out_size, void* d_ws, size_t ws_size,
                              hipStream_t stream){
  const float* x       = (const float*)d_in[0];
  const float* eattr   = (const float*)d_in[1];
  const float* w_node  = (const float*)d_in[2];
  const float* b_node  = (const float*)d_in[3];
  const float* w_edge  = (const float*)d_in[4];
  const float* b_edge  = (const float*)d_in[5];
  const float* conv_W  = (const float*)d_in[6];
  const float* conv_We = (const float*)d_in[7];
  const float* att_s   = (const float*)d_in[8];
  const float* att_d   = (const float*)d_in[9];
  const float* att_e   = (const float*)d_in[10];
  const float* conv_b  = (const float*)d_in[11];
  const float* gWih    = (const float*)d_in[12];
  const float* gWhh    = (const float*)d_in[13];
  const float* gbih    = (const float*)d_in[14];
  const float* gbhh    = (const float*)d_in[15];
  const float* w_out   = (const float*)d_in[16];
  const float* b_out   = (const float*)d_in[17];
  const int*   eidx    = (const int*)d_in[18];
  const int*   batch   = (const int*)d_in[19];
  float* out = (float*)d_out;

  int N = in_sizes[0]/DIN;
  int E = in_sizes[1]/DE;
  int G = out_size;
  int EN = E + N;
  const int* src = eidx;
  const int* dst = eidx + E;

  char* p = (char*)d_ws;
  auto carve = [&](size_t bytes)->void*{ void* r=(void*)p; p += (bytes+255)&~(size_t)255; return r; };
  short*  xi0    = (short*)carve((size_t)N*H_*2);
  short*  xi1    = (short*)carve((size_t)N*H_*2);
  __half* h16    = (__half*)carve((size_t)N*H_*2);
  short*  hgat16 = (short*)carve((size_t)N*H_*2);
  float*  ssc    = (float*)carve((size_t)N*4);
  float*  dsc    = (float*)carve((size_t)N*4);
  uint2*  esc8   = (uint2*)carve((size_t)E*8);
  uint2*  rec    = (uint2*)carve((size_t)EN*8);
  uint2*  bin8   = (uint2*)carve((size_t)256*CAP*8);
  unsigned short* bin2 = (unsigned short*)carve((size_t)256*CAP*2);
  int*    deg    = (int*)carve((size_t)N*4);
  int*    off    = (int*)carve((size_t)(N+1)*4);
  int*    bcur   = (int*)carve((size_t)256*4);
  int*    gstart = (int*)carve((size_t)(G+1)*4);
  int*    bsum   = (int*)carve((size_t)1024*4);
  int*    boff   = (int*)carve((size_t)1024*4);
  short*  wnT16  = (short*)carve((size_t)DIN*H_*2);
  short*  weT16p = (short*)carve((size_t)64*32*2);
  short*  cWT16  = (short*)carve((size_t)3*H_*H_*2);
  short*  WihT16 = (short*)carve((size_t)3*192*H_*2);
  short*  WhhT16 = (short*)carve((size_t)3*192*H_*2);
  float*  ve     = (float*)carve((size_t)3*H_*4);

  auto cdiv=[](int a,int b){return (a+b-1)/b;};
  int NB  = cdiv(N,256);
  int NBK = cdiv(N,BNODE);

  int prep_total = 2048+2048+12288+36864+36864+192+256;
  k_prep<<<cdiv(prep_total,256),256,0,stream>>>(w_node, w_edge, conv_W, gWih, gWhh, conv_We, att_e,
                                                wnT16, weT16p, cWT16, WihT16, WhhT16, ve, bcur);
  k_nmlp_m<<<cdiv(N,64),256,0,stream>>>(x, wnT16, b_node, xi0, N);
  k_edge_m<<<cdiv(E,64),256,0,stream>>>(eattr, weT16p, b_edge, ve, src, esc8, E);
  k_binA<<<cdiv(E,ACH),256,0,stream>>>(esc8, dst, bcur, bin8, bin2, E);
  k_hist<<<NBK,256,0,stream>>>(bin2, bcur, deg, N);
  k_bsum<<<NB,256,0,stream>>>(deg, bsum, N);
  k_bscan<<<1,1024,0,stream>>>(bsum, boff, NB, off+N, EN);
  k_scan_fin<<<NB,256,0,stream>>>(deg, boff, off, N);
  k_binB<<<NBK,256,0,stream>>>(bin8, bin2, bcur, off, rec, N);
  k_selfloop_csr<<<cdiv(N,256),256,0,stream>>>(off, rec, N);
  k_gbounds<<<NB,256,0,stream>>>(batch, gstart, N, G);

  int NB128 = cdiv(N,128);
  int NB16  = cdiv(N,16);
  for (int l=0; l<3; l++){
    const short* xin = (l&1) ? xi1 : xi0;
    short*       xo  = (l&1) ? xi0 : xi1;
    k_linh_m<<<NB128,256,0,stream>>>(xin, cWT16 + (size_t)l*H_*H_, att_s + l*H_, att_d + l*H_,
                                     h16, ssc, dsc, N);
    if (l==0)      k_gat_g4<0><<<NB16,256,0,stream>>>(h16, ssc, dsc, rec, off, conv_b + l*H_, hgat16, N);
    else if (l==1) k_gat_g4<1><<<NB16,256,0,stream>>>(h16, ssc, dsc, rec, off, conv_b + l*H_, hgat16, N);
    else           k_gat_g4<2><<<NB16,256,0,stream>>>(h16, ssc, dsc, rec, off, conv_b + l*H_, hgat16, N);
    k_gru_m<<<NB128,256,0,stream>>>(hgat16, xin, xo, WihT16 + (size_t)l*192*H_, WhhT16 + (size_t)l*192*H_,
                                    gbih + l*3*H_, gbhh + l*3*H_, N);
  }

  k_pool_g<<<G,256,0,stream>>>(xi1, w_out, gstart, b_out, out);
}

// Round 19
// 374.278 us; speedup vs baseline: 46.9825x; 1.0111x over previous
//
#include <hip/hip_runtime.h>
#include <hip/hip_fp16.h>

constexpr int H_  = 64;   // hidden
constexpr int DIN = 32;   // atom feature dim
constexpr int DE  = 16;   // edge feature dim
constexpr int BNODE = 512;  // nodes per scatter bucket (dstlocal < 512)
constexpr int ACH   = 2048; // edges per binning chunk
constexpr int CAP   = 6144; // per-bucket bin region capacity (mean 5120 + 14 sigma)
constexpr int CAP2  = CAP + BNODE; // per-bucket rec region (edges + self-loops)
#define SLOPE 0.2f

typedef __attribute__((ext_vector_type(8))) short bf16x8;
typedef __attribute__((ext_vector_type(4))) float f32x4;

__device__ __forceinline__ float sigm_(float x){ return 1.0f/(1.0f+__expf(-x)); }
__device__ __forceinline__ float tanh_(float x){ float e=__expf(2.0f*x); return 1.0f - 2.0f/(e+1.0f); }
__device__ __forceinline__ short f2bf(float f){   // RNE float->bf16
  unsigned u = __float_as_uint(f);
  u += 0x7FFF + ((u>>16)&1);
  return (short)(u>>16);
}
__device__ __forceinline__ float bf2f(unsigned short s){
  return __uint_as_float(((unsigned)s)<<16);
}
__device__ __forceinline__ float h2f_(unsigned hb){
  return __half2float(__ushort_as_half((unsigned short)hb));
}

// mega-kernel: weight prep + bcur init + graph bounds
__global__ void k_prep(const float* __restrict__ w_node, const float* __restrict__ w_edge,
                       const float* __restrict__ b_edge,
                       const float* __restrict__ conv_W, const float* __restrict__ gWih,
                       const float* __restrict__ gWhh, const float* __restrict__ conv_We,
                       const float* __restrict__ att_e, const int* __restrict__ batch,
                       short* __restrict__ wnT16, short* __restrict__ weT16p,
                       short* __restrict__ cWT16, short* __restrict__ WihT16,
                       short* __restrict__ WhhT16, float* __restrict__ ve,
                       int* __restrict__ bcur, int* __restrict__ gstart, int N, int G){
  int id = blockIdx.x*blockDim.x + threadIdx.x;
  if (id < 2048){                                   // wnT16 [64][32]
    int j = id >> 5, k = id & 31;
    wnT16[id] = f2bf(w_node[k*64 + j]);
    return;
  }
  id -= 2048;
  if (id < 2048){                                   // weT16p [64][32]; k=16 row = bias
    int j = id >> 5, k = id & 31;
    weT16p[id] = (k < DE) ? f2bf(w_edge[k*64 + j]) : (k == DE ? f2bf(b_edge[j]) : (short)0);
    return;
  }
  id -= 2048;
  if (id < 12288){                                  // cWT16 [3][64 j][64 k]
    int l = id / 4096, rem = id & 4095, j = rem >> 6, k = rem & 63;
    cWT16[id] = f2bf(conv_W[l*4096 + k*64 + j]);
    return;
  }
  id -= 12288;
  if (id < 36864){                                  // WihT16 [3][192 j][64 k]
    int l = id / 12288, rem = id % 12288, j = rem >> 6, k = rem & 63;
    WihT16[id] = f2bf(gWih[l*12288 + k*192 + j]);
    return;
  }
  id -= 36864;
  if (id < 36864){                                  // WhhT16
    int l = id / 12288, rem = id % 12288, j = rem >> 6, k = rem & 63;
    WhhT16[id] = f2bf(gWhh[l*12288 + k*192 + j]);
    return;
  }
  id -= 36864;
  if (id < 192){                                    // ve[l][k]
    int l = id >> 6, k = id & 63;
    const float* w = conv_We + (size_t)(l*64+k)*64;
    const float* a = att_e + l*64;
    float s = 0.f;
    #pragma unroll
    for (int j=0;j<64;j++) s += w[j]*a[j];
    ve[id] = s;
    return;
  }
  id -= 192;
  if (id < 256){ bcur[id] = id*CAP; return; }       // fixed-capacity bin regions
  id -= 256;
  if (id < N){                                      // graph bounds (sorted batch)
    int b = batch[id];
    int bp = (id==0) ? -1 : batch[id-1];
    for (int g=bp+1; g<=b; g++) gstart[g]=id;
    if (id==N-1){ for (int g=b+1; g<=G; g++) gstart[g]=N; }
  }
}

// MFMA node MLP: xi16 = bf16(relu(x @ w_node + b)), K=32 exact. No LDS.
__global__ void __launch_bounds__(256,4)
k_nmlp_m(const float* __restrict__ x, const short* __restrict__ wT16,
         const float* __restrict__ b, short* __restrict__ xi, int N){
  int lane = threadIdx.x & 63, w = threadIdx.x >> 6;
  int m16 = lane & 15, kb = lane >> 4;
  int n0 = blockIdx.x*64 + w*16;
  int arow = n0 + m16; if (arow > N-1) arow = N-1;
  const float* xr = x + (size_t)arow*DIN + kb*8;
  float4 a0 = *(const float4*)xr, a1 = *(const float4*)(xr+4);
  bf16x8 af;
  af[0]=f2bf(a0.x); af[1]=f2bf(a0.y); af[2]=f2bf(a0.z); af[3]=f2bf(a0.w);
  af[4]=f2bf(a1.x); af[5]=f2bf(a1.y); af[6]=f2bf(a1.z); af[7]=f2bf(a1.w);
  f32x4 acc[4];
  #pragma unroll
  for (int t=0;t<4;t++) acc[t]=(f32x4){0.f,0.f,0.f,0.f};
  const short* wp = wT16 + (size_t)m16*DIN + kb*8;
  #pragma unroll
  for (int t=0;t<4;t++){
    bf16x8 bb = *(const bf16x8*)(wp + (size_t)(t*16)*DIN);
    acc[t] = __builtin_amdgcn_mfma_f32_16x16x32_bf16(af, bb, acc[t], 0,0,0);
  }
  int mrow = (lane>>4)*4;
  #pragma unroll
  for (int t=0;t<4;t++){
    int f = t*16 + m16;
    float bj = b[f];
    #pragma unroll
    for (int q=0;q<4;q++){
      int node = n0 + mrow + q;
      if (node < N) xi[(size_t)node*H_ + f] = f2bf(fmaxf(acc[t][q] + bj, 0.f));
    }
  }
}

// MFMA edge scores: 16 edges/wave, bias folded into k=16 weight row. No atomics.
__global__ void __launch_bounds__(256,4)
k_edge_m(const float* __restrict__ attr, const short* __restrict__ weT16p,
         const float* __restrict__ ve, const int* __restrict__ src,
         uint2* __restrict__ esc8, int E){
  int lane = threadIdx.x & 63, w = threadIdx.x >> 6;
  int m16 = lane & 15, kb = lane >> 4;
  int e0 = (blockIdx.x*4 + w)*16;
  if (e0 >= E) return;
  bf16x8 af = {0,0,0,0,0,0,0,0};
  if (kb < 2){
    int arow = e0 + m16; if (arow > E-1) arow = E-1;
    const float* ap = attr + (size_t)arow*DE + kb*8;
    float4 a0 = *(const float4*)ap, a1 = *(const float4*)(ap+4);
    af[0]=f2bf(a0.x); af[1]=f2bf(a0.y); af[2]=f2bf(a0.z); af[3]=f2bf(a0.w);
    af[4]=f2bf(a1.x); af[5]=f2bf(a1.y); af[6]=f2bf(a1.z); af[7]=f2bf(a1.w);
  } else if (kb == 2){
    af[0] = (short)0x3F80;              // 1.0 at k=16 -> adds bias row
  }
  f32x4 acc[4];
  #pragma unroll
  for (int t=0;t<4;t++) acc[t]=(f32x4){0.f,0.f,0.f,0.f};
  const short* wp = weT16p + (size_t)m16*32 + kb*8;
  #pragma unroll
  for (int t=0;t<4;t++){
    bf16x8 bb = *(const bf16x8*)(wp + (size_t)(t*16)*32);
    acc[t] = __builtin_amdgcn_mfma_f32_16x16x32_bf16(af, bb, acc[t], 0,0,0);
  }
  int mrow = (lane>>4)*4;
  float s0[4]={0.f,0.f,0.f,0.f}, s1[4]={0.f,0.f,0.f,0.f}, s2[4]={0.f,0.f,0.f,0.f};
  #pragma unroll
  for (int t=0;t<4;t++){
    int j = t*16 + m16;
    float v0 = ve[j], v1 = ve[64+j], v2 = ve[128+j];
    #pragma unroll
    for (int q=0;q<4;q++){
      float ea = fmaxf(acc[t][q], 0.f);
      s0[q] = fmaf(ea, v0, s0[q]);
      s1[q] = fmaf(ea, v1, s1[q]);
      s2[q] = fmaf(ea, v2, s2[q]);
    }
  }
  #pragma unroll
  for (int d=1; d<16; d<<=1){
    #pragma unroll
    for (int q=0;q<4;q++){
      s0[q] += __shfl_xor(s0[q], d);
      s1[q] += __shfl_xor(s1[q], d);
      s2[q] += __shfl_xor(s2[q], d);
    }
  }
  if (m16==0){
    #pragma unroll
    for (int q=0;q<4;q++){
      int e = e0 + mrow + q;
      if (e < E){
        unsigned sv = (unsigned)src[e];
        unsigned h0 = (__half_as_ushort(__float2half(s0[q])) & 0xFFFEu) | (sv >> 16);
        unsigned h1 = __half_as_ushort(__float2half(s1[q]));
        unsigned h2 = __half_as_ushort(__float2half(s2[q]));
        esc8[e] = make_uint2(h0 | (h1<<16), (sv & 0xFFFFu) | (h2<<16));
      }
    }
  }
}

// pass A: LDS-binned append of 8B records + 2B dstlocal into fixed per-bucket regions.
__global__ void __launch_bounds__(256)
k_binA(const uint2* __restrict__ esc8, const int* __restrict__ dst,
       int* __restrict__ bcur, uint2* __restrict__ bin8, unsigned short* __restrict__ bin2,
       int E){
  __shared__ int cnt[256];
  __shared__ int ofs[256];
  __shared__ int gofs[256];
  __shared__ uint2 st8[ACH];
  __shared__ unsigned short st2[ACH];
  __shared__ unsigned char sbid[ACH];
  int tid = threadIdx.x;
  int base = blockIdx.x * ACH;
  cnt[tid] = 0;
  __syncthreads();
  uint2 r8[8]; int bb[8]; int ms[8]; int dl[8];
  #pragma unroll
  for (int k=0;k<8;k++){
    int e = base + tid + k*256;
    bb[k] = -1;
    if (e < E){
      r8[k] = esc8[e];
      int d = dst[e];
      bb[k] = d >> 9;
      dl[k] = d & (BNODE-1);
      ms[k] = atomicAdd(&cnt[bb[k]], 1);
    }
  }
  __syncthreads();
  int v = cnt[tid];
  ofs[tid] = v;
  __syncthreads();
  for (int d=1; d<256; d<<=1){
    int t = 0;
    if (tid>=d) t = ofs[tid-d];
    __syncthreads();
    if (tid>=d) ofs[tid] += t;
    __syncthreads();
  }
  int total = ofs[255];
  int excl = ofs[tid] - v;
  __syncthreads();
  ofs[tid] = excl;
  __syncthreads();
  #pragma unroll
  for (int k=0;k<8;k++){
    if (bb[k] >= 0){
      int slot = ofs[bb[k]] + ms[k];
      st8[slot] = r8[k];
      st2[slot] = (unsigned short)dl[k];
      sbid[slot] = (unsigned char)bb[k];
    }
  }
  if (v > 0) gofs[tid] = atomicAdd(&bcur[tid], v);
  __syncthreads();
  for (int slot = tid; slot < total; slot += 256){
    int b = sbid[slot];
    int gp = gofs[b] + (slot - ofs[b]);
    bin8[gp] = st8[slot];
    bin2[gp] = st2[slot];
  }
}

// fused pass B: per bucket = histogram -> LDS scan -> offS/offE -> scatter (+LDS score
// sums) -> self-loop records. Zero global atomics, no global scan kernels.
__global__ void __launch_bounds__(256)
k_binB2(const uint2* __restrict__ bin8, const unsigned short* __restrict__ bin2,
        const int* __restrict__ bcur, int* __restrict__ offS, int* __restrict__ offE,
        uint2* __restrict__ rec, int N){
  __shared__ int lcnt[BNODE];
  __shared__ int lcur[BNODE];
  __shared__ int loffS[BNODE];
  __shared__ int sc[256];
  __shared__ float ls0[BNODE], ls1[BNODE], ls2[BNODE];
  int b = blockIdx.x, tid = threadIdx.x;
  int n0 = b*BNODE;
  int n1 = n0 + BNODE; if (n1 > N) n1 = N;
  int nn = n1 - n0;
  for (int i=tid;i<BNODE;i+=256){ lcnt[i]=0; ls0[i]=0.f; ls1[i]=0.f; ls2[i]=0.f; }
  __syncthreads();
  int beg = b*CAP, cntb = bcur[b] - beg;
  for (int idx=tid; idx<cntb; idx+=256) atomicAdd(&lcnt[bin2[beg+idx]], 1);
  __syncthreads();
  // scan deg=lcnt+1 (2 entries/thread)
  int i0 = 2*tid, i1 = 2*tid+1;
  int a0 = (i0<nn) ? lcnt[i0]+1 : 0;
  int a1 = (i1<nn) ? lcnt[i1]+1 : 0;
  int pair = a0+a1;
  sc[tid] = pair;
  __syncthreads();
  for (int d=1; d<256; d<<=1){
    int t = 0; if (tid>=d) t = sc[tid-d];
    __syncthreads();
    if (tid>=d) sc[tid] += t;
    __syncthreads();
  }
  int excl = sc[tid] - pair;
  int base = b*CAP2;
  if (i0<nn){ int o=base+excl;    offS[n0+i0]=o; offE[n0+i0]=o+a0; loffS[i0]=o; lcur[i0]=o+1; }
  if (i1<nn){ int o=base+excl+a0; offS[n0+i1]=o; offE[n0+i1]=o+a1; loffS[i1]=o; lcur[i1]=o+1; }
  __syncthreads();
  // scatter + score sums
  for (int idx=tid; idx<cntb; idx+=256){
    uint2 r = bin8[beg+idx];
    int dl = bin2[beg+idx];
    int p = atomicAdd(&lcur[dl], 1);
    rec[p] = r;
    atomicAdd(&ls0[dl], h2f_(r.x & 0xFFFEu));
    atomicAdd(&ls1[dl], h2f_(r.x >> 16));
    atomicAdd(&ls2[dl], h2f_(r.y >> 16));
  }
  __syncthreads();
  // self-loop records
  for (int i=tid; i<nn; i+=256){
    int cnt = lcnt[i];
    float inv = (cnt>0) ? 1.0f/(float)cnt : 0.0f;
    unsigned h0 = __half_as_ushort(__float2half(ls0[i]*inv)) & 0xFFFEu;
    unsigned h1 = __half_as_ushort(__float2half(ls1[i]*inv));
    unsigned h2 = __half_as_ushort(__float2half(ls2[i]*inv));
    unsigned s = (unsigned)(n0+i);
    rec[loffS[i]] = make_uint2(h0 | (s>>16) | (h1<<16), (s & 0xFFFFu) | (h2<<16));
  }
}

// MFMA GRU: 2 node-strips per wave (32 nodes), block = 128 nodes. bf16 state.
__global__ void __launch_bounds__(256,2)
k_gru_m(const short* __restrict__ hg16, const short* __restrict__ xin, short* __restrict__ xout,
        const short* __restrict__ WihT16, const short* __restrict__ WhhT16,
        const float* __restrict__ bih, const float* __restrict__ bhh, int N){
  int lane = threadIdx.x & 63, w = threadIdx.x >> 6;
  int m16 = lane & 15;
  int kb  = lane >> 4;
  int n0 = blockIdx.x*128 + w*32;

  int r0 = n0 + m16;      if (r0 > N-1) r0 = N-1;
  int r1 = n0 + 16 + m16; if (r1 > N-1) r1 = N-1;
  const short* h0p = hg16 + (size_t)r0*H_ + kb*8;
  const short* h1p = hg16 + (size_t)r1*H_ + kb*8;
  bf16x8 ah0a = *(const bf16x8*)(h0p), ah1a = *(const bf16x8*)(h0p+32);
  bf16x8 ah0b = *(const bf16x8*)(h1p), ah1b = *(const bf16x8*)(h1p+32);
  const short* x0p = xin + (size_t)r0*H_ + kb*8;
  const short* x1p = xin + (size_t)r1*H_ + kb*8;
  bf16x8 ax0a = *(const bf16x8*)(x0p), ax1a = *(const bf16x8*)(x0p+32);
  bf16x8 ax0b = *(const bf16x8*)(x1p), ax1b = *(const bf16x8*)(x1p+32);

  f32x4 aR[2][4], aZ[2][4], aNi[2][4], aNh[2][4];
  #pragma unroll
  for (int s=0;s<2;s++){
    #pragma unroll
    for (int t=0;t<4;t++){
      aR[s][t]=(f32x4){0.f,0.f,0.f,0.f}; aZ[s][t]=(f32x4){0.f,0.f,0.f,0.f};
      aNi[s][t]=(f32x4){0.f,0.f,0.f,0.f}; aNh[s][t]=(f32x4){0.f,0.f,0.f,0.f};
    }
  }

  const short* wi = WihT16 + (size_t)m16*H_ + kb*8;
  const short* wh = WhhT16 + (size_t)m16*H_ + kb*8;
  #pragma unroll
  for (int t=0;t<4;t++){
    bf16x8 b;
    b = *(const bf16x8*)(wi + (size_t)(t*16)*H_);
    aR[0][t] = __builtin_amdgcn_mfma_f32_16x16x32_bf16(ah0a, b, aR[0][t], 0,0,0);
    aR[1][t] = __builtin_amdgcn_mfma_f32_16x16x32_bf16(ah0b, b, aR[1][t], 0,0,0);
    b = *(const bf16x8*)(wi + (size_t)(t*16)*H_ + 32);
    aR[0][t] = __builtin_amdgcn_mfma_f32_16x16x32_bf16(ah1a, b, aR[0][t], 0,0,0);
    aR[1][t] = __builtin_amdgcn_mfma_f32_16x16x32_bf16(ah1b, b, aR[1][t], 0,0,0);
    b = *(const bf16x8*)(wh + (size_t)(t*16)*H_);
    aR[0][t] = __builtin_amdgcn_mfma_f32_16x16x32_bf16(ax0a, b, aR[0][t], 0,0,0);
    aR[1][t] = __builtin_amdgcn_mfma_f32_16x16x32_bf16(ax0b, b, aR[1][t], 0,0,0);
    b = *(const bf16x8*)(wh + (size_t)(t*16)*H_ + 32);
    aR[0][t] = __builtin_amdgcn_mfma_f32_16x16x32_bf16(ax1a, b, aR[0][t], 0,0,0);
    aR[1][t] = __builtin_amdgcn_mfma_f32_16x16x32_bf16(ax1b, b, aR[1][t], 0,0,0);

    b = *(const bf16x8*)(wi + (size_t)(64+t*16)*H_);
    aZ[0][t] = __builtin_amdgcn_mfma_f32_16x16x32_bf16(ah0a, b, aZ[0][t], 0,0,0);
    aZ[1][t] = __builtin_amdgcn_mfma_f32_16x16x32_bf16(ah0b, b, aZ[1][t], 0,0,0);
    b = *(const bf16x8*)(wi + (size_t)(64+t*16)*H_ + 32);
    aZ[0][t] = __builtin_amdgcn_mfma_f32_16x16x32_bf16(ah1a, b, aZ[0][t], 0,0,0);
    aZ[1][t] = __builtin_amdgcn_mfma_f32_16x16x32_bf16(ah1b, b, aZ[1][t], 0,0,0);
    b = *(const bf16x8*)(wh + (size_t)(64+t*16)*H_);
    aZ[0][t] = __builtin_amdgcn_mfma_f32_16x16x32_bf16(ax0a, b, aZ[0][t], 0,0,0);
    aZ[1][t] = __builtin_amdgcn_mfma_f32_16x16x32_bf16(ax0b, b, aZ[1][t], 0,0,0);
    b = *(const bf16x8*)(wh + (size_t)(64+t*16)*H_ + 32);
    aZ[0][t] = __builtin_amdgcn_mfma_f32_16x16x32_bf16(ax1a, b, aZ[0][t], 0,0,0);
    aZ[1][t] = __builtin_amdgcn_mfma_f32_16x16x32_bf16(ax1b, b, aZ[1][t], 0,0,0);

    b = *(const bf16x8*)(wi + (size_t)(128+t*16)*H_);
    aNi[0][t] = __builtin_amdgcn_mfma_f32_16x16x32_bf16(ah0a, b, aNi[0][t], 0,0,0);
    aNi[1][t] = __builtin_amdgcn_mfma_f32_16x16x32_bf16(ah0b, b, aNi[1][t], 0,0,0);
    b = *(const bf16x8*)(wi + (size_t)(128+t*16)*H_ + 32);
    aNi[0][t] = __builtin_amdgcn_mfma_f32_16x16x32_bf16(ah1a, b, aNi[0][t], 0,0,0);
    aNi[1][t] = __builtin_amdgcn_mfma_f32_16x16x32_bf16(ah1b, b, aNi[1][t], 0,0,0);
    b = *(const bf16x8*)(wh + (size_t)(128+t*16)*H_);
    aNh[0][t] = __builtin_amdgcn_mfma_f32_16x16x32_bf16(ax0a, b, aNh[0][t], 0,0,0);
    aNh[1][t] = __builtin_amdgcn_mfma_f32_16x16x32_bf16(ax0b, b, aNh[1][t], 0,0,0);
    b = *(const bf16x8*)(wh + (size_t)(128+t*16)*H_ + 32);
    aNh[0][t] = __builtin_amdgcn_mfma_f32_16x16x32_bf16(ax1a, b, aNh[0][t], 0,0,0);
    aNh[1][t] = __builtin_amdgcn_mfma_f32_16x16x32_bf16(ax1b, b, aNh[1][t], 0,0,0);
  }

  int mrow = (lane>>4)*4;
  #pragma unroll
  for (int s=0;s<2;s++){
    #pragma unroll
    for (int t=0;t<4;t++){
      int f = t*16 + m16;
      float br = bih[f]     + bhh[f];
      float bz = bih[64+f]  + bhh[64+f];
      float bin= bih[128+f], bhn = bhh[128+f];
      #pragma unroll
      for (int q=0;q<4;q++){
        int node = n0 + s*16 + mrow + q;
        if (node < N){
          float r  = sigm_(aR[s][t][q] + br);
          float z  = sigm_(aZ[s][t][q] + bz);
          float nn = tanh_(aNi[s][t][q] + bin + r*(aNh[s][t][q] + bhn));
          float xv = bf2f((unsigned short)xin[(size_t)node*H_ + f]);
          xout[(size_t)node*H_ + f] = f2bf(fmaxf((1.f-z)*nn + z*xv, 0.f));
        }
      }
    }
  }
}

// MFMA linear-h: 2 node-strips per wave (32 nodes), block = 128 nodes. bf16 input.
__global__ void __launch_bounds__(256,4)
k_linh_m(const short* __restrict__ xi, const short* __restrict__ wT16,
         const float* __restrict__ atts, const float* __restrict__ attd,
         __half* __restrict__ h16, float* __restrict__ ssc, float* __restrict__ dsc, int N){
  int lane = threadIdx.x & 63, w = threadIdx.x >> 6;
  int m16 = lane & 15, kb = lane >> 4;
  int n0 = blockIdx.x*128 + w*32;
  int r0 = n0 + m16;      if (r0 > N-1) r0 = N-1;
  int r1 = n0 + 16 + m16; if (r1 > N-1) r1 = N-1;
  const short* x0p = xi + (size_t)r0*H_ + kb*8;
  const short* x1p = xi + (size_t)r1*H_ + kb*8;
  bf16x8 ax0a = *(const bf16x8*)(x0p), ax1a = *(const bf16x8*)(x0p+32);
  bf16x8 ax0b = *(const bf16x8*)(x1p), ax1b = *(const bf16x8*)(x1p+32);

  f32x4 acc[2][4];
  #pragma unroll
  for (int s=0;s<2;s++)
    #pragma unroll
    for (int t=0;t<4;t++) acc[s][t]=(f32x4){0.f,0.f,0.f,0.f};
  const short* wp = wT16 + (size_t)m16*H_ + kb*8;
  #pragma unroll
  for (int t=0;t<4;t++){
    bf16x8 b0 = *(const bf16x8*)(wp + (size_t)(t*16)*H_);
    acc[0][t] = __builtin_amdgcn_mfma_f32_16x16x32_bf16(ax0a, b0, acc[0][t], 0,0,0);
    acc[1][t] = __builtin_amdgcn_mfma_f32_16x16x32_bf16(ax0b, b0, acc[1][t], 0,0,0);
    bf16x8 b1 = *(const bf16x8*)(wp + (size_t)(t*16)*H_ + 32);
    acc[0][t] = __builtin_amdgcn_mfma_f32_16x16x32_bf16(ax1a, b1, acc[0][t], 0,0,0);
    acc[1][t] = __builtin_amdgcn_mfma_f32_16x16x32_bf16(ax1b, b1, acc[1][t], 0,0,0);
  }

  int mrow = (lane>>4)*4;
  float ps[2][4], pd[2][4];
  #pragma unroll
  for (int s=0;s<2;s++)
    #pragma unroll
    for (int q=0;q<4;q++){ ps[s][q]=0.f; pd[s][q]=0.f; }
  #pragma unroll
  for (int t=0;t<4;t++){
    int f = t*16 + m16;
    float as = atts[f], ad = attd[f];
    #pragma unroll
    for (int s=0;s<2;s++){
      #pragma unroll
      for (int q=0;q<4;q++){
        int node = n0 + s*16 + mrow + q;
        float v = acc[s][t][q];
        if (node < N) h16[(size_t)node*H_ + f] = __float2half(v);
        ps[s][q] = fmaf(v, as, ps[s][q]); pd[s][q] = fmaf(v, ad, pd[s][q]);
      }
    }
  }
  #pragma unroll
  for (int d=1; d<16; d<<=1){
    #pragma unroll
    for (int s=0;s<2;s++)
      #pragma unroll
      for (int q=0;q<4;q++){ ps[s][q] += __shfl_xor(ps[s][q], d); pd[s][q] += __shfl_xor(pd[s][q], d); }
  }
  if (m16==0){
    #pragma unroll
    for (int s=0;s<2;s++){
      #pragma unroll
      for (int q=0;q<4;q++){
        int node = n0 + s*16 + mrow + q;
        if (node < N){ ssc[node]=ps[s][q]; dsc[node]=pd[s][q]; }
      }
    }
  }
}

// GAT: 4 nodes/wave, 16 lanes/node. Single-pass safe-exp softmax. offS/offE bounds.
template<int L>
__global__ void __launch_bounds__(256)
k_gat_g4(const __half* __restrict__ h16, const float* __restrict__ ssc,
         const float* __restrict__ dsc, const uint2* __restrict__ rec,
         const int* __restrict__ offS, const int* __restrict__ offE,
         const float* __restrict__ bias, short* __restrict__ hgat16, int N){
  int lane = threadIdx.x & 63, w = threadIdx.x >> 6;
  int g = lane >> 4, fl = lane & 15;
  int node = blockIdx.x*16 + w*4 + g;
  if (node >= N) return;
  int e0 = offS[node], e1 = offE[node];
  float dval = dsc[node];
  float acc0=0.f, acc1=0.f, acc2=0.f, acc3=0.f, den=0.f;
  int gbase = lane & 48;                 // g*16
  for (int base = e0; base < e1; base += 16){
    int p = base + fl;
    float ex = 0.f; int s = 0;
    if (p < e1){
      uint2 r = rec[p];
      s = (int)((r.y & 0xFFFFu) | ((r.x & 1u) << 16));
      unsigned hb = (L==0) ? (r.x & 0xFFFEu) : (L==1) ? (r.x >> 16) : (r.y >> 16);
      float a = ssc[s] + dval + h2f_(hb);
      a = (a > 0.f) ? a : SLOPE*a;
      ex = __expf(a);
    }
    den += ex;
    int cnt = e1 - base; if (cnt > 16) cnt = 16;
    for (int j = 0; j < cnt; j++){
      float exb = __shfl(ex, gbase + j);
      int   sb  = __shfl(s,  gbase + j);
      uint2 hv = *(const uint2*)(h16 + (size_t)sb*H_ + 4*fl);
      float2 f0 = __half22float2(*(__half2*)&hv.x);
      float2 f1 = __half22float2(*(__half2*)&hv.y);
      acc0 = fmaf(exb, f0.x, acc0);
      acc1 = fmaf(exb, f0.y, acc1);
      acc2 = fmaf(exb, f1.x, acc2);
      acc3 = fmaf(exb, f1.y, acc3);
    }
  }
  #pragma unroll
  for (int d=1; d<16; d<<=1) den += __shfl_xor(den, d);
  float4 bv = *(const float4*)(bias + 4*fl);
  float inv = 1.0f/den;
  float v0 = fmaxf(fmaf(acc0,inv,bv.x), 0.f);
  float v1 = fmaxf(fmaf(acc1,inv,bv.y), 0.f);
  float v2 = fmaxf(fmaf(acc2,inv,bv.z), 0.f);
  float v3 = fmaxf(fmaf(acc3,inv,bv.w), 0.f);
  uint2 o;
  o.x = ((unsigned)(unsigned short)f2bf(v1)<<16) | (unsigned short)f2bf(v0);
  o.y = ((unsigned)(unsigned short)f2bf(v3)<<16) | (unsigned short)f2bf(v2);
  *(uint2*)(hgat16 + (size_t)node*H_ + 4*fl) = o;
}

// block per graph: zero-atomic pooled output (batch sorted, xi bf16)
__global__ void __launch_bounds__(256)
k_pool_g(const short* __restrict__ xi, const float* __restrict__ wout,
         const int* __restrict__ gstart, const float* __restrict__ b_out,
         float* __restrict__ out){
  int g = blockIdx.x;
  int a = gstart[g], b = gstart[g+1];
  float acc = 0.f;
  for (int n = a + threadIdx.x; n < b; n += 256){
    const uint4* xr = (const uint4*)(xi + (size_t)n*H_);   // 8 bf16 per uint4
    float s = 0.f;
    #pragma unroll
    for (int q=0;q<8;q++){
      uint4 v = xr[q];
      s += bf2f((unsigned short)(v.x&0xFFFF))*wout[8*q]   + bf2f((unsigned short)(v.x>>16))*wout[8*q+1]
         + bf2f((unsigned short)(v.y&0xFFFF))*wout[8*q+2] + bf2f((unsigned short)(v.y>>16))*wout[8*q+3]
         + bf2f((unsigned short)(v.z&0xFFFF))*wout[8*q+4] + bf2f((unsigned short)(v.z>>16))*wout[8*q+5]
         + bf2f((unsigned short)(v.w&0xFFFF))*wout[8*q+6] + bf2f((unsigned short)(v.w>>16))*wout[8*q+7];
    }
    acc += s;
  }
  #pragma unroll
  for (int d=32; d; d>>=1) acc += __shfl_xor(acc, d);
  __shared__ float sh[4];
  if ((threadIdx.x&63)==0) sh[threadIdx.x>>6] = acc;
  __syncthreads();
  if (threadIdx.x==0) out[g] = sh[0]+sh[1]+sh[2]+sh[3] + b_out[0];
}

extern "C" void kernel_launch(void* const* d_in, const int* in_sizes, int n_in,
                              void* d_out, int out_size, void* d_ws, size_t ws_size,
                              hipStream_t stream){
  const float* x       = (const float*)d_in[0];
  const float* eattr   = (const float*)d_in[1];
  const float* w_node  = (const float*)d_in[2];
  const float* b_node  = (const float*)d_in[3];
  const float* w_edge  = (const float*)d_in[4];
  const float* b_edge  = (const float*)d_in[5];
  const float* conv_W  = (const float*)d_in[6];
  const float* conv_We = (const float*)d_in[7];
  const float* att_s   = (const float*)d_in[8];
  const float* att_d   = (const float*)d_in[9];
  const float* att_e   = (const float*)d_in[10];
  const float* conv_b  = (const float*)d_in[11];
  const float* gWih    = (const float*)d_in[12];
  const float* gWhh    = (const float*)d_in[13];
  const float* gbih    = (const float*)d_in[14];
  const float* gbhh    = (const float*)d_in[15];
  const float* w_out   = (const float*)d_in[16];
  const float* b_out   = (const float*)d_in[17];
  const int*   eidx    = (const int*)d_in[18];
  const int*   batch   = (const int*)d_in[19];
  float* out = (float*)d_out;

  int N = in_sizes[0]/DIN;
  int E = in_sizes[1]/DE;
  int G = out_size;
  const int* src = eidx;
  const int* dst = eidx + E;

  char* p = (char*)d_ws;
  auto carve = [&](size_t bytes)->void*{ void* r=(void*)p; p += (bytes+255)&~(size_t)255; return r; };
  short*  xi0    = (short*)carve((size_t)N*H_*2);
  short*  xi1    = (short*)carve((size_t)N*H_*2);
  __half* h16    = (__half*)carve((size_t)N*H_*2);
  short*  hgat16 = (short*)carve((size_t)N*H_*2);
  float*  ssc    = (float*)carve((size_t)N*4);
  float*  dsc    = (float*)carve((size_t)N*4);
  uint2*  esc8   = (uint2*)carve((size_t)E*8);
  uint2*  rec    = (uint2*)carve((size_t)256*CAP2*8);
  uint2*  bin8   = (uint2*)carve((size_t)256*CAP*8);
  unsigned short* bin2 = (unsigned short*)carve((size_t)256*CAP*2);
  int*    offS   = (int*)carve((size_t)N*4);
  int*    offE   = (int*)carve((size_t)N*4);
  int*    bcur   = (int*)carve((size_t)256*4);
  int*    gstart = (int*)carve((size_t)(G+1)*4);
  short*  wnT16  = (short*)carve((size_t)DIN*H_*2);
  short*  weT16p = (short*)carve((size_t)64*32*2);
  short*  cWT16  = (short*)carve((size_t)3*H_*H_*2);
  short*  WihT16 = (short*)carve((size_t)3*192*H_*2);
  short*  WhhT16 = (short*)carve((size_t)3*192*H_*2);
  float*  ve     = (float*)carve((size_t)3*H_*4);

  auto cdiv=[](int a,int b){return (a+b-1)/b;};
  int NBK = cdiv(N,BNODE);

  int prep_total = 2048+2048+12288+36864+36864+192+256+N;
  k_prep<<<cdiv(prep_total,256),256,0,stream>>>(w_node, w_edge, b_edge, conv_W, gWih, gWhh,
                                                conv_We, att_e, batch,
                                                wnT16, weT16p, cWT16, WihT16, WhhT16, ve,
                                                bcur, gstart, N, G);
  k_nmlp_m<<<cdiv(N,64),256,0,stream>>>(x, wnT16, b_node, xi0, N);
  k_edge_m<<<cdiv(E,64),256,0,stream>>>(eattr, weT16p, ve, src, esc8, E);
  k_binA<<<cdiv(E,ACH),256,0,stream>>>(esc8, dst, bcur, bin8, bin2, E);
  k_binB2<<<NBK,256,0,stream>>>(bin8, bin2, bcur, offS, offE, rec, N);

  int NB128 = cdiv(N,128);
  int NB16  = cdiv(N,16);
  for (int l=0; l<3; l++){
    const short* xin = (l&1) ? xi1 : xi0;
    short*       xo  = (l&1) ? xi0 : xi1;
    k_linh_m<<<NB128,256,0,stream>>>(xin, cWT16 + (size_t)l*H_*H_, att_s + l*H_, att_d + l*H_,
                                     h16, ssc, dsc, N);
    if (l==0)      k_gat_g4<0><<<NB16,256,0,stream>>>(h16, ssc, dsc, rec, offS, offE, conv_b + l*H_, hgat16, N);
    else if (l==1) k_gat_g4<1><<<NB16,256,0,stream>>>(h16, ssc, dsc, rec, offS, offE, conv_b + l*H_, hgat16, N);
    else           k_gat_g4<2><<<NB16,256,0,stream>>>(h16, ssc, dsc, rec, offS, offE, conv_b + l*H_, hgat16, N);
    k_gru_m<<<NB128,256,0,stream>>>(hgat16, xin, xo, WihT16 + (size_t)l*192*H_, WhhT16 + (size_t)l*192*H_,
                                    gbih + l*3*H_, gbhh + l*3*H_, N);
  }

  k_pool_g<<<G,256,0,stream>>>(xi1, w_out, gstart, b_out, out);
}

// Round 20
// 365.412 us; speedup vs baseline: 48.1223x; 1.0243x over previous
//
#include <hip/hip_runtime.h>
#include <hip/hip_fp16.h>

constexpr int H_  = 64;   // hidden
constexpr int DIN = 32;   // atom feature dim
constexpr int DE  = 16;   // edge feature dim
constexpr int BNODE = 512;  // nodes per scatter bucket (dstlocal < 512)
constexpr int ACH   = 2048; // edges per binning chunk
constexpr int CAP   = 6144; // per-bucket bin region capacity (mean 5120 + 14 sigma)
constexpr int CAP2  = CAP + BNODE; // per-bucket rec region (edges + self-loops)
#define SLOPE 0.2f

typedef __attribute__((ext_vector_type(8))) short bf16x8;
typedef __attribute__((ext_vector_type(4))) float f32x4;

__device__ __forceinline__ float sigm_(float x){ return 1.0f/(1.0f+__expf(-x)); }
__device__ __forceinline__ float tanh_(float x){ float e=__expf(2.0f*x); return 1.0f - 2.0f/(e+1.0f); }
__device__ __forceinline__ short f2bf(float f){   // RNE float->bf16
  unsigned u = __float_as_uint(f);
  u += 0x7FFF + ((u>>16)&1);
  return (short)(u>>16);
}
__device__ __forceinline__ float bf2f(unsigned short s){
  return __uint_as_float(((unsigned)s)<<16);
}
__device__ __forceinline__ float h2f_(unsigned hb){
  return __half2float(__ushort_as_half((unsigned short)hb));
}

// mega-kernel: weight prep + bcur init + graph bounds
__global__ void k_prep(const float* __restrict__ w_node, const float* __restrict__ w_edge,
                       const float* __restrict__ b_edge,
                       const float* __restrict__ conv_W, const float* __restrict__ gWih,
                       const float* __restrict__ gWhh, const float* __restrict__ conv_We,
                       const float* __restrict__ att_e, const int* __restrict__ batch,
                       short* __restrict__ wnT16, short* __restrict__ weT16p,
                       short* __restrict__ cWT16, short* __restrict__ WihT16,
                       short* __restrict__ WhhT16, float* __restrict__ ve,
                       int* __restrict__ bcur, int* __restrict__ gstart, int N, int G){
  int id = blockIdx.x*blockDim.x + threadIdx.x;
  if (id < 2048){                                   // wnT16 [64][32]
    int j = id >> 5, k = id & 31;
    wnT16[id] = f2bf(w_node[k*64 + j]);
    return;
  }
  id -= 2048;
  if (id < 2048){                                   // weT16p [64][32]; k=16 row = bias
    int j = id >> 5, k = id & 31;
    weT16p[id] = (k < DE) ? f2bf(w_edge[k*64 + j]) : (k == DE ? f2bf(b_edge[j]) : (short)0);
    return;
  }
  id -= 2048;
  if (id < 12288){                                  // cWT16 [3][64 j][64 k]
    int l = id / 4096, rem = id & 4095, j = rem >> 6, k = rem & 63;
    cWT16[id] = f2bf(conv_W[l*4096 + k*64 + j]);
    return;
  }
  id -= 12288;
  if (id < 36864){                                  // WihT16 [3][192 j][64 k]
    int l = id / 12288, rem = id % 12288, j = rem >> 6, k = rem & 63;
    WihT16[id] = f2bf(gWih[l*12288 + k*192 + j]);
    return;
  }
  id -= 36864;
  if (id < 36864){                                  // WhhT16
    int l = id / 12288, rem = id % 12288, j = rem >> 6, k = rem & 63;
    WhhT16[id] = f2bf(gWhh[l*12288 + k*192 + j]);
    return;
  }
  id -= 36864;
  if (id < 192){                                    // ve[l][k]
    int l = id >> 6, k = id & 63;
    const float* w = conv_We + (size_t)(l*64+k)*64;
    const float* a = att_e + l*64;
    float s = 0.f;
    #pragma unroll
    for (int j=0;j<64;j++) s += w[j]*a[j];
    ve[id] = s;
    return;
  }
  id -= 192;
  if (id < 256){ bcur[id] = id*CAP; return; }       // fixed-capacity bin regions
  id -= 256;
  if (id < N){                                      // graph bounds (sorted batch)
    int b = batch[id];
    int bp = (id==0) ? -1 : batch[id-1];
    for (int g=bp+1; g<=b; g++) gstart[g]=id;
    if (id==N-1){ for (int g=b+1; g<=G; g++) gstart[g]=N; }
  }
}

// MFMA node MLP: xi16 = bf16(relu(x @ w_node + b)), K=32 exact. No LDS.
__global__ void __launch_bounds__(256,4)
k_nmlp_m(const float* __restrict__ x, const short* __restrict__ wT16,
         const float* __restrict__ b, short* __restrict__ xi, int N){
  int lane = threadIdx.x & 63, w = threadIdx.x >> 6;
  int m16 = lane & 15, kb = lane >> 4;
  int n0 = blockIdx.x*64 + w*16;
  int arow = n0 + m16; if (arow > N-1) arow = N-1;
  const float* xr = x + (size_t)arow*DIN + kb*8;
  float4 a0 = *(const float4*)xr, a1 = *(const float4*)(xr+4);
  bf16x8 af;
  af[0]=f2bf(a0.x); af[1]=f2bf(a0.y); af[2]=f2bf(a0.z); af[3]=f2bf(a0.w);
  af[4]=f2bf(a1.x); af[5]=f2bf(a1.y); af[6]=f2bf(a1.z); af[7]=f2bf(a1.w);
  f32x4 acc[4];
  #pragma unroll
  for (int t=0;t<4;t++) acc[t]=(f32x4){0.f,0.f,0.f,0.f};
  const short* wp = wT16 + (size_t)m16*DIN + kb*8;
  #pragma unroll
  for (int t=0;t<4;t++){
    bf16x8 bb = *(const bf16x8*)(wp + (size_t)(t*16)*DIN);
    acc[t] = __builtin_amdgcn_mfma_f32_16x16x32_bf16(af, bb, acc[t], 0,0,0);
  }
  int mrow = (lane>>4)*4;
  #pragma unroll
  for (int t=0;t<4;t++){
    int f = t*16 + m16;
    float bj = b[f];
    #pragma unroll
    for (int q=0;q<4;q++){
      int node = n0 + mrow + q;
      if (node < N) xi[(size_t)node*H_ + f] = f2bf(fmaxf(acc[t][q] + bj, 0.f));
    }
  }
}

// Transposed MFMA edge scores: D = W^T @ attr^T so each lane holds 16 j-values of ONE
// edge -> ve-dot is lane-local; reduce is only over the 4 kb groups (2 shfl steps).
// 2 edge-tiles per wave share the 4 weight A-frags. Bias folded at k=16.
__global__ void __launch_bounds__(256,4)
k_edge_m(const float* __restrict__ attr, const short* __restrict__ weT16p,
         const float* __restrict__ ve, const int* __restrict__ src,
         uint2* __restrict__ esc8, int E){
  int lane = threadIdx.x & 63, w = threadIdx.x >> 6;
  int m16 = lane & 15, kb = lane >> 4;
  int e0 = (blockIdx.x*4 + w)*32;        // 2 tiles of 16 edges
  if (e0 >= E) return;
  // weight A-frags (j rows t*16+m16, k chunk kb*8), shared across both tiles
  const short* wp = weT16p + (size_t)m16*32 + kb*8;
  bf16x8 wA0 = *(const bf16x8*)(wp);
  bf16x8 wA1 = *(const bf16x8*)(wp + 16*32);
  bf16x8 wA2 = *(const bf16x8*)(wp + 32*32);
  bf16x8 wA3 = *(const bf16x8*)(wp + 48*32);
  // attr B-frags per tile: lane (m16,kb) holds attr[e][kb*8..+8]; kb==2 -> 1.0 at k=16
  bf16x8 af0 = {0,0,0,0,0,0,0,0}, af1 = {0,0,0,0,0,0,0,0};
  if (kb < 2){
    int r0 = e0 + m16;      if (r0 > E-1) r0 = E-1;
    int r1 = e0 + 16 + m16; if (r1 > E-1) r1 = E-1;
    const float* ap0 = attr + (size_t)r0*DE + kb*8;
    const float* ap1 = attr + (size_t)r1*DE + kb*8;
    float4 a0 = *(const float4*)ap0, a1 = *(const float4*)(ap0+4);
    float4 b0 = *(const float4*)ap1, b1 = *(const float4*)(ap1+4);
    af0[0]=f2bf(a0.x); af0[1]=f2bf(a0.y); af0[2]=f2bf(a0.z); af0[3]=f2bf(a0.w);
    af0[4]=f2bf(a1.x); af0[5]=f2bf(a1.y); af0[6]=f2bf(a1.z); af0[7]=f2bf(a1.w);
    af1[0]=f2bf(b0.x); af1[1]=f2bf(b0.y); af1[2]=f2bf(b0.z); af1[3]=f2bf(b0.w);
    af1[4]=f2bf(b1.x); af1[5]=f2bf(b1.y); af1[6]=f2bf(b1.z); af1[7]=f2bf(b1.w);
  } else if (kb == 2){
    af0[0] = (short)0x3F80; af1[0] = (short)0x3F80;
  }
  f32x4 accA[4], accB[4];
  #pragma unroll
  for (int t=0;t<4;t++){ accA[t]=(f32x4){0.f,0.f,0.f,0.f}; accB[t]=(f32x4){0.f,0.f,0.f,0.f}; }
  accA[0] = __builtin_amdgcn_mfma_f32_16x16x32_bf16(wA0, af0, accA[0], 0,0,0);
  accB[0] = __builtin_amdgcn_mfma_f32_16x16x32_bf16(wA0, af1, accB[0], 0,0,0);
  accA[1] = __builtin_amdgcn_mfma_f32_16x16x32_bf16(wA1, af0, accA[1], 0,0,0);
  accB[1] = __builtin_amdgcn_mfma_f32_16x16x32_bf16(wA1, af1, accB[1], 0,0,0);
  accA[2] = __builtin_amdgcn_mfma_f32_16x16x32_bf16(wA2, af0, accA[2], 0,0,0);
  accB[2] = __builtin_amdgcn_mfma_f32_16x16x32_bf16(wA2, af1, accB[2], 0,0,0);
  accA[3] = __builtin_amdgcn_mfma_f32_16x16x32_bf16(wA3, af0, accA[3], 0,0,0);
  accB[3] = __builtin_amdgcn_mfma_f32_16x16x32_bf16(wA3, af1, accB[3], 0,0,0);

  // epilogue: j = t*16 + kb*4 + q  (D row), edge = m16 (D col)
  int kb4 = kb*4;
  float sA0=0.f,sA1=0.f,sA2=0.f, sB0=0.f,sB1=0.f,sB2=0.f;
  #pragma unroll
  for (int t=0;t<4;t++){
    float4 v0 = *(const float4*)(ve + t*16 + kb4);
    float4 v1 = *(const float4*)(ve + 64 + t*16 + kb4);
    float4 v2 = *(const float4*)(ve + 128 + t*16 + kb4);
    float eA0 = fmaxf(accA[t][0],0.f), eA1 = fmaxf(accA[t][1],0.f);
    float eA2 = fmaxf(accA[t][2],0.f), eA3 = fmaxf(accA[t][3],0.f);
    float eB0 = fmaxf(accB[t][0],0.f), eB1 = fmaxf(accB[t][1],0.f);
    float eB2 = fmaxf(accB[t][2],0.f), eB3 = fmaxf(accB[t][3],0.f);
    sA0 = fmaf(eA0,v0.x, fmaf(eA1,v0.y, fmaf(eA2,v0.z, fmaf(eA3,v0.w, sA0))));
    sA1 = fmaf(eA0,v1.x, fmaf(eA1,v1.y, fmaf(eA2,v1.z, fmaf(eA3,v1.w, sA1))));
    sA2 = fmaf(eA0,v2.x, fmaf(eA1,v2.y, fmaf(eA2,v2.z, fmaf(eA3,v2.w, sA2))));
    sB0 = fmaf(eB0,v0.x, fmaf(eB1,v0.y, fmaf(eB2,v0.z, fmaf(eB3,v0.w, sB0))));
    sB1 = fmaf(eB0,v1.x, fmaf(eB1,v1.y, fmaf(eB2,v1.z, fmaf(eB3,v1.w, sB1))));
    sB2 = fmaf(eB0,v2.x, fmaf(eB1,v2.y, fmaf(eB2,v2.z, fmaf(eB3,v2.w, sB2))));
  }
  sA0 += __shfl_xor(sA0,16); sA0 += __shfl_xor(sA0,32);
  sA1 += __shfl_xor(sA1,16); sA1 += __shfl_xor(sA1,32);
  sA2 += __shfl_xor(sA2,16); sA2 += __shfl_xor(sA2,32);
  sB0 += __shfl_xor(sB0,16); sB0 += __shfl_xor(sB0,32);
  sB1 += __shfl_xor(sB1,16); sB1 += __shfl_xor(sB1,32);
  sB2 += __shfl_xor(sB2,16); sB2 += __shfl_xor(sB2,32);
  if (lane < 16){
    int eA = e0 + lane;
    if (eA < E){
      unsigned sv = (unsigned)src[eA];
      unsigned h0 = (__half_as_ushort(__float2half(sA0)) & 0xFFFEu) | (sv >> 16);
      unsigned h1 = __half_as_ushort(__float2half(sA1));
      unsigned h2 = __half_as_ushort(__float2half(sA2));
      esc8[eA] = make_uint2(h0 | (h1<<16), (sv & 0xFFFFu) | (h2<<16));
    }
    int eB = e0 + 16 + lane;
    if (eB < E){
      unsigned sv = (unsigned)src[eB];
      unsigned h0 = (__half_as_ushort(__float2half(sB0)) & 0xFFFEu) | (sv >> 16);
      unsigned h1 = __half_as_ushort(__float2half(sB1));
      unsigned h2 = __half_as_ushort(__float2half(sB2));
      esc8[eB] = make_uint2(h0 | (h1<<16), (sv & 0xFFFFu) | (h2<<16));
    }
  }
}

// pass A: LDS-binned append of 8B records + 2B dstlocal into fixed per-bucket regions.
__global__ void __launch_bounds__(256)
k_binA(const uint2* __restrict__ esc8, const int* __restrict__ dst,
       int* __restrict__ bcur, uint2* __restrict__ bin8, unsigned short* __restrict__ bin2,
       int E){
  __shared__ int cnt[256];
  __shared__ int ofs[256];
  __shared__ int gofs[256];
  __shared__ uint2 st8[ACH];
  __shared__ unsigned short st2[ACH];
  __shared__ unsigned char sbid[ACH];
  int tid = threadIdx.x;
  int base = blockIdx.x * ACH;
  cnt[tid] = 0;
  __syncthreads();
  uint2 r8[8]; int bb[8]; int ms[8]; int dl[8];
  #pragma unroll
  for (int k=0;k<8;k++){
    int e = base + tid + k*256;
    bb[k] = -1;
    if (e < E){
      r8[k] = esc8[e];
      int d = dst[e];
      bb[k] = d >> 9;
      dl[k] = d & (BNODE-1);
      ms[k] = atomicAdd(&cnt[bb[k]], 1);
    }
  }
  __syncthreads();
  int v = cnt[tid];
  ofs[tid] = v;
  __syncthreads();
  for (int d=1; d<256; d<<=1){
    int t = 0;
    if (tid>=d) t = ofs[tid-d];
    __syncthreads();
    if (tid>=d) ofs[tid] += t;
    __syncthreads();
  }
  int total = ofs[255];
  int excl = ofs[tid] - v;
  __syncthreads();
  ofs[tid] = excl;
  __syncthreads();
  #pragma unroll
  for (int k=0;k<8;k++){
    if (bb[k] >= 0){
      int slot = ofs[bb[k]] + ms[k];
      st8[slot] = r8[k];
      st2[slot] = (unsigned short)dl[k];
      sbid[slot] = (unsigned char)bb[k];
    }
  }
  if (v > 0) gofs[tid] = atomicAdd(&bcur[tid], v);
  __syncthreads();
  for (int slot = tid; slot < total; slot += 256){
    int b = sbid[slot];
    int gp = gofs[b] + (slot - ofs[b]);
    bin8[gp] = st8[slot];
    bin2[gp] = st2[slot];
  }
}

// fused pass B: per bucket = histogram -> LDS scan -> offS/offE -> scatter (+LDS score
// sums) -> self-loop records. Zero global atomics, no global scan kernels.
__global__ void __launch_bounds__(256)
k_binB2(const uint2* __restrict__ bin8, const unsigned short* __restrict__ bin2,
        const int* __restrict__ bcur, int* __restrict__ offS, int* __restrict__ offE,
        uint2* __restrict__ rec, int N){
  __shared__ int lcnt[BNODE];
  __shared__ int lcur[BNODE];
  __shared__ int loffS[BNODE];
  __shared__ int sc[256];
  __shared__ float ls0[BNODE], ls1[BNODE], ls2[BNODE];
  int b = blockIdx.x, tid = threadIdx.x;
  int n0 = b*BNODE;
  int n1 = n0 + BNODE; if (n1 > N) n1 = N;
  int nn = n1 - n0;
  for (int i=tid;i<BNODE;i+=256){ lcnt[i]=0; ls0[i]=0.f; ls1[i]=0.f; ls2[i]=0.f; }
  __syncthreads();
  int beg = b*CAP, cntb = bcur[b] - beg;
  for (int idx=tid; idx<cntb; idx+=256) atomicAdd(&lcnt[bin2[beg+idx]], 1);
  __syncthreads();
  // scan deg=lcnt+1 (2 entries/thread)
  int i0 = 2*tid, i1 = 2*tid+1;
  int a0 = (i0<nn) ? lcnt[i0]+1 : 0;
  int a1 = (i1<nn) ? lcnt[i1]+1 : 0;
  int pair = a0+a1;
  sc[tid] = pair;
  __syncthreads();
  for (int d=1; d<256; d<<=1){
    int t = 0; if (tid>=d) t = sc[tid-d];
    __syncthreads();
    if (tid>=d) sc[tid] += t;
    __syncthreads();
  }
  int excl = sc[tid] - pair;
  int base = b*CAP2;
  if (i0<nn){ int o=base+excl;    offS[n0+i0]=o; offE[n0+i0]=o+a0; loffS[i0]=o; lcur[i0]=o+1; }
  if (i1<nn){ int o=base+excl+a0; offS[n0+i1]=o; offE[n0+i1]=o+a1; loffS[i1]=o; lcur[i1]=o+1; }
  __syncthreads();
  // scatter + score sums
  for (int idx=tid; idx<cntb; idx+=256){
    uint2 r = bin8[beg+idx];
    int dl = bin2[beg+idx];
    int p = atomicAdd(&lcur[dl], 1);
    rec[p] = r;
    atomicAdd(&ls0[dl], h2f_(r.x & 0xFFFEu));
    atomicAdd(&ls1[dl], h2f_(r.x >> 16));
    atomicAdd(&ls2[dl], h2f_(r.y >> 16));
  }
  __syncthreads();
  // self-loop records
  for (int i=tid; i<nn; i+=256){
    int cnt = lcnt[i];
    float inv = (cnt>0) ? 1.0f/(float)cnt : 0.0f;
    unsigned h0 = __half_as_ushort(__float2half(ls0[i]*inv)) & 0xFFFEu;
    unsigned h1 = __half_as_ushort(__float2half(ls1[i]*inv));
    unsigned h2 = __half_as_ushort(__float2half(ls2[i]*inv));
    unsigned s = (unsigned)(n0+i);
    rec[loffS[i]] = make_uint2(h0 | (s>>16) | (h1<<16), (s & 0xFFFFu) | (h2<<16));
  }
}

// MFMA GRU: 2 node-strips per wave (32 nodes), block = 128 nodes. bf16 state.
__global__ void __launch_bounds__(256,2)
k_gru_m(const short* __restrict__ hg16, const short* __restrict__ xin, short* __restrict__ xout,
        const short* __restrict__ WihT16, const short* __restrict__ WhhT16,
        const float* __restrict__ bih, const float* __restrict__ bhh, int N){
  int lane = threadIdx.x & 63, w = threadIdx.x >> 6;
  int m16 = lane & 15;
  int kb  = lane >> 4;
  int n0 = blockIdx.x*128 + w*32;

  int r0 = n0 + m16;      if (r0 > N-1) r0 = N-1;
  int r1 = n0 + 16 + m16; if (r1 > N-1) r1 = N-1;
  const short* h0p = hg16 + (size_t)r0*H_ + kb*8;
  const short* h1p = hg16 + (size_t)r1*H_ + kb*8;
  bf16x8 ah0a = *(const bf16x8*)(h0p), ah1a = *(const bf16x8*)(h0p+32);
  bf16x8 ah0b = *(const bf16x8*)(h1p), ah1b = *(const bf16x8*)(h1p+32);
  const short* x0p = xin + (size_t)r0*H_ + kb*8;
  const short* x1p = xin + (size_t)r1*H_ + kb*8;
  bf16x8 ax0a = *(const bf16x8*)(x0p), ax1a = *(const bf16x8*)(x0p+32);
  bf16x8 ax0b = *(const bf16x8*)(x1p), ax1b = *(const bf16x8*)(x1p+32);

  f32x4 aR[2][4], aZ[2][4], aNi[2][4], aNh[2][4];
  #pragma unroll
  for (int s=0;s<2;s++){
    #pragma unroll
    for (int t=0;t<4;t++){
      aR[s][t]=(f32x4){0.f,0.f,0.f,0.f}; aZ[s][t]=(f32x4){0.f,0.f,0.f,0.f};
      aNi[s][t]=(f32x4){0.f,0.f,0.f,0.f}; aNh[s][t]=(f32x4){0.f,0.f,0.f,0.f};
    }
  }

  const short* wi = WihT16 + (size_t)m16*H_ + kb*8;
  const short* wh = WhhT16 + (size_t)m16*H_ + kb*8;
  #pragma unroll
  for (int t=0;t<4;t++){
    bf16x8 b;
    b = *(const bf16x8*)(wi + (size_t)(t*16)*H_);
    aR[0][t] = __builtin_amdgcn_mfma_f32_16x16x32_bf16(ah0a, b, aR[0][t], 0,0,0);
    aR[1][t] = __builtin_amdgcn_mfma_f32_16x16x32_bf16(ah0b, b, aR[1][t], 0,0,0);
    b = *(const bf16x8*)(wi + (size_t)(t*16)*H_ + 32);
    aR[0][t] = __builtin_amdgcn_mfma_f32_16x16x32_bf16(ah1a, b, aR[0][t], 0,0,0);
    aR[1][t] = __builtin_amdgcn_mfma_f32_16x16x32_bf16(ah1b, b, aR[1][t], 0,0,0);
    b = *(const bf16x8*)(wh + (size_t)(t*16)*H_);
    aR[0][t] = __builtin_amdgcn_mfma_f32_16x16x32_bf16(ax0a, b, aR[0][t], 0,0,0);
    aR[1][t] = __builtin_amdgcn_mfma_f32_16x16x32_bf16(ax0b, b, aR[1][t], 0,0,0);
    b = *(const bf16x8*)(wh + (size_t)(t*16)*H_ + 32);
    aR[0][t] = __builtin_amdgcn_mfma_f32_16x16x32_bf16(ax1a, b, aR[0][t], 0,0,0);
    aR[1][t] = __builtin_amdgcn_mfma_f32_16x16x32_bf16(ax1b, b, aR[1][t], 0,0,0);

    b = *(const bf16x8*)(wi + (size_t)(64+t*16)*H_);
    aZ[0][t] = __builtin_amdgcn_mfma_f32_16x16x32_bf16(ah0a, b, aZ[0][t], 0,0,0);
    aZ[1][t] = __builtin_amdgcn_mfma_f32_16x16x32_bf16(ah0b, b, aZ[1][t], 0,0,0);
    b = *(const bf16x8*)(wi + (size_t)(64+t*16)*H_ + 32);
    aZ[0][t] = __builtin_amdgcn_mfma_f32_16x16x32_bf16(ah1a, b, aZ[0][t], 0,0,0);
    aZ[1][t] = __builtin_amdgcn_mfma_f32_16x16x32_bf16(ah1b, b, aZ[1][t], 0,0,0);
    b = *(const bf16x8*)(wh + (size_t)(64+t*16)*H_);
    aZ[0][t] = __builtin_amdgcn_mfma_f32_16x16x32_bf16(ax0a, b, aZ[0][t], 0,0,0);
    aZ[1][t] = __builtin_amdgcn_mfma_f32_16x16x32_bf16(ax0b, b, aZ[1][t], 0,0,0);
    b = *(const bf16x8*)(wh + (size_t)(64+t*16)*H_ + 32);
    aZ[0][t] = __builtin_amdgcn_mfma_f32_16x16x32_bf16(ax1a, b, aZ[0][t], 0,0,0);
    aZ[1][t] = __builtin_amdgcn_mfma_f32_16x16x32_bf16(ax1b, b, aZ[1][t], 0,0,0);

    b = *(const bf16x8*)(wi + (size_t)(128+t*16)*H_);
    aNi[0][t] = __builtin_amdgcn_mfma_f32_16x16x32_bf16(ah0a, b, aNi[0][t], 0,0,0);
    aNi[1][t] = __builtin_amdgcn_mfma_f32_16x16x32_bf16(ah0b, b, aNi[1][t], 0,0,0);
    b = *(const bf16x8*)(wi + (size_t)(128+t*16)*H_ + 32);
    aNi[0][t] = __builtin_amdgcn_mfma_f32_16x16x32_bf16(ah1a, b, aNi[0][t], 0,0,0);
    aNi[1][t] = __builtin_amdgcn_mfma_f32_16x16x32_bf16(ah1b, b, aNi[1][t], 0,0,0);
    b = *(const bf16x8*)(wh + (size_t)(128+t*16)*H_);
    aNh[0][t] = __builtin_amdgcn_mfma_f32_16x16x32_bf16(ax0a, b, aNh[0][t], 0,0,0);
    aNh[1][t] = __builtin_amdgcn_mfma_f32_16x16x32_bf16(ax0b, b, aNh[1][t], 0,0,0);
    b = *(const bf16x8*)(wh + (size_t)(128+t*16)*H_ + 32);
    aNh[0][t] = __builtin_amdgcn_mfma_f32_16x16x32_bf16(ax1a, b, aNh[0][t], 0,0,0);
    aNh[1][t] = __builtin_amdgcn_mfma_f32_16x16x32_bf16(ax1b, b, aNh[1][t], 0,0,0);
  }

  int mrow = (lane>>4)*4;
  #pragma unroll
  for (int s=0;s<2;s++){
    #pragma unroll
    for (int t=0;t<4;t++){
      int f = t*16 + m16;
      float br = bih[f]     + bhh[f];
      float bz = bih[64+f]  + bhh[64+f];
      float bin= bih[128+f], bhn = bhh[128+f];
      #pragma unroll
      for (int q=0;q<4;q++){
        int node = n0 + s*16 + mrow + q;
        if (node < N){
          float r  = sigm_(aR[s][t][q] + br);
          float z  = sigm_(aZ[s][t][q] + bz);
          float nn = tanh_(aNi[s][t][q] + bin + r*(aNh[s][t][q] + bhn));
          float xv = bf2f((unsigned short)xin[(size_t)node*H_ + f]);
          xout[(size_t)node*H_ + f] = f2bf(fmaxf((1.f-z)*nn + z*xv, 0.f));
        }
      }
    }
  }
}

// MFMA linear-h: 2 node-strips per wave (32 nodes), block = 128 nodes. bf16 input.
__global__ void __launch_bounds__(256,4)
k_linh_m(const short* __restrict__ xi, const short* __restrict__ wT16,
         const float* __restrict__ atts, const float* __restrict__ attd,
         __half* __restrict__ h16, float* __restrict__ ssc, float* __restrict__ dsc, int N){
  int lane = threadIdx.x & 63, w = threadIdx.x >> 6;
  int m16 = lane & 15, kb = lane >> 4;
  int n0 = blockIdx.x*128 + w*32;
  int r0 = n0 + m16;      if (r0 > N-1) r0 = N-1;
  int r1 = n0 + 16 + m16; if (r1 > N-1) r1 = N-1;
  const short* x0p = xi + (size_t)r0*H_ + kb*8;
  const short* x1p = xi + (size_t)r1*H_ + kb*8;
  bf16x8 ax0a = *(const bf16x8*)(x0p), ax1a = *(const bf16x8*)(x0p+32);
  bf16x8 ax0b = *(const bf16x8*)(x1p), ax1b = *(const bf16x8*)(x1p+32);

  f32x4 acc[2][4];
  #pragma unroll
  for (int s=0;s<2;s++)
    #pragma unroll
    for (int t=0;t<4;t++) acc[s][t]=(f32x4){0.f,0.f,0.f,0.f};
  const short* wp = wT16 + (size_t)m16*H_ + kb*8;
  #pragma unroll
  for (int t=0;t<4;t++){
    bf16x8 b0 = *(const bf16x8*)(wp + (size_t)(t*16)*H_);
    acc[0][t] = __builtin_amdgcn_mfma_f32_16x16x32_bf16(ax0a, b0, acc[0][t], 0,0,0);
    acc[1][t] = __builtin_amdgcn_mfma_f32_16x16x32_bf16(ax0b, b0, acc[1][t], 0,0,0);
    bf16x8 b1 = *(const bf16x8*)(wp + (size_t)(t*16)*H_ + 32);
    acc[0][t] = __builtin_amdgcn_mfma_f32_16x16x32_bf16(ax1a, b1, acc[0][t], 0,0,0);
    acc[1][t] = __builtin_amdgcn_mfma_f32_16x16x32_bf16(ax1b, b1, acc[1][t], 0,0,0);
  }

  int mrow = (lane>>4)*4;
  float ps[2][4], pd[2][4];
  #pragma unroll
  for (int s=0;s<2;s++)
    #pragma unroll
    for (int q=0;q<4;q++){ ps[s][q]=0.f; pd[s][q]=0.f; }
  #pragma unroll
  for (int t=0;t<4;t++){
    int f = t*16 + m16;
    float as = atts[f], ad = attd[f];
    #pragma unroll
    for (int s=0;s<2;s++){
      #pragma unroll
      for (int q=0;q<4;q++){
        int node = n0 + s*16 + mrow + q;
        float v = acc[s][t][q];
        if (node < N) h16[(size_t)node*H_ + f] = __float2half(v);
        ps[s][q] = fmaf(v, as, ps[s][q]); pd[s][q] = fmaf(v, ad, pd[s][q]);
      }
    }
  }
  #pragma unroll
  for (int d=1; d<16; d<<=1){
    #pragma unroll
    for (int s=0;s<2;s++)
      #pragma unroll
      for (int q=0;q<4;q++){ ps[s][q] += __shfl_xor(ps[s][q], d); pd[s][q] += __shfl_xor(pd[s][q], d); }
  }
  if (m16==0){
    #pragma unroll
    for (int s=0;s<2;s++){
      #pragma unroll
      for (int q=0;q<4;q++){
        int node = n0 + s*16 + mrow + q;
        if (node < N){ ssc[node]=ps[s][q]; dsc[node]=pd[s][q]; }
      }
    }
  }
}

// GAT: 4 nodes/wave, 16 lanes/node. Single-pass safe-exp softmax. offS/offE bounds.
template<int L>
__global__ void __launch_bounds__(256)
k_gat_g4(const __half* __restrict__ h16, const float* __restrict__ ssc,
         const float* __restrict__ dsc, const uint2* __restrict__ rec,
         const int* __restrict__ offS, const int* __restrict__ offE,
         const float* __restrict__ bias, short* __restrict__ hgat16, int N){
  int lane = threadIdx.x & 63, w = threadIdx.x >> 6;
  int g = lane >> 4, fl = lane & 15;
  int node = blockIdx.x*16 + w*4 + g;
  if (node >= N) return;
  int e0 = offS[node], e1 = offE[node];
  float dval = dsc[node];
  float acc0=0.f, acc1=0.f, acc2=0.f, acc3=0.f, den=0.f;
  int gbase = lane & 48;                 // g*16
  for (int base = e0; base < e1; base += 16){
    int p = base + fl;
    float ex = 0.f; int s = 0;
    if (p < e1){
      uint2 r = rec[p];
      s = (int)((r.y & 0xFFFFu) | ((r.x & 1u) << 16));
      unsigned hb = (L==0) ? (r.x & 0xFFFEu) : (L==1) ? (r.x >> 16) : (r.y >> 16);
      float a = ssc[s] + dval + h2f_(hb);
      a = (a > 0.f) ? a : SLOPE*a;
      ex = __expf(a);
    }
    den += ex;
    int cnt = e1 - base; if (cnt > 16) cnt = 16;
    for (int j = 0; j < cnt; j++){
      float exb = __shfl(ex, gbase + j);
      int   sb  = __shfl(s,  gbase + j);
      uint2 hv = *(const uint2*)(h16 + (size_t)sb*H_ + 4*fl);
      float2 f0 = __half22float2(*(__half2*)&hv.x);
      float2 f1 = __half22float2(*(__half2*)&hv.y);
      acc0 = fmaf(exb, f0.x, acc0);
      acc1 = fmaf(exb, f0.y, acc1);
      acc2 = fmaf(exb, f1.x, acc2);
      acc3 = fmaf(exb, f1.y, acc3);
    }
  }
  #pragma unroll
  for (int d=1; d<16; d<<=1) den += __shfl_xor(den, d);
  float4 bv = *(const float4*)(bias + 4*fl);
  float inv = 1.0f/den;
  float v0 = fmaxf(fmaf(acc0,inv,bv.x), 0.f);
  float v1 = fmaxf(fmaf(acc1,inv,bv.y), 0.f);
  float v2 = fmaxf(fmaf(acc2,inv,bv.z), 0.f);
  float v3 = fmaxf(fmaf(acc3,inv,bv.w), 0.f);
  uint2 o;
  o.x = ((unsigned)(unsigned short)f2bf(v1)<<16) | (unsigned short)f2bf(v0);
  o.y = ((unsigned)(unsigned short)f2bf(v3)<<16) | (unsigned short)f2bf(v2);
  *(uint2*)(hgat16 + (size_t)node*H_ + 4*fl) = o;
}

// block per graph: zero-atomic pooled output (batch sorted, xi bf16)
__global__ void __launch_bounds__(256)
k_pool_g(const short* __restrict__ xi, const float* __restrict__ wout,
         const int* __restrict__ gstart, const float* __restrict__ b_out,
         float* __restrict__ out){
  int g = blockIdx.x;
  int a = gstart[g], b = gstart[g+1];
  float acc = 0.f;
  for (int n = a + threadIdx.x; n < b; n += 256){
    const uint4* xr = (const uint4*)(xi + (size_t)n*H_);   // 8 bf16 per uint4
    float s = 0.f;
    #pragma unroll
    for (int q=0;q<8;q++){
      uint4 v = xr[q];
      s += bf2f((unsigned short)(v.x&0xFFFF))*wout[8*q]   + bf2f((unsigned short)(v.x>>16))*wout[8*q+1]
         + bf2f((unsigned short)(v.y&0xFFFF))*wout[8*q+2] + bf2f((unsigned short)(v.y>>16))*wout[8*q+3]
         + bf2f((unsigned short)(v.z&0xFFFF))*wout[8*q+4] + bf2f((unsigned short)(v.z>>16))*wout[8*q+5]
         + bf2f((unsigned short)(v.w&0xFFFF))*wout[8*q+6] + bf2f((unsigned short)(v.w>>16))*wout[8*q+7];
    }
    acc += s;
  }
  #pragma unroll
  for (int d=32; d; d>>=1) acc += __shfl_xor(acc, d);
  __shared__ float sh[4];
  if ((threadIdx.x&63)==0) sh[threadIdx.x>>6] = acc;
  __syncthreads();
  if (threadIdx.x==0) out[g] = sh[0]+sh[1]+sh[2]+sh[3] + b_out[0];
}

extern "C" void kernel_launch(void* const* d_in, const int* in_sizes, int n_in,
                              void* d_out, int out_size, void* d_ws, size_t ws_size,
                              hipStream_t stream){
  const float* x       = (const float*)d_in[0];
  const float* eattr   = (const float*)d_in[1];
  const float* w_node  = (const float*)d_in[2];
  const float* b_node  = (const float*)d_in[3];
  const float* w_edge  = (const float*)d_in[4];
  const float* b_edge  = (const float*)d_in[5];
  const float* conv_W  = (const float*)d_in[6];
  const float* conv_We = (const float*)d_in[7];
  const float* att_s   = (const float*)d_in[8];
  const float* att_d   = (const float*)d_in[9];
  const float* att_e   = (const float*)d_in[10];
  const float* conv_b  = (const float*)d_in[11];
  const float* gWih    = (const float*)d_in[12];
  const float* gWhh    = (const float*)d_in[13];
  const float* gbih    = (const float*)d_in[14];
  const float* gbhh    = (const float*)d_in[15];
  const float* w_out   = (const float*)d_in[16];
  const float* b_out   = (const float*)d_in[17];
  const int*   eidx    = (const int*)d_in[18];
  const int*   batch   = (const int*)d_in[19];
  float* out = (float*)d_out;

  int N = in_sizes[0]/DIN;
  int E = in_sizes[1]/DE;
  int G = out_size;
  const int* src = eidx;
  const int* dst = eidx + E;

  char* p = (char*)d_ws;
  auto carve = [&](size_t bytes)->void*{ void* r=(void*)p; p += (bytes+255)&~(size_t)255; return r; };
  short*  xi0    = (short*)carve((size_t)N*H_*2);
  short*  xi1    = (short*)carve((size_t)N*H_*2);
  __half* h16    = (__half*)carve((size_t)N*H_*2);
  short*  hgat16 = (short*)carve((size_t)N*H_*2);
  float*  ssc    = (float*)carve((size_t)N*4);
  float*  dsc    = (float*)carve((size_t)N*4);
  uint2*  esc8   = (uint2*)carve((size_t)E*8);
  uint2*  rec    = (uint2*)carve((size_t)256*CAP2*8);
  uint2*  bin8   = (uint2*)carve((size_t)256*CAP*8);
  unsigned short* bin2 = (unsigned short*)carve((size_t)256*CAP*2);
  int*    offS   = (int*)carve((size_t)N*4);
  int*    offE   = (int*)carve((size_t)N*4);
  int*    bcur   = (int*)carve((size_t)256*4);
  int*    gstart = (int*)carve((size_t)(G+1)*4);
  short*  wnT16  = (short*)carve((size_t)DIN*H_*2);
  short*  weT16p = (short*)carve((size_t)64*32*2);
  short*  cWT16  = (short*)carve((size_t)3*H_*H_*2);
  short*  WihT16 = (short*)carve((size_t)3*192*H_*2);
  short*  WhhT16 = (short*)carve((size_t)3*192*H_*2);
  float*  ve     = (float*)carve((size_t)3*H_*4);

  auto cdiv=[](int a,int b){return (a+b-1)/b;};
  int NBK = cdiv(N,BNODE);

  int prep_total = 2048+2048+12288+36864+36864+192+256+N;
  k_prep<<<cdiv(prep_total,256),256,0,stream>>>(w_node, w_edge, b_edge, conv_W, gWih, gWhh,
                                                conv_We, att_e, batch,
                                                wnT16, weT16p, cWT16, WihT16, WhhT16, ve,
                                                bcur, gstart, N, G);
  k_nmlp_m<<<cdiv(N,64),256,0,stream>>>(x, wnT16, b_node, xi0, N);
  k_edge_m<<<cdiv(E,128),256,0,stream>>>(eattr, weT16p, ve, src, esc8, E);
  k_binA<<<cdiv(E,ACH),256,0,stream>>>(esc8, dst, bcur, bin8, bin2, E);
  k_binB2<<<NBK,256,0,stream>>>(bin8, bin2, bcur, offS, offE, rec, N);

  int NB128 = cdiv(N,128);
  int NB16  = cdiv(N,16);
  for (int l=0; l<3; l++){
    const short* xin = (l&1) ? xi1 : xi0;
    short*       xo  = (l&1) ? xi0 : xi1;
    k_linh_m<<<NB128,256,0,stream>>>(xin, cWT16 + (size_t)l*H_*H_, att_s + l*H_, att_d + l*H_,
                                     h16, ssc, dsc, N);
    if (l==0)      k_gat_g4<0><<<NB16,256,0,stream>>>(h16, ssc, dsc, rec, offS, offE, conv_b + l*H_, hgat16, N);
    else if (l==1) k_gat_g4<1><<<NB16,256,0,stream>>>(h16, ssc, dsc, rec, offS, offE, conv_b + l*H_, hgat16, N);
    else           k_gat_g4<2><<<NB16,256,0,stream>>>(h16, ssc, dsc, rec, offS, offE, conv_b + l*H_, hgat16, N);
    k_gru_m<<<NB128,256,0,stream>>>(hgat16, xin, xo, WihT16 + (size_t)l*192*H_, WhhT16 + (size_t)l*192*H_,
                                    gbih + l*3*H_, gbhh + l*3*H_, N);
  }

  k_pool_g<<<G,256,0,stream>>>(xi1, w_out, gstart, b_out, out);
}

// Round 21
// 357.318 us; speedup vs baseline: 49.2124x; 1.0227x over previous
//
#include <hip/hip_runtime.h>
#include <hip/hip_fp16.h>

constexpr int H_  = 64;   // hidden
constexpr int DIN = 32;   // atom feature dim
constexpr int DE  = 16;   // edge feature dim
constexpr int BNODE = 512;  // nodes per scatter bucket (dstlocal < 512)
constexpr int ACH   = 2048; // edges per binning chunk
constexpr int CAP   = 6144; // per-bucket bin region capacity (mean 5120 + 14 sigma)
constexpr int CAP2  = CAP + BNODE; // per-bucket rec region (edges + self-loops)
#define SLOPE 0.2f

typedef __attribute__((ext_vector_type(8))) short bf16x8;
typedef __attribute__((ext_vector_type(4))) float f32x4;

__device__ __forceinline__ float sigm_(float x){ return 1.0f/(1.0f+__expf(-x)); }
__device__ __forceinline__ float tanh_(float x){ float e=__expf(2.0f*x); return 1.0f - 2.0f/(e+1.0f); }
__device__ __forceinline__ short f2bf(float f){   // RNE float->bf16
  unsigned u = __float_as_uint(f);
  u += 0x7FFF + ((u>>16)&1);
  return (short)(u>>16);
}
__device__ __forceinline__ float bf2f(unsigned short s){
  return __uint_as_float(((unsigned)s)<<16);
}
__device__ __forceinline__ float h2f_(unsigned hb){
  return __half2float(__ushort_as_half((unsigned short)hb));
}

// mega-kernel: weight prep + bcur init + graph bounds
__global__ void k_prep(const float* __restrict__ w_node, const float* __restrict__ w_edge,
                       const float* __restrict__ b_edge,
                       const float* __restrict__ conv_W, const float* __restrict__ gWih,
                       const float* __restrict__ gWhh, const float* __restrict__ conv_We,
                       const float* __restrict__ att_e, const int* __restrict__ batch,
                       short* __restrict__ wnT16, short* __restrict__ weT16p,
                       short* __restrict__ cWT16, short* __restrict__ WihT16,
                       short* __restrict__ WhhT16, float* __restrict__ ve,
                       int* __restrict__ bcur, int* __restrict__ gstart, int N, int G){
  int id = blockIdx.x*blockDim.x + threadIdx.x;
  if (id < 2048){                                   // wnT16 [64][32]
    int j = id >> 5, k = id & 31;
    wnT16[id] = f2bf(w_node[k*64 + j]);
    return;
  }
  id -= 2048;
  if (id < 2048){                                   // weT16p [64][32]; k=16 row = bias
    int j = id >> 5, k = id & 31;
    weT16p[id] = (k < DE) ? f2bf(w_edge[k*64 + j]) : (k == DE ? f2bf(b_edge[j]) : (short)0);
    return;
  }
  id -= 2048;
  if (id < 12288){                                  // cWT16 [3][64 j][64 k]
    int l = id / 4096, rem = id & 4095, j = rem >> 6, k = rem & 63;
    cWT16[id] = f2bf(conv_W[l*4096 + k*64 + j]);
    return;
  }
  id -= 12288;
  if (id < 36864){                                  // WihT16 [3][192 j][64 k]
    int l = id / 12288, rem = id % 12288, j = rem >> 6, k = rem & 63;
    WihT16[id] = f2bf(gWih[l*12288 + k*192 + j]);
    return;
  }
  id -= 36864;
  if (id < 36864){                                  // WhhT16
    int l = id / 12288, rem = id % 12288, j = rem >> 6, k = rem & 63;
    WhhT16[id] = f2bf(gWhh[l*12288 + k*192 + j]);
    return;
  }
  id -= 36864;
  if (id < 192){                                    // ve[l][k]
    int l = id >> 6, k = id & 63;
    const float* w = conv_We + (size_t)(l*64+k)*64;
    const float* a = att_e + l*64;
    float s = 0.f;
    #pragma unroll
    for (int j=0;j<64;j++) s += w[j]*a[j];
    ve[id] = s;
    return;
  }
  id -= 192;
  if (id < 256){ bcur[id] = id*CAP; return; }       // fixed-capacity bin regions
  id -= 256;
  if (id < N){                                      // graph bounds (sorted batch)
    int b = batch[id];
    int bp = (id==0) ? -1 : batch[id-1];
    for (int g=bp+1; g<=b; g++) gstart[g]=id;
    if (id==N-1){ for (int g=b+1; g<=G; g++) gstart[g]=N; }
  }
}

// MFMA node MLP: xi16 = bf16(relu(x @ w_node + b)), K=32 exact. No LDS.
__global__ void __launch_bounds__(256,4)
k_nmlp_m(const float* __restrict__ x, const short* __restrict__ wT16,
         const float* __restrict__ b, short* __restrict__ xi, int N){
  int lane = threadIdx.x & 63, w = threadIdx.x >> 6;
  int m16 = lane & 15, kb = lane >> 4;
  int n0 = blockIdx.x*64 + w*16;
  int arow = n0 + m16; if (arow > N-1) arow = N-1;
  const float* xr = x + (size_t)arow*DIN + kb*8;
  float4 a0 = *(const float4*)xr, a1 = *(const float4*)(xr+4);
  bf16x8 af;
  af[0]=f2bf(a0.x); af[1]=f2bf(a0.y); af[2]=f2bf(a0.z); af[3]=f2bf(a0.w);
  af[4]=f2bf(a1.x); af[5]=f2bf(a1.y); af[6]=f2bf(a1.z); af[7]=f2bf(a1.w);
  f32x4 acc[4];
  #pragma unroll
  for (int t=0;t<4;t++) acc[t]=(f32x4){0.f,0.f,0.f,0.f};
  const short* wp = wT16 + (size_t)m16*DIN + kb*8;
  #pragma unroll
  for (int t=0;t<4;t++){
    bf16x8 bb = *(const bf16x8*)(wp + (size_t)(t*16)*DIN);
    acc[t] = __builtin_amdgcn_mfma_f32_16x16x32_bf16(af, bb, acc[t], 0,0,0);
  }
  int mrow = (lane>>4)*4;
  #pragma unroll
  for (int t=0;t<4;t++){
    int f = t*16 + m16;
    float bj = b[f];
    #pragma unroll
    for (int q=0;q<4;q++){
      int node = n0 + mrow + q;
      if (node < N) xi[(size_t)node*H_ + f] = f2bf(fmaxf(acc[t][q] + bj, 0.f));
    }
  }
}

// Transposed MFMA edge scores: D = W^T @ attr^T so each lane holds 16 j-values of ONE
// edge -> ve-dot is lane-local; reduce is only over the 4 kb groups (2 shfl steps).
__global__ void __launch_bounds__(256,4)
k_edge_m(const float* __restrict__ attr, const short* __restrict__ weT16p,
         const float* __restrict__ ve, const int* __restrict__ src,
         uint2* __restrict__ esc8, int E){
  int lane = threadIdx.x & 63, w = threadIdx.x >> 6;
  int m16 = lane & 15, kb = lane >> 4;
  int e0 = (blockIdx.x*4 + w)*32;        // 2 tiles of 16 edges
  if (e0 >= E) return;
  const short* wp = weT16p + (size_t)m16*32 + kb*8;
  bf16x8 wA0 = *(const bf16x8*)(wp);
  bf16x8 wA1 = *(const bf16x8*)(wp + 16*32);
  bf16x8 wA2 = *(const bf16x8*)(wp + 32*32);
  bf16x8 wA3 = *(const bf16x8*)(wp + 48*32);
  bf16x8 af0 = {0,0,0,0,0,0,0,0}, af1 = {0,0,0,0,0,0,0,0};
  if (kb < 2){
    int r0 = e0 + m16;      if (r0 > E-1) r0 = E-1;
    int r1 = e0 + 16 + m16; if (r1 > E-1) r1 = E-1;
    const float* ap0 = attr + (size_t)r0*DE + kb*8;
    const float* ap1 = attr + (size_t)r1*DE + kb*8;
    float4 a0 = *(const float4*)ap0, a1 = *(const float4*)(ap0+4);
    float4 b0 = *(const float4*)ap1, b1 = *(const float4*)(ap1+4);
    af0[0]=f2bf(a0.x); af0[1]=f2bf(a0.y); af0[2]=f2bf(a0.z); af0[3]=f2bf(a0.w);
    af0[4]=f2bf(a1.x); af0[5]=f2bf(a1.y); af0[6]=f2bf(a1.z); af0[7]=f2bf(a1.w);
    af1[0]=f2bf(b0.x); af1[1]=f2bf(b0.y); af1[2]=f2bf(b0.z); af1[3]=f2bf(b0.w);
    af1[4]=f2bf(b1.x); af1[5]=f2bf(b1.y); af1[6]=f2bf(b1.z); af1[7]=f2bf(b1.w);
  } else if (kb == 2){
    af0[0] = (short)0x3F80; af1[0] = (short)0x3F80;
  }
  f32x4 accA[4], accB[4];
  #pragma unroll
  for (int t=0;t<4;t++){ accA[t]=(f32x4){0.f,0.f,0.f,0.f}; accB[t]=(f32x4){0.f,0.f,0.f,0.f}; }
  accA[0] = __builtin_amdgcn_mfma_f32_16x16x32_bf16(wA0, af0, accA[0], 0,0,0);
  accB[0] = __builtin_amdgcn_mfma_f32_16x16x32_bf16(wA0, af1, accB[0], 0,0,0);
  accA[1] = __builtin_amdgcn_mfma_f32_16x16x32_bf16(wA1, af0, accA[1], 0,0,0);
  accB[1] = __builtin_amdgcn_mfma_f32_16x16x32_bf16(wA1, af1, accB[1], 0,0,0);
  accA[2] = __builtin_amdgcn_mfma_f32_16x16x32_bf16(wA2, af0, accA[2], 0,0,0);
  accB[2] = __builtin_amdgcn_mfma_f32_16x16x32_bf16(wA2, af1, accB[2], 0,0,0);
  accA[3] = __builtin_amdgcn_mfma_f32_16x16x32_bf16(wA3, af0, accA[3], 0,0,0);
  accB[3] = __builtin_amdgcn_mfma_f32_16x16x32_bf16(wA3, af1, accB[3], 0,0,0);

  int kb4 = kb*4;
  float sA0=0.f,sA1=0.f,sA2=0.f, sB0=0.f,sB1=0.f,sB2=0.f;
  #pragma unroll
  for (int t=0;t<4;t++){
    float4 v0 = *(const float4*)(ve + t*16 + kb4);
    float4 v1 = *(const float4*)(ve + 64 + t*16 + kb4);
    float4 v2 = *(const float4*)(ve + 128 + t*16 + kb4);
    float eA0 = fmaxf(accA[t][0],0.f), eA1 = fmaxf(accA[t][1],0.f);
    float eA2 = fmaxf(accA[t][2],0.f), eA3 = fmaxf(accA[t][3],0.f);
    float eB0 = fmaxf(accB[t][0],0.f), eB1 = fmaxf(accB[t][1],0.f);
    float eB2 = fmaxf(accB[t][2],0.f), eB3 = fmaxf(accB[t][3],0.f);
    sA0 = fmaf(eA0,v0.x, fmaf(eA1,v0.y, fmaf(eA2,v0.z, fmaf(eA3,v0.w, sA0))));
    sA1 = fmaf(eA0,v1.x, fmaf(eA1,v1.y, fmaf(eA2,v1.z, fmaf(eA3,v1.w, sA1))));
    sA2 = fmaf(eA0,v2.x, fmaf(eA1,v2.y, fmaf(eA2,v2.z, fmaf(eA3,v2.w, sA2))));
    sB0 = fmaf(eB0,v0.x, fmaf(eB1,v0.y, fmaf(eB2,v0.z, fmaf(eB3,v0.w, sB0))));
    sB1 = fmaf(eB0,v1.x, fmaf(eB1,v1.y, fmaf(eB2,v1.z, fmaf(eB3,v1.w, sB1))));
    sB2 = fmaf(eB0,v2.x, fmaf(eB1,v2.y, fmaf(eB2,v2.z, fmaf(eB3,v2.w, sB2))));
  }
  sA0 += __shfl_xor(sA0,16); sA0 += __shfl_xor(sA0,32);
  sA1 += __shfl_xor(sA1,16); sA1 += __shfl_xor(sA1,32);
  sA2 += __shfl_xor(sA2,16); sA2 += __shfl_xor(sA2,32);
  sB0 += __shfl_xor(sB0,16); sB0 += __shfl_xor(sB0,32);
  sB1 += __shfl_xor(sB1,16); sB1 += __shfl_xor(sB1,32);
  sB2 += __shfl_xor(sB2,16); sB2 += __shfl_xor(sB2,32);
  if (lane < 16){
    int eA = e0 + lane;
    if (eA < E){
      unsigned sv = (unsigned)src[eA];
      unsigned h0 = (__half_as_ushort(__float2half(sA0)) & 0xFFFEu) | (sv >> 16);
      unsigned h1 = __half_as_ushort(__float2half(sA1));
      unsigned h2 = __half_as_ushort(__float2half(sA2));
      esc8[eA] = make_uint2(h0 | (h1<<16), (sv & 0xFFFFu) | (h2<<16));
    }
    int eB = e0 + 16 + lane;
    if (eB < E){
      unsigned sv = (unsigned)src[eB];
      unsigned h0 = (__half_as_ushort(__float2half(sB0)) & 0xFFFEu) | (sv >> 16);
      unsigned h1 = __half_as_ushort(__float2half(sB1));
      unsigned h2 = __half_as_ushort(__float2half(sB2));
      esc8[eB] = make_uint2(h0 | (h1<<16), (sv & 0xFFFFu) | (h2<<16));
    }
  }
}

// pass A: LDS-binned append of 8B records + 2B dstlocal into fixed per-bucket regions.
__global__ void __launch_bounds__(256)
k_binA(const uint2* __restrict__ esc8, const int* __restrict__ dst,
       int* __restrict__ bcur, uint2* __restrict__ bin8, unsigned short* __restrict__ bin2,
       int E){
  __shared__ int cnt[256];
  __shared__ int ofs[256];
  __shared__ int gofs[256];
  __shared__ uint2 st8[ACH];
  __shared__ unsigned short st2[ACH];
  __shared__ unsigned char sbid[ACH];
  int tid = threadIdx.x;
  int base = blockIdx.x * ACH;
  cnt[tid] = 0;
  __syncthreads();
  uint2 r8[8]; int bb[8]; int ms[8]; int dl[8];
  #pragma unroll
  for (int k=0;k<8;k++){
    int e = base + tid + k*256;
    bb[k] = -1;
    if (e < E){
      r8[k] = esc8[e];
      int d = dst[e];
      bb[k] = d >> 9;
      dl[k] = d & (BNODE-1);
      ms[k] = atomicAdd(&cnt[bb[k]], 1);
    }
  }
  __syncthreads();
  int v = cnt[tid];
  ofs[tid] = v;
  __syncthreads();
  for (int d=1; d<256; d<<=1){
    int t = 0;
    if (tid>=d) t = ofs[tid-d];
    __syncthreads();
    if (tid>=d) ofs[tid] += t;
    __syncthreads();
  }
  int total = ofs[255];
  int excl = ofs[tid] - v;
  __syncthreads();
  ofs[tid] = excl;
  __syncthreads();
  #pragma unroll
  for (int k=0;k<8;k++){
    if (bb[k] >= 0){
      int slot = ofs[bb[k]] + ms[k];
      st8[slot] = r8[k];
      st2[slot] = (unsigned short)dl[k];
      sbid[slot] = (unsigned char)bb[k];
    }
  }
  if (v > 0) gofs[tid] = atomicAdd(&bcur[tid], v);
  __syncthreads();
  for (int slot = tid; slot < total; slot += 256){
    int b = sbid[slot];
    int gp = gofs[b] + (slot - ofs[b]);
    bin8[gp] = st8[slot];
    bin2[gp] = st2[slot];
  }
}

// fused pass B: per bucket = histogram -> LDS scan -> offS/offE -> scatter (+LDS score
// sums) -> self-loop records. Zero global atomics, no global scan kernels.
__global__ void __launch_bounds__(256)
k_binB2(const uint2* __restrict__ bin8, const unsigned short* __restrict__ bin2,
        const int* __restrict__ bcur, int* __restrict__ offS, int* __restrict__ offE,
        uint2* __restrict__ rec, int N){
  __shared__ int lcnt[BNODE];
  __shared__ int lcur[BNODE];
  __shared__ int loffS[BNODE];
  __shared__ int sc[256];
  __shared__ float ls0[BNODE], ls1[BNODE], ls2[BNODE];
  int b = blockIdx.x, tid = threadIdx.x;
  int n0 = b*BNODE;
  int n1 = n0 + BNODE; if (n1 > N) n1 = N;
  int nn = n1 - n0;
  for (int i=tid;i<BNODE;i+=256){ lcnt[i]=0; ls0[i]=0.f; ls1[i]=0.f; ls2[i]=0.f; }
  __syncthreads();
  int beg = b*CAP, cntb = bcur[b] - beg;
  for (int idx=tid; idx<cntb; idx+=256) atomicAdd(&lcnt[bin2[beg+idx]], 1);
  __syncthreads();
  int i0 = 2*tid, i1 = 2*tid+1;
  int a0 = (i0<nn) ? lcnt[i0]+1 : 0;
  int a1 = (i1<nn) ? lcnt[i1]+1 : 0;
  int pair = a0+a1;
  sc[tid] = pair;
  __syncthreads();
  for (int d=1; d<256; d<<=1){
    int t = 0; if (tid>=d) t = sc[tid-d];
    __syncthreads();
    if (tid>=d) sc[tid] += t;
    __syncthreads();
  }
  int excl = sc[tid] - pair;
  int base = b*CAP2;
  if (i0<nn){ int o=base+excl;    offS[n0+i0]=o; offE[n0+i0]=o+a0; loffS[i0]=o; lcur[i0]=o+1; }
  if (i1<nn){ int o=base+excl+a0; offS[n0+i1]=o; offE[n0+i1]=o+a1; loffS[i1]=o; lcur[i1]=o+1; }
  __syncthreads();
  for (int idx=tid; idx<cntb; idx+=256){
    uint2 r = bin8[beg+idx];
    int dl = bin2[beg+idx];
    int p = atomicAdd(&lcur[dl], 1);
    rec[p] = r;
    atomicAdd(&ls0[dl], h2f_(r.x & 0xFFFEu));
    atomicAdd(&ls1[dl], h2f_(r.x >> 16));
    atomicAdd(&ls2[dl], h2f_(r.y >> 16));
  }
  __syncthreads();
  for (int i=tid; i<nn; i+=256){
    int cnt = lcnt[i];
    float inv = (cnt>0) ? 1.0f/(float)cnt : 0.0f;
    unsigned h0 = __half_as_ushort(__float2half(ls0[i]*inv)) & 0xFFFEu;
    unsigned h1 = __half_as_ushort(__float2half(ls1[i]*inv));
    unsigned h2 = __half_as_ushort(__float2half(ls2[i]*inv));
    unsigned s = (unsigned)(n0+i);
    rec[loffS[i]] = make_uint2(h0 | (s>>16) | (h1<<16), (s & 0xFFFFu) | (h2<<16));
  }
}

// MFMA GRU: 2 strips/wave, per-tile epilogue -> only 8 live accumulators.
__global__ void __launch_bounds__(256,4)
k_gru_m(const short* __restrict__ hg16, const short* __restrict__ xin, short* __restrict__ xout,
        const short* __restrict__ WihT16, const short* __restrict__ WhhT16,
        const float* __restrict__ bih, const float* __restrict__ bhh, int N){
  int lane = threadIdx.x & 63, w = threadIdx.x >> 6;
  int m16 = lane & 15;
  int kb  = lane >> 4;
  int n0 = blockIdx.x*128 + w*32;

  int r0 = n0 + m16;      if (r0 > N-1) r0 = N-1;
  int r1 = n0 + 16 + m16; if (r1 > N-1) r1 = N-1;
  const short* h0p = hg16 + (size_t)r0*H_ + kb*8;
  const short* h1p = hg16 + (size_t)r1*H_ + kb*8;
  bf16x8 ah0a = *(const bf16x8*)(h0p), ah1a = *(const bf16x8*)(h0p+32);
  bf16x8 ah0b = *(const bf16x8*)(h1p), ah1b = *(const bf16x8*)(h1p+32);
  const short* x0p = xin + (size_t)r0*H_ + kb*8;
  const short* x1p = xin + (size_t)r1*H_ + kb*8;
  bf16x8 ax0a = *(const bf16x8*)(x0p), ax1a = *(const bf16x8*)(x0p+32);
  bf16x8 ax0b = *(const bf16x8*)(x1p), ax1b = *(const bf16x8*)(x1p+32);

  const short* wi = WihT16 + (size_t)m16*H_ + kb*8;
  const short* wh = WhhT16 + (size_t)m16*H_ + kb*8;
  int mrow = (lane>>4)*4;

  #pragma unroll
  for (int t=0;t<4;t++){
    f32x4 aR0=(f32x4){0.f,0.f,0.f,0.f}, aR1=(f32x4){0.f,0.f,0.f,0.f};
    f32x4 aZ0=(f32x4){0.f,0.f,0.f,0.f}, aZ1=(f32x4){0.f,0.f,0.f,0.f};
    f32x4 aNi0=(f32x4){0.f,0.f,0.f,0.f}, aNi1=(f32x4){0.f,0.f,0.f,0.f};
    f32x4 aNh0=(f32x4){0.f,0.f,0.f,0.f}, aNh1=(f32x4){0.f,0.f,0.f,0.f};
    bf16x8 b;
    b = *(const bf16x8*)(wi + (size_t)(t*16)*H_);
    aR0 = __builtin_amdgcn_mfma_f32_16x16x32_bf16(ah0a, b, aR0, 0,0,0);
    aR1 = __builtin_amdgcn_mfma_f32_16x16x32_bf16(ah0b, b, aR1, 0,0,0);
    b = *(const bf16x8*)(wi + (size_t)(t*16)*H_ + 32);
    aR0 = __builtin_amdgcn_mfma_f32_16x16x32_bf16(ah1a, b, aR0, 0,0,0);
    aR1 = __builtin_amdgcn_mfma_f32_16x16x32_bf16(ah1b, b, aR1, 0,0,0);
    b = *(const bf16x8*)(wh + (size_t)(t*16)*H_);
    aR0 = __builtin_amdgcn_mfma_f32_16x16x32_bf16(ax0a, b, aR0, 0,0,0);
    aR1 = __builtin_amdgcn_mfma_f32_16x16x32_bf16(ax0b, b, aR1, 0,0,0);
    b = *(const bf16x8*)(wh + (size_t)(t*16)*H_ + 32);
    aR0 = __builtin_amdgcn_mfma_f32_16x16x32_bf16(ax1a, b, aR0, 0,0,0);
    aR1 = __builtin_amdgcn_mfma_f32_16x16x32_bf16(ax1b, b, aR1, 0,0,0);

    b = *(const bf16x8*)(wi + (size_t)(64+t*16)*H_);
    aZ0 = __builtin_amdgcn_mfma_f32_16x16x32_bf16(ah0a, b, aZ0, 0,0,0);
    aZ1 = __builtin_amdgcn_mfma_f32_16x16x32_bf16(ah0b, b, aZ1, 0,0,0);
    b = *(const bf16x8*)(wi + (size_t)(64+t*16)*H_ + 32);
    aZ0 = __builtin_amdgcn_mfma_f32_16x16x32_bf16(ah1a, b, aZ0, 0,0,0);
    aZ1 = __builtin_amdgcn_mfma_f32_16x16x32_bf16(ah1b, b, aZ1, 0,0,0);
    b = *(const bf16x8*)(wh + (size_t)(64+t*16)*H_);
    aZ0 = __builtin_amdgcn_mfma_f32_16x16x32_bf16(ax0a, b, aZ0, 0,0,0);
    aZ1 = __builtin_amdgcn_mfma_f32_16x16x32_bf16(ax0b, b, aZ1, 0,0,0);
    b = *(const bf16x8*)(wh + (size_t)(64+t*16)*H_ + 32);
    aZ0 = __builtin_amdgcn_mfma_f32_16x16x32_bf16(ax1a, b, aZ0, 0,0,0);
    aZ1 = __builtin_amdgcn_mfma_f32_16x16x32_bf16(ax1b, b, aZ1, 0,0,0);

    b = *(const bf16x8*)(wi + (size_t)(128+t*16)*H_);
    aNi0 = __builtin_amdgcn_mfma_f32_16x16x32_bf16(ah0a, b, aNi0, 0,0,0);
    aNi1 = __builtin_amdgcn_mfma_f32_16x16x32_bf16(ah0b, b, aNi1, 0,0,0);
    b = *(const bf16x8*)(wi + (size_t)(128+t*16)*H_ + 32);
    aNi0 = __builtin_amdgcn_mfma_f32_16x16x32_bf16(ah1a, b, aNi0, 0,0,0);
    aNi1 = __builtin_amdgcn_mfma_f32_16x16x32_bf16(ah1b, b, aNi1, 0,0,0);
    b = *(const bf16x8*)(wh + (size_t)(128+t*16)*H_);
    aNh0 = __builtin_amdgcn_mfma_f32_16x16x32_bf16(ax0a, b, aNh0, 0,0,0);
    aNh1 = __builtin_amdgcn_mfma_f32_16x16x32_bf16(ax0b, b, aNh1, 0,0,0);
    b = *(const bf16x8*)(wh + (size_t)(128+t*16)*H_ + 32);
    aNh0 = __builtin_amdgcn_mfma_f32_16x16x32_bf16(ax1a, b, aNh0, 0,0,0);
    aNh1 = __builtin_amdgcn_mfma_f32_16x16x32_bf16(ax1b, b, aNh1, 0,0,0);

    int f = t*16 + m16;
    float br = bih[f]     + bhh[f];
    float bz = bih[64+f]  + bhh[64+f];
    float bin= bih[128+f], bhn = bhh[128+f];
    #pragma unroll
    for (int q=0;q<4;q++){
      int node = n0 + mrow + q;
      if (node < N){
        float r  = sigm_(aR0[q] + br);
        float z  = sigm_(aZ0[q] + bz);
        float nn = tanh_(aNi0[q] + bin + r*(aNh0[q] + bhn));
        float xv = bf2f((unsigned short)xin[(size_t)node*H_ + f]);
        xout[(size_t)node*H_ + f] = f2bf(fmaxf((1.f-z)*nn + z*xv, 0.f));
      }
    }
    #pragma unroll
    for (int q=0;q<4;q++){
      int node = n0 + 16 + mrow + q;
      if (node < N){
        float r  = sigm_(aR1[q] + br);
        float z  = sigm_(aZ1[q] + bz);
        float nn = tanh_(aNi1[q] + bin + r*(aNh1[q] + bhn));
        float xv = bf2f((unsigned short)xin[(size_t)node*H_ + f]);
        xout[(size_t)node*H_ + f] = f2bf(fmaxf((1.f-z)*nn + z*xv, 0.f));
      }
    }
  }
}

// MFMA linear-h: 2 node-strips per wave (32 nodes), block = 128 nodes. bf16 input.
__global__ void __launch_bounds__(256,4)
k_linh_m(const short* __restrict__ xi, const short* __restrict__ wT16,
         const float* __restrict__ atts, const float* __restrict__ attd,
         __half* __restrict__ h16, float* __restrict__ ssc, float* __restrict__ dsc, int N){
  int lane = threadIdx.x & 63, w = threadIdx.x >> 6;
  int m16 = lane & 15, kb = lane >> 4;
  int n0 = blockIdx.x*128 + w*32;
  int r0 = n0 + m16;      if (r0 > N-1) r0 = N-1;
  int r1 = n0 + 16 + m16; if (r1 > N-1) r1 = N-1;
  const short* x0p = xi + (size_t)r0*H_ + kb*8;
  const short* x1p = xi + (size_t)r1*H_ + kb*8;
  bf16x8 ax0a = *(const bf16x8*)(x0p), ax1a = *(const bf16x8*)(x0p+32);
  bf16x8 ax0b = *(const bf16x8*)(x1p), ax1b = *(const bf16x8*)(x1p+32);

  f32x4 acc[2][4];
  #pragma unroll
  for (int s=0;s<2;s++)
    #pragma unroll
    for (int t=0;t<4;t++) acc[s][t]=(f32x4){0.f,0.f,0.f,0.f};
  const short* wp = wT16 + (size_t)m16*H_ + kb*8;
  #pragma unroll
  for (int t=0;t<4;t++){
    bf16x8 b0 = *(const bf16x8*)(wp + (size_t)(t*16)*H_);
    acc[0][t] = __builtin_amdgcn_mfma_f32_16x16x32_bf16(ax0a, b0, acc[0][t], 0,0,0);
    acc[1][t] = __builtin_amdgcn_mfma_f32_16x16x32_bf16(ax0b, b0, acc[1][t], 0,0,0);
    bf16x8 b1 = *(const bf16x8*)(wp + (size_t)(t*16)*H_ + 32);
    acc[0][t] = __builtin_amdgcn_mfma_f32_16x16x32_bf16(ax1a, b1, acc[0][t], 0,0,0);
    acc[1][t] = __builtin_amdgcn_mfma_f32_16x16x32_bf16(ax1b, b1, acc[1][t], 0,0,0);
  }

  int mrow = (lane>>4)*4;
  float ps[2][4], pd[2][4];
  #pragma unroll
  for (int s=0;s<2;s++)
    #pragma unroll
    for (int q=0;q<4;q++){ ps[s][q]=0.f; pd[s][q]=0.f; }
  #pragma unroll
  for (int t=0;t<4;t++){
    int f = t*16 + m16;
    float as = atts[f], ad = attd[f];
    #pragma unroll
    for (int s=0;s<2;s++){
      #pragma unroll
      for (int q=0;q<4;q++){
        int node = n0 + s*16 + mrow + q;
        float v = acc[s][t][q];
        if (node < N) h16[(size_t)node*H_ + f] = __float2half(v);
        ps[s][q] = fmaf(v, as, ps[s][q]); pd[s][q] = fmaf(v, ad, pd[s][q]);
      }
    }
  }
  #pragma unroll
  for (int d=1; d<16; d<<=1){
    #pragma unroll
    for (int s=0;s<2;s++)
      #pragma unroll
      for (int q=0;q<4;q++){ ps[s][q] += __shfl_xor(ps[s][q], d); pd[s][q] += __shfl_xor(pd[s][q], d); }
  }
  if (m16==0){
    #pragma unroll
    for (int s=0;s<2;s++){
      #pragma unroll
      for (int q=0;q<4;q++){
        int node = n0 + s*16 + mrow + q;
        if (node < N){ ssc[node]=ps[s][q]; dsc[node]=pd[s][q]; }
      }
    }
  }
}

// GAT: 4 nodes/wave, 16 lanes/node. Single-pass safe-exp softmax. offS/offE bounds.
template<int L>
__global__ void __launch_bounds__(256)
k_gat_g4(const __half* __restrict__ h16, const float* __restrict__ ssc,
         const float* __restrict__ dsc, const uint2* __restrict__ rec,
         const int* __restrict__ offS, const int* __restrict__ offE,
         const float* __restrict__ bias, short* __restrict__ hgat16, int N){
  int lane = threadIdx.x & 63, w = threadIdx.x >> 6;
  int g = lane >> 4, fl = lane & 15;
  int node = blockIdx.x*16 + w*4 + g;
  if (node >= N) return;
  int e0 = offS[node], e1 = offE[node];
  float dval = dsc[node];
  float acc0=0.f, acc1=0.f, acc2=0.f, acc3=0.f, den=0.f;
  int gbase = lane & 48;                 // g*16
  for (int base = e0; base < e1; base += 16){
    int p = base + fl;
    float ex = 0.f; int s = 0;
    if (p < e1){
      uint2 r = rec[p];
      s = (int)((r.y & 0xFFFFu) | ((r.x & 1u) << 16));
      unsigned hb = (L==0) ? (r.x & 0xFFFEu) : (L==1) ? (r.x >> 16) : (r.y >> 16);
      float a = ssc[s] + dval + h2f_(hb);
      a = (a > 0.f) ? a : SLOPE*a;
      ex = __expf(a);
    }
    den += ex;
    int cnt = e1 - base; if (cnt > 16) cnt = 16;
    for (int j = 0; j < cnt; j++){
      float exb = __shfl(ex, gbase + j);
      int   sb  = __shfl(s,  gbase + j);
      uint2 hv = *(const uint2*)(h16 + (size_t)sb*H_ + 4*fl);
      float2 f0 = __half22float2(*(__half2*)&hv.x);
      float2 f1 = __half22float2(*(__half2*)&hv.y);
      acc0 = fmaf(exb, f0.x, acc0);
      acc1 = fmaf(exb, f0.y, acc1);
      acc2 = fmaf(exb, f1.x, acc2);
      acc3 = fmaf(exb, f1.y, acc3);
    }
  }
  #pragma unroll
  for (int d=1; d<16; d<<=1) den += __shfl_xor(den, d);
  float4 bv = *(const float4*)(bias + 4*fl);
  float inv = 1.0f/den;
  float v0 = fmaxf(fmaf(acc0,inv,bv.x), 0.f);
  float v1 = fmaxf(fmaf(acc1,inv,bv.y), 0.f);
  float v2 = fmaxf(fmaf(acc2,inv,bv.z), 0.f);
  float v3 = fmaxf(fmaf(acc3,inv,bv.w), 0.f);
  uint2 o;
  o.x = ((unsigned)(unsigned short)f2bf(v1)<<16) | (unsigned short)f2bf(v0);
  o.y = ((unsigned)(unsigned short)f2bf(v3)<<16) | (unsigned short)f2bf(v2);
  *(uint2*)(hgat16 + (size_t)node*H_ + 4*fl) = o;
}

// block per graph: zero-atomic pooled output (batch sorted, xi bf16)
__global__ void __launch_bounds__(256)
k_pool_g(const short* __restrict__ xi, const float* __restrict__ wout,
         const int* __restrict__ gstart, const float* __restrict__ b_out,
         float* __restrict__ out){
  int g = blockIdx.x;
  int a = gstart[g], b = gstart[g+1];
  float acc = 0.f;
  for (int n = a + threadIdx.x; n < b; n += 256){
    const uint4* xr = (const uint4*)(xi + (size_t)n*H_);   // 8 bf16 per uint4
    float s = 0.f;
    #pragma unroll
    for (int q=0;q<8;q++){
      uint4 v = xr[q];
      s += bf2f((unsigned short)(v.x&0xFFFF))*wout[8*q]   + bf2f((unsigned short)(v.x>>16))*wout[8*q+1]
         + bf2f((unsigned short)(v.y&0xFFFF))*wout[8*q+2] + bf2f((unsigned short)(v.y>>16))*wout[8*q+3]
         + bf2f((unsigned short)(v.z&0xFFFF))*wout[8*q+4] + bf2f((unsigned short)(v.z>>16))*wout[8*q+5]
         + bf2f((unsigned short)(v.w&0xFFFF))*wout[8*q+6] + bf2f((unsigned short)(v.w>>16))*wout[8*q+7];
    }
    acc += s;
  }
  #pragma unroll
  for (int d=32; d; d>>=1) acc += __shfl_xor(acc, d);
  __shared__ float sh[4];
  if ((threadIdx.x&63)==0) sh[threadIdx.x>>6] = acc;
  __syncthreads();
  if (threadIdx.x==0) out[g] = sh[0]+sh[1]+sh[2]+sh[3] + b_out[0];
}

extern "C" void kernel_launch(void* const* d_in, const int* in_sizes, int n_in,
                              void* d_out, int out_size, void* d_ws, size_t ws_size,
                              hipStream_t stream){
  const float* x       = (const float*)d_in[0];
  const float* eattr   = (const float*)d_in[1];
  const float* w_node  = (const float*)d_in[2];
  const float* b_node  = (const float*)d_in[3];
  const float* w_edge  = (const float*)d_in[4];
  const float* b_edge  = (const float*)d_in[5];
  const float* conv_W  = (const float*)d_in[6];
  const float* conv_We = (const float*)d_in[7];
  const float* att_s   = (const float*)d_in[8];
  const float* att_d   = (const float*)d_in[9];
  const float* att_e   = (const float*)d_in[10];
  const float* conv_b  = (const float*)d_in[11];
  const float* gWih    = (const float*)d_in[12];
  const float* gWhh    = (const float*)d_in[13];
  const float* gbih    = (const float*)d_in[14];
  const float* gbhh    = (const float*)d_in[15];
  const float* w_out   = (const float*)d_in[16];
  const float* b_out   = (const float*)d_in[17];
  const int*   eidx    = (const int*)d_in[18];
  const int*   batch   = (const int*)d_in[19];
  float* out = (float*)d_out;

  int N = in_sizes[0]/DIN;
  int E = in_sizes[1]/DE;
  int G = out_size;
  const int* src = eidx;
  const int* dst = eidx + E;

  char* p = (char*)d_ws;
  auto carve = [&](size_t bytes)->void*{ void* r=(void*)p; p += (bytes+255)&~(size_t)255; return r; };
  short*  xi0    = (short*)carve((size_t)N*H_*2);
  short*  xi1    = (short*)carve((size_t)N*H_*2);
  __half* h16    = (__half*)carve((size_t)N*H_*2);
  short*  hgat16 = (short*)carve((size_t)N*H_*2);
  float*  ssc    = (float*)carve((size_t)N*4);
  float*  dsc    = (float*)carve((size_t)N*4);
  uint2*  esc8   = (uint2*)carve((size_t)E*8);
  uint2*  rec    = (uint2*)carve((size_t)256*CAP2*8);
  uint2*  bin8   = (uint2*)carve((size_t)256*CAP*8);
  unsigned short* bin2 = (unsigned short*)carve((size_t)256*CAP*2);
  int*    offS   = (int*)carve((size_t)N*4);
  int*    offE   = (int*)carve((size_t)N*4);
  int*    bcur   = (int*)carve((size_t)256*4);
  int*    gstart = (int*)carve((size_t)(G+1)*4);
  short*  wnT16  = (short*)carve((size_t)DIN*H_*2);
  short*  weT16p = (short*)carve((size_t)64*32*2);
  short*  cWT16  = (short*)carve((size_t)3*H_*H_*2);
  short*  WihT16 = (short*)carve((size_t)3*192*H_*2);
  short*  WhhT16 = (short*)carve((size_t)3*192*H_*2);
  float*  ve     = (float*)carve((size_t)3*H_*4);

  auto cdiv=[](int a,int b){return (a+b-1)/b;};
  int NBK = cdiv(N,BNODE);

  int prep_total = 2048+2048+12288+36864+36864+192+256+N;
  k_prep<<<cdiv(prep_total,256),256,0,stream>>>(w_node, w_edge, b_edge, conv_W, gWih, gWhh,
                                                conv_We, att_e, batch,
                                                wnT16, weT16p, cWT16, WihT16, WhhT16, ve,
                                                bcur, gstart, N, G);
  k_nmlp_m<<<cdiv(N,64),256,0,stream>>>(x, wnT16, b_node, xi0, N);
  k_edge_m<<<cdiv(E,128),256,0,stream>>>(eattr, weT16p, ve, src, esc8, E);
  k_binA<<<cdiv(E,ACH),256,0,stream>>>(esc8, dst, bcur, bin8, bin2, E);
  k_binB2<<<NBK,256,0,stream>>>(bin8, bin2, bcur, offS, offE, rec, N);

  int NB128 = cdiv(N,128);
  int NB16  = cdiv(N,16);
  for (int l=0; l<3; l++){
    const short* xin = (l&1) ? xi1 : xi0;
    short*       xo  = (l&1) ? xi0 : xi1;
    k_linh_m<<<NB128,256,0,stream>>>(xin, cWT16 + (size_t)l*H_*H_, att_s + l*H_, att_d + l*H_,
                                     h16, ssc, dsc, N);
    if (l==0)      k_gat_g4<0><<<NB16,256,0,stream>>>(h16, ssc, dsc, rec, offS, offE, conv_b + l*H_, hgat16, N);
    else if (l==1) k_gat_g4<1><<<NB16,256,0,stream>>>(h16, ssc, dsc, rec, offS, offE, conv_b + l*H_, hgat16, N);
    else           k_gat_g4<2><<<NB16,256,0,stream>>>(h16, ssc, dsc, rec, offS, offE, conv_b + l*H_, hgat16, N);
    k_gru_m<<<NB128,256,0,stream>>>(hgat16, xin, xo, WihT16 + (size_t)l*192*H_, WhhT16 + (size_t)l*192*H_,
                                    gbih + l*3*H_, gbhh + l*3*H_, N);
  }

  k_pool_g<<<G,256,0,stream>>>(xi1, w_out, gstart, b_out, out);
}